// Round 4
// baseline (2872.131 us; speedup 1.0000x reference)
//
#include <hip/hip_runtime.h>
#include <float.h>
#include <math.h>
#include <stdint.h>

// ---------------------------------------------------------------------------
// Model_33062658245168: Informer-style time-series model. fp32 in/out
// (runtime-detected; bf16 fallback kept). B=32 S=512 C=512 D=512 DF=2048 H=8
// E=64 P=16 PRED=96 K(topk)=10, N=16384.
//
// Round 15: global_load_lds mgemm + parallel instnorm.
//  - instnorm_stats was 85us at 2.6% occupancy (64 blocks, 512 serial loads
//    per thread). Two-phase: 512-block partial pass + tiny reduce.
//  - mgemm(128^2)/mgemm64: reg-staged float4->ds_write round-trip replaced by
//    __builtin_amdgcn_global_load_lds width-16 (m93->m97: 517->874 TF).
//    Linear LDS dest (wave-uniform base + lane*16) + inverse-swizzled global
//    source + swizzled ds_read (slot ^= (row>>1)&3) => 2-way (free) bank
//    pattern on the b128 fragment reads. LDS 20->16KB / 10->8KB.
// ---------------------------------------------------------------------------

#define NB   32
#define SS   512
#define CC   512
#define DD   512
#define DFF  2048
#define HH   8
#define EE   64
#define PRED 96

typedef __attribute__((ext_vector_type(8))) short short8;
typedef __attribute__((ext_vector_type(4))) float f32x4;

__device__ __forceinline__ float b2f(ushort u) {
  union { float f; uint32_t i; } c; c.i = ((uint32_t)u) << 16; return c.f;
}
__device__ __forceinline__ ushort f2b(float f) {
  union { float f; uint32_t i; } c; c.f = f;
  uint32_t x = c.i;
  return (ushort)((x + 0x7fffu + ((x >> 16) & 1u)) >> 16);   // RNE
}
__device__ __forceinline__ float lin(const void* p, size_t i, int f32) {
  return f32 ? ((const float*)p)[i] : b2f(((const ushort*)p)[i]);
}
__device__ __forceinline__ void split_bf(float x, ushort& hi, ushort& lo) {
  hi = f2b(x);
  lo = f2b(x - b2f(hi));
}
// async global->LDS, 16B per lane; dst is wave-uniform base (+lane*16 by HW)
__device__ __forceinline__ void gl_lds16(const void* g, void* l) {
  __builtin_amdgcn_global_load_lds(
      (const __attribute__((address_space(1))) void*)g,
      (__attribute__((address_space(3))) void*)l, 16, 0, 0);
}

// ---- DPP 16-lane all-reduce (VALU only) ----
template<int CTRL>
__device__ __forceinline__ float dppmov(float x) {
  union { float f; int i; } a, b;
  a.f = x;
  b.i = __builtin_amdgcn_update_dpp(a.i, a.i, CTRL, 0xF, 0xF, false);
  return b.f;
}
__device__ __forceinline__ float red16_max(float x) {
  x = fmaxf(x, dppmov<0xB1>(x));    // quad_perm xor1
  x = fmaxf(x, dppmov<0x4E>(x));    // quad_perm xor2
  x = fmaxf(x, dppmov<0x141>(x));   // row_half_mirror
  x = fmaxf(x, dppmov<0x140>(x));   // row_mirror
  return x;
}
__device__ __forceinline__ float red16_sum(float x) {
  x += dppmov<0xB1>(x);
  x += dppmov<0x4E>(x);
  x += dppmov<0x141>(x);
  x += dppmov<0x140>(x);
  return x;
}

// ---------------- dtype detection (1 = fp32 inputs) ----------------
__global__ __launch_bounds__(256) void detect_dtype(
    const ushort* __restrict__ x, int* __restrict__ flag)
{
  __shared__ float red[256];
  const int t = threadIdx.x;
  float v = fabsf(b2f(x[2 * t]));
  if (!(v < 1e30f)) v = 1e30f;
  red[t] = v;
  __syncthreads();
  for (int off = 128; off > 0; off >>= 1) {
    if (t < off) red[t] = fmaxf(red[t], red[t + off]);
    __syncthreads();
  }
  if (t == 0) flag[0] = (red[0] > 1e6f) ? 1 : 0;
}

// ---------------- instance norm stats, two-phase ----------------
__global__ __launch_bounds__(256) void instnorm_partial(
    const void* __restrict__ x, float* __restrict__ ps, float* __restrict__ pq,
    const int* __restrict__ dtf)
{
  const int f32 = *dtf;
  const int c = blockIdx.x * 256 + threadIdx.x;
  const int b = blockIdx.y;
  const int t0 = blockIdx.z * 64;
  float s = 0.f, s2 = 0.f;
  for (int t = t0; t < t0 + 64; ++t) {
    const float xv = lin(x, ((size_t)(b * SS) + t) * CC + c, f32);
    s += xv; s2 += xv * xv;
  }
  const int pidx = (b * 8 + blockIdx.z) * CC + c;
  ps[pidx] = s; pq[pidx] = s2;
}

__global__ __launch_bounds__(256) void instnorm_reduce(
    const float* __restrict__ ps, const float* __restrict__ pq,
    float* __restrict__ meanb, float* __restrict__ stdb)
{
  const int c = blockIdx.x * 256 + threadIdx.x;
  const int b = blockIdx.y;
  float s = 0.f, s2 = 0.f;
  #pragma unroll
  for (int i = 0; i < 8; ++i) {
    s  += ps[(b * 8 + i) * CC + c];
    s2 += pq[(b * 8 + i) * CC + c];
  }
  const float mu  = s * (1.f / SS);
  const float var = s2 * (1.f / SS) - mu * mu;
  meanb[b * CC + c] = mu;
  stdb [b * CC + c] = sqrtf(var + 1e-5f);
}

// ---------------- normalize + transpose one chunk (fp32, fallback) ---------
__global__ __launch_bounds__(256) void norm_transpose(
    const void* __restrict__ x, const float* __restrict__ meanb,
    const float* __restrict__ stdb, float* __restrict__ xTc, int b_base,
    const int* __restrict__ dtf)
{
  const int f32 = *dtf;
  __shared__ float t[32][33];
  const int s0 = blockIdx.x * 32, c0 = blockIdx.y * 32, lb = blockIdx.z;
  const int b = b_base + lb;
  const int tx = threadIdx.x & 31, ty = threadIdx.x >> 5;
  #pragma unroll
  for (int i = 0; i < 4; ++i) {
    const int s = s0 + ty + i * 8;
    t[ty + i * 8][tx] = lin(x, ((size_t)(b * SS) + s) * CC + c0 + tx, f32);
  }
  __syncthreads();
  #pragma unroll
  for (int i = 0; i < 4; ++i) {
    const int c = c0 + ty + i * 8;
    const float mu = meanb[b * CC + c], sd = stdb[b * CC + c];
    xTc[((size_t)(lb * CC) + c) * SS + s0 + tx] = (t[tx][ty + i * 8] - mu) / sd;
  }
}

// ---------------- normalize + transpose, hi/lo split output ----------------
__global__ __launch_bounds__(256) void norm_transpose_split(
    const void* __restrict__ x, const float* __restrict__ meanb,
    const float* __restrict__ stdb, ushort* __restrict__ xh,
    ushort* __restrict__ xl, int b_base, const int* __restrict__ dtf)
{
  const int f32 = *dtf;
  __shared__ float t[32][33];
  const int s0 = blockIdx.x * 32, c0 = blockIdx.y * 32, lb = blockIdx.z;
  const int b = b_base + lb;
  const int tx = threadIdx.x & 31, ty = threadIdx.x >> 5;
  #pragma unroll
  for (int i = 0; i < 4; ++i) {
    const int s = s0 + ty + i * 8;
    t[ty + i * 8][tx] = lin(x, ((size_t)(b * SS) + s) * CC + c0 + tx, f32);
  }
  __syncthreads();
  #pragma unroll
  for (int i = 0; i < 4; ++i) {
    const int c = c0 + ty + i * 8;
    const float mu = meanb[b * CC + c], sd = stdb[b * CC + c];
    const float v = (t[tx][ty + i * 8] - mu) / sd;
    const size_t idx = ((size_t)(lb * CC) + c) * SS + s0 + tx;
    ushort hi, lo; split_bf(v, hi, lo);
    xh[idx] = hi; xl[idx] = lo;
  }
}

// ---------------- weight convert+transpose: W (KxN, input dtype) -> bf16 (NxK)
__global__ __launch_bounds__(256) void transpose_w(
    const void* __restrict__ W, ushort* __restrict__ Wt, int K, int N,
    const int* __restrict__ dtf)
{
  const int f32 = *dtf;
  __shared__ float t[32][33];
  const int n0 = blockIdx.x * 32, k0 = blockIdx.y * 32;
  const int tx = threadIdx.x & 31, ty = threadIdx.x >> 5;
  #pragma unroll
  for (int i = 0; i < 4; ++i)
    t[ty + i * 8][tx] = lin(W, (size_t)(k0 + ty + i * 8) * N + n0 + tx, f32);
  __syncthreads();
  #pragma unroll
  for (int i = 0; i < 4; ++i)
    Wt[(size_t)(n0 + ty + i * 8) * K + k0 + tx] = f2b(t[tx][ty + i * 8]);
}

// ---------------- weight transpose + hi/lo split ----------------
__global__ __launch_bounds__(256) void transpose_w_split(
    const void* __restrict__ W, ushort* __restrict__ Whi, ushort* __restrict__ Wlo,
    int K, int N, const int* __restrict__ dtf)
{
  const int f32 = *dtf;
  __shared__ float t[32][33];
  const int n0 = blockIdx.x * 32, k0 = blockIdx.y * 32;
  const int tx = threadIdx.x & 31, ty = threadIdx.x >> 5;
  #pragma unroll
  for (int i = 0; i < 4; ++i)
    t[ty + i * 8][tx] = lin(W, (size_t)(k0 + ty + i * 8) * N + n0 + tx, f32);
  __syncthreads();
  #pragma unroll
  for (int i = 0; i < 4; ++i) {
    const size_t idx = (size_t)(n0 + ty + i * 8) * K + k0 + tx;
    ushort hi, lo; split_bf(t[tx][ty + i * 8], hi, lo);
    Whi[idx] = hi; Wlo[idx] = lo;
  }
}

// ---------------- generic fp32 tiled GEMM (fallback path) ----------
enum GemmMode { M_BIAS = 0, M_BIAS_RELU = 1, M_RELU_PE = 2,
                M_ADD_BIAS_LEAKY = 3, M_ADD_BIAS_ELU = 4, M_ADD_BIAS = 5,
                M_ADD2_BIAS_LEAKY = 6 };

template<typename AT, typename ADT, typename OT, int MODE>
__global__ __launch_bounds__(256) void gemm_kernel(
    const AT* __restrict__ A, const void* __restrict__ Bw,
    const void* __restrict__ bias, const ADT* __restrict__ addend,
    OT* __restrict__ Cout, int M, int K, int Nn, const int* __restrict__ dtf)
{
  const int f32 = *dtf;
  __shared__ __align__(16) float As[16][68];
  __shared__ __align__(16) float Bs[16][68];
  const int tid = threadIdx.x;
  const int m0 = blockIdx.y * 64, n0 = blockIdx.x * 64;
  const int tx = tid & 15, ty = tid >> 4;
  const int la_m = tid >> 2, la_k = (tid & 3) * 4;
  const int lb_k = tid >> 4, lb_n = (tid & 15) * 4;
  float acc[4][4];
  #pragma unroll
  for (int i = 0; i < 4; ++i)
    #pragma unroll
    for (int j = 0; j < 4; ++j) acc[i][j] = 0.f;
  const size_t a_row = (size_t)(m0 + la_m) * K;

  for (int k0 = 0; k0 < K; k0 += 16) {
    if constexpr (sizeof(AT) == 4) {
      const float4 av = *reinterpret_cast<const float4*>(A + a_row + k0 + la_k);
      As[la_k + 0][la_m] = av.x; As[la_k + 1][la_m] = av.y;
      As[la_k + 2][la_m] = av.z; As[la_k + 3][la_m] = av.w;
    } else {
      const ushort4 av = *reinterpret_cast<const ushort4*>(A + a_row + k0 + la_k);
      As[la_k + 0][la_m] = b2f(av.x); As[la_k + 1][la_m] = b2f(av.y);
      As[la_k + 2][la_m] = b2f(av.z); As[la_k + 3][la_m] = b2f(av.w);
    }
    {
      const size_t boff = (size_t)(k0 + lb_k) * Nn + n0 + lb_n;
      if (f32) {
        const float4 bv = *reinterpret_cast<const float4*>((const float*)Bw + boff);
        Bs[lb_k][lb_n + 0] = bv.x; Bs[lb_k][lb_n + 1] = bv.y;
        Bs[lb_k][lb_n + 2] = bv.z; Bs[lb_k][lb_n + 3] = bv.w;
      } else {
        const ushort4 bv = *reinterpret_cast<const ushort4*>((const ushort*)Bw + boff);
        Bs[lb_k][lb_n + 0] = b2f(bv.x); Bs[lb_k][lb_n + 1] = b2f(bv.y);
        Bs[lb_k][lb_n + 2] = b2f(bv.z); Bs[lb_k][lb_n + 3] = b2f(bv.w);
      }
    }
    __syncthreads();
    #pragma unroll
    for (int k = 0; k < 16; ++k) {
      const float4 a4 = *reinterpret_cast<const float4*>(&As[k][ty * 4]);
      const float4 b4 = *reinterpret_cast<const float4*>(&Bs[k][tx * 4]);
      const float aa[4] = {a4.x, a4.y, a4.z, a4.w};
      const float bb[4] = {b4.x, b4.y, b4.z, b4.w};
      #pragma unroll
      for (int i = 0; i < 4; ++i)
        #pragma unroll
        for (int j = 0; j < 4; ++j)
          acc[i][j] = fmaf(aa[i], bb[j], acc[i][j]);
    }
    __syncthreads();
  }

  float biasv[4];
  if constexpr (MODE != M_RELU_PE) {
    #pragma unroll
    for (int j = 0; j < 4; ++j) biasv[j] = lin(bias, n0 + tx * 4 + j, f32);
  }
  #pragma unroll
  for (int i = 0; i < 4; ++i) {
    const int m = m0 + ty * 4 + i;
    #pragma unroll
    for (int j = 0; j < 4; ++j) {
      const int n = n0 + tx * 4 + j;
      float v = acc[i][j];
      if constexpr (MODE == M_BIAS) {
        v += biasv[j];
      } else if constexpr (MODE == M_BIAS_RELU) {
        v = fmaxf(v + biasv[j], 0.f);
      } else if constexpr (MODE == M_RELU_PE) {
        v = fmaxf(v, 0.f);
        const float freq = expf((float)(n & ~1) * (-0.017988946f)); // -ln(1e4)/512
        const float ang  = (float)(m & (CC - 1)) * freq;            // pos = c
        v += (n & 1) ? cosf(ang) : sinf(ang);
      } else {
        float ad;
        if constexpr (sizeof(ADT) == 4) ad = ((const float*)addend)[(size_t)m * Nn + n];
        else                            ad = b2f(((const ushort*)addend)[(size_t)m * Nn + n]);
        v = ad + v + biasv[j];
        if constexpr (MODE == M_ADD_BIAS_LEAKY) v = (v >= 0.f) ? v : 0.5f * v;
        else if constexpr (MODE == M_ADD_BIAS_ELU) v = (v > 0.f) ? v : expm1f(v);
      }
      if constexpr (sizeof(OT) == 4) ((float*)Cout)[(size_t)m * Nn + n] = v;
      else                           ((ushort*)Cout)[(size_t)m * Nn + n] = f2b(v);
    }
  }
}

template<typename AT, typename ADT, typename OT, int MODE>
static void launch_gemm(const void* A, const void* Bw, const void* bias, const void* add,
                        void* Cout, int M, int K, int Nn, const int* dtf, hipStream_t stream)
{
  dim3 grid(Nn / 64, M / 64);
  gemm_kernel<AT, ADT, OT, MODE><<<grid, dim3(256), 0, stream>>>(
      (const AT*)A, Bw, bias, (const ADT*)add, (OT*)Cout, M, K, Nn, dtf);
}

// ---------------- MFMA bf16 GEMM (128x128 tile), global_load_lds staging ----
// LDS linear [128][32] (64B rows); source col-slot pre-swizzled with
// slot ^= (row>>1)&3 so the swizzled ds_read_b128 frag reads are 2-way (free).
template<typename ADT, typename OT, int MODE>
__global__ __launch_bounds__(256) void mgemm_kernel(
    const ushort* __restrict__ A, const ushort* __restrict__ Wt,
    const void* __restrict__ bias, const ADT* __restrict__ addend,
    const ushort* __restrict__ addend2,
    OT* __restrict__ Cout, int M, int K, int Nn, const int* __restrict__ dtf)
{
  const int f32 = *dtf;
  __shared__ __align__(16) ushort As[128][32];
  __shared__ __align__(16) ushort Bs[128][32];
  const int tid = threadIdx.x;
  const int m0 = blockIdx.y * 128, n0 = blockIdx.x * 128;
  const int wave = tid >> 6, lane = tid & 63;
  const int wm = wave & 1, wn = wave >> 1;
  const int quad = lane >> 4, l15 = lane & 15;

  f32x4 acc[4][4];
  #pragma unroll
  for (int i = 0; i < 4; ++i)
    #pragma unroll
    for (int j = 0; j < 4; ++j) acc[i][j] = (f32x4){0.f, 0.f, 0.f, 0.f};

  // staging geometry: wave w, issue i covers rows w*32+i*16 .. +15
  const int srow_l = lane >> 2;                  // 0..15 within issue
  const int slot   = lane & 3;

  for (int k0 = 0; k0 < K; k0 += 32) {
    #pragma unroll
    for (int i = 0; i < 2; ++i) {
      const int row = wave * 32 + i * 16 + srow_l;
      const int sseg = (slot ^ ((row >> 1) & 3)) * 8;
      gl_lds16(A  + (size_t)(m0 + row) * K + k0 + sseg, &As[wave * 32 + i * 16][0]);
      gl_lds16(Wt + (size_t)(n0 + row) * K + k0 + sseg, &Bs[wave * 32 + i * 16][0]);
    }
    __syncthreads();
    short8 af[4], bf[4];
    #pragma unroll
    for (int i = 0; i < 4; ++i) {
      const int ra = wm * 64 + i * 16 + l15;
      af[i] = *reinterpret_cast<const short8*>(&As[ra][(quad ^ ((ra >> 1) & 3)) * 8]);
      const int rb = wn * 64 + i * 16 + l15;
      bf[i] = *reinterpret_cast<const short8*>(&Bs[rb][(quad ^ ((rb >> 1) & 3)) * 8]);
    }
    #pragma unroll
    for (int i = 0; i < 4; ++i)
      #pragma unroll
      for (int j = 0; j < 4; ++j)
        acc[i][j] = __builtin_amdgcn_mfma_f32_16x16x32_bf16(af[i], bf[j], acc[i][j], 0, 0, 0);
    __syncthreads();
  }

  #pragma unroll
  for (int j = 0; j < 4; ++j) {
    const int n = n0 + wn * 64 + j * 16 + l15;
    const float bv = lin(bias, n, f32);
    #pragma unroll
    for (int i = 0; i < 4; ++i) {
      #pragma unroll
      for (int r = 0; r < 4; ++r) {
        const int m = m0 + wm * 64 + i * 16 + quad * 4 + r;
        float v = acc[i][j][r];
        if constexpr (MODE == M_BIAS) {
          v += bv;
        } else if constexpr (MODE == M_BIAS_RELU) {
          v = fmaxf(v + bv, 0.f);
        } else if constexpr (MODE == M_ADD2_BIAS_LEAKY) {
          const size_t ix = (size_t)m * Nn + n;
          const float ad = b2f(((const ushort*)addend)[ix]) + b2f(addend2[ix]);
          v = ad + v + bv;
          v = (v >= 0.f) ? v : 0.5f * v;
        } else {
          float ad;
          if constexpr (sizeof(ADT) == 4) ad = ((const float*)addend)[(size_t)m * Nn + n];
          else                            ad = b2f(((const ushort*)addend)[(size_t)m * Nn + n]);
          v = ad + v + bv;
          if constexpr (MODE == M_ADD_BIAS_ELU)   v = (v > 0.f) ? v : expm1f(v);
          else if constexpr (MODE == M_ADD_BIAS_LEAKY) v = (v >= 0.f) ? v : 0.5f * v;
        }
        if constexpr (sizeof(OT) == 4) ((float*)Cout)[(size_t)m * Nn + n] = v;
        else                           ((ushort*)Cout)[(size_t)m * Nn + n] = f2b(v);
      }
    }
  }
}

template<typename ADT, typename OT, int MODE>
static void launch_mgemm(const void* A, const void* Wt, const void* bias, const void* add,
                         void* Cout, int M, int K, int Nn, const int* dtf, hipStream_t stream,
                         const void* add2 = nullptr)
{
  dim3 grid(Nn / 128, M / 128);
  mgemm_kernel<ADT, OT, MODE><<<grid, dim3(256), 0, stream>>>(
      (const ushort*)A, (const ushort*)Wt, bias, (const ADT*)add, (const ushort*)add2,
      (OT*)Cout, M, K, Nn, dtf);
}

// ---------------- MFMA bf16 GEMM (64x64 tile), global_load_lds staging ------
template<typename ADT, typename OT, int MODE>
__global__ __launch_bounds__(256) void mgemm64_kernel(
    const ushort* __restrict__ A, const ushort* __restrict__ Wt,
    const void* __restrict__ bias, const ADT* __restrict__ addend,
    const ushort* __restrict__ addend2,
    OT* __restrict__ Cout, int M, int K, int Nn, const int* __restrict__ dtf)
{
  const int f32 = *dtf;
  __shared__ __align__(16) ushort As[64][32];
  __shared__ __align__(16) ushort Bs[64][32];
  const int tid = threadIdx.x;
  const int m0 = blockIdx.y * 64, n0 = blockIdx.x * 64;
  const int wave = tid >> 6, lane = tid & 63;
  const int wm = wave & 1, wn = wave >> 1;
  const int quad = lane >> 4, l15 = lane & 15;

  f32x4 acc[2][2];
  #pragma unroll
  for (int i = 0; i < 2; ++i)
    #pragma unroll
    for (int j = 0; j < 2; ++j) acc[i][j] = (f32x4){0.f, 0.f, 0.f, 0.f};

  const int srow_l = lane >> 2;
  const int slot   = lane & 3;

  for (int k0 = 0; k0 < K; k0 += 32) {
    {
      const int row = wave * 16 + srow_l;
      const int sseg = (slot ^ ((row >> 1) & 3)) * 8;
      gl_lds16(A  + (size_t)(m0 + row) * K + k0 + sseg, &As[wave * 16][0]);
      gl_lds16(Wt + (size_t)(n0 + row) * K + k0 + sseg, &Bs[wave * 16][0]);
    }
    __syncthreads();
    short8 af[2], bf[2];
    #pragma unroll
    for (int i = 0; i < 2; ++i) {
      const int ra = wm * 32 + i * 16 + l15;
      af[i] = *reinterpret_cast<const short8*>(&As[ra][(quad ^ ((ra >> 1) & 3)) * 8]);
      const int rb = wn * 32 + i * 16 + l15;
      bf[i] = *reinterpret_cast<const short8*>(&Bs[rb][(quad ^ ((rb >> 1) & 3)) * 8]);
    }
    #pragma unroll
    for (int i = 0; i < 2; ++i)
      #pragma unroll
      for (int j = 0; j < 2; ++j)
        acc[i][j] = __builtin_amdgcn_mfma_f32_16x16x32_bf16(af[i], bf[j], acc[i][j], 0, 0, 0);
    __syncthreads();
  }

  #pragma unroll
  for (int j = 0; j < 2; ++j) {
    const int n = n0 + wn * 32 + j * 16 + l15;
    const float bv = lin(bias, n, f32);
    #pragma unroll
    for (int i = 0; i < 2; ++i) {
      #pragma unroll
      for (int r = 0; r < 4; ++r) {
        const int m = m0 + wm * 32 + i * 16 + quad * 4 + r;
        float v = acc[i][j][r];
        if constexpr (MODE == M_BIAS) {
          v += bv;
        } else if constexpr (MODE == M_BIAS_RELU) {
          v = fmaxf(v + bv, 0.f);
        } else if constexpr (MODE == M_ADD2_BIAS_LEAKY) {
          const size_t ix = (size_t)m * Nn + n;
          const float ad = b2f(((const ushort*)addend)[ix]) + b2f(addend2[ix]);
          v = ad + v + bv;
          v = (v >= 0.f) ? v : 0.5f * v;
        } else {
          float ad;
          if constexpr (sizeof(ADT) == 4) ad = ((const float*)addend)[(size_t)m * Nn + n];
          else                            ad = b2f(((const ushort*)addend)[(size_t)m * Nn + n]);
          v = ad + v + bv;
          if constexpr (MODE == M_ADD_BIAS_ELU)   v = (v > 0.f) ? v : expm1f(v);
          else if constexpr (MODE == M_ADD_BIAS_LEAKY) v = (v >= 0.f) ? v : 0.5f * v;
        }
        if constexpr (sizeof(OT) == 4) ((float*)Cout)[(size_t)m * Nn + n] = v;
        else                           ((ushort*)Cout)[(size_t)m * Nn + n] = f2b(v);
      }
    }
  }
}

template<typename ADT, typename OT, int MODE>
static void launch_mgemm64(const void* A, const void* Wt, const void* bias, const void* add,
                           void* Cout, int M, int K, int Nn, const int* dtf, hipStream_t stream,
                           const void* add2 = nullptr)
{
  dim3 grid(Nn / 64, M / 64);
  mgemm64_kernel<ADT, OT, MODE><<<grid, dim3(256), 0, stream>>>(
      (const ushort*)A, (const ushort*)Wt, bias, (const ADT*)add, (const ushort*)add2,
      (OT*)Cout, M, K, Nn, dtf);
}

// ---------------- mgemm3: 64x64-tile hi/lo-split 3-MFMA GEMM ----------------
enum Epi3 { E3_RELU_PE = 0, E3_RELU_SPLIT = 1, E3_SPLIT = 2, E3_RELU_VT = 3 };

template<int EPI>
__global__ __launch_bounds__(256) void mgemm3_kernel(
    const ushort* __restrict__ Ah, const ushort* __restrict__ Al,
    const ushort* __restrict__ Bh, const ushort* __restrict__ Bl,
    const void* __restrict__ bias,
    ushort* __restrict__ Oh, ushort* __restrict__ Ol,
    int M, int K, int Nn, const int* __restrict__ dtf)
{
  const int f32 = *dtf;
  __shared__ __align__(16) ushort AsH[64][40];
  __shared__ __align__(16) ushort AsL[64][40];
  __shared__ __align__(16) ushort BsH[64][40];
  __shared__ __align__(16) ushort BsL[64][40];
  const int tid = threadIdx.x;
  const int m0 = blockIdx.y * 64, n0 = blockIdx.x * 64;
  const int wave = tid >> 6, lane = tid & 63;
  const int wm = wave & 1, wn = wave >> 1;
  const int quad = lane >> 4, l15 = lane & 15;

  f32x4 acc[2][2];
  #pragma unroll
  for (int i = 0; i < 2; ++i)
    #pragma unroll
    for (int j = 0; j < 2; ++j) acc[i][j] = (f32x4){0.f, 0.f, 0.f, 0.f};

  const int srow = tid >> 2, sseg = (tid & 3) * 8;
  const size_t a_base = (size_t)(m0 + srow) * K + sseg;
  const size_t b_base = (size_t)(n0 + srow) * K + sseg;

  for (int k0 = 0; k0 < K; k0 += 32) {
    *reinterpret_cast<float4*>(&AsH[srow][sseg]) =
        *reinterpret_cast<const float4*>(Ah + a_base + k0);
    *reinterpret_cast<float4*>(&AsL[srow][sseg]) =
        *reinterpret_cast<const float4*>(Al + a_base + k0);
    *reinterpret_cast<float4*>(&BsH[srow][sseg]) =
        *reinterpret_cast<const float4*>(Bh + b_base + k0);
    *reinterpret_cast<float4*>(&BsL[srow][sseg]) =
        *reinterpret_cast<const float4*>(Bl + b_base + k0);
    __syncthreads();
    short8 afh[2], afl[2], bfh[2], bfl[2];
    #pragma unroll
    for (int i = 0; i < 2; ++i) {
      afh[i] = *reinterpret_cast<const short8*>(&AsH[wm * 32 + i * 16 + l15][quad * 8]);
      afl[i] = *reinterpret_cast<const short8*>(&AsL[wm * 32 + i * 16 + l15][quad * 8]);
      bfh[i] = *reinterpret_cast<const short8*>(&BsH[wn * 32 + i * 16 + l15][quad * 8]);
      bfl[i] = *reinterpret_cast<const short8*>(&BsL[wn * 32 + i * 16 + l15][quad * 8]);
    }
    #pragma unroll
    for (int i = 0; i < 2; ++i)
      #pragma unroll
      for (int j = 0; j < 2; ++j) {
        acc[i][j] = __builtin_amdgcn_mfma_f32_16x16x32_bf16(afh[i], bfh[j], acc[i][j], 0, 0, 0);
        acc[i][j] = __builtin_amdgcn_mfma_f32_16x16x32_bf16(afh[i], bfl[j], acc[i][j], 0, 0, 0);
        acc[i][j] = __builtin_amdgcn_mfma_f32_16x16x32_bf16(afl[i], bfh[j], acc[i][j], 0, 0, 0);
      }
    __syncthreads();
  }

  #pragma unroll
  for (int j = 0; j < 2; ++j) {
    const int n = n0 + wn * 32 + j * 16 + l15;
    float bv = 0.f;
    if constexpr (EPI != E3_RELU_PE) bv = lin(bias, n, f32);
    #pragma unroll
    for (int i = 0; i < 2; ++i) {
      #pragma unroll
      for (int r = 0; r < 4; ++r) {
        const int m = m0 + wm * 32 + i * 16 + quad * 4 + r;
        float v = acc[i][j][r];
        if constexpr (EPI == E3_RELU_PE) {
          v = fmaxf(v, 0.f);
          const float freq = expf((float)(n & ~1) * (-0.017988946f)); // -ln(1e4)/512
          const float ang  = (float)(m & (CC - 1)) * freq;            // pos = c
          v += (n & 1) ? cosf(ang) : sinf(ang);
        } else if constexpr (EPI == E3_RELU_SPLIT || EPI == E3_RELU_VT) {
          v = fmaxf(v + bv, 0.f);
        } else {
          v = v + bv;
        }
        if constexpr (EPI == E3_RELU_VT) {
          // pre-transposed: vT[(lb*512 + n)][s] with lb = m>>9, s = m&511
          Oh[((size_t)((m >> 9) * 512 + n)) * 512 + (m & 511)] = f2b(v);
        } else {
          ushort hi, lo; split_bf(v, hi, lo);
          Oh[(size_t)m * Nn + n] = hi;
          Ol[(size_t)m * Nn + n] = lo;
        }
      }
    }
  }
}

template<int EPI>
static void launch_mgemm3(const void* Ahv, const void* Alv, const ushort* Bh,
                          const ushort* Bl, const void* bias, void* Oh, void* Ol,
                          int M, int K, int Nn, const int* dtf, hipStream_t stream)
{
  dim3 grid(Nn / 64, M / 64);
  mgemm3_kernel<EPI><<<grid, dim3(256), 0, stream>>>(
      (const ushort*)Ahv, (const ushort*)Alv, Bh, Bl, bias,
      (ushort*)Oh, (ushort*)Ol, M, K, Nn, dtf);
}

// ---------------- GAttn via MFMA: register scores + DPP top-k ---------------
__global__ __launch_bounds__(256, 4) void gattn_mfma(
    const ushort* __restrict__ qsh, const ushort* __restrict__ qsl,
    const ushort* __restrict__ ksh, const ushort* __restrict__ ksl,
    const ushort* __restrict__ vt, ushort* __restrict__ out)
{
  const int tid = threadIdx.x;
  const int wave = tid >> 6, lane = tid & 63;
  const int quad = lane >> 4, l15 = lane & 15;
  const int l0 = blockIdx.x * 16;
  const int h = blockIdx.y, bz = blockIdx.z;

  __shared__ __align__(16) ushort P[16][520];    // 16640 B (unnormalized bf16 weights)
  __shared__ float cand[16][40];                 // 2560 B (4 waves x sorted top-10)
  __shared__ float psum[16][4];                  // 256 B  (per-wave partial sums)

  // ---- Q fragments (hi/lo), kk-chunks 0,1 ----
  short8 ah[2], al[2];
  {
    const size_t qoff = ((size_t)bz * CC + l0 + l15) * DD + h * EE + quad * 8;
    ah[0] = *reinterpret_cast<const short8*>(qsh + qoff);
    ah[1] = *reinterpret_cast<const short8*>(qsh + qoff + 32);
    al[0] = *reinterpret_cast<const short8*>(qsl + qoff);
    al[1] = *reinterpret_cast<const short8*>(qsl + qoff + 32);
  }

  // ---- S phase into registers: sacc[c][r] = S[quad*4+r][c*64+wave*16+l15] --
  f32x4 sacc[8];
  {
    const size_t kbase = ((size_t)bz * CC + wave * 16 + l15) * DD + h * EE + quad * 8;
    #pragma unroll
    for (int c = 0; c < 8; ++c) {
      f32x4 acc = (f32x4){0.f, 0.f, 0.f, 0.f};
      #pragma unroll
      for (int kk = 0; kk < 2; ++kk) {
        const size_t off = kbase + (size_t)(c * 64) * DD + kk * 32;
        const short8 bh = *reinterpret_cast<const short8*>(ksh + off);
        const short8 bl = *reinterpret_cast<const short8*>(ksl + off);
        acc = __builtin_amdgcn_mfma_f32_16x16x32_bf16(ah[kk], bh, acc, 0, 0, 0);
        acc = __builtin_amdgcn_mfma_f32_16x16x32_bf16(ah[kk], bl, acc, 0, 0, 0);
        acc = __builtin_amdgcn_mfma_f32_16x16x32_bf16(al[kk], bh, acc, 0, 0, 0);
      }
      sacc[c] = acc;
    }
  }

  // ---- stage-1 top-k: each quad extracts its row's wave-local top-10 ----
  #pragma unroll
  for (int r = 0; r < 4; ++r) {
    float wk[8];
    #pragma unroll
    for (int c = 0; c < 8; ++c) wk[c] = sacc[c][r];
    float myg = 0.f;
    for (int it = 0; it < 10; ++it) {
      float lm = wk[0];
      #pragma unroll
      for (int c = 1; c < 8; ++c) lm = fmaxf(lm, wk[c]);
      const float gm = red16_max(lm);
      if (l15 == it) myg = gm;
      if (it < 9) {
        const unsigned long long msk = __ballot(lm == gm);
        const int sel = (__ffsll((unsigned long long)((msk >> (quad * 16)) & 0xFFFFull)) - 1)
                        + quad * 16;
        if (lane == sel) {
          #pragma unroll
          for (int c = 0; c < 8; ++c) { if (wk[c] == gm) { wk[c] = -FLT_MAX; break; } }
        }
      }
    }
    if (l15 < 10) cand[quad * 4 + r][wave * 10 + l15] = myg;
  }
  __syncthreads();

  // ---- merge 4 sorted lists of 10 -> global maxv + thr (10th) ----
  float mx, thr;
  {
    const int mr = lane & 15;
    float h0 = cand[mr][0], h1 = cand[mr][10], h2 = cand[mr][20], h3 = cand[mr][30];
    int i0 = 0, i1 = 0, i2 = 0, i3 = 0;
    float cur = 0.f;
    mx = 0.f;
    #pragma unroll
    for (int t = 0; t < 10; ++t) {
      cur = fmaxf(fmaxf(h0, h1), fmaxf(h2, h3));
      if (t == 0) mx = cur;
      if (t < 9) {
        const bool a0 = (cur == h0);
        const bool a1 = !a0 && (cur == h1);
        const bool a2 = !a0 && !a1 && (cur == h2);
        const int ni0 = i0 + (a0 ? 1 : 0);
        const int ni1 = i1 + (a1 ? 1 : 0);
        const int ni2 = i2 + (a2 ? 1 : 0);
        const int ni3 = i3 + ((a0 || a1 || a2) ? 0 : 1);
        const int off = a0 ? ni0 : (a1 ? 10 + ni1 : (a2 ? 20 + ni2 : 30 + ni3));
        const float nv = cand[mr][off];
        h0 = a0 ? nv : h0;
        h1 = a1 ? nv : h1;
        h2 = a2 ? nv : h2;
        h3 = (a0 || a1 || a2) ? h3 : nv;
        i0 = ni0; i1 = ni1; i2 = ni2; i3 = ni3;
      }
    }
    thr = cur;
  }
  // distribute row thr/max to the quad that owns the row
  float thrR[4], mxR[4];
  #pragma unroll
  for (int r = 0; r < 4; ++r) {
    thrR[r] = __shfl(thr, quad * 4 + r);
    mxR[r]  = __shfl(mx,  quad * 4 + r);
  }

  // ---- exp + partial sums + P write ----
  #pragma unroll
  for (int r = 0; r < 4; ++r) {
    const int Rr = quad * 4 + r;
    float s = 0.f;
    #pragma unroll
    for (int c = 0; c < 8; ++c) {
      const float sc = sacc[c][r];
      const float p = (sc >= thrR[r]) ? expf((sc - mxR[r]) * 0.125f) : 0.f;
      P[Rr][c * 64 + wave * 16 + l15] = f2b(p);
      s += p;
    }
    s = red16_sum(s);
    if (l15 == 0) psum[Rr][wave] = s;
  }
  __syncthreads();

  // ---- PV phase: wave w owns e-cols w*16..w*16+15; vT loaded direct ----
  f32x4 pacc = (f32x4){0.f, 0.f, 0.f, 0.f};
  const size_t vbase = ((size_t)bz * 512 + h * EE + wave * 16 + l15) * 512 + quad * 8;
  #pragma unroll
  for (int c = 0; c < 4; ++c) {
    #pragma unroll
    for (int ks = 0; ks < 4; ++ks) {
      const int s0 = c * 128 + ks * 32;
      const short8 pa = *reinterpret_cast<const short8*>(&P[l15][s0 + quad * 8]);
      const short8 vb = *reinterpret_cast<const short8*>(vt + vbase + s0);
      pacc = __builtin_amdgcn_mfma_f32_16x16x32_bf16(pa, vb, pacc, 0, 0, 0);
    }
  }

  // ---- epilogue ----
  #pragma unroll
  for (int r = 0; r < 4; ++r) {
    const int Rr = quad * 4 + r;
    const float4 ps = *reinterpret_cast<const float4*>(&psum[Rr][0]);
    const float inv = 1.f / (ps.x + ps.y + ps.z + ps.w);
    out[((size_t)bz * CC + l0 + Rr) * DD + h * EE + wave * 16 + l15] = f2b(pacc[r] * inv);
  }
}

// ---------------- GAttn fallback (fp32 path only) -----------
template<typename OT>
__global__ __launch_bounds__(256) void gattn_fb(
    const float* __restrict__ q, const float* __restrict__ k,
    const float* __restrict__ v, OT* __restrict__ out)
{
  const int tid = threadIdx.x;
  const int wave = tid >> 6, lane = tid & 63;
  const int l0 = blockIdx.x * 4;
  const int h = blockIdx.y, bz = blockIdx.z;
  const int l = l0 + wave;
  const size_t base = ((size_t)bz * CC) * DD + h * EE;

  __shared__ __align__(16) float kt[64][68];
  __shared__ __align__(16) float qs[4][64];
  __shared__ __align__(16) float ww[4][512];

  qs[wave][lane] = q[((size_t)bz * CC + l) * DD + h * EE + lane];

  float sc[8];
  const int sl = tid >> 4;
  const int e4 = (tid & 15) * 4;
  for (int c8 = 0; c8 < 8; ++c8) {
    #pragma unroll
    for (int r = 0; r < 4; ++r) {
      const int s_local = sl + r * 16;
      const float4 kv = *reinterpret_cast<const float4*>(
          k + base + (size_t)(c8 * 64 + s_local) * DD + e4);
      *reinterpret_cast<float4*>(&kt[s_local][e4]) = kv;
    }
    __syncthreads();
    float a = 0.f;
    #pragma unroll
    for (int e = 0; e < 16; ++e) {
      const float4 qv = *reinterpret_cast<const float4*>(&qs[wave][e * 4]);
      const float4 kv = *reinterpret_cast<const float4*>(&kt[lane][e * 4]);
      a += qv.x * kv.x + qv.y * kv.y + qv.z * kv.z + qv.w * kv.w;
    }
    sc[c8] = a;
    __syncthreads();
  }

  float wk[8];
  #pragma unroll
  for (int j = 0; j < 8; ++j) wk[j] = sc[j];
  float maxv = 0.f, thr = 0.f;
  for (int it = 0; it < 10; ++it) {
    float lm = wk[0];
    #pragma unroll
    for (int j = 1; j < 8; ++j) lm = fmaxf(lm, wk[j]);
    float gm = lm;
    #pragma unroll
    for (int off = 32; off > 0; off >>= 1) gm = fmaxf(gm, __shfl_xor(gm, off));
    if (it == 0) maxv = gm;
    if (it == 9) { thr = gm; break; }
    const unsigned long long msk = __ballot(lm == gm);
    if (lane == __ffsll(msk) - 1) {
      #pragma unroll
      for (int j = 0; j < 8; ++j) { if (wk[j] == gm) { wk[j] = -FLT_MAX; break; } }
    }
  }

  float lsum = 0.f;
  #pragma unroll
  for (int j = 0; j < 8; ++j) {
    const float p = (sc[j] >= thr) ? expf((sc[j] - maxv) * 0.125f) : 0.f;
    ww[wave][j * 64 + lane] = p;
    lsum += p;
  }
  #pragma unroll
  for (int off = 32; off > 0; off >>= 1) lsum += __shfl_xor(lsum, off);
  const float inv = 1.f / lsum;
  __syncthreads();

  float acc = 0.f;
  const float* vp = v + base + lane;
  const float* wp = ww[wave];
  for (int s = 0; s < 512; s += 4) {
    const float4 w4 = *reinterpret_cast<const float4*>(&wp[s]);
    acc = fmaf(w4.x, vp[(size_t)(s + 0) * DD], acc);
    acc = fmaf(w4.y, vp[(size_t)(s + 1) * DD], acc);
    acc = fmaf(w4.z, vp[(size_t)(s + 2) * DD], acc);
    acc = fmaf(w4.w, vp[(size_t)(s + 3) * DD], acc);
  }
  const float res = acc * inv;
  const size_t oi = ((size_t)bz * CC + l) * DD + h * EE + lane;
  if constexpr (sizeof(OT) == 4) out[oi] = res;
  else                           out[oi] = f2b(res);
}

// ---------------- pwattn1 via MFMA: one row per wave ----------------
__global__ __launch_bounds__(256) void pwattn1_mfma(
    const ushort* __restrict__ query, const float* __restrict__ k1,
    const float* __restrict__ v1, ushort* __restrict__ V1)
{
  const int tid = threadIdx.x;
  const int wave = tid >> 6, lane = tid & 63;
  const int quad = lane >> 4, l15 = lane & 15;
  const int n = blockIdx.x * 4 + wave;

  __shared__ __align__(16) ushort Pl[4][16][40];   // stride 80B (16B-aligned)

  const ushort* qrow = query + (size_t)n * DFF;
  const float*  krow = k1 + (size_t)n * 512;
  const float*  vrow = v1 + (size_t)n * 512;
  ushort* orow = V1 + (size_t)n * DFF;

  const short8 zz = {0, 0, 0, 0, 0, 0, 0, 0};
  const f32x4 zacc = (f32x4){0.f, 0.f, 0.f, 0.f};

  // B-frags for scores: col s = nt*16+l15, k = e = quad*8+i (valid e<16)
  short8 bh[2], bl[2];
  #pragma unroll
  for (int nt = 0; nt < 2; ++nt) {
    short8 hh = zz, ll = zz;
    if (quad < 2) {
      const float* kp = krow + (nt * 16 + l15) * 16 + quad * 8;
      #pragma unroll
      for (int i = 0; i < 8; ++i) {
        ushort hi_, lo_; split_bf(kp[i], hi_, lo_);
        hh[i] = (short)hi_; ll[i] = (short)lo_;
      }
    }
    bh[nt] = hh; bl[nt] = ll;
  }
  // B-frag for PV: v[k=s=quad*8+i][n=e=l15]
  short8 vb;
  #pragma unroll
  for (int i = 0; i < 8; ++i) vb[i] = (short)f2b(vrow[(quad * 8 + i) * 16 + l15]);

  #pragma unroll
  for (int mt = 0; mt < 8; ++mt) {
    short8 qa = zz;
    if (quad < 2)
      qa = *reinterpret_cast<const short8*>(qrow + (mt * 16 + l15) * 16 + quad * 8);
    f32x4 acc[2];
    #pragma unroll
    for (int nt = 0; nt < 2; ++nt) {
      f32x4 t = __builtin_amdgcn_mfma_f32_16x16x32_bf16(qa, bl[nt], zacc, 0, 0, 0);
      acc[nt] = __builtin_amdgcn_mfma_f32_16x16x32_bf16(qa, bh[nt], t, 0, 0, 0);
    }
    // softmax over 32 cols (2 nt x 16 lanes); rows quad*4+r
    float inv[4];
    #pragma unroll
    for (int r = 0; r < 4; ++r) {
      float m = red16_max(fmaxf(acc[0][r], acc[1][r]));
      const float p0 = expf((acc[0][r] - m) * 0.25f);
      const float p1 = expf((acc[1][r] - m) * 0.25f);
      acc[0][r] = p0; acc[1][r] = p1;
      const float s = red16_sum(p0 + p1);
      inv[r] = 1.f / s;
    }
    #pragma unroll
    for (int nt = 0; nt < 2; ++nt)
      #pragma unroll
      for (int r = 0; r < 4; ++r)
        Pl[wave][quad * 4 + r][nt * 16 + l15] = f2b(acc[nt][r]);
    const short8 pa = *reinterpret_cast<const short8*>(&Pl[wave][l15][quad * 8]);
    const f32x4 pv = __builtin_amdgcn_mfma_f32_16x16x32_bf16(pa, vb, zacc, 0, 0, 0);
    #pragma unroll
    for (int r = 0; r < 4; ++r)
      orow[(mt * 16 + quad * 4 + r) * 16 + l15] = f2b(pv[r] * inv[r]);
  }
}

// ---------------- pwattn2 via MFMA: one row per wave ----------------
__global__ __launch_bounds__(256) void pwattn2_mfma(
    const float* __restrict__ query2, const ushort* __restrict__ k2,
    const ushort* __restrict__ v2, ushort* __restrict__ V2)
{
  const int tid = threadIdx.x;
  const int wave = tid >> 6, lane = tid & 63;
  const int quad = lane >> 4, l15 = lane & 15;
  const int n = blockIdx.x * 4 + wave;

  __shared__ __align__(16) ushort Pl[4][16][136];  // stride 272B (16B-aligned)

  const float*  qrow = query2 + (size_t)n * 512;
  const ushort* krow = k2 + (size_t)n * DFF;
  const ushort* vrow = v2 + (size_t)n * DFF;
  ushort* orow = V2 + (size_t)n * 512;

  const short8 zz = {0, 0, 0, 0, 0, 0, 0, 0};
  const f32x4 zacc = (f32x4){0.f, 0.f, 0.f, 0.f};

  // B-frags for scores: col s = nt*16+l15 (8 nt), k = e = quad*8+i (<16)
  short8 kb[8];
  #pragma unroll
  for (int nt = 0; nt < 8; ++nt)
    kb[nt] = (quad < 2)
        ? *reinterpret_cast<const short8*>(krow + (nt * 16 + l15) * 16 + quad * 8)
        : zz;

  // B-frags for PV: v[k=s=kt*32+quad*8+i][n=e=l15]
  short8 vb[4];
  #pragma unroll
  for (int kt = 0; kt < 4; ++kt)
    #pragma unroll
    for (int i = 0; i < 8; ++i)
      vb[kt][i] = (short)vrow[(kt * 32 + quad * 8 + i) * 16 + l15];

  #pragma unroll
  for (int mt = 0; mt < 2; ++mt) {
    // A hi/lo: q[m=mt*16+l15][k=quad*8+i (<16)]
    short8 ahh = zz, all_ = zz;
    if (quad < 2) {
      const float* qp = qrow + (mt * 16 + l15) * 16 + quad * 8;
      #pragma unroll
      for (int i = 0; i < 8; ++i) {
        ushort hi_, lo_; split_bf(qp[i], hi_, lo_);
        ahh[i] = (short)hi_; all_[i] = (short)lo_;
      }
    }
    f32x4 acc[8];
    #pragma unroll
    for (int nt = 0; nt < 8; ++nt) {
      f32x4 t = __builtin_amdgcn_mfma_f32_16x16x32_bf16(all_, kb[nt], zacc, 0, 0, 0);
      acc[nt] = __builtin_amdgcn_mfma_f32_16x16x32_bf16(ahh, kb[nt], t, 0, 0, 0);
    }
    // softmax over 128 cols (8 nt x 16 lanes); rows quad*4+r
    float inv[4];
    #pragma unroll
    for (int r = 0; r < 4; ++r) {
      float m = acc[0][r];
      #pragma unroll
      for (int nt = 1; nt < 8; ++nt) m = fmaxf(m, acc[nt][r]);
      m = red16_max(m);
      float s = 0.f;
      #pragma unroll
      for (int nt = 0; nt < 8; ++nt) {
        const float p = expf((acc[nt][r] - m) * 0.25f);
        acc[nt][r] = p; s += p;
      }
      s = red16_sum(s);
      inv[r] = 1.f / s;
    }
    #pragma unroll
    for (int nt = 0; nt < 8; ++nt)
      #pragma unroll
      for (int r = 0; r < 4; ++r)
        Pl[wave][quad * 4 + r][nt * 16 + l15] = f2b(acc[nt][r]);
    f32x4 pv = zacc;
    #pragma unroll
    for (int kt = 0; kt < 4; ++kt) {
      const short8 pa = *reinterpret_cast<const short8*>(&Pl[wave][l15][kt * 32 + quad * 8]);
      pv = __builtin_amdgcn_mfma_f32_16x16x32_bf16(pa, vb[kt], pv, 0, 0, 0);
    }
    #pragma unroll
    for (int r = 0; r < 4; ++r)
      orow[(mt * 16 + quad * 4 + r) * 16 + l15] = f2b(pv[r] * inv[r]);
  }
}

// ---------------- pwattn1 (fallback) ----------------
__global__ __launch_bounds__(128) void pwattn1_kernel(
    const ushort* __restrict__ query, const float* __restrict__ k1,
    const float* __restrict__ v1, ushort* __restrict__ V1)
{
  const int n = blockIdx.x, tid = threadIdx.x;
  __shared__ float ks[512], vs[512];
  __shared__ float Am[128][33];
  for (int i = tid; i < 512; i += 128) { ks[i] = k1[(size_t)n * 512 + i]; vs[i] = v1[(size_t)n * 512 + i]; }
  __syncthreads();
  {
    const int l = tid;
    float qv[16];
    const ushort* qp = query + (size_t)n * DFF + l * 16;
    #pragma unroll
    for (int e = 0; e < 16; ++e) qv[e] = b2f(qp[e]);
    float scl[32], mx = -FLT_MAX;
    #pragma unroll
    for (int s = 0; s < 32; ++s) {
      float a = 0.f;
      #pragma unroll
      for (int e = 0; e < 16; ++e) a += qv[e] * ks[s * 16 + e];
      scl[s] = a; mx = fmaxf(mx, a);
    }
    float sum = 0.f;
    #pragma unroll
    for (int s = 0; s < 32; ++s) { const float p = expf((scl[s] - mx) * 0.25f); scl[s] = p; sum += p; }
    const float invs = 1.f / sum;
    #pragma unroll
    for (int s = 0; s < 32; ++s) Am[l][s] = scl[s] * invs;
  }
  __syncthreads();
  #pragma unroll
  for (int r = 0; r < 16; ++r) {
    const int idx = tid + 128 * r;
    const int l = idx >> 4, e = idx & 15;
    float a = 0.f;
    #pragma unroll
    for (int s = 0; s < 32; ++s) a += Am[l][s] * vs[s * 16 + e];
    V1[(size_t)n * DFF + idx] = f2b(a);
  }
}

// ---------------- LayerNorm over 2048, in-place bf16 ----------------
__global__ __launch_bounds__(256) void ln_kernel(
    ushort* __restrict__ h, const void* __restrict__ g, const void* __restrict__ bt,
    const int* __restrict__ dtf)
{
  const int f32 = *dtf;
  const int n = blockIdx.x, tid = threadIdx.x;
  ushort* hp = h + (size_t)n * DFF;
  float x[8]; float s = 0.f, s2 = 0.f;
  #pragma unroll
  for (int i = 0; i < 8; ++i) {
    const float xv = b2f(hp[tid + 256 * i]);
    x[i] = xv; s += xv; s2 += xv * xv;
  }
  __shared__ float rs[256], rq[256];
  rs[tid] = s; rq[tid] = s2;
  __syncthreads();
  for (int off = 128; off > 0; off >>= 1) {
    if (tid < off) { rs[tid] += rs[tid + off]; rq[tid] += rq[tid + off]; }
    __syncthreads();
  }
  const float mu  = rs[0] * (1.f / DFF);
  const float var = rq[0] * (1.f / DFF) - mu * mu;
  const float inv = rsqrtf(var + 1e-5f);
  #pragma unroll
  for (int i = 0; i < 8; ++i) {
    const int d = tid + 256 * i;
    hp[d] = f2b((x[i] - mu) * inv * lin(g, d, f32) + lin(bt, d, f32));
  }
}

// ---------------- pwattn2 (fallback), templated output -----------
template<typename OT>
__global__ __launch_bounds__(128) void pwattn2_kernel(
    const float* __restrict__ query2, const ushort* __restrict__ k2,
    const ushort* __restrict__ v2, OT* __restrict__ V2)
{
  const int n = blockIdx.x, tid = threadIdx.x;
  __shared__ float ks[2048], vs[2048];
  __shared__ float Am[32][129];
  for (int i = tid; i < 2048; i += 128) {
    ks[i] = b2f(k2[(size_t)n * DFF + i]);
    vs[i] = b2f(v2[(size_t)n * DFF + i]);
  }
  __syncthreads();
  if (tid < 32) {
    const int l = tid;
    float qv[16];
    #pragma unroll
    for (int e = 0; e < 16; ++e) qv[e] = query2[(size_t)n * 512 + l * 16 + e];
    float mx = -FLT_MAX;
    for (int s = 0; s < 128; ++s) {
      float a = 0.f;
      #pragma unroll
      for (int e = 0; e < 16; ++e) a += qv[e] * ks[s * 16 + e];
      Am[l][s] = a; mx = fmaxf(mx, a);
    }
    float sum = 0.f;
    for (int s = 0; s < 128; ++s) { const float p = expf((Am[l][s] - mx) * 0.25f); Am[l][s] = p; sum += p; }
    const float invs = 1.f / sum;
    for (int s = 0; s < 128; ++s) Am[l][s] *= invs;
  }
  __syncthreads();
  #pragma unroll
  for (int r = 0; r < 4; ++r) {
    const int idx = tid + 128 * r;
    const int l = idx >> 4, e = idx & 15;
    float a = 0.f;
    for (int s = 0; s < 128; ++s) a += Am[l][s] * vs[s * 16 + e];
    if constexpr (sizeof(OT) == 4) V2[(size_t)n * 512 + idx] = a;
    else                           V2[(size_t)n * 512 + idx] = f2b(a);
  }
}

// ---------------- final: dec = y@fc_w + fc_b; out = dec*std+mean -----------
__global__ __launch_bounds__(128) void final_kernel(
    const float* __restrict__ y, const void* __restrict__ fc_w,
    const void* __restrict__ fc_b, const float* __restrict__ meanb,
    const float* __restrict__ stdb, void* __restrict__ out, int row_base,
    const int* __restrict__ dtf)
{
  const int f32 = *dtf;
  const int row = row_base + blockIdx.x;
  const int b = row >> 9, c = row & 511;
  const int tid = threadIdx.x;
  __shared__ float yr[512];
  for (int i = tid; i < 512; i += 128) yr[i] = y[(size_t)blockIdx.x * 512 + i];
  __syncthreads();
  if (tid < PRED) {
    float a = 0.f;
    for (int d = 0; d < 512; ++d) a += yr[d] * lin(fc_w, d * PRED + tid, f32);
    a += lin(fc_b, tid, f32);
    const float r = a * stdb[row] + meanb[row];
    const size_t oi = ((size_t)b * PRED + tid) * CC + c;
    if (f32) ((float*)out)[oi] = r;
    else     ((ushort*)out)[oi] = f2b(r);
  }
}

// ---------------------------------------------------------------------------
extern "C" void kernel_launch(void* const* d_in, const int* in_sizes, int n_in,
                              void* d_out, int out_size, void* d_ws, size_t ws_size,
                              hipStream_t stream)
{
  (void)in_sizes; (void)n_in; (void)out_size;
  const void* x_enc   = d_in[0];
  const void* embed_w = d_in[4];
  const void* q_w = d_in[5],  * q_b = d_in[6];
  const void* k_w = d_in[7],  * k_b = d_in[8];
  const void* v_w = d_in[9],  * v_b = d_in[10];
  const void* o_w = d_in[11], * o_b = d_in[12];
  const void* enc_w = d_in[13], * enc_b = d_in[14];
  const void* f1q_w = d_in[15], * f1q_b = d_in[16];
  const void* f1k_w = d_in[17], * f1k_b = d_in[18];
  const void* f1v_w = d_in[19], * f1v_b = d_in[20];
  const void* f1o_w = d_in[21], * f1o_b = d_in[22];
  const void* f2q_w = d_in[23], * f2q_b = d_in[24];
  const void* f2k_w = d_in[25], * f2k_b = d_in[26];
  const void* f2v_w = d_in[27], * f2v_b = d_in[28];
  const void* f2o_w = d_in[29], * f2o_b = d_in[30];
  const void* ln_g  = d_in[31], * ln_b  = d_in[32];
  const void* fc_w  = d_in[33], * fc_b  = d_in[34];

  const size_t HDR = 131072 + 1024;
  const size_t E_F1Q = 512ull * 2048, E_F1O = 2048ull * 2048, E_F2Q = 2048ull * 512;
  const size_t E_F2K = 2048ull * 2048, E_F2V = 2048ull * 2048, E_F2O = 512ull * 512;
  const size_t E_SQ  = 512ull * 512;   // o_w, enc_w, f1k_w, f1v_w each
  // + 8 split arrays (embed/q/k/v hi+lo)
  const size_t WT_EL = E_F1Q + E_F1O + E_F2Q + E_F2K + E_F2V + E_F2O + 4 * E_SQ + 8 * E_SQ;
  const size_t WT_BYTES = WT_EL * 2;   // ~34.5 MB
  const size_t PB_MFMA = 4ull * 512 * 512 * 4 + 3ull * 512 * DFF * 2; // 10.0MB
  const size_t PB_FB   = 5ull * 512 * 512 * 4 + 3ull * 512 * DFF * 2; // 11.0MB

  const int use_mfma = (HDR + WT_BYTES + PB_MFMA <= ws_size) ? 1 : 0;
  const size_t PER_BATCH = use_mfma ? PB_MFMA : PB_FB;
  const size_t FIXED = HDR + (use_mfma ? WT_BYTES : 0);
  int BPC = 1;
  for (int c = 8; c >= 1; c >>= 1) {
    if (FIXED + (size_t)c * PER_BATCH <= ws_size) { BPC = c; break; }
  }
  const int R = BPC * 512;

  char* ws = (char*)d_ws;
  float* meanb = (float*)ws;
  float* stdb  = (float*)(ws + 65536);
  int*   dtf   = (int*)(ws + 131072);
  ushort* wt_base = (ushort*)(ws + HDR);
  ushort* wt_f1q = wt_base;
  ushort* wt_f1o = wt_f1q + E_F1Q;
  ushort* wt_f2q = wt_f1o + E_F1O;
  ushort* wt_f2k = wt_f2q + E_F2Q;
  ushort* wt_f2v = wt_f2k + E_F2K;
  ushort* wt_f2o = wt_f2v + E_F2V;
  ushort* wt_o   = wt_f2o + E_F2O;
  ushort* wt_enc = wt_o   + E_SQ;
  ushort* wt_f1k = wt_enc + E_SQ;
  ushort* wt_f1v = wt_f1k + E_SQ;
  ushort* wt_embh = wt_f1v + E_SQ;
  ushort* wt_embl = wt_embh + E_SQ;
  ushort* wt_qh   = wt_embl + E_SQ;
  ushort* wt_ql   = wt_qh   + E_SQ;
  ushort* wt_kh   = wt_ql   + E_SQ;
  ushort* wt_kl   = wt_kh   + E_SQ;
  ushort* wt_vh   = wt_kl   + E_SQ;
  ushort* wt_vl   = wt_vh   + E_SQ;

  char* arena = ws + FIXED;
  const size_t FSL = (size_t)R * 512 * 4;
  const size_t GSL = (size_t)R * DFF * 2;
  void* A_ = arena;
  void* B_ = arena + FSL;
  void* C_ = arena + 2 * FSL;
  void* D_ = arena + 3 * FSL;
  void* E_ = arena + 4 * FSL;                     // fallback path only
  char* gb = arena + (size_t)(use_mfma ? 4 : 5) * FSL;
  void* G1 = gb;
  void* G2 = gb + GSL;
  void* G3 = gb + 2 * GSL;

  // mfma-path split buffers
  ushort* xTh  = (ushort*)G1; ushort* xTl  = xTh  + (size_t)R * 512; // in G1 (dead before f1q)
  ushort* embh = (ushort*)G2; ushort* embl = embh + (size_t)R * 512; // in G2 (dead before pwattn1)
  ushort* qsh  = (ushort*)C_; ushort* qsl  = qsh  + (size_t)R * 512;
  ushort* ksh  = (ushort*)D_; ushort* ksl  = ksh  + (size_t)R * 512;
  ushort* vt   = (ushort*)B_;                                        // vT, dead before f1v

  detect_dtype<<<1, 256, 0, stream>>>((const ushort*)x_enc, dtf);
  // two-phase instance-norm stats; partials live in the (still idle) arena
  instnorm_partial<<<dim3(2, NB, 8), 256, 0, stream>>>(
      x_enc, (float*)A_, (float*)B_, dtf);
  instnorm_reduce<<<dim3(2, NB), 256, 0, stream>>>(
      (const float*)A_, (const float*)B_, meanb, stdb);

  if (use_mfma) {   // one-time weight convert+transpose (KxN -> bf16 NxK)
    transpose_w<<<dim3(DFF / 32, 512 / 32), 256, 0, stream>>>(f1q_w, wt_f1q, 512, DFF, dtf);
    transpose_w<<<dim3(DFF / 32, DFF / 32), 256, 0, stream>>>(f1o_w, wt_f1o, DFF, DFF, dtf);
    transpose_w<<<dim3(512 / 32, DFF / 32), 256, 0, stream>>>(f2q_w, wt_f2q, DFF, 512, dtf);
    transpose_w<<<dim3(DFF / 32, DFF / 32), 256, 0, stream>>>(f2k_w, wt_f2k, DFF, DFF, dtf);
    transpose_w<<<dim3(DFF / 32, DFF / 32), 256, 0, stream>>>(f2v_w, wt_f2v, DFF, DFF, dtf);
    transpose_w<<<dim3(512 / 32, 512 / 32), 256, 0, stream>>>(f2o_w, wt_f2o, 512, 512, dtf);
    transpose_w<<<dim3(512 / 32, 512 / 32), 256, 0, stream>>>(o_w,   wt_o,   512, 512, dtf);
    transpose_w<<<dim3(512 / 32, 512 / 32), 256, 0, stream>>>(enc_w, wt_enc, 512, 512, dtf);
    transpose_w<<<dim3(512 / 32, 512 / 32), 256, 0, stream>>>(f1k_w, wt_f1k, 512, 512, dtf);
    transpose_w<<<dim3(512 / 32, 512 / 32), 256, 0, stream>>>(f1v_w, wt_f1v, 512, 512, dtf);
    transpose_w_split<<<dim3(512 / 32, 512 / 32), 256, 0, stream>>>(embed_w, wt_embh, wt_embl, 512, 512, dtf);
    transpose_w_split<<<dim3(512 / 32, 512 / 32), 256, 0, stream>>>(q_w, wt_qh, wt_ql, 512, 512, dtf);
    transpose_w_split<<<dim3(512 / 32, 512 / 32), 256, 0, stream>>>(k_w, wt_kh, wt_kl, 512, 512, dtf);
    transpose_w_split<<<dim3(512 / 32, 512 / 32), 256, 0, stream>>>(v_w, wt_vh, wt_vl, 512, 512, dtf);
  }

  for (int bc = 0; bc < NB / BPC; ++bc) {
    const int b0 = bc * BPC;
    if (use_mfma) {
      // --- stage 1: split-MFMA GEMMs ---
      norm_transpose_split<<<dim3(16, 16, BPC), 256, 0, stream>>>(
          x_enc, meanb, stdb, xTh, xTl, b0, dtf);
      launch_mgemm3<E3_RELU_PE>(xTh, xTl, wt_embh, wt_embl, nullptr,
                                embh, embl, R, 512, 512, dtf, stream);         // emb hi/lo
      launch_mgemm3<E3_RELU_SPLIT>(embh, embl, wt_qh, wt_ql, q_b,
                                   qsh, qsl, R, 512, 512, dtf, stream);        // q hi/lo
      launch_mgemm3<E3_SPLIT>(embh, embl, wt_kh, wt_kl, k_b,
                              ksh, ksl, R, 512, 512, dtf, stream);             // k hi/lo
      launch_mgemm3<E3_RELU_VT>(embh, embl, wt_vh, wt_vl, v_b,
                                vt, nullptr, R, 512, 512, dtf, stream);        // vT bf16
      gattn_mfma<<<dim3(CC / 16, HH, BPC), 256, 0, stream>>>(
          qsh, qsl, ksh, ksl, vt, (ushort*)A_);                                // attn bf16
      launch_mgemm64<ushort, ushort, M_ADD2_BIAS_LEAKY>(
          A_, wt_o, o_b, embh, C_, R, 512, 512, dtf, stream, embl);            // y bf16
      launch_mgemm64<float, ushort, M_BIAS>(C_, wt_enc, enc_b, nullptr, D_, R, 512, 512, dtf, stream);  // X1 bf16
      // --- stage 2: pwattn1 + LN ---
      launch_mgemm<float, ushort, M_BIAS_RELU>(D_, wt_f1q, f1q_b, nullptr, G1, R, 512, DFF, dtf, stream); // query1
      launch_mgemm64<float, float, M_BIAS     >(D_, wt_f1k, f1k_b, nullptr, A_, R, 512, 512, dtf, stream); // k1 f32
      launch_mgemm64<float, float, M_BIAS_RELU>(D_, wt_f1v, f1v_b, nullptr, B_, R, 512, 512, dtf, stream); // v1 f32
      pwattn1_mfma<<<R / 4, 256, 0, stream>>>(
          (const ushort*)G1, (const float*)A_, (const float*)B_, (ushort*)G2);
      launch_mgemm<ushort, ushort, M_ADD_BIAS_ELU>(G2, wt_f1o, f1o_b, G1, G1, R, DFF, DFF, dtf, stream);  // h
      ln_kernel<<<R, 256, 0, stream>>>((ushort*)G1, ln_g, ln_b, dtf);
      // --- stage 3: pwattn2 + out ---
      launch_mgemm64<float, float, M_BIAS_RELU>(G1, wt_f2q, f2q_b, nullptr, A_, R, DFF, 512, dtf, stream); // query2
      launch_mgemm<float, ushort, M_BIAS     >(G1, wt_f2k, f2k_b, nullptr, G2, R, DFF, DFF, dtf, stream); // k2
      launch_mgemm<float, ushort, M_BIAS_RELU>(G1, wt_f2v, f2v_b, nullptr, G3, R, DFF, DFF, dtf, stream); // v2
      pwattn2_mfma<<<R / 4, 256, 0, stream>>>(
          (const float*)A_, (const ushort*)G2, (const ushort*)G3, (ushort*)B_);
      launch_mgemm64<float, float, M_ADD_BIAS>(B_, wt_f2o, f2o_b, A_, C_, R, 512, 512, dtf, stream);      // y2
    } else {
      norm_transpose<<<dim3(16, 16, BPC), 256, 0, stream>>>(x_enc, meanb, stdb, (float*)A_, b0, dtf);
      launch_gemm<float, float, float, M_RELU_PE >(A_, embed_w, nullptr, nullptr, B_, R, 512, 512, dtf, stream);
      launch_gemm<float, float, float, M_BIAS_RELU>(B_, q_w, q_b, nullptr, C_, R, 512, 512, dtf, stream);
      launch_gemm<float, float, float, M_BIAS     >(B_, k_w, k_b, nullptr, D_, R, 512, 512, dtf, stream);
      launch_gemm<float, float, float, M_BIAS_RELU>(B_, v_w, v_b, nullptr, E_, R, 512, 512, dtf, stream);
      gattn_fb<float><<<dim3(CC / 4, HH, BPC), 256, 0, stream>>>(
          (float*)C_, (float*)D_, (float*)E_, (float*)A_);
      launch_gemm<float, float, float, M_ADD_BIAS_LEAKY>(A_, o_w, o_b, B_, C_, R, 512, 512, dtf, stream);
      launch_gemm<float, float, float, M_BIAS>(C_, enc_w, enc_b, nullptr, D_, R, 512, 512, dtf, stream);
      launch_gemm<float, float, ushort, M_BIAS_RELU>(D_, f1q_w, f1q_b, nullptr, G1, R, 512, DFF, dtf, stream);
      launch_gemm<float, float, float,  M_BIAS     >(D_, f1k_w, f1k_b, nullptr, A_, R, 512, 512, dtf, stream);
      launch_gemm<float, float, float,  M_BIAS_RELU>(D_, f1v_w, f1v_b, nullptr, B_, R, 512, 512, dtf, stream);
      pwattn1_kernel<<<R, 128, 0, stream>>>((const ushort*)G1, (const float*)A_, (const float*)B_, (ushort*)G2);
      launch_gemm<ushort, ushort, ushort, M_ADD_BIAS_ELU>(G2, f1o_w, f1o_b, G1, G1, R, DFF, DFF, dtf, stream);
      ln_kernel<<<R, 256, 0, stream>>>((ushort*)G1, ln_g, ln_b, dtf);
      launch_gemm<ushort, float, float,  M_BIAS_RELU>(G1, f2q_w, f2q_b, nullptr, A_, R, DFF, 512, dtf, stream);
      launch_gemm<ushort, float, ushort, M_BIAS     >(G1, f2k_w, f2k_b, nullptr, G2, R, DFF, DFF, dtf, stream);
      launch_gemm<ushort, float, ushort, M_BIAS_RELU>(G1, f2v_w, f2v_b, nullptr, G3, R, DFF, DFF, dtf, stream);
      pwattn2_kernel<float><<<R, 128, 0, stream>>>((const float*)A_, (const ushort*)G2, (const ushort*)G3, (float*)B_);
      launch_gemm<float, float, float, M_ADD_BIAS>(B_, f2o_w, f2o_b, A_, C_, R, 512, 512, dtf, stream);
    }
    final_kernel<<<R, 128, 0, stream>>>((const float*)C_, fc_w, fc_b, meanb, stdb, d_out, b0 * 512, dtf);
  }
}

// Round 5
// 2521.326 us; speedup vs baseline: 1.1391x; 1.1391x over previous
//
#include <hip/hip_runtime.h>
#include <float.h>
#include <math.h>
#include <stdint.h>

// ---------------------------------------------------------------------------
// Model_33062658245168: Informer-style time-series model. fp32 in/out
// (runtime-detected; bf16 fallback kept). B=32 S=512 C=512 D=512 DF=2048 H=8
// E=64 P=16 PRED=96 K(topk)=10, N=16384.
//
// Round 16: A/B revert. R15's mgemm global_load_lds rewrite correlated with a
// +53% regression of the UNCHANGED gattn kernel (84 -> 128.7us, VGPR tier
// flipped to 64) and was at best neutral itself. Reverted mgemm/mgemm64 to
// the proven reg-staged r14 forms. Kept two-phase instnorm (verified -77us).
// gattn: launch_bounds (256,4)->(256,2) to un-pin the allocator from the
// 64-VGPR tier; s_setprio(1) around MFMA clusters (m191: +4-7% on attn).
// ---------------------------------------------------------------------------

#define NB   32
#define SS   512
#define CC   512
#define DD   512
#define DFF  2048
#define HH   8
#define EE   64
#define PRED 96

typedef __attribute__((ext_vector_type(8))) short short8;
typedef __attribute__((ext_vector_type(4))) float f32x4;

__device__ __forceinline__ float b2f(ushort u) {
  union { float f; uint32_t i; } c; c.i = ((uint32_t)u) << 16; return c.f;
}
__device__ __forceinline__ ushort f2b(float f) {
  union { float f; uint32_t i; } c; c.f = f;
  uint32_t x = c.i;
  return (ushort)((x + 0x7fffu + ((x >> 16) & 1u)) >> 16);   // RNE
}
__device__ __forceinline__ float lin(const void* p, size_t i, int f32) {
  return f32 ? ((const float*)p)[i] : b2f(((const ushort*)p)[i]);
}
__device__ __forceinline__ void split_bf(float x, ushort& hi, ushort& lo) {
  hi = f2b(x);
  lo = f2b(x - b2f(hi));
}

// ---- DPP 16-lane all-reduce (VALU only) ----
template<int CTRL>
__device__ __forceinline__ float dppmov(float x) {
  union { float f; int i; } a, b;
  a.f = x;
  b.i = __builtin_amdgcn_update_dpp(a.i, a.i, CTRL, 0xF, 0xF, false);
  return b.f;
}
__device__ __forceinline__ float red16_max(float x) {
  x = fmaxf(x, dppmov<0xB1>(x));    // quad_perm xor1
  x = fmaxf(x, dppmov<0x4E>(x));    // quad_perm xor2
  x = fmaxf(x, dppmov<0x141>(x));   // row_half_mirror
  x = fmaxf(x, dppmov<0x140>(x));   // row_mirror
  return x;
}
__device__ __forceinline__ float red16_sum(float x) {
  x += dppmov<0xB1>(x);
  x += dppmov<0x4E>(x);
  x += dppmov<0x141>(x);
  x += dppmov<0x140>(x);
  return x;
}

// ---------------- dtype detection (1 = fp32 inputs) ----------------
__global__ __launch_bounds__(256) void detect_dtype(
    const ushort* __restrict__ x, int* __restrict__ flag)
{
  __shared__ float red[256];
  const int t = threadIdx.x;
  float v = fabsf(b2f(x[2 * t]));
  if (!(v < 1e30f)) v = 1e30f;
  red[t] = v;
  __syncthreads();
  for (int off = 128; off > 0; off >>= 1) {
    if (t < off) red[t] = fmaxf(red[t], red[t + off]);
    __syncthreads();
  }
  if (t == 0) flag[0] = (red[0] > 1e6f) ? 1 : 0;
}

// ---------------- instance norm stats, two-phase ----------------
__global__ __launch_bounds__(256) void instnorm_partial(
    const void* __restrict__ x, float* __restrict__ ps, float* __restrict__ pq,
    const int* __restrict__ dtf)
{
  const int f32 = *dtf;
  const int c = blockIdx.x * 256 + threadIdx.x;
  const int b = blockIdx.y;
  const int t0 = blockIdx.z * 64;
  float s = 0.f, s2 = 0.f;
  for (int t = t0; t < t0 + 64; ++t) {
    const float xv = lin(x, ((size_t)(b * SS) + t) * CC + c, f32);
    s += xv; s2 += xv * xv;
  }
  const int pidx = (b * 8 + blockIdx.z) * CC + c;
  ps[pidx] = s; pq[pidx] = s2;
}

__global__ __launch_bounds__(256) void instnorm_reduce(
    const float* __restrict__ ps, const float* __restrict__ pq,
    float* __restrict__ meanb, float* __restrict__ stdb)
{
  const int c = blockIdx.x * 256 + threadIdx.x;
  const int b = blockIdx.y;
  float s = 0.f, s2 = 0.f;
  #pragma unroll
  for (int i = 0; i < 8; ++i) {
    s  += ps[(b * 8 + i) * CC + c];
    s2 += pq[(b * 8 + i) * CC + c];
  }
  const float mu  = s * (1.f / SS);
  const float var = s2 * (1.f / SS) - mu * mu;
  meanb[b * CC + c] = mu;
  stdb [b * CC + c] = sqrtf(var + 1e-5f);
}

// ---------------- normalize + transpose one chunk (fp32, fallback) ---------
__global__ __launch_bounds__(256) void norm_transpose(
    const void* __restrict__ x, const float* __restrict__ meanb,
    const float* __restrict__ stdb, float* __restrict__ xTc, int b_base,
    const int* __restrict__ dtf)
{
  const int f32 = *dtf;
  __shared__ float t[32][33];
  const int s0 = blockIdx.x * 32, c0 = blockIdx.y * 32, lb = blockIdx.z;
  const int b = b_base + lb;
  const int tx = threadIdx.x & 31, ty = threadIdx.x >> 5;
  #pragma unroll
  for (int i = 0; i < 4; ++i) {
    const int s = s0 + ty + i * 8;
    t[ty + i * 8][tx] = lin(x, ((size_t)(b * SS) + s) * CC + c0 + tx, f32);
  }
  __syncthreads();
  #pragma unroll
  for (int i = 0; i < 4; ++i) {
    const int c = c0 + ty + i * 8;
    const float mu = meanb[b * CC + c], sd = stdb[b * CC + c];
    xTc[((size_t)(lb * CC) + c) * SS + s0 + tx] = (t[tx][ty + i * 8] - mu) / sd;
  }
}

// ---------------- normalize + transpose, hi/lo split output ----------------
__global__ __launch_bounds__(256) void norm_transpose_split(
    const void* __restrict__ x, const float* __restrict__ meanb,
    const float* __restrict__ stdb, ushort* __restrict__ xh,
    ushort* __restrict__ xl, int b_base, const int* __restrict__ dtf)
{
  const int f32 = *dtf;
  __shared__ float t[32][33];
  const int s0 = blockIdx.x * 32, c0 = blockIdx.y * 32, lb = blockIdx.z;
  const int b = b_base + lb;
  const int tx = threadIdx.x & 31, ty = threadIdx.x >> 5;
  #pragma unroll
  for (int i = 0; i < 4; ++i) {
    const int s = s0 + ty + i * 8;
    t[ty + i * 8][tx] = lin(x, ((size_t)(b * SS) + s) * CC + c0 + tx, f32);
  }
  __syncthreads();
  #pragma unroll
  for (int i = 0; i < 4; ++i) {
    const int c = c0 + ty + i * 8;
    const float mu = meanb[b * CC + c], sd = stdb[b * CC + c];
    const float v = (t[tx][ty + i * 8] - mu) / sd;
    const size_t idx = ((size_t)(lb * CC) + c) * SS + s0 + tx;
    ushort hi, lo; split_bf(v, hi, lo);
    xh[idx] = hi; xl[idx] = lo;
  }
}

// ---------------- weight convert+transpose: W (KxN, input dtype) -> bf16 (NxK)
__global__ __launch_bounds__(256) void transpose_w(
    const void* __restrict__ W, ushort* __restrict__ Wt, int K, int N,
    const int* __restrict__ dtf)
{
  const int f32 = *dtf;
  __shared__ float t[32][33];
  const int n0 = blockIdx.x * 32, k0 = blockIdx.y * 32;
  const int tx = threadIdx.x & 31, ty = threadIdx.x >> 5;
  #pragma unroll
  for (int i = 0; i < 4; ++i)
    t[ty + i * 8][tx] = lin(W, (size_t)(k0 + ty + i * 8) * N + n0 + tx, f32);
  __syncthreads();
  #pragma unroll
  for (int i = 0; i < 4; ++i)
    Wt[(size_t)(n0 + ty + i * 8) * K + k0 + tx] = f2b(t[tx][ty + i * 8]);
}

// ---------------- weight transpose + hi/lo split ----------------
__global__ __launch_bounds__(256) void transpose_w_split(
    const void* __restrict__ W, ushort* __restrict__ Whi, ushort* __restrict__ Wlo,
    int K, int N, const int* __restrict__ dtf)
{
  const int f32 = *dtf;
  __shared__ float t[32][33];
  const int n0 = blockIdx.x * 32, k0 = blockIdx.y * 32;
  const int tx = threadIdx.x & 31, ty = threadIdx.x >> 5;
  #pragma unroll
  for (int i = 0; i < 4; ++i)
    t[ty + i * 8][tx] = lin(W, (size_t)(k0 + ty + i * 8) * N + n0 + tx, f32);
  __syncthreads();
  #pragma unroll
  for (int i = 0; i < 4; ++i) {
    const size_t idx = (size_t)(n0 + ty + i * 8) * K + k0 + tx;
    ushort hi, lo; split_bf(t[tx][ty + i * 8], hi, lo);
    Whi[idx] = hi; Wlo[idx] = lo;
  }
}

// ---------------- generic fp32 tiled GEMM (fallback path) ----------
enum GemmMode { M_BIAS = 0, M_BIAS_RELU = 1, M_RELU_PE = 2,
                M_ADD_BIAS_LEAKY = 3, M_ADD_BIAS_ELU = 4, M_ADD_BIAS = 5,
                M_ADD2_BIAS_LEAKY = 6 };

template<typename AT, typename ADT, typename OT, int MODE>
__global__ __launch_bounds__(256) void gemm_kernel(
    const AT* __restrict__ A, const void* __restrict__ Bw,
    const void* __restrict__ bias, const ADT* __restrict__ addend,
    OT* __restrict__ Cout, int M, int K, int Nn, const int* __restrict__ dtf)
{
  const int f32 = *dtf;
  __shared__ __align__(16) float As[16][68];
  __shared__ __align__(16) float Bs[16][68];
  const int tid = threadIdx.x;
  const int m0 = blockIdx.y * 64, n0 = blockIdx.x * 64;
  const int tx = tid & 15, ty = tid >> 4;
  const int la_m = tid >> 2, la_k = (tid & 3) * 4;
  const int lb_k = tid >> 4, lb_n = (tid & 15) * 4;
  float acc[4][4];
  #pragma unroll
  for (int i = 0; i < 4; ++i)
    #pragma unroll
    for (int j = 0; j < 4; ++j) acc[i][j] = 0.f;
  const size_t a_row = (size_t)(m0 + la_m) * K;

  for (int k0 = 0; k0 < K; k0 += 16) {
    if constexpr (sizeof(AT) == 4) {
      const float4 av = *reinterpret_cast<const float4*>(A + a_row + k0 + la_k);
      As[la_k + 0][la_m] = av.x; As[la_k + 1][la_m] = av.y;
      As[la_k + 2][la_m] = av.z; As[la_k + 3][la_m] = av.w;
    } else {
      const ushort4 av = *reinterpret_cast<const ushort4*>(A + a_row + k0 + la_k);
      As[la_k + 0][la_m] = b2f(av.x); As[la_k + 1][la_m] = b2f(av.y);
      As[la_k + 2][la_m] = b2f(av.z); As[la_k + 3][la_m] = b2f(av.w);
    }
    {
      const size_t boff = (size_t)(k0 + lb_k) * Nn + n0 + lb_n;
      if (f32) {
        const float4 bv = *reinterpret_cast<const float4*>((const float*)Bw + boff);
        Bs[lb_k][lb_n + 0] = bv.x; Bs[lb_k][lb_n + 1] = bv.y;
        Bs[lb_k][lb_n + 2] = bv.z; Bs[lb_k][lb_n + 3] = bv.w;
      } else {
        const ushort4 bv = *reinterpret_cast<const ushort4*>((const ushort*)Bw + boff);
        Bs[lb_k][lb_n + 0] = b2f(bv.x); Bs[lb_k][lb_n + 1] = b2f(bv.y);
        Bs[lb_k][lb_n + 2] = b2f(bv.z); Bs[lb_k][lb_n + 3] = b2f(bv.w);
      }
    }
    __syncthreads();
    #pragma unroll
    for (int k = 0; k < 16; ++k) {
      const float4 a4 = *reinterpret_cast<const float4*>(&As[k][ty * 4]);
      const float4 b4 = *reinterpret_cast<const float4*>(&Bs[k][tx * 4]);
      const float aa[4] = {a4.x, a4.y, a4.z, a4.w};
      const float bb[4] = {b4.x, b4.y, b4.z, b4.w};
      #pragma unroll
      for (int i = 0; i < 4; ++i)
        #pragma unroll
        for (int j = 0; j < 4; ++j)
          acc[i][j] = fmaf(aa[i], bb[j], acc[i][j]);
    }
    __syncthreads();
  }

  float biasv[4];
  if constexpr (MODE != M_RELU_PE) {
    #pragma unroll
    for (int j = 0; j < 4; ++j) biasv[j] = lin(bias, n0 + tx * 4 + j, f32);
  }
  #pragma unroll
  for (int i = 0; i < 4; ++i) {
    const int m = m0 + ty * 4 + i;
    #pragma unroll
    for (int j = 0; j < 4; ++j) {
      const int n = n0 + tx * 4 + j;
      float v = acc[i][j];
      if constexpr (MODE == M_BIAS) {
        v += biasv[j];
      } else if constexpr (MODE == M_BIAS_RELU) {
        v = fmaxf(v + biasv[j], 0.f);
      } else if constexpr (MODE == M_RELU_PE) {
        v = fmaxf(v, 0.f);
        const float freq = expf((float)(n & ~1) * (-0.017988946f)); // -ln(1e4)/512
        const float ang  = (float)(m & (CC - 1)) * freq;            // pos = c
        v += (n & 1) ? cosf(ang) : sinf(ang);
      } else {
        float ad;
        if constexpr (sizeof(ADT) == 4) ad = ((const float*)addend)[(size_t)m * Nn + n];
        else                            ad = b2f(((const ushort*)addend)[(size_t)m * Nn + n]);
        v = ad + v + biasv[j];
        if constexpr (MODE == M_ADD_BIAS_LEAKY) v = (v >= 0.f) ? v : 0.5f * v;
        else if constexpr (MODE == M_ADD_BIAS_ELU) v = (v > 0.f) ? v : expm1f(v);
      }
      if constexpr (sizeof(OT) == 4) ((float*)Cout)[(size_t)m * Nn + n] = v;
      else                           ((ushort*)Cout)[(size_t)m * Nn + n] = f2b(v);
    }
  }
}

template<typename AT, typename ADT, typename OT, int MODE>
static void launch_gemm(const void* A, const void* Bw, const void* bias, const void* add,
                        void* Cout, int M, int K, int Nn, const int* dtf, hipStream_t stream)
{
  dim3 grid(Nn / 64, M / 64);
  gemm_kernel<AT, ADT, OT, MODE><<<grid, dim3(256), 0, stream>>>(
      (const AT*)A, Bw, bias, (const ADT*)add, (OT*)Cout, M, K, Nn, dtf);
}

// ---------------- MFMA bf16 GEMM (128x128 tile): Cout = epi(A @ Wt^T) ------
template<typename ADT, typename OT, int MODE>
__global__ __launch_bounds__(256) void mgemm_kernel(
    const ushort* __restrict__ A, const ushort* __restrict__ Wt,
    const void* __restrict__ bias, const ADT* __restrict__ addend,
    const ushort* __restrict__ addend2,
    OT* __restrict__ Cout, int M, int K, int Nn, const int* __restrict__ dtf)
{
  const int f32 = *dtf;
  __shared__ __align__(16) ushort As[128][40];
  __shared__ __align__(16) ushort Bs[128][40];
  const int tid = threadIdx.x;
  const int m0 = blockIdx.y * 128, n0 = blockIdx.x * 128;
  const int wave = tid >> 6, lane = tid & 63;
  const int wm = wave & 1, wn = wave >> 1;
  const int quad = lane >> 4, l15 = lane & 15;

  f32x4 acc[4][4];
  #pragma unroll
  for (int i = 0; i < 4; ++i)
    #pragma unroll
    for (int j = 0; j < 4; ++j) acc[i][j] = (f32x4){0.f, 0.f, 0.f, 0.f};

  const int srow = tid >> 1, sseg = (tid & 1) * 16;
  const size_t a_base = (size_t)(m0 + srow) * K + sseg;
  const size_t b_base = (size_t)(n0 + srow) * K + sseg;

  for (int k0 = 0; k0 < K; k0 += 32) {
    {
      const float4* ga = reinterpret_cast<const float4*>(A + a_base + k0);
      const float4* gb = reinterpret_cast<const float4*>(Wt + b_base + k0);
      const float4 a0 = ga[0], a1 = ga[1];
      const float4 b0 = gb[0], b1 = gb[1];
      float4* da = reinterpret_cast<float4*>(&As[srow][sseg]);
      float4* db = reinterpret_cast<float4*>(&Bs[srow][sseg]);
      da[0] = a0; da[1] = a1;
      db[0] = b0; db[1] = b1;
    }
    __syncthreads();
    short8 af[4], bf[4];
    #pragma unroll
    for (int i = 0; i < 4; ++i)
      af[i] = *reinterpret_cast<const short8*>(&As[wm * 64 + i * 16 + l15][quad * 8]);
    #pragma unroll
    for (int j = 0; j < 4; ++j)
      bf[j] = *reinterpret_cast<const short8*>(&Bs[wn * 64 + j * 16 + l15][quad * 8]);
    #pragma unroll
    for (int i = 0; i < 4; ++i)
      #pragma unroll
      for (int j = 0; j < 4; ++j)
        acc[i][j] = __builtin_amdgcn_mfma_f32_16x16x32_bf16(af[i], bf[j], acc[i][j], 0, 0, 0);
    __syncthreads();
  }

  #pragma unroll
  for (int j = 0; j < 4; ++j) {
    const int n = n0 + wn * 64 + j * 16 + l15;
    const float bv = lin(bias, n, f32);
    #pragma unroll
    for (int i = 0; i < 4; ++i) {
      #pragma unroll
      for (int r = 0; r < 4; ++r) {
        const int m = m0 + wm * 64 + i * 16 + quad * 4 + r;
        float v = acc[i][j][r];
        if constexpr (MODE == M_BIAS) {
          v += bv;
        } else if constexpr (MODE == M_BIAS_RELU) {
          v = fmaxf(v + bv, 0.f);
        } else if constexpr (MODE == M_ADD2_BIAS_LEAKY) {
          const size_t ix = (size_t)m * Nn + n;
          const float ad = b2f(((const ushort*)addend)[ix]) + b2f(addend2[ix]);
          v = ad + v + bv;
          v = (v >= 0.f) ? v : 0.5f * v;
        } else {
          float ad;
          if constexpr (sizeof(ADT) == 4) ad = ((const float*)addend)[(size_t)m * Nn + n];
          else                            ad = b2f(((const ushort*)addend)[(size_t)m * Nn + n]);
          v = ad + v + bv;
          if constexpr (MODE == M_ADD_BIAS_ELU)   v = (v > 0.f) ? v : expm1f(v);
          else if constexpr (MODE == M_ADD_BIAS_LEAKY) v = (v >= 0.f) ? v : 0.5f * v;
        }
        if constexpr (sizeof(OT) == 4) ((float*)Cout)[(size_t)m * Nn + n] = v;
        else                           ((ushort*)Cout)[(size_t)m * Nn + n] = f2b(v);
      }
    }
  }
}

template<typename ADT, typename OT, int MODE>
static void launch_mgemm(const void* A, const void* Wt, const void* bias, const void* add,
                         void* Cout, int M, int K, int Nn, const int* dtf, hipStream_t stream,
                         const void* add2 = nullptr)
{
  dim3 grid(Nn / 128, M / 128);
  mgemm_kernel<ADT, OT, MODE><<<grid, dim3(256), 0, stream>>>(
      (const ushort*)A, (const ushort*)Wt, bias, (const ADT*)add, (const ushort*)add2,
      (OT*)Cout, M, K, Nn, dtf);
}

// ---------------- MFMA bf16 GEMM (64x64 tile) for N<=512 layers -------------
template<typename ADT, typename OT, int MODE>
__global__ __launch_bounds__(256) void mgemm64_kernel(
    const ushort* __restrict__ A, const ushort* __restrict__ Wt,
    const void* __restrict__ bias, const ADT* __restrict__ addend,
    const ushort* __restrict__ addend2,
    OT* __restrict__ Cout, int M, int K, int Nn, const int* __restrict__ dtf)
{
  const int f32 = *dtf;
  __shared__ __align__(16) ushort As[64][40];
  __shared__ __align__(16) ushort Bs[64][40];
  const int tid = threadIdx.x;
  const int m0 = blockIdx.y * 64, n0 = blockIdx.x * 64;
  const int wave = tid >> 6, lane = tid & 63;
  const int wm = wave & 1, wn = wave >> 1;
  const int quad = lane >> 4, l15 = lane & 15;

  f32x4 acc[2][2];
  #pragma unroll
  for (int i = 0; i < 2; ++i)
    #pragma unroll
    for (int j = 0; j < 2; ++j) acc[i][j] = (f32x4){0.f, 0.f, 0.f, 0.f};

  const int srow = tid >> 2, sseg = (tid & 3) * 8;
  const size_t a_base = (size_t)(m0 + srow) * K + sseg;
  const size_t b_base = (size_t)(n0 + srow) * K + sseg;

  for (int k0 = 0; k0 < K; k0 += 32) {
    *reinterpret_cast<float4*>(&As[srow][sseg]) =
        *reinterpret_cast<const float4*>(A + a_base + k0);
    *reinterpret_cast<float4*>(&Bs[srow][sseg]) =
        *reinterpret_cast<const float4*>(Wt + b_base + k0);
    __syncthreads();
    short8 af[2], bf[2];
    #pragma unroll
    for (int i = 0; i < 2; ++i) {
      af[i] = *reinterpret_cast<const short8*>(&As[wm * 32 + i * 16 + l15][quad * 8]);
      bf[i] = *reinterpret_cast<const short8*>(&Bs[wn * 32 + i * 16 + l15][quad * 8]);
    }
    #pragma unroll
    for (int i = 0; i < 2; ++i)
      #pragma unroll
      for (int j = 0; j < 2; ++j)
        acc[i][j] = __builtin_amdgcn_mfma_f32_16x16x32_bf16(af[i], bf[j], acc[i][j], 0, 0, 0);
    __syncthreads();
  }

  #pragma unroll
  for (int j = 0; j < 2; ++j) {
    const int n = n0 + wn * 32 + j * 16 + l15;
    const float bv = lin(bias, n, f32);
    #pragma unroll
    for (int i = 0; i < 2; ++i) {
      #pragma unroll
      for (int r = 0; r < 4; ++r) {
        const int m = m0 + wm * 32 + i * 16 + quad * 4 + r;
        float v = acc[i][j][r];
        if constexpr (MODE == M_BIAS) {
          v += bv;
        } else if constexpr (MODE == M_BIAS_RELU) {
          v = fmaxf(v + bv, 0.f);
        } else if constexpr (MODE == M_ADD2_BIAS_LEAKY) {
          const size_t ix = (size_t)m * Nn + n;
          const float ad = b2f(((const ushort*)addend)[ix]) + b2f(addend2[ix]);
          v = ad + v + bv;
          v = (v >= 0.f) ? v : 0.5f * v;
        } else {
          float ad;
          if constexpr (sizeof(ADT) == 4) ad = ((const float*)addend)[(size_t)m * Nn + n];
          else                            ad = b2f(((const ushort*)addend)[(size_t)m * Nn + n]);
          v = ad + v + bv;
          if constexpr (MODE == M_ADD_BIAS_ELU)   v = (v > 0.f) ? v : expm1f(v);
          else if constexpr (MODE == M_ADD_BIAS_LEAKY) v = (v >= 0.f) ? v : 0.5f * v;
        }
        if constexpr (sizeof(OT) == 4) ((float*)Cout)[(size_t)m * Nn + n] = v;
        else                           ((ushort*)Cout)[(size_t)m * Nn + n] = f2b(v);
      }
    }
  }
}

template<typename ADT, typename OT, int MODE>
static void launch_mgemm64(const void* A, const void* Wt, const void* bias, const void* add,
                           void* Cout, int M, int K, int Nn, const int* dtf, hipStream_t stream,
                           const void* add2 = nullptr)
{
  dim3 grid(Nn / 64, M / 64);
  mgemm64_kernel<ADT, OT, MODE><<<grid, dim3(256), 0, stream>>>(
      (const ushort*)A, (const ushort*)Wt, bias, (const ADT*)add, (const ushort*)add2,
      (OT*)Cout, M, K, Nn, dtf);
}

// ---------------- mgemm3: 64x64-tile hi/lo-split 3-MFMA GEMM ----------------
enum Epi3 { E3_RELU_PE = 0, E3_RELU_SPLIT = 1, E3_SPLIT = 2, E3_RELU_VT = 3 };

template<int EPI>
__global__ __launch_bounds__(256) void mgemm3_kernel(
    const ushort* __restrict__ Ah, const ushort* __restrict__ Al,
    const ushort* __restrict__ Bh, const ushort* __restrict__ Bl,
    const void* __restrict__ bias,
    ushort* __restrict__ Oh, ushort* __restrict__ Ol,
    int M, int K, int Nn, const int* __restrict__ dtf)
{
  const int f32 = *dtf;
  __shared__ __align__(16) ushort AsH[64][40];
  __shared__ __align__(16) ushort AsL[64][40];
  __shared__ __align__(16) ushort BsH[64][40];
  __shared__ __align__(16) ushort BsL[64][40];
  const int tid = threadIdx.x;
  const int m0 = blockIdx.y * 64, n0 = blockIdx.x * 64;
  const int wave = tid >> 6, lane = tid & 63;
  const int wm = wave & 1, wn = wave >> 1;
  const int quad = lane >> 4, l15 = lane & 15;

  f32x4 acc[2][2];
  #pragma unroll
  for (int i = 0; i < 2; ++i)
    #pragma unroll
    for (int j = 0; j < 2; ++j) acc[i][j] = (f32x4){0.f, 0.f, 0.f, 0.f};

  const int srow = tid >> 2, sseg = (tid & 3) * 8;
  const size_t a_base = (size_t)(m0 + srow) * K + sseg;
  const size_t b_base = (size_t)(n0 + srow) * K + sseg;

  for (int k0 = 0; k0 < K; k0 += 32) {
    *reinterpret_cast<float4*>(&AsH[srow][sseg]) =
        *reinterpret_cast<const float4*>(Ah + a_base + k0);
    *reinterpret_cast<float4*>(&AsL[srow][sseg]) =
        *reinterpret_cast<const float4*>(Al + a_base + k0);
    *reinterpret_cast<float4*>(&BsH[srow][sseg]) =
        *reinterpret_cast<const float4*>(Bh + b_base + k0);
    *reinterpret_cast<float4*>(&BsL[srow][sseg]) =
        *reinterpret_cast<const float4*>(Bl + b_base + k0);
    __syncthreads();
    short8 afh[2], afl[2], bfh[2], bfl[2];
    #pragma unroll
    for (int i = 0; i < 2; ++i) {
      afh[i] = *reinterpret_cast<const short8*>(&AsH[wm * 32 + i * 16 + l15][quad * 8]);
      afl[i] = *reinterpret_cast<const short8*>(&AsL[wm * 32 + i * 16 + l15][quad * 8]);
      bfh[i] = *reinterpret_cast<const short8*>(&BsH[wn * 32 + i * 16 + l15][quad * 8]);
      bfl[i] = *reinterpret_cast<const short8*>(&BsL[wn * 32 + i * 16 + l15][quad * 8]);
    }
    #pragma unroll
    for (int i = 0; i < 2; ++i)
      #pragma unroll
      for (int j = 0; j < 2; ++j) {
        acc[i][j] = __builtin_amdgcn_mfma_f32_16x16x32_bf16(afh[i], bfh[j], acc[i][j], 0, 0, 0);
        acc[i][j] = __builtin_amdgcn_mfma_f32_16x16x32_bf16(afh[i], bfl[j], acc[i][j], 0, 0, 0);
        acc[i][j] = __builtin_amdgcn_mfma_f32_16x16x32_bf16(afl[i], bfh[j], acc[i][j], 0, 0, 0);
      }
    __syncthreads();
  }

  #pragma unroll
  for (int j = 0; j < 2; ++j) {
    const int n = n0 + wn * 32 + j * 16 + l15;
    float bv = 0.f;
    if constexpr (EPI != E3_RELU_PE) bv = lin(bias, n, f32);
    #pragma unroll
    for (int i = 0; i < 2; ++i) {
      #pragma unroll
      for (int r = 0; r < 4; ++r) {
        const int m = m0 + wm * 32 + i * 16 + quad * 4 + r;
        float v = acc[i][j][r];
        if constexpr (EPI == E3_RELU_PE) {
          v = fmaxf(v, 0.f);
          const float freq = expf((float)(n & ~1) * (-0.017988946f)); // -ln(1e4)/512
          const float ang  = (float)(m & (CC - 1)) * freq;            // pos = c
          v += (n & 1) ? cosf(ang) : sinf(ang);
        } else if constexpr (EPI == E3_RELU_SPLIT || EPI == E3_RELU_VT) {
          v = fmaxf(v + bv, 0.f);
        } else {
          v = v + bv;
        }
        if constexpr (EPI == E3_RELU_VT) {
          // pre-transposed: vT[(lb*512 + n)][s] with lb = m>>9, s = m&511
          Oh[((size_t)((m >> 9) * 512 + n)) * 512 + (m & 511)] = f2b(v);
        } else {
          ushort hi, lo; split_bf(v, hi, lo);
          Oh[(size_t)m * Nn + n] = hi;
          Ol[(size_t)m * Nn + n] = lo;
        }
      }
    }
  }
}

template<int EPI>
static void launch_mgemm3(const void* Ahv, const void* Alv, const ushort* Bh,
                          const ushort* Bl, const void* bias, void* Oh, void* Ol,
                          int M, int K, int Nn, const int* dtf, hipStream_t stream)
{
  dim3 grid(Nn / 64, M / 64);
  mgemm3_kernel<EPI><<<grid, dim3(256), 0, stream>>>(
      (const ushort*)Ahv, (const ushort*)Alv, Bh, Bl, bias,
      (ushort*)Oh, (ushort*)Ol, M, K, Nn, dtf);
}

// ---------------- GAttn via MFMA: register scores + DPP top-k ---------------
__global__ __launch_bounds__(256, 2) void gattn_mfma(
    const ushort* __restrict__ qsh, const ushort* __restrict__ qsl,
    const ushort* __restrict__ ksh, const ushort* __restrict__ ksl,
    const ushort* __restrict__ vt, ushort* __restrict__ out)
{
  const int tid = threadIdx.x;
  const int wave = tid >> 6, lane = tid & 63;
  const int quad = lane >> 4, l15 = lane & 15;
  const int l0 = blockIdx.x * 16;
  const int h = blockIdx.y, bz = blockIdx.z;

  __shared__ __align__(16) ushort P[16][520];    // 16640 B (unnormalized bf16 weights)
  __shared__ float cand[16][40];                 // 2560 B (4 waves x sorted top-10)
  __shared__ float psum[16][4];                  // 256 B  (per-wave partial sums)

  // ---- Q fragments (hi/lo), kk-chunks 0,1 ----
  short8 ah[2], al[2];
  {
    const size_t qoff = ((size_t)bz * CC + l0 + l15) * DD + h * EE + quad * 8;
    ah[0] = *reinterpret_cast<const short8*>(qsh + qoff);
    ah[1] = *reinterpret_cast<const short8*>(qsh + qoff + 32);
    al[0] = *reinterpret_cast<const short8*>(qsl + qoff);
    al[1] = *reinterpret_cast<const short8*>(qsl + qoff + 32);
  }

  // ---- S phase into registers: sacc[c][r] = S[quad*4+r][c*64+wave*16+l15] --
  f32x4 sacc[8];
  {
    const size_t kbase = ((size_t)bz * CC + wave * 16 + l15) * DD + h * EE + quad * 8;
    #pragma unroll
    for (int c = 0; c < 8; ++c) {
      f32x4 acc = (f32x4){0.f, 0.f, 0.f, 0.f};
      #pragma unroll
      for (int kk = 0; kk < 2; ++kk) {
        const size_t off = kbase + (size_t)(c * 64) * DD + kk * 32;
        const short8 bh = *reinterpret_cast<const short8*>(ksh + off);
        const short8 bl = *reinterpret_cast<const short8*>(ksl + off);
        __builtin_amdgcn_s_setprio(1);
        acc = __builtin_amdgcn_mfma_f32_16x16x32_bf16(ah[kk], bh, acc, 0, 0, 0);
        acc = __builtin_amdgcn_mfma_f32_16x16x32_bf16(ah[kk], bl, acc, 0, 0, 0);
        acc = __builtin_amdgcn_mfma_f32_16x16x32_bf16(al[kk], bh, acc, 0, 0, 0);
        __builtin_amdgcn_s_setprio(0);
      }
      sacc[c] = acc;
    }
  }

  // ---- stage-1 top-k: each quad extracts its row's wave-local top-10 ----
  #pragma unroll
  for (int r = 0; r < 4; ++r) {
    float wk[8];
    #pragma unroll
    for (int c = 0; c < 8; ++c) wk[c] = sacc[c][r];
    float myg = 0.f;
    for (int it = 0; it < 10; ++it) {
      float lm = wk[0];
      #pragma unroll
      for (int c = 1; c < 8; ++c) lm = fmaxf(lm, wk[c]);
      const float gm = red16_max(lm);
      if (l15 == it) myg = gm;
      if (it < 9) {
        const unsigned long long msk = __ballot(lm == gm);
        const int sel = (__ffsll((unsigned long long)((msk >> (quad * 16)) & 0xFFFFull)) - 1)
                        + quad * 16;
        if (lane == sel) {
          #pragma unroll
          for (int c = 0; c < 8; ++c) { if (wk[c] == gm) { wk[c] = -FLT_MAX; break; } }
        }
      }
    }
    if (l15 < 10) cand[quad * 4 + r][wave * 10 + l15] = myg;
  }
  __syncthreads();

  // ---- merge 4 sorted lists of 10 -> global maxv + thr (10th) ----
  float mx, thr;
  {
    const int mr = lane & 15;
    float h0 = cand[mr][0], h1 = cand[mr][10], h2 = cand[mr][20], h3 = cand[mr][30];
    int i0 = 0, i1 = 0, i2 = 0, i3 = 0;
    float cur = 0.f;
    mx = 0.f;
    #pragma unroll
    for (int t = 0; t < 10; ++t) {
      cur = fmaxf(fmaxf(h0, h1), fmaxf(h2, h3));
      if (t == 0) mx = cur;
      if (t < 9) {
        const bool a0 = (cur == h0);
        const bool a1 = !a0 && (cur == h1);
        const bool a2 = !a0 && !a1 && (cur == h2);
        const int ni0 = i0 + (a0 ? 1 : 0);
        const int ni1 = i1 + (a1 ? 1 : 0);
        const int ni2 = i2 + (a2 ? 1 : 0);
        const int ni3 = i3 + ((a0 || a1 || a2) ? 0 : 1);
        const int off = a0 ? ni0 : (a1 ? 10 + ni1 : (a2 ? 20 + ni2 : 30 + ni3));
        const float nv = cand[mr][off];
        h0 = a0 ? nv : h0;
        h1 = a1 ? nv : h1;
        h2 = a2 ? nv : h2;
        h3 = (a0 || a1 || a2) ? h3 : nv;
        i0 = ni0; i1 = ni1; i2 = ni2; i3 = ni3;
      }
    }
    thr = cur;
  }
  // distribute row thr/max to the quad that owns the row
  float thrR[4], mxR[4];
  #pragma unroll
  for (int r = 0; r < 4; ++r) {
    thrR[r] = __shfl(thr, quad * 4 + r);
    mxR[r]  = __shfl(mx,  quad * 4 + r);
  }

  // ---- exp + partial sums + P write ----
  #pragma unroll
  for (int r = 0; r < 4; ++r) {
    const int Rr = quad * 4 + r;
    float s = 0.f;
    #pragma unroll
    for (int c = 0; c < 8; ++c) {
      const float sc = sacc[c][r];
      const float p = (sc >= thrR[r]) ? expf((sc - mxR[r]) * 0.125f) : 0.f;
      P[Rr][c * 64 + wave * 16 + l15] = f2b(p);
      s += p;
    }
    s = red16_sum(s);
    if (l15 == 0) psum[Rr][wave] = s;
  }
  __syncthreads();

  // ---- PV phase: wave w owns e-cols w*16..w*16+15; vT loaded direct ----
  f32x4 pacc = (f32x4){0.f, 0.f, 0.f, 0.f};
  const size_t vbase = ((size_t)bz * 512 + h * EE + wave * 16 + l15) * 512 + quad * 8;
  #pragma unroll
  for (int c = 0; c < 4; ++c) {
    #pragma unroll
    for (int ks = 0; ks < 4; ++ks) {
      const int s0 = c * 128 + ks * 32;
      const short8 pa = *reinterpret_cast<const short8*>(&P[l15][s0 + quad * 8]);
      const short8 vb = *reinterpret_cast<const short8*>(vt + vbase + s0);
      __builtin_amdgcn_s_setprio(1);
      pacc = __builtin_amdgcn_mfma_f32_16x16x32_bf16(pa, vb, pacc, 0, 0, 0);
      __builtin_amdgcn_s_setprio(0);
    }
  }

  // ---- epilogue ----
  #pragma unroll
  for (int r = 0; r < 4; ++r) {
    const int Rr = quad * 4 + r;
    const float4 ps = *reinterpret_cast<const float4*>(&psum[Rr][0]);
    const float inv = 1.f / (ps.x + ps.y + ps.z + ps.w);
    out[((size_t)bz * CC + l0 + Rr) * DD + h * EE + wave * 16 + l15] = f2b(pacc[r] * inv);
  }
}

// ---------------- GAttn fallback (fp32 path only) -----------
template<typename OT>
__global__ __launch_bounds__(256) void gattn_fb(
    const float* __restrict__ q, const float* __restrict__ k,
    const float* __restrict__ v, OT* __restrict__ out)
{
  const int tid = threadIdx.x;
  const int wave = tid >> 6, lane = tid & 63;
  const int l0 = blockIdx.x * 4;
  const int h = blockIdx.y, bz = blockIdx.z;
  const int l = l0 + wave;
  const size_t base = ((size_t)bz * CC) * DD + h * EE;

  __shared__ __align__(16) float kt[64][68];
  __shared__ __align__(16) float qs[4][64];
  __shared__ __align__(16) float ww[4][512];

  qs[wave][lane] = q[((size_t)bz * CC + l) * DD + h * EE + lane];

  float sc[8];
  const int sl = tid >> 4;
  const int e4 = (tid & 15) * 4;
  for (int c8 = 0; c8 < 8; ++c8) {
    #pragma unroll
    for (int r = 0; r < 4; ++r) {
      const int s_local = sl + r * 16;
      const float4 kv = *reinterpret_cast<const float4*>(
          k + base + (size_t)(c8 * 64 + s_local) * DD + e4);
      *reinterpret_cast<float4*>(&kt[s_local][e4]) = kv;
    }
    __syncthreads();
    float a = 0.f;
    #pragma unroll
    for (int e = 0; e < 16; ++e) {
      const float4 qv = *reinterpret_cast<const float4*>(&qs[wave][e * 4]);
      const float4 kv = *reinterpret_cast<const float4*>(&kt[lane][e * 4]);
      a += qv.x * kv.x + qv.y * kv.y + qv.z * kv.z + qv.w * kv.w;
    }
    sc[c8] = a;
    __syncthreads();
  }

  float wk[8];
  #pragma unroll
  for (int j = 0; j < 8; ++j) wk[j] = sc[j];
  float maxv = 0.f, thr = 0.f;
  for (int it = 0; it < 10; ++it) {
    float lm = wk[0];
    #pragma unroll
    for (int j = 1; j < 8; ++j) lm = fmaxf(lm, wk[j]);
    float gm = lm;
    #pragma unroll
    for (int off = 32; off > 0; off >>= 1) gm = fmaxf(gm, __shfl_xor(gm, off));
    if (it == 0) maxv = gm;
    if (it == 9) { thr = gm; break; }
    const unsigned long long msk = __ballot(lm == gm);
    if (lane == __ffsll(msk) - 1) {
      #pragma unroll
      for (int j = 0; j < 8; ++j) { if (wk[j] == gm) { wk[j] = -FLT_MAX; break; } }
    }
  }

  float lsum = 0.f;
  #pragma unroll
  for (int j = 0; j < 8; ++j) {
    const float p = (sc[j] >= thr) ? expf((sc[j] - maxv) * 0.125f) : 0.f;
    ww[wave][j * 64 + lane] = p;
    lsum += p;
  }
  #pragma unroll
  for (int off = 32; off > 0; off >>= 1) lsum += __shfl_xor(lsum, off);
  const float inv = 1.f / lsum;
  __syncthreads();

  float acc = 0.f;
  const float* vp = v + base + lane;
  const float* wp = ww[wave];
  for (int s = 0; s < 512; s += 4) {
    const float4 w4 = *reinterpret_cast<const float4*>(&wp[s]);
    acc = fmaf(w4.x, vp[(size_t)(s + 0) * DD], acc);
    acc = fmaf(w4.y, vp[(size_t)(s + 1) * DD], acc);
    acc = fmaf(w4.z, vp[(size_t)(s + 2) * DD], acc);
    acc = fmaf(w4.w, vp[(size_t)(s + 3) * DD], acc);
  }
  const float res = acc * inv;
  const size_t oi = ((size_t)bz * CC + l) * DD + h * EE + lane;
  if constexpr (sizeof(OT) == 4) out[oi] = res;
  else                           out[oi] = f2b(res);
}

// ---------------- pwattn1 via MFMA: one row per wave ----------------
__global__ __launch_bounds__(256) void pwattn1_mfma(
    const ushort* __restrict__ query, const float* __restrict__ k1,
    const float* __restrict__ v1, ushort* __restrict__ V1)
{
  const int tid = threadIdx.x;
  const int wave = tid >> 6, lane = tid & 63;
  const int quad = lane >> 4, l15 = lane & 15;
  const int n = blockIdx.x * 4 + wave;

  __shared__ __align__(16) ushort Pl[4][16][40];   // stride 80B (16B-aligned)

  const ushort* qrow = query + (size_t)n * DFF;
  const float*  krow = k1 + (size_t)n * 512;
  const float*  vrow = v1 + (size_t)n * 512;
  ushort* orow = V1 + (size_t)n * DFF;

  const short8 zz = {0, 0, 0, 0, 0, 0, 0, 0};
  const f32x4 zacc = (f32x4){0.f, 0.f, 0.f, 0.f};

  // B-frags for scores: col s = nt*16+l15, k = e = quad*8+i (valid e<16)
  short8 bh[2], bl[2];
  #pragma unroll
  for (int nt = 0; nt < 2; ++nt) {
    short8 hh = zz, ll = zz;
    if (quad < 2) {
      const float* kp = krow + (nt * 16 + l15) * 16 + quad * 8;
      #pragma unroll
      for (int i = 0; i < 8; ++i) {
        ushort hi_, lo_; split_bf(kp[i], hi_, lo_);
        hh[i] = (short)hi_; ll[i] = (short)lo_;
      }
    }
    bh[nt] = hh; bl[nt] = ll;
  }
  // B-frag for PV: v[k=s=quad*8+i][n=e=l15]
  short8 vb;
  #pragma unroll
  for (int i = 0; i < 8; ++i) vb[i] = (short)f2b(vrow[(quad * 8 + i) * 16 + l15]);

  #pragma unroll
  for (int mt = 0; mt < 8; ++mt) {
    short8 qa = zz;
    if (quad < 2)
      qa = *reinterpret_cast<const short8*>(qrow + (mt * 16 + l15) * 16 + quad * 8);
    f32x4 acc[2];
    #pragma unroll
    for (int nt = 0; nt < 2; ++nt) {
      f32x4 t = __builtin_amdgcn_mfma_f32_16x16x32_bf16(qa, bl[nt], zacc, 0, 0, 0);
      acc[nt] = __builtin_amdgcn_mfma_f32_16x16x32_bf16(qa, bh[nt], t, 0, 0, 0);
    }
    // softmax over 32 cols (2 nt x 16 lanes); rows quad*4+r
    float inv[4];
    #pragma unroll
    for (int r = 0; r < 4; ++r) {
      float m = red16_max(fmaxf(acc[0][r], acc[1][r]));
      const float p0 = expf((acc[0][r] - m) * 0.25f);
      const float p1 = expf((acc[1][r] - m) * 0.25f);
      acc[0][r] = p0; acc[1][r] = p1;
      const float s = red16_sum(p0 + p1);
      inv[r] = 1.f / s;
    }
    #pragma unroll
    for (int nt = 0; nt < 2; ++nt)
      #pragma unroll
      for (int r = 0; r < 4; ++r)
        Pl[wave][quad * 4 + r][nt * 16 + l15] = f2b(acc[nt][r]);
    const short8 pa = *reinterpret_cast<const short8*>(&Pl[wave][l15][quad * 8]);
    const f32x4 pv = __builtin_amdgcn_mfma_f32_16x16x32_bf16(pa, vb, zacc, 0, 0, 0);
    #pragma unroll
    for (int r = 0; r < 4; ++r)
      orow[(mt * 16 + quad * 4 + r) * 16 + l15] = f2b(pv[r] * inv[r]);
  }
}

// ---------------- pwattn2 via MFMA: one row per wave ----------------
__global__ __launch_bounds__(256) void pwattn2_mfma(
    const float* __restrict__ query2, const ushort* __restrict__ k2,
    const ushort* __restrict__ v2, ushort* __restrict__ V2)
{
  const int tid = threadIdx.x;
  const int wave = tid >> 6, lane = tid & 63;
  const int quad = lane >> 4, l15 = lane & 15;
  const int n = blockIdx.x * 4 + wave;

  __shared__ __align__(16) ushort Pl[4][16][136];  // stride 272B (16B-aligned)

  const float*  qrow = query2 + (size_t)n * 512;
  const ushort* krow = k2 + (size_t)n * DFF;
  const ushort* vrow = v2 + (size_t)n * DFF;
  ushort* orow = V2 + (size_t)n * 512;

  const short8 zz = {0, 0, 0, 0, 0, 0, 0, 0};
  const f32x4 zacc = (f32x4){0.f, 0.f, 0.f, 0.f};

  // B-frags for scores: col s = nt*16+l15 (8 nt), k = e = quad*8+i (<16)
  short8 kb[8];
  #pragma unroll
  for (int nt = 0; nt < 8; ++nt)
    kb[nt] = (quad < 2)
        ? *reinterpret_cast<const short8*>(krow + (nt * 16 + l15) * 16 + quad * 8)
        : zz;

  // B-frags for PV: v[k=s=kt*32+quad*8+i][n=e=l15]
  short8 vb[4];
  #pragma unroll
  for (int kt = 0; kt < 4; ++kt)
    #pragma unroll
    for (int i = 0; i < 8; ++i)
      vb[kt][i] = (short)vrow[(kt * 32 + quad * 8 + i) * 16 + l15];

  #pragma unroll
  for (int mt = 0; mt < 2; ++mt) {
    // A hi/lo: q[m=mt*16+l15][k=quad*8+i (<16)]
    short8 ahh = zz, all_ = zz;
    if (quad < 2) {
      const float* qp = qrow + (mt * 16 + l15) * 16 + quad * 8;
      #pragma unroll
      for (int i = 0; i < 8; ++i) {
        ushort hi_, lo_; split_bf(qp[i], hi_, lo_);
        ahh[i] = (short)hi_; all_[i] = (short)lo_;
      }
    }
    f32x4 acc[8];
    #pragma unroll
    for (int nt = 0; nt < 8; ++nt) {
      f32x4 t = __builtin_amdgcn_mfma_f32_16x16x32_bf16(all_, kb[nt], zacc, 0, 0, 0);
      acc[nt] = __builtin_amdgcn_mfma_f32_16x16x32_bf16(ahh, kb[nt], t, 0, 0, 0);
    }
    // softmax over 128 cols (8 nt x 16 lanes); rows quad*4+r
    float inv[4];
    #pragma unroll
    for (int r = 0; r < 4; ++r) {
      float m = acc[0][r];
      #pragma unroll
      for (int nt = 1; nt < 8; ++nt) m = fmaxf(m, acc[nt][r]);
      m = red16_max(m);
      float s = 0.f;
      #pragma unroll
      for (int nt = 0; nt < 8; ++nt) {
        const float p = expf((acc[nt][r] - m) * 0.25f);
        acc[nt][r] = p; s += p;
      }
      s = red16_sum(s);
      inv[r] = 1.f / s;
    }
    #pragma unroll
    for (int nt = 0; nt < 8; ++nt)
      #pragma unroll
      for (int r = 0; r < 4; ++r)
        Pl[wave][quad * 4 + r][nt * 16 + l15] = f2b(acc[nt][r]);
    f32x4 pv = zacc;
    #pragma unroll
    for (int kt = 0; kt < 4; ++kt) {
      const short8 pa = *reinterpret_cast<const short8*>(&Pl[wave][l15][kt * 32 + quad * 8]);
      pv = __builtin_amdgcn_mfma_f32_16x16x32_bf16(pa, vb[kt], pv, 0, 0, 0);
    }
    #pragma unroll
    for (int r = 0; r < 4; ++r)
      orow[(mt * 16 + quad * 4 + r) * 16 + l15] = f2b(pv[r] * inv[r]);
  }
}

// ---------------- pwattn1 (fallback) ----------------
__global__ __launch_bounds__(128) void pwattn1_kernel(
    const ushort* __restrict__ query, const float* __restrict__ k1,
    const float* __restrict__ v1, ushort* __restrict__ V1)
{
  const int n = blockIdx.x, tid = threadIdx.x;
  __shared__ float ks[512], vs[512];
  __shared__ float Am[128][33];
  for (int i = tid; i < 512; i += 128) { ks[i] = k1[(size_t)n * 512 + i]; vs[i] = v1[(size_t)n * 512 + i]; }
  __syncthreads();
  {
    const int l = tid;
    float qv[16];
    const ushort* qp = query + (size_t)n * DFF + l * 16;
    #pragma unroll
    for (int e = 0; e < 16; ++e) qv[e] = b2f(qp[e]);
    float scl[32], mx = -FLT_MAX;
    #pragma unroll
    for (int s = 0; s < 32; ++s) {
      float a = 0.f;
      #pragma unroll
      for (int e = 0; e < 16; ++e) a += qv[e] * ks[s * 16 + e];
      scl[s] = a; mx = fmaxf(mx, a);
    }
    float sum = 0.f;
    #pragma unroll
    for (int s = 0; s < 32; ++s) { const float p = expf((scl[s] - mx) * 0.25f); scl[s] = p; sum += p; }
    const float invs = 1.f / sum;
    #pragma unroll
    for (int s = 0; s < 32; ++s) Am[l][s] = scl[s] * invs;
  }
  __syncthreads();
  #pragma unroll
  for (int r = 0; r < 16; ++r) {
    const int idx = tid + 128 * r;
    const int l = idx >> 4, e = idx & 15;
    float a = 0.f;
    #pragma unroll
    for (int s = 0; s < 32; ++s) a += Am[l][s] * vs[s * 16 + e];
    V1[(size_t)n * DFF + idx] = f2b(a);
  }
}

// ---------------- LayerNorm over 2048, in-place bf16 ----------------
__global__ __launch_bounds__(256) void ln_kernel(
    ushort* __restrict__ h, const void* __restrict__ g, const void* __restrict__ bt,
    const int* __restrict__ dtf)
{
  const int f32 = *dtf;
  const int n = blockIdx.x, tid = threadIdx.x;
  ushort* hp = h + (size_t)n * DFF;
  float x[8]; float s = 0.f, s2 = 0.f;
  #pragma unroll
  for (int i = 0; i < 8; ++i) {
    const float xv = b2f(hp[tid + 256 * i]);
    x[i] = xv; s += xv; s2 += xv * xv;
  }
  __shared__ float rs[256], rq[256];
  rs[tid] = s; rq[tid] = s2;
  __syncthreads();
  for (int off = 128; off > 0; off >>= 1) {
    if (tid < off) { rs[tid] += rs[tid + off]; rq[tid] += rq[tid + off]; }
    __syncthreads();
  }
  const float mu  = rs[0] * (1.f / DFF);
  const float var = rq[0] * (1.f / DFF) - mu * mu;
  const float inv = rsqrtf(var + 1e-5f);
  #pragma unroll
  for (int i = 0; i < 8; ++i) {
    const int d = tid + 256 * i;
    hp[d] = f2b((x[i] - mu) * inv * lin(g, d, f32) + lin(bt, d, f32));
  }
}

// ---------------- pwattn2 (fallback), templated output -----------
template<typename OT>
__global__ __launch_bounds__(128) void pwattn2_kernel(
    const float* __restrict__ query2, const ushort* __restrict__ k2,
    const ushort* __restrict__ v2, OT* __restrict__ V2)
{
  const int n = blockIdx.x, tid = threadIdx.x;
  __shared__ float ks[2048], vs[2048];
  __shared__ float Am[32][129];
  for (int i = tid; i < 2048; i += 128) {
    ks[i] = b2f(k2[(size_t)n * DFF + i]);
    vs[i] = b2f(v2[(size_t)n * DFF + i]);
  }
  __syncthreads();
  if (tid < 32) {
    const int l = tid;
    float qv[16];
    #pragma unroll
    for (int e = 0; e < 16; ++e) qv[e] = query2[(size_t)n * 512 + l * 16 + e];
    float mx = -FLT_MAX;
    for (int s = 0; s < 128; ++s) {
      float a = 0.f;
      #pragma unroll
      for (int e = 0; e < 16; ++e) a += qv[e] * ks[s * 16 + e];
      Am[l][s] = a; mx = fmaxf(mx, a);
    }
    float sum = 0.f;
    for (int s = 0; s < 128; ++s) { const float p = expf((Am[l][s] - mx) * 0.25f); Am[l][s] = p; sum += p; }
    const float invs = 1.f / sum;
    for (int s = 0; s < 128; ++s) Am[l][s] *= invs;
  }
  __syncthreads();
  #pragma unroll
  for (int r = 0; r < 4; ++r) {
    const int idx = tid + 128 * r;
    const int l = idx >> 4, e = idx & 15;
    float a = 0.f;
    for (int s = 0; s < 128; ++s) a += Am[l][s] * vs[s * 16 + e];
    if constexpr (sizeof(OT) == 4) V2[(size_t)n * 512 + idx] = a;
    else                           V2[(size_t)n * 512 + idx] = f2b(a);
  }
}

// ---------------- final: dec = y@fc_w + fc_b; out = dec*std+mean -----------
__global__ __launch_bounds__(128) void final_kernel(
    const float* __restrict__ y, const void* __restrict__ fc_w,
    const void* __restrict__ fc_b, const float* __restrict__ meanb,
    const float* __restrict__ stdb, void* __restrict__ out, int row_base,
    const int* __restrict__ dtf)
{
  const int f32 = *dtf;
  const int row = row_base + blockIdx.x;
  const int b = row >> 9, c = row & 511;
  const int tid = threadIdx.x;
  __shared__ float yr[512];
  for (int i = tid; i < 512; i += 128) yr[i] = y[(size_t)blockIdx.x * 512 + i];
  __syncthreads();
  if (tid < PRED) {
    float a = 0.f;
    for (int d = 0; d < 512; ++d) a += yr[d] * lin(fc_w, d * PRED + tid, f32);
    a += lin(fc_b, tid, f32);
    const float r = a * stdb[row] + meanb[row];
    const size_t oi = ((size_t)b * PRED + tid) * CC + c;
    if (f32) ((float*)out)[oi] = r;
    else     ((ushort*)out)[oi] = f2b(r);
  }
}

// ---------------------------------------------------------------------------
extern "C" void kernel_launch(void* const* d_in, const int* in_sizes, int n_in,
                              void* d_out, int out_size, void* d_ws, size_t ws_size,
                              hipStream_t stream)
{
  (void)in_sizes; (void)n_in; (void)out_size;
  const void* x_enc   = d_in[0];
  const void* embed_w = d_in[4];
  const void* q_w = d_in[5],  * q_b = d_in[6];
  const void* k_w = d_in[7],  * k_b = d_in[8];
  const void* v_w = d_in[9],  * v_b = d_in[10];
  const void* o_w = d_in[11], * o_b = d_in[12];
  const void* enc_w = d_in[13], * enc_b = d_in[14];
  const void* f1q_w = d_in[15], * f1q_b = d_in[16];
  const void* f1k_w = d_in[17], * f1k_b = d_in[18];
  const void* f1v_w = d_in[19], * f1v_b = d_in[20];
  const void* f1o_w = d_in[21], * f1o_b = d_in[22];
  const void* f2q_w = d_in[23], * f2q_b = d_in[24];
  const void* f2k_w = d_in[25], * f2k_b = d_in[26];
  const void* f2v_w = d_in[27], * f2v_b = d_in[28];
  const void* f2o_w = d_in[29], * f2o_b = d_in[30];
  const void* ln_g  = d_in[31], * ln_b  = d_in[32];
  const void* fc_w  = d_in[33], * fc_b  = d_in[34];

  const size_t HDR = 131072 + 1024;
  const size_t E_F1Q = 512ull * 2048, E_F1O = 2048ull * 2048, E_F2Q = 2048ull * 512;
  const size_t E_F2K = 2048ull * 2048, E_F2V = 2048ull * 2048, E_F2O = 512ull * 512;
  const size_t E_SQ  = 512ull * 512;   // o_w, enc_w, f1k_w, f1v_w each
  // + 8 split arrays (embed/q/k/v hi+lo)
  const size_t WT_EL = E_F1Q + E_F1O + E_F2Q + E_F2K + E_F2V + E_F2O + 4 * E_SQ + 8 * E_SQ;
  const size_t WT_BYTES = WT_EL * 2;   // ~34.5 MB
  const size_t PB_MFMA = 4ull * 512 * 512 * 4 + 3ull * 512 * DFF * 2; // 10.0MB
  const size_t PB_FB   = 5ull * 512 * 512 * 4 + 3ull * 512 * DFF * 2; // 11.0MB

  const int use_mfma = (HDR + WT_BYTES + PB_MFMA <= ws_size) ? 1 : 0;
  const size_t PER_BATCH = use_mfma ? PB_MFMA : PB_FB;
  const size_t FIXED = HDR + (use_mfma ? WT_BYTES : 0);
  int BPC = 1;
  for (int c = 8; c >= 1; c >>= 1) {
    if (FIXED + (size_t)c * PER_BATCH <= ws_size) { BPC = c; break; }
  }
  const int R = BPC * 512;

  char* ws = (char*)d_ws;
  float* meanb = (float*)ws;
  float* stdb  = (float*)(ws + 65536);
  int*   dtf   = (int*)(ws + 131072);
  ushort* wt_base = (ushort*)(ws + HDR);
  ushort* wt_f1q = wt_base;
  ushort* wt_f1o = wt_f1q + E_F1Q;
  ushort* wt_f2q = wt_f1o + E_F1O;
  ushort* wt_f2k = wt_f2q + E_F2Q;
  ushort* wt_f2v = wt_f2k + E_F2K;
  ushort* wt_f2o = wt_f2v + E_F2V;
  ushort* wt_o   = wt_f2o + E_F2O;
  ushort* wt_enc = wt_o   + E_SQ;
  ushort* wt_f1k = wt_enc + E_SQ;
  ushort* wt_f1v = wt_f1k + E_SQ;
  ushort* wt_embh = wt_f1v + E_SQ;
  ushort* wt_embl = wt_embh + E_SQ;
  ushort* wt_qh   = wt_embl + E_SQ;
  ushort* wt_ql   = wt_qh   + E_SQ;
  ushort* wt_kh   = wt_ql   + E_SQ;
  ushort* wt_kl   = wt_kh   + E_SQ;
  ushort* wt_vh   = wt_kl   + E_SQ;
  ushort* wt_vl   = wt_vh   + E_SQ;

  char* arena = ws + FIXED;
  const size_t FSL = (size_t)R * 512 * 4;
  const size_t GSL = (size_t)R * DFF * 2;
  void* A_ = arena;
  void* B_ = arena + FSL;
  void* C_ = arena + 2 * FSL;
  void* D_ = arena + 3 * FSL;
  void* E_ = arena + 4 * FSL;                     // fallback path only
  char* gb = arena + (size_t)(use_mfma ? 4 : 5) * FSL;
  void* G1 = gb;
  void* G2 = gb + GSL;
  void* G3 = gb + 2 * GSL;

  // mfma-path split buffers
  ushort* xTh  = (ushort*)G1; ushort* xTl  = xTh  + (size_t)R * 512; // in G1 (dead before f1q)
  ushort* embh = (ushort*)G2; ushort* embl = embh + (size_t)R * 512; // in G2 (dead before pwattn1)
  ushort* qsh  = (ushort*)C_; ushort* qsl  = qsh  + (size_t)R * 512;
  ushort* ksh  = (ushort*)D_; ushort* ksl  = ksh  + (size_t)R * 512;
  ushort* vt   = (ushort*)B_;                                        // vT, dead before f1v

  detect_dtype<<<1, 256, 0, stream>>>((const ushort*)x_enc, dtf);
  // two-phase instance-norm stats; partials live in the (still idle) arena
  instnorm_partial<<<dim3(2, NB, 8), 256, 0, stream>>>(
      x_enc, (float*)A_, (float*)B_, dtf);
  instnorm_reduce<<<dim3(2, NB), 256, 0, stream>>>(
      (const float*)A_, (const float*)B_, meanb, stdb);

  if (use_mfma) {   // one-time weight convert+transpose (KxN -> bf16 NxK)
    transpose_w<<<dim3(DFF / 32, 512 / 32), 256, 0, stream>>>(f1q_w, wt_f1q, 512, DFF, dtf);
    transpose_w<<<dim3(DFF / 32, DFF / 32), 256, 0, stream>>>(f1o_w, wt_f1o, DFF, DFF, dtf);
    transpose_w<<<dim3(512 / 32, DFF / 32), 256, 0, stream>>>(f2q_w, wt_f2q, DFF, 512, dtf);
    transpose_w<<<dim3(DFF / 32, DFF / 32), 256, 0, stream>>>(f2k_w, wt_f2k, DFF, DFF, dtf);
    transpose_w<<<dim3(DFF / 32, DFF / 32), 256, 0, stream>>>(f2v_w, wt_f2v, DFF, DFF, dtf);
    transpose_w<<<dim3(512 / 32, 512 / 32), 256, 0, stream>>>(f2o_w, wt_f2o, 512, 512, dtf);
    transpose_w<<<dim3(512 / 32, 512 / 32), 256, 0, stream>>>(o_w,   wt_o,   512, 512, dtf);
    transpose_w<<<dim3(512 / 32, 512 / 32), 256, 0, stream>>>(enc_w, wt_enc, 512, 512, dtf);
    transpose_w<<<dim3(512 / 32, 512 / 32), 256, 0, stream>>>(f1k_w, wt_f1k, 512, 512, dtf);
    transpose_w<<<dim3(512 / 32, 512 / 32), 256, 0, stream>>>(f1v_w, wt_f1v, 512, 512, dtf);
    transpose_w_split<<<dim3(512 / 32, 512 / 32), 256, 0, stream>>>(embed_w, wt_embh, wt_embl, 512, 512, dtf);
    transpose_w_split<<<dim3(512 / 32, 512 / 32), 256, 0, stream>>>(q_w, wt_qh, wt_ql, 512, 512, dtf);
    transpose_w_split<<<dim3(512 / 32, 512 / 32), 256, 0, stream>>>(k_w, wt_kh, wt_kl, 512, 512, dtf);
    transpose_w_split<<<dim3(512 / 32, 512 / 32), 256, 0, stream>>>(v_w, wt_vh, wt_vl, 512, 512, dtf);
  }

  for (int bc = 0; bc < NB / BPC; ++bc) {
    const int b0 = bc * BPC;
    if (use_mfma) {
      // --- stage 1: split-MFMA GEMMs ---
      norm_transpose_split<<<dim3(16, 16, BPC), 256, 0, stream>>>(
          x_enc, meanb, stdb, xTh, xTl, b0, dtf);
      launch_mgemm3<E3_RELU_PE>(xTh, xTl, wt_embh, wt_embl, nullptr,
                                embh, embl, R, 512, 512, dtf, stream);         // emb hi/lo
      launch_mgemm3<E3_RELU_SPLIT>(embh, embl, wt_qh, wt_ql, q_b,
                                   qsh, qsl, R, 512, 512, dtf, stream);        // q hi/lo
      launch_mgemm3<E3_SPLIT>(embh, embl, wt_kh, wt_kl, k_b,
                              ksh, ksl, R, 512, 512, dtf, stream);             // k hi/lo
      launch_mgemm3<E3_RELU_VT>(embh, embl, wt_vh, wt_vl, v_b,
                                vt, nullptr, R, 512, 512, dtf, stream);        // vT bf16
      gattn_mfma<<<dim3(CC / 16, HH, BPC), 256, 0, stream>>>(
          qsh, qsl, ksh, ksl, vt, (ushort*)A_);                                // attn bf16
      launch_mgemm64<ushort, ushort, M_ADD2_BIAS_LEAKY>(
          A_, wt_o, o_b, embh, C_, R, 512, 512, dtf, stream, embl);            // y bf16
      launch_mgemm64<float, ushort, M_BIAS>(C_, wt_enc, enc_b, nullptr, D_, R, 512, 512, dtf, stream);  // X1 bf16
      // --- stage 2: pwattn1 + LN ---
      launch_mgemm<float, ushort, M_BIAS_RELU>(D_, wt_f1q, f1q_b, nullptr, G1, R, 512, DFF, dtf, stream); // query1
      launch_mgemm64<float, float, M_BIAS     >(D_, wt_f1k, f1k_b, nullptr, A_, R, 512, 512, dtf, stream); // k1 f32
      launch_mgemm64<float, float, M_BIAS_RELU>(D_, wt_f1v, f1v_b, nullptr, B_, R, 512, 512, dtf, stream); // v1 f32
      pwattn1_mfma<<<R / 4, 256, 0, stream>>>(
          (const ushort*)G1, (const float*)A_, (const float*)B_, (ushort*)G2);
      launch_mgemm<ushort, ushort, M_ADD_BIAS_ELU>(G2, wt_f1o, f1o_b, G1, G1, R, DFF, DFF, dtf, stream);  // h
      ln_kernel<<<R, 256, 0, stream>>>((ushort*)G1, ln_g, ln_b, dtf);
      // --- stage 3: pwattn2 + out ---
      launch_mgemm64<float, float, M_BIAS_RELU>(G1, wt_f2q, f2q_b, nullptr, A_, R, DFF, 512, dtf, stream); // query2
      launch_mgemm<float, ushort, M_BIAS     >(G1, wt_f2k, f2k_b, nullptr, G2, R, DFF, DFF, dtf, stream); // k2
      launch_mgemm<float, ushort, M_BIAS_RELU>(G1, wt_f2v, f2v_b, nullptr, G3, R, DFF, DFF, dtf, stream); // v2
      pwattn2_mfma<<<R / 4, 256, 0, stream>>>(
          (const float*)A_, (const ushort*)G2, (const ushort*)G3, (ushort*)B_);
      launch_mgemm64<float, float, M_ADD_BIAS>(B_, wt_f2o, f2o_b, A_, C_, R, 512, 512, dtf, stream);      // y2
    } else {
      norm_transpose<<<dim3(16, 16, BPC), 256, 0, stream>>>(x_enc, meanb, stdb, (float*)A_, b0, dtf);
      launch_gemm<float, float, float, M_RELU_PE >(A_, embed_w, nullptr, nullptr, B_, R, 512, 512, dtf, stream);
      launch_gemm<float, float, float, M_BIAS_RELU>(B_, q_w, q_b, nullptr, C_, R, 512, 512, dtf, stream);
      launch_gemm<float, float, float, M_BIAS     >(B_, k_w, k_b, nullptr, D_, R, 512, 512, dtf, stream);
      launch_gemm<float, float, float, M_BIAS_RELU>(B_, v_w, v_b, nullptr, E_, R, 512, 512, dtf, stream);
      gattn_fb<float><<<dim3(CC / 4, HH, BPC), 256, 0, stream>>>(
          (float*)C_, (float*)D_, (float*)E_, (float*)A_);
      launch_gemm<float, float, float, M_ADD_BIAS_LEAKY>(A_, o_w, o_b, B_, C_, R, 512, 512, dtf, stream);
      launch_gemm<float, float, float, M_BIAS>(C_, enc_w, enc_b, nullptr, D_, R, 512, 512, dtf, stream);
      launch_gemm<float, float, ushort, M_BIAS_RELU>(D_, f1q_w, f1q_b, nullptr, G1, R, 512, DFF, dtf, stream);
      launch_gemm<float, float, float,  M_BIAS     >(D_, f1k_w, f1k_b, nullptr, A_, R, 512, 512, dtf, stream);
      launch_gemm<float, float, float,  M_BIAS_RELU>(D_, f1v_w, f1v_b, nullptr, B_, R, 512, 512, dtf, stream);
      pwattn1_kernel<<<R, 128, 0, stream>>>((const ushort*)G1, (const float*)A_, (const float*)B_, (ushort*)G2);
      launch_gemm<ushort, ushort, ushort, M_ADD_BIAS_ELU>(G2, f1o_w, f1o_b, G1, G1, R, DFF, DFF, dtf, stream);
      ln_kernel<<<R, 256, 0, stream>>>((ushort*)G1, ln_g, ln_b, dtf);
      launch_gemm<ushort, float, float,  M_BIAS_RELU>(G1, f2q_w, f2q_b, nullptr, A_, R, DFF, 512, dtf, stream);
      launch_gemm<ushort, float, ushort, M_BIAS     >(G1, f2k_w, f2k_b, nullptr, G2, R, DFF, DFF, dtf, stream);
      launch_gemm<ushort, float, ushort, M_BIAS_RELU>(G1, f2v_w, f2v_b, nullptr, G3, R, DFF, DFF, dtf, stream);
      pwattn2_kernel<float><<<R, 128, 0, stream>>>((const float*)A_, (const ushort*)G2, (const ushort*)G3, (float*)B_);
      launch_gemm<float, float, float, M_ADD_BIAS>(B_, f2o_w, f2o_b, A_, C_, R, 512, 512, dtf, stream);
    }
    final_kernel<<<R, 128, 0, stream>>>((const float*)C_, fc_w, fc_b, meanb, stdb, d_out, b0 * 512, dtf);
  }
}

// Round 6
// 2419.638 us; speedup vs baseline: 1.1870x; 1.0420x over previous
//
#include <hip/hip_runtime.h>
#include <float.h>
#include <math.h>
#include <stdint.h>

// ---------------------------------------------------------------------------
// Model_33062658245168: Informer-style time-series model. fp32 in/out
// (runtime-detected; bf16 fallback kept). B=32 S=512 C=512 D=512 DF=2048 H=8
// E=64 P=16 PRED=96 K(topk)=10, N=16384.
//
// Round 17: gattn S-phase prefetch + fast exp2.
//  - gattn VGPR=36 => compiler serialized K-frag load->MFMA per chunk
//    (exposed L2 latency x16/wave). Explicit 2-stage pipeline: chunk c+1's
//    4 fragments loaded into named regs before chunk c's 6 MFMAs.
//  - expf -> __builtin_amdgcn_exp2f (1 v_exp_f32, arg pre-scaled by log2e)
//    in gattn/pwattn1/pwattn2; expm1f -> exp2-1 in mgemm ELU epilogues.
//    Inputs bounded; abs err ~1e-7 << 0.0078 tolerance.
//  - everything else byte-frozen at the round-16 state (2521us).
// ---------------------------------------------------------------------------

#define NB   32
#define SS   512
#define CC   512
#define DD   512
#define DFF  2048
#define HH   8
#define EE   64
#define PRED 96

typedef __attribute__((ext_vector_type(8))) short short8;
typedef __attribute__((ext_vector_type(4))) float f32x4;

#define LOG2E 1.4426950408889634f

__device__ __forceinline__ float b2f(ushort u) {
  union { float f; uint32_t i; } c; c.i = ((uint32_t)u) << 16; return c.f;
}
__device__ __forceinline__ ushort f2b(float f) {
  union { float f; uint32_t i; } c; c.f = f;
  uint32_t x = c.i;
  return (ushort)((x + 0x7fffu + ((x >> 16) & 1u)) >> 16);   // RNE
}
__device__ __forceinline__ float lin(const void* p, size_t i, int f32) {
  return f32 ? ((const float*)p)[i] : b2f(((const ushort*)p)[i]);
}
__device__ __forceinline__ void split_bf(float x, ushort& hi, ushort& lo) {
  hi = f2b(x);
  lo = f2b(x - b2f(hi));
}

// ---- DPP 16-lane all-reduce (VALU only) ----
template<int CTRL>
__device__ __forceinline__ float dppmov(float x) {
  union { float f; int i; } a, b;
  a.f = x;
  b.i = __builtin_amdgcn_update_dpp(a.i, a.i, CTRL, 0xF, 0xF, false);
  return b.f;
}
__device__ __forceinline__ float red16_max(float x) {
  x = fmaxf(x, dppmov<0xB1>(x));    // quad_perm xor1
  x = fmaxf(x, dppmov<0x4E>(x));    // quad_perm xor2
  x = fmaxf(x, dppmov<0x141>(x));   // row_half_mirror
  x = fmaxf(x, dppmov<0x140>(x));   // row_mirror
  return x;
}
__device__ __forceinline__ float red16_sum(float x) {
  x += dppmov<0xB1>(x);
  x += dppmov<0x4E>(x);
  x += dppmov<0x141>(x);
  x += dppmov<0x140>(x);
  return x;
}

// ---------------- dtype detection (1 = fp32 inputs) ----------------
__global__ __launch_bounds__(256) void detect_dtype(
    const ushort* __restrict__ x, int* __restrict__ flag)
{
  __shared__ float red[256];
  const int t = threadIdx.x;
  float v = fabsf(b2f(x[2 * t]));
  if (!(v < 1e30f)) v = 1e30f;
  red[t] = v;
  __syncthreads();
  for (int off = 128; off > 0; off >>= 1) {
    if (t < off) red[t] = fmaxf(red[t], red[t + off]);
    __syncthreads();
  }
  if (t == 0) flag[0] = (red[0] > 1e6f) ? 1 : 0;
}

// ---------------- instance norm stats, two-phase ----------------
__global__ __launch_bounds__(256) void instnorm_partial(
    const void* __restrict__ x, float* __restrict__ ps, float* __restrict__ pq,
    const int* __restrict__ dtf)
{
  const int f32 = *dtf;
  const int c = blockIdx.x * 256 + threadIdx.x;
  const int b = blockIdx.y;
  const int t0 = blockIdx.z * 64;
  float s = 0.f, s2 = 0.f;
  for (int t = t0; t < t0 + 64; ++t) {
    const float xv = lin(x, ((size_t)(b * SS) + t) * CC + c, f32);
    s += xv; s2 += xv * xv;
  }
  const int pidx = (b * 8 + blockIdx.z) * CC + c;
  ps[pidx] = s; pq[pidx] = s2;
}

__global__ __launch_bounds__(256) void instnorm_reduce(
    const float* __restrict__ ps, const float* __restrict__ pq,
    float* __restrict__ meanb, float* __restrict__ stdb)
{
  const int c = blockIdx.x * 256 + threadIdx.x;
  const int b = blockIdx.y;
  float s = 0.f, s2 = 0.f;
  #pragma unroll
  for (int i = 0; i < 8; ++i) {
    s  += ps[(b * 8 + i) * CC + c];
    s2 += pq[(b * 8 + i) * CC + c];
  }
  const float mu  = s * (1.f / SS);
  const float var = s2 * (1.f / SS) - mu * mu;
  meanb[b * CC + c] = mu;
  stdb [b * CC + c] = sqrtf(var + 1e-5f);
}

// ---------------- normalize + transpose one chunk (fp32, fallback) ---------
__global__ __launch_bounds__(256) void norm_transpose(
    const void* __restrict__ x, const float* __restrict__ meanb,
    const float* __restrict__ stdb, float* __restrict__ xTc, int b_base,
    const int* __restrict__ dtf)
{
  const int f32 = *dtf;
  __shared__ float t[32][33];
  const int s0 = blockIdx.x * 32, c0 = blockIdx.y * 32, lb = blockIdx.z;
  const int b = b_base + lb;
  const int tx = threadIdx.x & 31, ty = threadIdx.x >> 5;
  #pragma unroll
  for (int i = 0; i < 4; ++i) {
    const int s = s0 + ty + i * 8;
    t[ty + i * 8][tx] = lin(x, ((size_t)(b * SS) + s) * CC + c0 + tx, f32);
  }
  __syncthreads();
  #pragma unroll
  for (int i = 0; i < 4; ++i) {
    const int c = c0 + ty + i * 8;
    const float mu = meanb[b * CC + c], sd = stdb[b * CC + c];
    xTc[((size_t)(lb * CC) + c) * SS + s0 + tx] = (t[tx][ty + i * 8] - mu) / sd;
  }
}

// ---------------- normalize + transpose, hi/lo split output ----------------
__global__ __launch_bounds__(256) void norm_transpose_split(
    const void* __restrict__ x, const float* __restrict__ meanb,
    const float* __restrict__ stdb, ushort* __restrict__ xh,
    ushort* __restrict__ xl, int b_base, const int* __restrict__ dtf)
{
  const int f32 = *dtf;
  __shared__ float t[32][33];
  const int s0 = blockIdx.x * 32, c0 = blockIdx.y * 32, lb = blockIdx.z;
  const int b = b_base + lb;
  const int tx = threadIdx.x & 31, ty = threadIdx.x >> 5;
  #pragma unroll
  for (int i = 0; i < 4; ++i) {
    const int s = s0 + ty + i * 8;
    t[ty + i * 8][tx] = lin(x, ((size_t)(b * SS) + s) * CC + c0 + tx, f32);
  }
  __syncthreads();
  #pragma unroll
  for (int i = 0; i < 4; ++i) {
    const int c = c0 + ty + i * 8;
    const float mu = meanb[b * CC + c], sd = stdb[b * CC + c];
    const float v = (t[tx][ty + i * 8] - mu) / sd;
    const size_t idx = ((size_t)(lb * CC) + c) * SS + s0 + tx;
    ushort hi, lo; split_bf(v, hi, lo);
    xh[idx] = hi; xl[idx] = lo;
  }
}

// ---------------- weight convert+transpose: W (KxN, input dtype) -> bf16 (NxK)
__global__ __launch_bounds__(256) void transpose_w(
    const void* __restrict__ W, ushort* __restrict__ Wt, int K, int N,
    const int* __restrict__ dtf)
{
  const int f32 = *dtf;
  __shared__ float t[32][33];
  const int n0 = blockIdx.x * 32, k0 = blockIdx.y * 32;
  const int tx = threadIdx.x & 31, ty = threadIdx.x >> 5;
  #pragma unroll
  for (int i = 0; i < 4; ++i)
    t[ty + i * 8][tx] = lin(W, (size_t)(k0 + ty + i * 8) * N + n0 + tx, f32);
  __syncthreads();
  #pragma unroll
  for (int i = 0; i < 4; ++i)
    Wt[(size_t)(n0 + ty + i * 8) * K + k0 + tx] = f2b(t[tx][ty + i * 8]);
}

// ---------------- weight transpose + hi/lo split ----------------
__global__ __launch_bounds__(256) void transpose_w_split(
    const void* __restrict__ W, ushort* __restrict__ Whi, ushort* __restrict__ Wlo,
    int K, int N, const int* __restrict__ dtf)
{
  const int f32 = *dtf;
  __shared__ float t[32][33];
  const int n0 = blockIdx.x * 32, k0 = blockIdx.y * 32;
  const int tx = threadIdx.x & 31, ty = threadIdx.x >> 5;
  #pragma unroll
  for (int i = 0; i < 4; ++i)
    t[ty + i * 8][tx] = lin(W, (size_t)(k0 + ty + i * 8) * N + n0 + tx, f32);
  __syncthreads();
  #pragma unroll
  for (int i = 0; i < 4; ++i) {
    const size_t idx = (size_t)(n0 + ty + i * 8) * K + k0 + tx;
    ushort hi, lo; split_bf(t[tx][ty + i * 8], hi, lo);
    Whi[idx] = hi; Wlo[idx] = lo;
  }
}

// ---------------- generic fp32 tiled GEMM (fallback path) ----------
enum GemmMode { M_BIAS = 0, M_BIAS_RELU = 1, M_RELU_PE = 2,
                M_ADD_BIAS_LEAKY = 3, M_ADD_BIAS_ELU = 4, M_ADD_BIAS = 5,
                M_ADD2_BIAS_LEAKY = 6 };

template<typename AT, typename ADT, typename OT, int MODE>
__global__ __launch_bounds__(256) void gemm_kernel(
    const AT* __restrict__ A, const void* __restrict__ Bw,
    const void* __restrict__ bias, const ADT* __restrict__ addend,
    OT* __restrict__ Cout, int M, int K, int Nn, const int* __restrict__ dtf)
{
  const int f32 = *dtf;
  __shared__ __align__(16) float As[16][68];
  __shared__ __align__(16) float Bs[16][68];
  const int tid = threadIdx.x;
  const int m0 = blockIdx.y * 64, n0 = blockIdx.x * 64;
  const int tx = tid & 15, ty = tid >> 4;
  const int la_m = tid >> 2, la_k = (tid & 3) * 4;
  const int lb_k = tid >> 4, lb_n = (tid & 15) * 4;
  float acc[4][4];
  #pragma unroll
  for (int i = 0; i < 4; ++i)
    #pragma unroll
    for (int j = 0; j < 4; ++j) acc[i][j] = 0.f;
  const size_t a_row = (size_t)(m0 + la_m) * K;

  for (int k0 = 0; k0 < K; k0 += 16) {
    if constexpr (sizeof(AT) == 4) {
      const float4 av = *reinterpret_cast<const float4*>(A + a_row + k0 + la_k);
      As[la_k + 0][la_m] = av.x; As[la_k + 1][la_m] = av.y;
      As[la_k + 2][la_m] = av.z; As[la_k + 3][la_m] = av.w;
    } else {
      const ushort4 av = *reinterpret_cast<const ushort4*>(A + a_row + k0 + la_k);
      As[la_k + 0][la_m] = b2f(av.x); As[la_k + 1][la_m] = b2f(av.y);
      As[la_k + 2][la_m] = b2f(av.z); As[la_k + 3][la_m] = b2f(av.w);
    }
    {
      const size_t boff = (size_t)(k0 + lb_k) * Nn + n0 + lb_n;
      if (f32) {
        const float4 bv = *reinterpret_cast<const float4*>((const float*)Bw + boff);
        Bs[lb_k][lb_n + 0] = bv.x; Bs[lb_k][lb_n + 1] = bv.y;
        Bs[lb_k][lb_n + 2] = bv.z; Bs[lb_k][lb_n + 3] = bv.w;
      } else {
        const ushort4 bv = *reinterpret_cast<const ushort4*>((const ushort*)Bw + boff);
        Bs[lb_k][lb_n + 0] = b2f(bv.x); Bs[lb_k][lb_n + 1] = b2f(bv.y);
        Bs[lb_k][lb_n + 2] = b2f(bv.z); Bs[lb_k][lb_n + 3] = b2f(bv.w);
      }
    }
    __syncthreads();
    #pragma unroll
    for (int k = 0; k < 16; ++k) {
      const float4 a4 = *reinterpret_cast<const float4*>(&As[k][ty * 4]);
      const float4 b4 = *reinterpret_cast<const float4*>(&Bs[k][tx * 4]);
      const float aa[4] = {a4.x, a4.y, a4.z, a4.w};
      const float bb[4] = {b4.x, b4.y, b4.z, b4.w};
      #pragma unroll
      for (int i = 0; i < 4; ++i)
        #pragma unroll
        for (int j = 0; j < 4; ++j)
          acc[i][j] = fmaf(aa[i], bb[j], acc[i][j]);
    }
    __syncthreads();
  }

  float biasv[4];
  if constexpr (MODE != M_RELU_PE) {
    #pragma unroll
    for (int j = 0; j < 4; ++j) biasv[j] = lin(bias, n0 + tx * 4 + j, f32);
  }
  #pragma unroll
  for (int i = 0; i < 4; ++i) {
    const int m = m0 + ty * 4 + i;
    #pragma unroll
    for (int j = 0; j < 4; ++j) {
      const int n = n0 + tx * 4 + j;
      float v = acc[i][j];
      if constexpr (MODE == M_BIAS) {
        v += biasv[j];
      } else if constexpr (MODE == M_BIAS_RELU) {
        v = fmaxf(v + biasv[j], 0.f);
      } else if constexpr (MODE == M_RELU_PE) {
        v = fmaxf(v, 0.f);
        const float freq = expf((float)(n & ~1) * (-0.017988946f)); // -ln(1e4)/512
        const float ang  = (float)(m & (CC - 1)) * freq;            // pos = c
        v += (n & 1) ? cosf(ang) : sinf(ang);
      } else {
        float ad;
        if constexpr (sizeof(ADT) == 4) ad = ((const float*)addend)[(size_t)m * Nn + n];
        else                            ad = b2f(((const ushort*)addend)[(size_t)m * Nn + n]);
        v = ad + v + biasv[j];
        if constexpr (MODE == M_ADD_BIAS_LEAKY) v = (v >= 0.f) ? v : 0.5f * v;
        else if constexpr (MODE == M_ADD_BIAS_ELU) v = (v > 0.f) ? v : expm1f(v);
      }
      if constexpr (sizeof(OT) == 4) ((float*)Cout)[(size_t)m * Nn + n] = v;
      else                           ((ushort*)Cout)[(size_t)m * Nn + n] = f2b(v);
    }
  }
}

template<typename AT, typename ADT, typename OT, int MODE>
static void launch_gemm(const void* A, const void* Bw, const void* bias, const void* add,
                        void* Cout, int M, int K, int Nn, const int* dtf, hipStream_t stream)
{
  dim3 grid(Nn / 64, M / 64);
  gemm_kernel<AT, ADT, OT, MODE><<<grid, dim3(256), 0, stream>>>(
      (const AT*)A, Bw, bias, (const ADT*)add, (OT*)Cout, M, K, Nn, dtf);
}

// ---------------- MFMA bf16 GEMM (128x128 tile): Cout = epi(A @ Wt^T) ------
template<typename ADT, typename OT, int MODE>
__global__ __launch_bounds__(256) void mgemm_kernel(
    const ushort* __restrict__ A, const ushort* __restrict__ Wt,
    const void* __restrict__ bias, const ADT* __restrict__ addend,
    const ushort* __restrict__ addend2,
    OT* __restrict__ Cout, int M, int K, int Nn, const int* __restrict__ dtf)
{
  const int f32 = *dtf;
  __shared__ __align__(16) ushort As[128][40];
  __shared__ __align__(16) ushort Bs[128][40];
  const int tid = threadIdx.x;
  const int m0 = blockIdx.y * 128, n0 = blockIdx.x * 128;
  const int wave = tid >> 6, lane = tid & 63;
  const int wm = wave & 1, wn = wave >> 1;
  const int quad = lane >> 4, l15 = lane & 15;

  f32x4 acc[4][4];
  #pragma unroll
  for (int i = 0; i < 4; ++i)
    #pragma unroll
    for (int j = 0; j < 4; ++j) acc[i][j] = (f32x4){0.f, 0.f, 0.f, 0.f};

  const int srow = tid >> 1, sseg = (tid & 1) * 16;
  const size_t a_base = (size_t)(m0 + srow) * K + sseg;
  const size_t b_base = (size_t)(n0 + srow) * K + sseg;

  for (int k0 = 0; k0 < K; k0 += 32) {
    {
      const float4* ga = reinterpret_cast<const float4*>(A + a_base + k0);
      const float4* gb = reinterpret_cast<const float4*>(Wt + b_base + k0);
      const float4 a0 = ga[0], a1 = ga[1];
      const float4 b0 = gb[0], b1 = gb[1];
      float4* da = reinterpret_cast<float4*>(&As[srow][sseg]);
      float4* db = reinterpret_cast<float4*>(&Bs[srow][sseg]);
      da[0] = a0; da[1] = a1;
      db[0] = b0; db[1] = b1;
    }
    __syncthreads();
    short8 af[4], bf[4];
    #pragma unroll
    for (int i = 0; i < 4; ++i)
      af[i] = *reinterpret_cast<const short8*>(&As[wm * 64 + i * 16 + l15][quad * 8]);
    #pragma unroll
    for (int j = 0; j < 4; ++j)
      bf[j] = *reinterpret_cast<const short8*>(&Bs[wn * 64 + j * 16 + l15][quad * 8]);
    #pragma unroll
    for (int i = 0; i < 4; ++i)
      #pragma unroll
      for (int j = 0; j < 4; ++j)
        acc[i][j] = __builtin_amdgcn_mfma_f32_16x16x32_bf16(af[i], bf[j], acc[i][j], 0, 0, 0);
    __syncthreads();
  }

  #pragma unroll
  for (int j = 0; j < 4; ++j) {
    const int n = n0 + wn * 64 + j * 16 + l15;
    const float bv = lin(bias, n, f32);
    #pragma unroll
    for (int i = 0; i < 4; ++i) {
      #pragma unroll
      for (int r = 0; r < 4; ++r) {
        const int m = m0 + wm * 64 + i * 16 + quad * 4 + r;
        float v = acc[i][j][r];
        if constexpr (MODE == M_BIAS) {
          v += bv;
        } else if constexpr (MODE == M_BIAS_RELU) {
          v = fmaxf(v + bv, 0.f);
        } else if constexpr (MODE == M_ADD2_BIAS_LEAKY) {
          const size_t ix = (size_t)m * Nn + n;
          const float ad = b2f(((const ushort*)addend)[ix]) + b2f(addend2[ix]);
          v = ad + v + bv;
          v = (v >= 0.f) ? v : 0.5f * v;
        } else {
          float ad;
          if constexpr (sizeof(ADT) == 4) ad = ((const float*)addend)[(size_t)m * Nn + n];
          else                            ad = b2f(((const ushort*)addend)[(size_t)m * Nn + n]);
          v = ad + v + bv;
          if constexpr (MODE == M_ADD_BIAS_ELU)
            v = (v > 0.f) ? v : (__builtin_amdgcn_exp2f(v * LOG2E) - 1.f);
          else if constexpr (MODE == M_ADD_BIAS_LEAKY) v = (v >= 0.f) ? v : 0.5f * v;
        }
        if constexpr (sizeof(OT) == 4) ((float*)Cout)[(size_t)m * Nn + n] = v;
        else                           ((ushort*)Cout)[(size_t)m * Nn + n] = f2b(v);
      }
    }
  }
}

template<typename ADT, typename OT, int MODE>
static void launch_mgemm(const void* A, const void* Wt, const void* bias, const void* add,
                         void* Cout, int M, int K, int Nn, const int* dtf, hipStream_t stream,
                         const void* add2 = nullptr)
{
  dim3 grid(Nn / 128, M / 128);
  mgemm_kernel<ADT, OT, MODE><<<grid, dim3(256), 0, stream>>>(
      (const ushort*)A, (const ushort*)Wt, bias, (const ADT*)add, (const ushort*)add2,
      (OT*)Cout, M, K, Nn, dtf);
}

// ---------------- MFMA bf16 GEMM (64x64 tile) for N<=512 layers -------------
template<typename ADT, typename OT, int MODE>
__global__ __launch_bounds__(256) void mgemm64_kernel(
    const ushort* __restrict__ A, const ushort* __restrict__ Wt,
    const void* __restrict__ bias, const ADT* __restrict__ addend,
    const ushort* __restrict__ addend2,
    OT* __restrict__ Cout, int M, int K, int Nn, const int* __restrict__ dtf)
{
  const int f32 = *dtf;
  __shared__ __align__(16) ushort As[64][40];
  __shared__ __align__(16) ushort Bs[64][40];
  const int tid = threadIdx.x;
  const int m0 = blockIdx.y * 64, n0 = blockIdx.x * 64;
  const int wave = tid >> 6, lane = tid & 63;
  const int wm = wave & 1, wn = wave >> 1;
  const int quad = lane >> 4, l15 = lane & 15;

  f32x4 acc[2][2];
  #pragma unroll
  for (int i = 0; i < 2; ++i)
    #pragma unroll
    for (int j = 0; j < 2; ++j) acc[i][j] = (f32x4){0.f, 0.f, 0.f, 0.f};

  const int srow = tid >> 2, sseg = (tid & 3) * 8;
  const size_t a_base = (size_t)(m0 + srow) * K + sseg;
  const size_t b_base = (size_t)(n0 + srow) * K + sseg;

  for (int k0 = 0; k0 < K; k0 += 32) {
    *reinterpret_cast<float4*>(&As[srow][sseg]) =
        *reinterpret_cast<const float4*>(A + a_base + k0);
    *reinterpret_cast<float4*>(&Bs[srow][sseg]) =
        *reinterpret_cast<const float4*>(Wt + b_base + k0);
    __syncthreads();
    short8 af[2], bf[2];
    #pragma unroll
    for (int i = 0; i < 2; ++i) {
      af[i] = *reinterpret_cast<const short8*>(&As[wm * 32 + i * 16 + l15][quad * 8]);
      bf[i] = *reinterpret_cast<const short8*>(&Bs[wn * 32 + i * 16 + l15][quad * 8]);
    }
    #pragma unroll
    for (int i = 0; i < 2; ++i)
      #pragma unroll
      for (int j = 0; j < 2; ++j)
        acc[i][j] = __builtin_amdgcn_mfma_f32_16x16x32_bf16(af[i], bf[j], acc[i][j], 0, 0, 0);
    __syncthreads();
  }

  #pragma unroll
  for (int j = 0; j < 2; ++j) {
    const int n = n0 + wn * 32 + j * 16 + l15;
    const float bv = lin(bias, n, f32);
    #pragma unroll
    for (int i = 0; i < 2; ++i) {
      #pragma unroll
      for (int r = 0; r < 4; ++r) {
        const int m = m0 + wm * 32 + i * 16 + quad * 4 + r;
        float v = acc[i][j][r];
        if constexpr (MODE == M_BIAS) {
          v += bv;
        } else if constexpr (MODE == M_BIAS_RELU) {
          v = fmaxf(v + bv, 0.f);
        } else if constexpr (MODE == M_ADD2_BIAS_LEAKY) {
          const size_t ix = (size_t)m * Nn + n;
          const float ad = b2f(((const ushort*)addend)[ix]) + b2f(addend2[ix]);
          v = ad + v + bv;
          v = (v >= 0.f) ? v : 0.5f * v;
        } else {
          float ad;
          if constexpr (sizeof(ADT) == 4) ad = ((const float*)addend)[(size_t)m * Nn + n];
          else                            ad = b2f(((const ushort*)addend)[(size_t)m * Nn + n]);
          v = ad + v + bv;
          if constexpr (MODE == M_ADD_BIAS_ELU)
            v = (v > 0.f) ? v : (__builtin_amdgcn_exp2f(v * LOG2E) - 1.f);
          else if constexpr (MODE == M_ADD_BIAS_LEAKY) v = (v >= 0.f) ? v : 0.5f * v;
        }
        if constexpr (sizeof(OT) == 4) ((float*)Cout)[(size_t)m * Nn + n] = v;
        else                           ((ushort*)Cout)[(size_t)m * Nn + n] = f2b(v);
      }
    }
  }
}

template<typename ADT, typename OT, int MODE>
static void launch_mgemm64(const void* A, const void* Wt, const void* bias, const void* add,
                           void* Cout, int M, int K, int Nn, const int* dtf, hipStream_t stream,
                           const void* add2 = nullptr)
{
  dim3 grid(Nn / 64, M / 64);
  mgemm64_kernel<ADT, OT, MODE><<<grid, dim3(256), 0, stream>>>(
      (const ushort*)A, (const ushort*)Wt, bias, (const ADT*)add, (const ushort*)add2,
      (OT*)Cout, M, K, Nn, dtf);
}

// ---------------- mgemm3: 64x64-tile hi/lo-split 3-MFMA GEMM ----------------
enum Epi3 { E3_RELU_PE = 0, E3_RELU_SPLIT = 1, E3_SPLIT = 2, E3_RELU_VT = 3 };

template<int EPI>
__global__ __launch_bounds__(256) void mgemm3_kernel(
    const ushort* __restrict__ Ah, const ushort* __restrict__ Al,
    const ushort* __restrict__ Bh, const ushort* __restrict__ Bl,
    const void* __restrict__ bias,
    ushort* __restrict__ Oh, ushort* __restrict__ Ol,
    int M, int K, int Nn, const int* __restrict__ dtf)
{
  const int f32 = *dtf;
  __shared__ __align__(16) ushort AsH[64][40];
  __shared__ __align__(16) ushort AsL[64][40];
  __shared__ __align__(16) ushort BsH[64][40];
  __shared__ __align__(16) ushort BsL[64][40];
  const int tid = threadIdx.x;
  const int m0 = blockIdx.y * 64, n0 = blockIdx.x * 64;
  const int wave = tid >> 6, lane = tid & 63;
  const int wm = wave & 1, wn = wave >> 1;
  const int quad = lane >> 4, l15 = lane & 15;

  f32x4 acc[2][2];
  #pragma unroll
  for (int i = 0; i < 2; ++i)
    #pragma unroll
    for (int j = 0; j < 2; ++j) acc[i][j] = (f32x4){0.f, 0.f, 0.f, 0.f};

  const int srow = tid >> 2, sseg = (tid & 3) * 8;
  const size_t a_base = (size_t)(m0 + srow) * K + sseg;
  const size_t b_base = (size_t)(n0 + srow) * K + sseg;

  for (int k0 = 0; k0 < K; k0 += 32) {
    *reinterpret_cast<float4*>(&AsH[srow][sseg]) =
        *reinterpret_cast<const float4*>(Ah + a_base + k0);
    *reinterpret_cast<float4*>(&AsL[srow][sseg]) =
        *reinterpret_cast<const float4*>(Al + a_base + k0);
    *reinterpret_cast<float4*>(&BsH[srow][sseg]) =
        *reinterpret_cast<const float4*>(Bh + b_base + k0);
    *reinterpret_cast<float4*>(&BsL[srow][sseg]) =
        *reinterpret_cast<const float4*>(Bl + b_base + k0);
    __syncthreads();
    short8 afh[2], afl[2], bfh[2], bfl[2];
    #pragma unroll
    for (int i = 0; i < 2; ++i) {
      afh[i] = *reinterpret_cast<const short8*>(&AsH[wm * 32 + i * 16 + l15][quad * 8]);
      afl[i] = *reinterpret_cast<const short8*>(&AsL[wm * 32 + i * 16 + l15][quad * 8]);
      bfh[i] = *reinterpret_cast<const short8*>(&BsH[wn * 32 + i * 16 + l15][quad * 8]);
      bfl[i] = *reinterpret_cast<const short8*>(&BsL[wn * 32 + i * 16 + l15][quad * 8]);
    }
    #pragma unroll
    for (int i = 0; i < 2; ++i)
      #pragma unroll
      for (int j = 0; j < 2; ++j) {
        acc[i][j] = __builtin_amdgcn_mfma_f32_16x16x32_bf16(afh[i], bfh[j], acc[i][j], 0, 0, 0);
        acc[i][j] = __builtin_amdgcn_mfma_f32_16x16x32_bf16(afh[i], bfl[j], acc[i][j], 0, 0, 0);
        acc[i][j] = __builtin_amdgcn_mfma_f32_16x16x32_bf16(afl[i], bfh[j], acc[i][j], 0, 0, 0);
      }
    __syncthreads();
  }

  #pragma unroll
  for (int j = 0; j < 2; ++j) {
    const int n = n0 + wn * 32 + j * 16 + l15;
    float bv = 0.f;
    if constexpr (EPI != E3_RELU_PE) bv = lin(bias, n, f32);
    #pragma unroll
    for (int i = 0; i < 2; ++i) {
      #pragma unroll
      for (int r = 0; r < 4; ++r) {
        const int m = m0 + wm * 32 + i * 16 + quad * 4 + r;
        float v = acc[i][j][r];
        if constexpr (EPI == E3_RELU_PE) {
          v = fmaxf(v, 0.f);
          const float freq = expf((float)(n & ~1) * (-0.017988946f)); // -ln(1e4)/512
          const float ang  = (float)(m & (CC - 1)) * freq;            // pos = c
          v += (n & 1) ? cosf(ang) : sinf(ang);
        } else if constexpr (EPI == E3_RELU_SPLIT || EPI == E3_RELU_VT) {
          v = fmaxf(v + bv, 0.f);
        } else {
          v = v + bv;
        }
        if constexpr (EPI == E3_RELU_VT) {
          // pre-transposed: vT[(lb*512 + n)][s] with lb = m>>9, s = m&511
          Oh[((size_t)((m >> 9) * 512 + n)) * 512 + (m & 511)] = f2b(v);
        } else {
          ushort hi, lo; split_bf(v, hi, lo);
          Oh[(size_t)m * Nn + n] = hi;
          Ol[(size_t)m * Nn + n] = lo;
        }
      }
    }
  }
}

template<int EPI>
static void launch_mgemm3(const void* Ahv, const void* Alv, const ushort* Bh,
                          const ushort* Bl, const void* bias, void* Oh, void* Ol,
                          int M, int K, int Nn, const int* dtf, hipStream_t stream)
{
  dim3 grid(Nn / 64, M / 64);
  mgemm3_kernel<EPI><<<grid, dim3(256), 0, stream>>>(
      (const ushort*)Ahv, (const ushort*)Alv, Bh, Bl, bias,
      (ushort*)Oh, (ushort*)Ol, M, K, Nn, dtf);
}

// ---------------- GAttn via MFMA: register scores + DPP top-k ---------------
// S-phase uses an explicit 2-stage prefetch pipeline (chunk c+1's K frags
// loaded into named regs before chunk c's MFMAs) so load latency overlaps
// MFMA regardless of regalloc heuristics.
__global__ __launch_bounds__(256, 2) void gattn_mfma(
    const ushort* __restrict__ qsh, const ushort* __restrict__ qsl,
    const ushort* __restrict__ ksh, const ushort* __restrict__ ksl,
    const ushort* __restrict__ vt, ushort* __restrict__ out)
{
  const int tid = threadIdx.x;
  const int wave = tid >> 6, lane = tid & 63;
  const int quad = lane >> 4, l15 = lane & 15;
  const int l0 = blockIdx.x * 16;
  const int h = blockIdx.y, bz = blockIdx.z;

  __shared__ __align__(16) ushort P[16][520];    // 16640 B (unnormalized bf16 weights)
  __shared__ float cand[16][40];                 // 2560 B (4 waves x sorted top-10)
  __shared__ float psum[16][4];                  // 256 B  (per-wave partial sums)

  // ---- Q fragments (hi/lo), kk-chunks 0,1 ----
  short8 ah[2], al[2];
  {
    const size_t qoff = ((size_t)bz * CC + l0 + l15) * DD + h * EE + quad * 8;
    ah[0] = *reinterpret_cast<const short8*>(qsh + qoff);
    ah[1] = *reinterpret_cast<const short8*>(qsh + qoff + 32);
    al[0] = *reinterpret_cast<const short8*>(qsl + qoff);
    al[1] = *reinterpret_cast<const short8*>(qsl + qoff + 32);
  }

  // ---- S phase into registers: sacc[c][r] = S[quad*4+r][c*64+wave*16+l15] --
  f32x4 sacc[8];
  {
    const size_t kbase = ((size_t)bz * CC + wave * 16 + l15) * DD + h * EE + quad * 8;
    short8 pbh0 = *reinterpret_cast<const short8*>(ksh + kbase);
    short8 pbl0 = *reinterpret_cast<const short8*>(ksl + kbase);
    short8 pbh1 = *reinterpret_cast<const short8*>(ksh + kbase + 32);
    short8 pbl1 = *reinterpret_cast<const short8*>(ksl + kbase + 32);
    #pragma unroll
    for (int c = 0; c < 8; ++c) {
      const short8 cbh0 = pbh0, cbl0 = pbl0, cbh1 = pbh1, cbl1 = pbl1;
      if (c < 7) {
        const size_t noff = kbase + (size_t)((c + 1) * 64) * DD;
        pbh0 = *reinterpret_cast<const short8*>(ksh + noff);
        pbl0 = *reinterpret_cast<const short8*>(ksl + noff);
        pbh1 = *reinterpret_cast<const short8*>(ksh + noff + 32);
        pbl1 = *reinterpret_cast<const short8*>(ksl + noff + 32);
      }
      f32x4 acc = (f32x4){0.f, 0.f, 0.f, 0.f};
      __builtin_amdgcn_s_setprio(1);
      acc = __builtin_amdgcn_mfma_f32_16x16x32_bf16(ah[0], cbh0, acc, 0, 0, 0);
      acc = __builtin_amdgcn_mfma_f32_16x16x32_bf16(ah[0], cbl0, acc, 0, 0, 0);
      acc = __builtin_amdgcn_mfma_f32_16x16x32_bf16(al[0], cbh0, acc, 0, 0, 0);
      acc = __builtin_amdgcn_mfma_f32_16x16x32_bf16(ah[1], cbh1, acc, 0, 0, 0);
      acc = __builtin_amdgcn_mfma_f32_16x16x32_bf16(ah[1], cbl1, acc, 0, 0, 0);
      acc = __builtin_amdgcn_mfma_f32_16x16x32_bf16(al[1], cbh1, acc, 0, 0, 0);
      __builtin_amdgcn_s_setprio(0);
      sacc[c] = acc;
    }
  }

  // ---- stage-1 top-k: each quad extracts its row's wave-local top-10 ----
  #pragma unroll
  for (int r = 0; r < 4; ++r) {
    float wk[8];
    #pragma unroll
    for (int c = 0; c < 8; ++c) wk[c] = sacc[c][r];
    float myg = 0.f;
    for (int it = 0; it < 10; ++it) {
      float lm = wk[0];
      #pragma unroll
      for (int c = 1; c < 8; ++c) lm = fmaxf(lm, wk[c]);
      const float gm = red16_max(lm);
      if (l15 == it) myg = gm;
      if (it < 9) {
        const unsigned long long msk = __ballot(lm == gm);
        const int sel = (__ffsll((unsigned long long)((msk >> (quad * 16)) & 0xFFFFull)) - 1)
                        + quad * 16;
        if (lane == sel) {
          #pragma unroll
          for (int c = 0; c < 8; ++c) { if (wk[c] == gm) { wk[c] = -FLT_MAX; break; } }
        }
      }
    }
    if (l15 < 10) cand[quad * 4 + r][wave * 10 + l15] = myg;
  }
  __syncthreads();

  // ---- merge 4 sorted lists of 10 -> global maxv + thr (10th) ----
  float mx, thr;
  {
    const int mr = lane & 15;
    float h0 = cand[mr][0], h1 = cand[mr][10], h2 = cand[mr][20], h3 = cand[mr][30];
    int i0 = 0, i1 = 0, i2 = 0, i3 = 0;
    float cur = 0.f;
    mx = 0.f;
    #pragma unroll
    for (int t = 0; t < 10; ++t) {
      cur = fmaxf(fmaxf(h0, h1), fmaxf(h2, h3));
      if (t == 0) mx = cur;
      if (t < 9) {
        const bool a0 = (cur == h0);
        const bool a1 = !a0 && (cur == h1);
        const bool a2 = !a0 && !a1 && (cur == h2);
        const int ni0 = i0 + (a0 ? 1 : 0);
        const int ni1 = i1 + (a1 ? 1 : 0);
        const int ni2 = i2 + (a2 ? 1 : 0);
        const int ni3 = i3 + ((a0 || a1 || a2) ? 0 : 1);
        const int off = a0 ? ni0 : (a1 ? 10 + ni1 : (a2 ? 20 + ni2 : 30 + ni3));
        const float nv = cand[mr][off];
        h0 = a0 ? nv : h0;
        h1 = a1 ? nv : h1;
        h2 = a2 ? nv : h2;
        h3 = (a0 || a1 || a2) ? h3 : nv;
        i0 = ni0; i1 = ni1; i2 = ni2; i3 = ni3;
      }
    }
    thr = cur;
  }
  // distribute row thr/max to the quad that owns the row
  float thrR[4], mxR[4];
  #pragma unroll
  for (int r = 0; r < 4; ++r) {
    thrR[r] = __shfl(thr, quad * 4 + r);
    mxR[r]  = __shfl(mx,  quad * 4 + r);
  }

  // ---- exp + partial sums + P write ----
  #pragma unroll
  for (int r = 0; r < 4; ++r) {
    const int Rr = quad * 4 + r;
    float s = 0.f;
    #pragma unroll
    for (int c = 0; c < 8; ++c) {
      const float sc = sacc[c][r];
      const float p = (sc >= thrR[r])
          ? __builtin_amdgcn_exp2f((sc - mxR[r]) * (0.125f * LOG2E)) : 0.f;
      P[Rr][c * 64 + wave * 16 + l15] = f2b(p);
      s += p;
    }
    s = red16_sum(s);
    if (l15 == 0) psum[Rr][wave] = s;
  }
  __syncthreads();

  // ---- PV phase: wave w owns e-cols w*16..w*16+15; vT loaded direct ----
  f32x4 pacc = (f32x4){0.f, 0.f, 0.f, 0.f};
  const size_t vbase = ((size_t)bz * 512 + h * EE + wave * 16 + l15) * 512 + quad * 8;
  #pragma unroll
  for (int c = 0; c < 4; ++c) {
    #pragma unroll
    for (int ks = 0; ks < 4; ++ks) {
      const int s0 = c * 128 + ks * 32;
      const short8 pa = *reinterpret_cast<const short8*>(&P[l15][s0 + quad * 8]);
      const short8 vb = *reinterpret_cast<const short8*>(vt + vbase + s0);
      __builtin_amdgcn_s_setprio(1);
      pacc = __builtin_amdgcn_mfma_f32_16x16x32_bf16(pa, vb, pacc, 0, 0, 0);
      __builtin_amdgcn_s_setprio(0);
    }
  }

  // ---- epilogue ----
  #pragma unroll
  for (int r = 0; r < 4; ++r) {
    const int Rr = quad * 4 + r;
    const float4 ps = *reinterpret_cast<const float4*>(&psum[Rr][0]);
    const float inv = 1.f / (ps.x + ps.y + ps.z + ps.w);
    out[((size_t)bz * CC + l0 + Rr) * DD + h * EE + wave * 16 + l15] = f2b(pacc[r] * inv);
  }
}

// ---------------- GAttn fallback (fp32 path only) -----------
template<typename OT>
__global__ __launch_bounds__(256) void gattn_fb(
    const float* __restrict__ q, const float* __restrict__ k,
    const float* __restrict__ v, OT* __restrict__ out)
{
  const int tid = threadIdx.x;
  const int wave = tid >> 6, lane = tid & 63;
  const int l0 = blockIdx.x * 4;
  const int h = blockIdx.y, bz = blockIdx.z;
  const int l = l0 + wave;
  const size_t base = ((size_t)bz * CC) * DD + h * EE;

  __shared__ __align__(16) float kt[64][68];
  __shared__ __align__(16) float qs[4][64];
  __shared__ __align__(16) float ww[4][512];

  qs[wave][lane] = q[((size_t)bz * CC + l) * DD + h * EE + lane];

  float sc[8];
  const int sl = tid >> 4;
  const int e4 = (tid & 15) * 4;
  for (int c8 = 0; c8 < 8; ++c8) {
    #pragma unroll
    for (int r = 0; r < 4; ++r) {
      const int s_local = sl + r * 16;
      const float4 kv = *reinterpret_cast<const float4*>(
          k + base + (size_t)(c8 * 64 + s_local) * DD + e4);
      *reinterpret_cast<float4*>(&kt[s_local][e4]) = kv;
    }
    __syncthreads();
    float a = 0.f;
    #pragma unroll
    for (int e = 0; e < 16; ++e) {
      const float4 qv = *reinterpret_cast<const float4*>(&qs[wave][e * 4]);
      const float4 kv = *reinterpret_cast<const float4*>(&kt[lane][e * 4]);
      a += qv.x * kv.x + qv.y * kv.y + qv.z * kv.z + qv.w * kv.w;
    }
    sc[c8] = a;
    __syncthreads();
  }

  float wk[8];
  #pragma unroll
  for (int j = 0; j < 8; ++j) wk[j] = sc[j];
  float maxv = 0.f, thr = 0.f;
  for (int it = 0; it < 10; ++it) {
    float lm = wk[0];
    #pragma unroll
    for (int j = 1; j < 8; ++j) lm = fmaxf(lm, wk[j]);
    float gm = lm;
    #pragma unroll
    for (int off = 32; off > 0; off >>= 1) gm = fmaxf(gm, __shfl_xor(gm, off));
    if (it == 0) maxv = gm;
    if (it == 9) { thr = gm; break; }
    const unsigned long long msk = __ballot(lm == gm);
    if (lane == __ffsll(msk) - 1) {
      #pragma unroll
      for (int j = 0; j < 8; ++j) { if (wk[j] == gm) { wk[j] = -FLT_MAX; break; } }
    }
  }

  float lsum = 0.f;
  #pragma unroll
  for (int j = 0; j < 8; ++j) {
    const float p = (sc[j] >= thr) ? expf((sc[j] - maxv) * 0.125f) : 0.f;
    ww[wave][j * 64 + lane] = p;
    lsum += p;
  }
  #pragma unroll
  for (int off = 32; off > 0; off >>= 1) lsum += __shfl_xor(lsum, off);
  const float inv = 1.f / lsum;
  __syncthreads();

  float acc = 0.f;
  const float* vp = v + base + lane;
  const float* wp = ww[wave];
  for (int s = 0; s < 512; s += 4) {
    const float4 w4 = *reinterpret_cast<const float4*>(&wp[s]);
    acc = fmaf(w4.x, vp[(size_t)(s + 0) * DD], acc);
    acc = fmaf(w4.y, vp[(size_t)(s + 1) * DD], acc);
    acc = fmaf(w4.z, vp[(size_t)(s + 2) * DD], acc);
    acc = fmaf(w4.w, vp[(size_t)(s + 3) * DD], acc);
  }
  const float res = acc * inv;
  const size_t oi = ((size_t)bz * CC + l) * DD + h * EE + lane;
  if constexpr (sizeof(OT) == 4) out[oi] = res;
  else                           out[oi] = f2b(res);
}

// ---------------- pwattn1 via MFMA: one row per wave ----------------
__global__ __launch_bounds__(256) void pwattn1_mfma(
    const ushort* __restrict__ query, const float* __restrict__ k1,
    const float* __restrict__ v1, ushort* __restrict__ V1)
{
  const int tid = threadIdx.x;
  const int wave = tid >> 6, lane = tid & 63;
  const int quad = lane >> 4, l15 = lane & 15;
  const int n = blockIdx.x * 4 + wave;

  __shared__ __align__(16) ushort Pl[4][16][40];   // stride 80B (16B-aligned)

  const ushort* qrow = query + (size_t)n * DFF;
  const float*  krow = k1 + (size_t)n * 512;
  const float*  vrow = v1 + (size_t)n * 512;
  ushort* orow = V1 + (size_t)n * DFF;

  const short8 zz = {0, 0, 0, 0, 0, 0, 0, 0};
  const f32x4 zacc = (f32x4){0.f, 0.f, 0.f, 0.f};

  // B-frags for scores: col s = nt*16+l15, k = e = quad*8+i (valid e<16)
  short8 bh[2], bl[2];
  #pragma unroll
  for (int nt = 0; nt < 2; ++nt) {
    short8 hh = zz, ll = zz;
    if (quad < 2) {
      const float* kp = krow + (nt * 16 + l15) * 16 + quad * 8;
      #pragma unroll
      for (int i = 0; i < 8; ++i) {
        ushort hi_, lo_; split_bf(kp[i], hi_, lo_);
        hh[i] = (short)hi_; ll[i] = (short)lo_;
      }
    }
    bh[nt] = hh; bl[nt] = ll;
  }
  // B-frag for PV: v[k=s=quad*8+i][n=e=l15]
  short8 vb;
  #pragma unroll
  for (int i = 0; i < 8; ++i) vb[i] = (short)f2b(vrow[(quad * 8 + i) * 16 + l15]);

  #pragma unroll
  for (int mt = 0; mt < 8; ++mt) {
    short8 qa = zz;
    if (quad < 2)
      qa = *reinterpret_cast<const short8*>(qrow + (mt * 16 + l15) * 16 + quad * 8);
    f32x4 acc[2];
    #pragma unroll
    for (int nt = 0; nt < 2; ++nt) {
      f32x4 t = __builtin_amdgcn_mfma_f32_16x16x32_bf16(qa, bl[nt], zacc, 0, 0, 0);
      acc[nt] = __builtin_amdgcn_mfma_f32_16x16x32_bf16(qa, bh[nt], t, 0, 0, 0);
    }
    // softmax over 32 cols (2 nt x 16 lanes); rows quad*4+r
    float inv[4];
    #pragma unroll
    for (int r = 0; r < 4; ++r) {
      float m = red16_max(fmaxf(acc[0][r], acc[1][r]));
      const float p0 = __builtin_amdgcn_exp2f((acc[0][r] - m) * (0.25f * LOG2E));
      const float p1 = __builtin_amdgcn_exp2f((acc[1][r] - m) * (0.25f * LOG2E));
      acc[0][r] = p0; acc[1][r] = p1;
      const float s = red16_sum(p0 + p1);
      inv[r] = 1.f / s;
    }
    #pragma unroll
    for (int nt = 0; nt < 2; ++nt)
      #pragma unroll
      for (int r = 0; r < 4; ++r)
        Pl[wave][quad * 4 + r][nt * 16 + l15] = f2b(acc[nt][r]);
    const short8 pa = *reinterpret_cast<const short8*>(&Pl[wave][l15][quad * 8]);
    const f32x4 pv = __builtin_amdgcn_mfma_f32_16x16x32_bf16(pa, vb, zacc, 0, 0, 0);
    #pragma unroll
    for (int r = 0; r < 4; ++r)
      orow[(mt * 16 + quad * 4 + r) * 16 + l15] = f2b(pv[r] * inv[r]);
  }
}

// ---------------- pwattn2 via MFMA: one row per wave ----------------
__global__ __launch_bounds__(256) void pwattn2_mfma(
    const float* __restrict__ query2, const ushort* __restrict__ k2,
    const ushort* __restrict__ v2, ushort* __restrict__ V2)
{
  const int tid = threadIdx.x;
  const int wave = tid >> 6, lane = tid & 63;
  const int quad = lane >> 4, l15 = lane & 15;
  const int n = blockIdx.x * 4 + wave;

  __shared__ __align__(16) ushort Pl[4][16][136];  // stride 272B (16B-aligned)

  const float*  qrow = query2 + (size_t)n * 512;
  const ushort* krow = k2 + (size_t)n * DFF;
  const ushort* vrow = v2 + (size_t)n * DFF;
  ushort* orow = V2 + (size_t)n * 512;

  const short8 zz = {0, 0, 0, 0, 0, 0, 0, 0};
  const f32x4 zacc = (f32x4){0.f, 0.f, 0.f, 0.f};

  // B-frags for scores: col s = nt*16+l15 (8 nt), k = e = quad*8+i (<16)
  short8 kb[8];
  #pragma unroll
  for (int nt = 0; nt < 8; ++nt)
    kb[nt] = (quad < 2)
        ? *reinterpret_cast<const short8*>(krow + (nt * 16 + l15) * 16 + quad * 8)
        : zz;

  // B-frags for PV: v[k=s=kt*32+quad*8+i][n=e=l15]
  short8 vb[4];
  #pragma unroll
  for (int kt = 0; kt < 4; ++kt)
    #pragma unroll
    for (int i = 0; i < 8; ++i)
      vb[kt][i] = (short)vrow[(kt * 32 + quad * 8 + i) * 16 + l15];

  #pragma unroll
  for (int mt = 0; mt < 2; ++mt) {
    // A hi/lo: q[m=mt*16+l15][k=quad*8+i (<16)]
    short8 ahh = zz, all_ = zz;
    if (quad < 2) {
      const float* qp = qrow + (mt * 16 + l15) * 16 + quad * 8;
      #pragma unroll
      for (int i = 0; i < 8; ++i) {
        ushort hi_, lo_; split_bf(qp[i], hi_, lo_);
        ahh[i] = (short)hi_; all_[i] = (short)lo_;
      }
    }
    f32x4 acc[8];
    #pragma unroll
    for (int nt = 0; nt < 8; ++nt) {
      f32x4 t = __builtin_amdgcn_mfma_f32_16x16x32_bf16(all_, kb[nt], zacc, 0, 0, 0);
      acc[nt] = __builtin_amdgcn_mfma_f32_16x16x32_bf16(ahh, kb[nt], t, 0, 0, 0);
    }
    // softmax over 128 cols (8 nt x 16 lanes); rows quad*4+r
    float inv[4];
    #pragma unroll
    for (int r = 0; r < 4; ++r) {
      float m = acc[0][r];
      #pragma unroll
      for (int nt = 1; nt < 8; ++nt) m = fmaxf(m, acc[nt][r]);
      m = red16_max(m);
      float s = 0.f;
      #pragma unroll
      for (int nt = 0; nt < 8; ++nt) {
        const float p = __builtin_amdgcn_exp2f((acc[nt][r] - m) * (0.25f * LOG2E));
        acc[nt][r] = p; s += p;
      }
      s = red16_sum(s);
      inv[r] = 1.f / s;
    }
    #pragma unroll
    for (int nt = 0; nt < 8; ++nt)
      #pragma unroll
      for (int r = 0; r < 4; ++r)
        Pl[wave][quad * 4 + r][nt * 16 + l15] = f2b(acc[nt][r]);
    f32x4 pv = zacc;
    #pragma unroll
    for (int kt = 0; kt < 4; ++kt) {
      const short8 pa = *reinterpret_cast<const short8*>(&Pl[wave][l15][kt * 32 + quad * 8]);
      pv = __builtin_amdgcn_mfma_f32_16x16x32_bf16(pa, vb[kt], pv, 0, 0, 0);
    }
    #pragma unroll
    for (int r = 0; r < 4; ++r)
      orow[(mt * 16 + quad * 4 + r) * 16 + l15] = f2b(pv[r] * inv[r]);
  }
}

// ---------------- pwattn1 (fallback) ----------------
__global__ __launch_bounds__(128) void pwattn1_kernel(
    const ushort* __restrict__ query, const float* __restrict__ k1,
    const float* __restrict__ v1, ushort* __restrict__ V1)
{
  const int n = blockIdx.x, tid = threadIdx.x;
  __shared__ float ks[512], vs[512];
  __shared__ float Am[128][33];
  for (int i = tid; i < 512; i += 128) { ks[i] = k1[(size_t)n * 512 + i]; vs[i] = v1[(size_t)n * 512 + i]; }
  __syncthreads();
  {
    const int l = tid;
    float qv[16];
    const ushort* qp = query + (size_t)n * DFF + l * 16;
    #pragma unroll
    for (int e = 0; e < 16; ++e) qv[e] = b2f(qp[e]);
    float scl[32], mx = -FLT_MAX;
    #pragma unroll
    for (int s = 0; s < 32; ++s) {
      float a = 0.f;
      #pragma unroll
      for (int e = 0; e < 16; ++e) a += qv[e] * ks[s * 16 + e];
      scl[s] = a; mx = fmaxf(mx, a);
    }
    float sum = 0.f;
    #pragma unroll
    for (int s = 0; s < 32; ++s) { const float p = expf((scl[s] - mx) * 0.25f); scl[s] = p; sum += p; }
    const float invs = 1.f / sum;
    #pragma unroll
    for (int s = 0; s < 32; ++s) Am[l][s] = scl[s] * invs;
  }
  __syncthreads();
  #pragma unroll
  for (int r = 0; r < 16; ++r) {
    const int idx = tid + 128 * r;
    const int l = idx >> 4, e = idx & 15;
    float a = 0.f;
    #pragma unroll
    for (int s = 0; s < 32; ++s) a += Am[l][s] * vs[s * 16 + e];
    V1[(size_t)n * DFF + idx] = f2b(a);
  }
}

// ---------------- LayerNorm over 2048, in-place bf16 ----------------
__global__ __launch_bounds__(256) void ln_kernel(
    ushort* __restrict__ h, const void* __restrict__ g, const void* __restrict__ bt,
    const int* __restrict__ dtf)
{
  const int f32 = *dtf;
  const int n = blockIdx.x, tid = threadIdx.x;
  ushort* hp = h + (size_t)n * DFF;
  float x[8]; float s = 0.f, s2 = 0.f;
  #pragma unroll
  for (int i = 0; i < 8; ++i) {
    const float xv = b2f(hp[tid + 256 * i]);
    x[i] = xv; s += xv; s2 += xv * xv;
  }
  __shared__ float rs[256], rq[256];
  rs[tid] = s; rq[tid] = s2;
  __syncthreads();
  for (int off = 128; off > 0; off >>= 1) {
    if (tid < off) { rs[tid] += rs[tid + off]; rq[tid] += rq[tid + off]; }
    __syncthreads();
  }
  const float mu  = rs[0] * (1.f / DFF);
  const float var = rq[0] * (1.f / DFF) - mu * mu;
  const float inv = rsqrtf(var + 1e-5f);
  #pragma unroll
  for (int i = 0; i < 8; ++i) {
    const int d = tid + 256 * i;
    hp[d] = f2b((x[i] - mu) * inv * lin(g, d, f32) + lin(bt, d, f32));
  }
}

// ---------------- pwattn2 (fallback), templated output -----------
template<typename OT>
__global__ __launch_bounds__(128) void pwattn2_kernel(
    const float* __restrict__ query2, const ushort* __restrict__ k2,
    const ushort* __restrict__ v2, OT* __restrict__ V2)
{
  const int n = blockIdx.x, tid = threadIdx.x;
  __shared__ float ks[2048], vs[2048];
  __shared__ float Am[32][129];
  for (int i = tid; i < 2048; i += 128) {
    ks[i] = b2f(k2[(size_t)n * DFF + i]);
    vs[i] = b2f(v2[(size_t)n * DFF + i]);
  }
  __syncthreads();
  if (tid < 32) {
    const int l = tid;
    float qv[16];
    #pragma unroll
    for (int e = 0; e < 16; ++e) qv[e] = query2[(size_t)n * 512 + l * 16 + e];
    float mx = -FLT_MAX;
    for (int s = 0; s < 128; ++s) {
      float a = 0.f;
      #pragma unroll
      for (int e = 0; e < 16; ++e) a += qv[e] * ks[s * 16 + e];
      Am[l][s] = a; mx = fmaxf(mx, a);
    }
    float sum = 0.f;
    for (int s = 0; s < 128; ++s) { const float p = expf((Am[l][s] - mx) * 0.25f); Am[l][s] = p; sum += p; }
    const float invs = 1.f / sum;
    for (int s = 0; s < 128; ++s) Am[l][s] *= invs;
  }
  __syncthreads();
  #pragma unroll
  for (int r = 0; r < 4; ++r) {
    const int idx = tid + 128 * r;
    const int l = idx >> 4, e = idx & 15;
    float a = 0.f;
    for (int s = 0; s < 128; ++s) a += Am[l][s] * vs[s * 16 + e];
    if constexpr (sizeof(OT) == 4) V2[(size_t)n * 512 + idx] = a;
    else                           V2[(size_t)n * 512 + idx] = f2b(a);
  }
}

// ---------------- final: dec = y@fc_w + fc_b; out = dec*std+mean -----------
__global__ __launch_bounds__(128) void final_kernel(
    const float* __restrict__ y, const void* __restrict__ fc_w,
    const void* __restrict__ fc_b, const float* __restrict__ meanb,
    const float* __restrict__ stdb, void* __restrict__ out, int row_base,
    const int* __restrict__ dtf)
{
  const int f32 = *dtf;
  const int row = row_base + blockIdx.x;
  const int b = row >> 9, c = row & 511;
  const int tid = threadIdx.x;
  __shared__ float yr[512];
  for (int i = tid; i < 512; i += 128) yr[i] = y[(size_t)blockIdx.x * 512 + i];
  __syncthreads();
  if (tid < PRED) {
    float a = 0.f;
    for (int d = 0; d < 512; ++d) a += yr[d] * lin(fc_w, d * PRED + tid, f32);
    a += lin(fc_b, tid, f32);
    const float r = a * stdb[row] + meanb[row];
    const size_t oi = ((size_t)b * PRED + tid) * CC + c;
    if (f32) ((float*)out)[oi] = r;
    else     ((ushort*)out)[oi] = f2b(r);
  }
}

// ---------------------------------------------------------------------------
extern "C" void kernel_launch(void* const* d_in, const int* in_sizes, int n_in,
                              void* d_out, int out_size, void* d_ws, size_t ws_size,
                              hipStream_t stream)
{
  (void)in_sizes; (void)n_in; (void)out_size;
  const void* x_enc   = d_in[0];
  const void* embed_w = d_in[4];
  const void* q_w = d_in[5],  * q_b = d_in[6];
  const void* k_w = d_in[7],  * k_b = d_in[8];
  const void* v_w = d_in[9],  * v_b = d_in[10];
  const void* o_w = d_in[11], * o_b = d_in[12];
  const void* enc_w = d_in[13], * enc_b = d_in[14];
  const void* f1q_w = d_in[15], * f1q_b = d_in[16];
  const void* f1k_w = d_in[17], * f1k_b = d_in[18];
  const void* f1v_w = d_in[19], * f1v_b = d_in[20];
  const void* f1o_w = d_in[21], * f1o_b = d_in[22];
  const void* f2q_w = d_in[23], * f2q_b = d_in[24];
  const void* f2k_w = d_in[25], * f2k_b = d_in[26];
  const void* f2v_w = d_in[27], * f2v_b = d_in[28];
  const void* f2o_w = d_in[29], * f2o_b = d_in[30];
  const void* ln_g  = d_in[31], * ln_b  = d_in[32];
  const void* fc_w  = d_in[33], * fc_b  = d_in[34];

  const size_t HDR = 131072 + 1024;
  const size_t E_F1Q = 512ull * 2048, E_F1O = 2048ull * 2048, E_F2Q = 2048ull * 512;
  const size_t E_F2K = 2048ull * 2048, E_F2V = 2048ull * 2048, E_F2O = 512ull * 512;
  const size_t E_SQ  = 512ull * 512;   // o_w, enc_w, f1k_w, f1v_w each
  // + 8 split arrays (embed/q/k/v hi+lo)
  const size_t WT_EL = E_F1Q + E_F1O + E_F2Q + E_F2K + E_F2V + E_F2O + 4 * E_SQ + 8 * E_SQ;
  const size_t WT_BYTES = WT_EL * 2;   // ~34.5 MB
  const size_t PB_MFMA = 4ull * 512 * 512 * 4 + 3ull * 512 * DFF * 2; // 10.0MB
  const size_t PB_FB   = 5ull * 512 * 512 * 4 + 3ull * 512 * DFF * 2; // 11.0MB

  const int use_mfma = (HDR + WT_BYTES + PB_MFMA <= ws_size) ? 1 : 0;
  const size_t PER_BATCH = use_mfma ? PB_MFMA : PB_FB;
  const size_t FIXED = HDR + (use_mfma ? WT_BYTES : 0);
  int BPC = 1;
  for (int c = 8; c >= 1; c >>= 1) {
    if (FIXED + (size_t)c * PER_BATCH <= ws_size) { BPC = c; break; }
  }
  const int R = BPC * 512;

  char* ws = (char*)d_ws;
  float* meanb = (float*)ws;
  float* stdb  = (float*)(ws + 65536);
  int*   dtf   = (int*)(ws + 131072);
  ushort* wt_base = (ushort*)(ws + HDR);
  ushort* wt_f1q = wt_base;
  ushort* wt_f1o = wt_f1q + E_F1Q;
  ushort* wt_f2q = wt_f1o + E_F1O;
  ushort* wt_f2k = wt_f2q + E_F2Q;
  ushort* wt_f2v = wt_f2k + E_F2K;
  ushort* wt_f2o = wt_f2v + E_F2V;
  ushort* wt_o   = wt_f2o + E_F2O;
  ushort* wt_enc = wt_o   + E_SQ;
  ushort* wt_f1k = wt_enc + E_SQ;
  ushort* wt_f1v = wt_f1k + E_SQ;
  ushort* wt_embh = wt_f1v + E_SQ;
  ushort* wt_embl = wt_embh + E_SQ;
  ushort* wt_qh   = wt_embl + E_SQ;
  ushort* wt_ql   = wt_qh   + E_SQ;
  ushort* wt_kh   = wt_ql   + E_SQ;
  ushort* wt_kl   = wt_kh   + E_SQ;
  ushort* wt_vh   = wt_kl   + E_SQ;
  ushort* wt_vl   = wt_vh   + E_SQ;

  char* arena = ws + FIXED;
  const size_t FSL = (size_t)R * 512 * 4;
  const size_t GSL = (size_t)R * DFF * 2;
  void* A_ = arena;
  void* B_ = arena + FSL;
  void* C_ = arena + 2 * FSL;
  void* D_ = arena + 3 * FSL;
  void* E_ = arena + 4 * FSL;                     // fallback path only
  char* gb = arena + (size_t)(use_mfma ? 4 : 5) * FSL;
  void* G1 = gb;
  void* G2 = gb + GSL;
  void* G3 = gb + 2 * GSL;

  // mfma-path split buffers
  ushort* xTh  = (ushort*)G1; ushort* xTl  = xTh  + (size_t)R * 512; // in G1 (dead before f1q)
  ushort* embh = (ushort*)G2; ushort* embl = embh + (size_t)R * 512; // in G2 (dead before pwattn1)
  ushort* qsh  = (ushort*)C_; ushort* qsl  = qsh  + (size_t)R * 512;
  ushort* ksh  = (ushort*)D_; ushort* ksl  = ksh  + (size_t)R * 512;
  ushort* vt   = (ushort*)B_;                                        // vT, dead before f1v

  detect_dtype<<<1, 256, 0, stream>>>((const ushort*)x_enc, dtf);
  // two-phase instance-norm stats; partials live in the (still idle) arena
  instnorm_partial<<<dim3(2, NB, 8), 256, 0, stream>>>(
      x_enc, (float*)A_, (float*)B_, dtf);
  instnorm_reduce<<<dim3(2, NB), 256, 0, stream>>>(
      (const float*)A_, (const float*)B_, meanb, stdb);

  if (use_mfma) {   // one-time weight convert+transpose (KxN -> bf16 NxK)
    transpose_w<<<dim3(DFF / 32, 512 / 32), 256, 0, stream>>>(f1q_w, wt_f1q, 512, DFF, dtf);
    transpose_w<<<dim3(DFF / 32, DFF / 32), 256, 0, stream>>>(f1o_w, wt_f1o, DFF, DFF, dtf);
    transpose_w<<<dim3(512 / 32, DFF / 32), 256, 0, stream>>>(f2q_w, wt_f2q, DFF, 512, dtf);
    transpose_w<<<dim3(DFF / 32, DFF / 32), 256, 0, stream>>>(f2k_w, wt_f2k, DFF, DFF, dtf);
    transpose_w<<<dim3(DFF / 32, DFF / 32), 256, 0, stream>>>(f2v_w, wt_f2v, DFF, DFF, dtf);
    transpose_w<<<dim3(512 / 32, 512 / 32), 256, 0, stream>>>(f2o_w, wt_f2o, 512, 512, dtf);
    transpose_w<<<dim3(512 / 32, 512 / 32), 256, 0, stream>>>(o_w,   wt_o,   512, 512, dtf);
    transpose_w<<<dim3(512 / 32, 512 / 32), 256, 0, stream>>>(enc_w, wt_enc, 512, 512, dtf);
    transpose_w<<<dim3(512 / 32, 512 / 32), 256, 0, stream>>>(f1k_w, wt_f1k, 512, 512, dtf);
    transpose_w<<<dim3(512 / 32, 512 / 32), 256, 0, stream>>>(f1v_w, wt_f1v, 512, 512, dtf);
    transpose_w_split<<<dim3(512 / 32, 512 / 32), 256, 0, stream>>>(embed_w, wt_embh, wt_embl, 512, 512, dtf);
    transpose_w_split<<<dim3(512 / 32, 512 / 32), 256, 0, stream>>>(q_w, wt_qh, wt_ql, 512, 512, dtf);
    transpose_w_split<<<dim3(512 / 32, 512 / 32), 256, 0, stream>>>(k_w, wt_kh, wt_kl, 512, 512, dtf);
    transpose_w_split<<<dim3(512 / 32, 512 / 32), 256, 0, stream>>>(v_w, wt_vh, wt_vl, 512, 512, dtf);
  }

  for (int bc = 0; bc < NB / BPC; ++bc) {
    const int b0 = bc * BPC;
    if (use_mfma) {
      // --- stage 1: split-MFMA GEMMs ---
      norm_transpose_split<<<dim3(16, 16, BPC), 256, 0, stream>>>(
          x_enc, meanb, stdb, xTh, xTl, b0, dtf);
      launch_mgemm3<E3_RELU_PE>(xTh, xTl, wt_embh, wt_embl, nullptr,
                                embh, embl, R, 512, 512, dtf, stream);         // emb hi/lo
      launch_mgemm3<E3_RELU_SPLIT>(embh, embl, wt_qh, wt_ql, q_b,
                                   qsh, qsl, R, 512, 512, dtf, stream);        // q hi/lo
      launch_mgemm3<E3_SPLIT>(embh, embl, wt_kh, wt_kl, k_b,
                              ksh, ksl, R, 512, 512, dtf, stream);             // k hi/lo
      launch_mgemm3<E3_RELU_VT>(embh, embl, wt_vh, wt_vl, v_b,
                                vt, nullptr, R, 512, 512, dtf, stream);        // vT bf16
      gattn_mfma<<<dim3(CC / 16, HH, BPC), 256, 0, stream>>>(
          qsh, qsl, ksh, ksl, vt, (ushort*)A_);                                // attn bf16
      launch_mgemm64<ushort, ushort, M_ADD2_BIAS_LEAKY>(
          A_, wt_o, o_b, embh, C_, R, 512, 512, dtf, stream, embl);            // y bf16
      launch_mgemm64<float, ushort, M_BIAS>(C_, wt_enc, enc_b, nullptr, D_, R, 512, 512, dtf, stream);  // X1 bf16
      // --- stage 2: pwattn1 + LN ---
      launch_mgemm<float, ushort, M_BIAS_RELU>(D_, wt_f1q, f1q_b, nullptr, G1, R, 512, DFF, dtf, stream); // query1
      launch_mgemm64<float, float, M_BIAS     >(D_, wt_f1k, f1k_b, nullptr, A_, R, 512, 512, dtf, stream); // k1 f32
      launch_mgemm64<float, float, M_BIAS_RELU>(D_, wt_f1v, f1v_b, nullptr, B_, R, 512, 512, dtf, stream); // v1 f32
      pwattn1_mfma<<<R / 4, 256, 0, stream>>>(
          (const ushort*)G1, (const float*)A_, (const float*)B_, (ushort*)G2);
      launch_mgemm<ushort, ushort, M_ADD_BIAS_ELU>(G2, wt_f1o, f1o_b, G1, G1, R, DFF, DFF, dtf, stream);  // h
      ln_kernel<<<R, 256, 0, stream>>>((ushort*)G1, ln_g, ln_b, dtf);
      // --- stage 3: pwattn2 + out ---
      launch_mgemm64<float, float, M_BIAS_RELU>(G1, wt_f2q, f2q_b, nullptr, A_, R, DFF, 512, dtf, stream); // query2
      launch_mgemm<float, ushort, M_BIAS     >(G1, wt_f2k, f2k_b, nullptr, G2, R, DFF, DFF, dtf, stream); // k2
      launch_mgemm<float, ushort, M_BIAS_RELU>(G1, wt_f2v, f2v_b, nullptr, G3, R, DFF, DFF, dtf, stream); // v2
      pwattn2_mfma<<<R / 4, 256, 0, stream>>>(
          (const float*)A_, (const ushort*)G2, (const ushort*)G3, (ushort*)B_);
      launch_mgemm64<float, float, M_ADD_BIAS>(B_, wt_f2o, f2o_b, A_, C_, R, 512, 512, dtf, stream);      // y2
    } else {
      norm_transpose<<<dim3(16, 16, BPC), 256, 0, stream>>>(x_enc, meanb, stdb, (float*)A_, b0, dtf);
      launch_gemm<float, float, float, M_RELU_PE >(A_, embed_w, nullptr, nullptr, B_, R, 512, 512, dtf, stream);
      launch_gemm<float, float, float, M_BIAS_RELU>(B_, q_w, q_b, nullptr, C_, R, 512, 512, dtf, stream);
      launch_gemm<float, float, float, M_BIAS     >(B_, k_w, k_b, nullptr, D_, R, 512, 512, dtf, stream);
      launch_gemm<float, float, float, M_BIAS_RELU>(B_, v_w, v_b, nullptr, E_, R, 512, 512, dtf, stream);
      gattn_fb<float><<<dim3(CC / 4, HH, BPC), 256, 0, stream>>>(
          (float*)C_, (float*)D_, (float*)E_, (float*)A_);
      launch_gemm<float, float, float, M_ADD_BIAS_LEAKY>(A_, o_w, o_b, B_, C_, R, 512, 512, dtf, stream);
      launch_gemm<float, float, float, M_BIAS>(C_, enc_w, enc_b, nullptr, D_, R, 512, 512, dtf, stream);
      launch_gemm<float, float, ushort, M_BIAS_RELU>(D_, f1q_w, f1q_b, nullptr, G1, R, 512, DFF, dtf, stream);
      launch_gemm<float, float, float,  M_BIAS     >(D_, f1k_w, f1k_b, nullptr, A_, R, 512, 512, dtf, stream);
      launch_gemm<float, float, float,  M_BIAS_RELU>(D_, f1v_w, f1v_b, nullptr, B_, R, 512, 512, dtf, stream);
      pwattn1_kernel<<<R, 128, 0, stream>>>((const ushort*)G1, (const float*)A_, (const float*)B_, (ushort*)G2);
      launch_gemm<ushort, ushort, ushort, M_ADD_BIAS_ELU>(G2, f1o_w, f1o_b, G1, G1, R, DFF, DFF, dtf, stream);
      ln_kernel<<<R, 256, 0, stream>>>((ushort*)G1, ln_g, ln_b, dtf);
      launch_gemm<ushort, float, float,  M_BIAS_RELU>(G1, f2q_w, f2q_b, nullptr, A_, R, DFF, 512, dtf, stream);
      launch_gemm<ushort, float, ushort, M_BIAS     >(G1, f2k_w, f2k_b, nullptr, G2, R, DFF, DFF, dtf, stream);
      launch_gemm<ushort, float, ushort, M_BIAS_RELU>(G1, f2v_w, f2v_b, nullptr, G3, R, DFF, DFF, dtf, stream);
      pwattn2_kernel<float><<<R, 128, 0, stream>>>((const float*)A_, (const ushort*)G2, (const ushort*)G3, (float*)B_);
      launch_gemm<float, float, float, M_ADD_BIAS>(B_, f2o_w, f2o_b, A_, C_, R, 512, 512, dtf, stream);
    }
    final_kernel<<<R, 128, 0, stream>>>((const float*)C_, fc_w, fc_b, meanb, stdb, d_out, b0 * 512, dtf);
  }
}

// Round 8
// 2328.474 us; speedup vs baseline: 1.2335x; 1.0392x over previous
//
#include <hip/hip_runtime.h>
#include <float.h>
#include <math.h>
#include <stdint.h>

// ---------------------------------------------------------------------------
// Model_33062658245168: Informer-style time-series model. fp32 in/out
// (runtime-detected; bf16 fallback kept). B=32 S=512 C=512 D=512 DF=2048 H=8
// E=64 P=16 PRED=96 K(topk)=10, N=16384.
//
// Round 19: RESUBMIT of round 18 (bench infra failed: "container failed
// twice"; no counters produced). Source is byte-identical to r18.
//  - final_kernel vectorization: thread owns 4 CONTIGUOUS output cols (one
//    float4/ushort4 fc_w load per k-iter), 8 rows/block LDS-staged, grid R/8.
//    fp32 arithmetic unchanged (absmax identical).
//  - everything else byte-frozen at the round-17 state (2420us).
// ---------------------------------------------------------------------------

#define NB   32
#define SS   512
#define CC   512
#define DD   512
#define DFF  2048
#define HH   8
#define EE   64
#define PRED 96

typedef __attribute__((ext_vector_type(8))) short short8;
typedef __attribute__((ext_vector_type(4))) float f32x4;

#define LOG2E 1.4426950408889634f

__device__ __forceinline__ float b2f(ushort u) {
  union { float f; uint32_t i; } c; c.i = ((uint32_t)u) << 16; return c.f;
}
__device__ __forceinline__ ushort f2b(float f) {
  union { float f; uint32_t i; } c; c.f = f;
  uint32_t x = c.i;
  return (ushort)((x + 0x7fffu + ((x >> 16) & 1u)) >> 16);   // RNE
}
__device__ __forceinline__ float lin(const void* p, size_t i, int f32) {
  return f32 ? ((const float*)p)[i] : b2f(((const ushort*)p)[i]);
}
__device__ __forceinline__ void split_bf(float x, ushort& hi, ushort& lo) {
  hi = f2b(x);
  lo = f2b(x - b2f(hi));
}

// ---- DPP 16-lane all-reduce (VALU only) ----
template<int CTRL>
__device__ __forceinline__ float dppmov(float x) {
  union { float f; int i; } a, b;
  a.f = x;
  b.i = __builtin_amdgcn_update_dpp(a.i, a.i, CTRL, 0xF, 0xF, false);
  return b.f;
}
__device__ __forceinline__ float red16_max(float x) {
  x = fmaxf(x, dppmov<0xB1>(x));    // quad_perm xor1
  x = fmaxf(x, dppmov<0x4E>(x));    // quad_perm xor2
  x = fmaxf(x, dppmov<0x141>(x));   // row_half_mirror
  x = fmaxf(x, dppmov<0x140>(x));   // row_mirror
  return x;
}
__device__ __forceinline__ float red16_sum(float x) {
  x += dppmov<0xB1>(x);
  x += dppmov<0x4E>(x);
  x += dppmov<0x141>(x);
  x += dppmov<0x140>(x);
  return x;
}

// ---------------- dtype detection (1 = fp32 inputs) ----------------
__global__ __launch_bounds__(256) void detect_dtype(
    const ushort* __restrict__ x, int* __restrict__ flag)
{
  __shared__ float red[256];
  const int t = threadIdx.x;
  float v = fabsf(b2f(x[2 * t]));
  if (!(v < 1e30f)) v = 1e30f;
  red[t] = v;
  __syncthreads();
  for (int off = 128; off > 0; off >>= 1) {
    if (t < off) red[t] = fmaxf(red[t], red[t + off]);
    __syncthreads();
  }
  if (t == 0) flag[0] = (red[0] > 1e6f) ? 1 : 0;
}

// ---------------- instance norm stats, two-phase ----------------
__global__ __launch_bounds__(256) void instnorm_partial(
    const void* __restrict__ x, float* __restrict__ ps, float* __restrict__ pq,
    const int* __restrict__ dtf)
{
  const int f32 = *dtf;
  const int c = blockIdx.x * 256 + threadIdx.x;
  const int b = blockIdx.y;
  const int t0 = blockIdx.z * 64;
  float s = 0.f, s2 = 0.f;
  for (int t = t0; t < t0 + 64; ++t) {
    const float xv = lin(x, ((size_t)(b * SS) + t) * CC + c, f32);
    s += xv; s2 += xv * xv;
  }
  const int pidx = (b * 8 + blockIdx.z) * CC + c;
  ps[pidx] = s; pq[pidx] = s2;
}

__global__ __launch_bounds__(256) void instnorm_reduce(
    const float* __restrict__ ps, const float* __restrict__ pq,
    float* __restrict__ meanb, float* __restrict__ stdb)
{
  const int c = blockIdx.x * 256 + threadIdx.x;
  const int b = blockIdx.y;
  float s = 0.f, s2 = 0.f;
  #pragma unroll
  for (int i = 0; i < 8; ++i) {
    s  += ps[(b * 8 + i) * CC + c];
    s2 += pq[(b * 8 + i) * CC + c];
  }
  const float mu  = s * (1.f / SS);
  const float var = s2 * (1.f / SS) - mu * mu;
  meanb[b * CC + c] = mu;
  stdb [b * CC + c] = sqrtf(var + 1e-5f);
}

// ---------------- normalize + transpose one chunk (fp32, fallback) ---------
__global__ __launch_bounds__(256) void norm_transpose(
    const void* __restrict__ x, const float* __restrict__ meanb,
    const float* __restrict__ stdb, float* __restrict__ xTc, int b_base,
    const int* __restrict__ dtf)
{
  const int f32 = *dtf;
  __shared__ float t[32][33];
  const int s0 = blockIdx.x * 32, c0 = blockIdx.y * 32, lb = blockIdx.z;
  const int b = b_base + lb;
  const int tx = threadIdx.x & 31, ty = threadIdx.x >> 5;
  #pragma unroll
  for (int i = 0; i < 4; ++i) {
    const int s = s0 + ty + i * 8;
    t[ty + i * 8][tx] = lin(x, ((size_t)(b * SS) + s) * CC + c0 + tx, f32);
  }
  __syncthreads();
  #pragma unroll
  for (int i = 0; i < 4; ++i) {
    const int c = c0 + ty + i * 8;
    const float mu = meanb[b * CC + c], sd = stdb[b * CC + c];
    xTc[((size_t)(lb * CC) + c) * SS + s0 + tx] = (t[tx][ty + i * 8] - mu) / sd;
  }
}

// ---------------- normalize + transpose, hi/lo split output ----------------
__global__ __launch_bounds__(256) void norm_transpose_split(
    const void* __restrict__ x, const float* __restrict__ meanb,
    const float* __restrict__ stdb, ushort* __restrict__ xh,
    ushort* __restrict__ xl, int b_base, const int* __restrict__ dtf)
{
  const int f32 = *dtf;
  __shared__ float t[32][33];
  const int s0 = blockIdx.x * 32, c0 = blockIdx.y * 32, lb = blockIdx.z;
  const int b = b_base + lb;
  const int tx = threadIdx.x & 31, ty = threadIdx.x >> 5;
  #pragma unroll
  for (int i = 0; i < 4; ++i) {
    const int s = s0 + ty + i * 8;
    t[ty + i * 8][tx] = lin(x, ((size_t)(b * SS) + s) * CC + c0 + tx, f32);
  }
  __syncthreads();
  #pragma unroll
  for (int i = 0; i < 4; ++i) {
    const int c = c0 + ty + i * 8;
    const float mu = meanb[b * CC + c], sd = stdb[b * CC + c];
    const float v = (t[tx][ty + i * 8] - mu) / sd;
    const size_t idx = ((size_t)(lb * CC) + c) * SS + s0 + tx;
    ushort hi, lo; split_bf(v, hi, lo);
    xh[idx] = hi; xl[idx] = lo;
  }
}

// ---------------- weight convert+transpose: W (KxN, input dtype) -> bf16 (NxK)
__global__ __launch_bounds__(256) void transpose_w(
    const void* __restrict__ W, ushort* __restrict__ Wt, int K, int N,
    const int* __restrict__ dtf)
{
  const int f32 = *dtf;
  __shared__ float t[32][33];
  const int n0 = blockIdx.x * 32, k0 = blockIdx.y * 32;
  const int tx = threadIdx.x & 31, ty = threadIdx.x >> 5;
  #pragma unroll
  for (int i = 0; i < 4; ++i)
    t[ty + i * 8][tx] = lin(W, (size_t)(k0 + ty + i * 8) * N + n0 + tx, f32);
  __syncthreads();
  #pragma unroll
  for (int i = 0; i < 4; ++i)
    Wt[(size_t)(n0 + ty + i * 8) * K + k0 + tx] = f2b(t[tx][ty + i * 8]);
}

// ---------------- weight transpose + hi/lo split ----------------
__global__ __launch_bounds__(256) void transpose_w_split(
    const void* __restrict__ W, ushort* __restrict__ Whi, ushort* __restrict__ Wlo,
    int K, int N, const int* __restrict__ dtf)
{
  const int f32 = *dtf;
  __shared__ float t[32][33];
  const int n0 = blockIdx.x * 32, k0 = blockIdx.y * 32;
  const int tx = threadIdx.x & 31, ty = threadIdx.x >> 5;
  #pragma unroll
  for (int i = 0; i < 4; ++i)
    t[ty + i * 8][tx] = lin(W, (size_t)(k0 + ty + i * 8) * N + n0 + tx, f32);
  __syncthreads();
  #pragma unroll
  for (int i = 0; i < 4; ++i) {
    const size_t idx = (size_t)(n0 + ty + i * 8) * K + k0 + tx;
    ushort hi, lo; split_bf(t[tx][ty + i * 8], hi, lo);
    Whi[idx] = hi; Wlo[idx] = lo;
  }
}

// ---------------- generic fp32 tiled GEMM (fallback path) ----------
enum GemmMode { M_BIAS = 0, M_BIAS_RELU = 1, M_RELU_PE = 2,
                M_ADD_BIAS_LEAKY = 3, M_ADD_BIAS_ELU = 4, M_ADD_BIAS = 5,
                M_ADD2_BIAS_LEAKY = 6 };

template<typename AT, typename ADT, typename OT, int MODE>
__global__ __launch_bounds__(256) void gemm_kernel(
    const AT* __restrict__ A, const void* __restrict__ Bw,
    const void* __restrict__ bias, const ADT* __restrict__ addend,
    OT* __restrict__ Cout, int M, int K, int Nn, const int* __restrict__ dtf)
{
  const int f32 = *dtf;
  __shared__ __align__(16) float As[16][68];
  __shared__ __align__(16) float Bs[16][68];
  const int tid = threadIdx.x;
  const int m0 = blockIdx.y * 64, n0 = blockIdx.x * 64;
  const int tx = tid & 15, ty = tid >> 4;
  const int la_m = tid >> 2, la_k = (tid & 3) * 4;
  const int lb_k = tid >> 4, lb_n = (tid & 15) * 4;
  float acc[4][4];
  #pragma unroll
  for (int i = 0; i < 4; ++i)
    #pragma unroll
    for (int j = 0; j < 4; ++j) acc[i][j] = 0.f;
  const size_t a_row = (size_t)(m0 + la_m) * K;

  for (int k0 = 0; k0 < K; k0 += 16) {
    if constexpr (sizeof(AT) == 4) {
      const float4 av = *reinterpret_cast<const float4*>(A + a_row + k0 + la_k);
      As[la_k + 0][la_m] = av.x; As[la_k + 1][la_m] = av.y;
      As[la_k + 2][la_m] = av.z; As[la_k + 3][la_m] = av.w;
    } else {
      const ushort4 av = *reinterpret_cast<const ushort4*>(A + a_row + k0 + la_k);
      As[la_k + 0][la_m] = b2f(av.x); As[la_k + 1][la_m] = b2f(av.y);
      As[la_k + 2][la_m] = b2f(av.z); As[la_k + 3][la_m] = b2f(av.w);
    }
    {
      const size_t boff = (size_t)(k0 + lb_k) * Nn + n0 + lb_n;
      if (f32) {
        const float4 bv = *reinterpret_cast<const float4*>((const float*)Bw + boff);
        Bs[lb_k][lb_n + 0] = bv.x; Bs[lb_k][lb_n + 1] = bv.y;
        Bs[lb_k][lb_n + 2] = bv.z; Bs[lb_k][lb_n + 3] = bv.w;
      } else {
        const ushort4 bv = *reinterpret_cast<const ushort4*>((const ushort*)Bw + boff);
        Bs[lb_k][lb_n + 0] = b2f(bv.x); Bs[lb_k][lb_n + 1] = b2f(bv.y);
        Bs[lb_k][lb_n + 2] = b2f(bv.z); Bs[lb_k][lb_n + 3] = b2f(bv.w);
      }
    }
    __syncthreads();
    #pragma unroll
    for (int k = 0; k < 16; ++k) {
      const float4 a4 = *reinterpret_cast<const float4*>(&As[k][ty * 4]);
      const float4 b4 = *reinterpret_cast<const float4*>(&Bs[k][tx * 4]);
      const float aa[4] = {a4.x, a4.y, a4.z, a4.w};
      const float bb[4] = {b4.x, b4.y, b4.z, b4.w};
      #pragma unroll
      for (int i = 0; i < 4; ++i)
        #pragma unroll
        for (int j = 0; j < 4; ++j)
          acc[i][j] = fmaf(aa[i], bb[j], acc[i][j]);
    }
    __syncthreads();
  }

  float biasv[4];
  if constexpr (MODE != M_RELU_PE) {
    #pragma unroll
    for (int j = 0; j < 4; ++j) biasv[j] = lin(bias, n0 + tx * 4 + j, f32);
  }
  #pragma unroll
  for (int i = 0; i < 4; ++i) {
    const int m = m0 + ty * 4 + i;
    #pragma unroll
    for (int j = 0; j < 4; ++j) {
      const int n = n0 + tx * 4 + j;
      float v = acc[i][j];
      if constexpr (MODE == M_BIAS) {
        v += biasv[j];
      } else if constexpr (MODE == M_BIAS_RELU) {
        v = fmaxf(v + biasv[j], 0.f);
      } else if constexpr (MODE == M_RELU_PE) {
        v = fmaxf(v, 0.f);
        const float freq = expf((float)(n & ~1) * (-0.017988946f)); // -ln(1e4)/512
        const float ang  = (float)(m & (CC - 1)) * freq;            // pos = c
        v += (n & 1) ? cosf(ang) : sinf(ang);
      } else {
        float ad;
        if constexpr (sizeof(ADT) == 4) ad = ((const float*)addend)[(size_t)m * Nn + n];
        else                            ad = b2f(((const ushort*)addend)[(size_t)m * Nn + n]);
        v = ad + v + biasv[j];
        if constexpr (MODE == M_ADD_BIAS_LEAKY) v = (v >= 0.f) ? v : 0.5f * v;
        else if constexpr (MODE == M_ADD_BIAS_ELU) v = (v > 0.f) ? v : expm1f(v);
      }
      if constexpr (sizeof(OT) == 4) ((float*)Cout)[(size_t)m * Nn + n] = v;
      else                           ((ushort*)Cout)[(size_t)m * Nn + n] = f2b(v);
    }
  }
}

template<typename AT, typename ADT, typename OT, int MODE>
static void launch_gemm(const void* A, const void* Bw, const void* bias, const void* add,
                        void* Cout, int M, int K, int Nn, const int* dtf, hipStream_t stream)
{
  dim3 grid(Nn / 64, M / 64);
  gemm_kernel<AT, ADT, OT, MODE><<<grid, dim3(256), 0, stream>>>(
      (const AT*)A, Bw, bias, (const ADT*)add, (OT*)Cout, M, K, Nn, dtf);
}

// ---------------- MFMA bf16 GEMM (128x128 tile): Cout = epi(A @ Wt^T) ------
template<typename ADT, typename OT, int MODE>
__global__ __launch_bounds__(256) void mgemm_kernel(
    const ushort* __restrict__ A, const ushort* __restrict__ Wt,
    const void* __restrict__ bias, const ADT* __restrict__ addend,
    const ushort* __restrict__ addend2,
    OT* __restrict__ Cout, int M, int K, int Nn, const int* __restrict__ dtf)
{
  const int f32 = *dtf;
  __shared__ __align__(16) ushort As[128][40];
  __shared__ __align__(16) ushort Bs[128][40];
  const int tid = threadIdx.x;
  const int m0 = blockIdx.y * 128, n0 = blockIdx.x * 128;
  const int wave = tid >> 6, lane = tid & 63;
  const int wm = wave & 1, wn = wave >> 1;
  const int quad = lane >> 4, l15 = lane & 15;

  f32x4 acc[4][4];
  #pragma unroll
  for (int i = 0; i < 4; ++i)
    #pragma unroll
    for (int j = 0; j < 4; ++j) acc[i][j] = (f32x4){0.f, 0.f, 0.f, 0.f};

  const int srow = tid >> 1, sseg = (tid & 1) * 16;
  const size_t a_base = (size_t)(m0 + srow) * K + sseg;
  const size_t b_base = (size_t)(n0 + srow) * K + sseg;

  for (int k0 = 0; k0 < K; k0 += 32) {
    {
      const float4* ga = reinterpret_cast<const float4*>(A + a_base + k0);
      const float4* gb = reinterpret_cast<const float4*>(Wt + b_base + k0);
      const float4 a0 = ga[0], a1 = ga[1];
      const float4 b0 = gb[0], b1 = gb[1];
      float4* da = reinterpret_cast<float4*>(&As[srow][sseg]);
      float4* db = reinterpret_cast<float4*>(&Bs[srow][sseg]);
      da[0] = a0; da[1] = a1;
      db[0] = b0; db[1] = b1;
    }
    __syncthreads();
    short8 af[4], bf[4];
    #pragma unroll
    for (int i = 0; i < 4; ++i)
      af[i] = *reinterpret_cast<const short8*>(&As[wm * 64 + i * 16 + l15][quad * 8]);
    #pragma unroll
    for (int j = 0; j < 4; ++j)
      bf[j] = *reinterpret_cast<const short8*>(&Bs[wn * 64 + j * 16 + l15][quad * 8]);
    #pragma unroll
    for (int i = 0; i < 4; ++i)
      #pragma unroll
      for (int j = 0; j < 4; ++j)
        acc[i][j] = __builtin_amdgcn_mfma_f32_16x16x32_bf16(af[i], bf[j], acc[i][j], 0, 0, 0);
    __syncthreads();
  }

  #pragma unroll
  for (int j = 0; j < 4; ++j) {
    const int n = n0 + wn * 64 + j * 16 + l15;
    const float bv = lin(bias, n, f32);
    #pragma unroll
    for (int i = 0; i < 4; ++i) {
      #pragma unroll
      for (int r = 0; r < 4; ++r) {
        const int m = m0 + wm * 64 + i * 16 + quad * 4 + r;
        float v = acc[i][j][r];
        if constexpr (MODE == M_BIAS) {
          v += bv;
        } else if constexpr (MODE == M_BIAS_RELU) {
          v = fmaxf(v + bv, 0.f);
        } else if constexpr (MODE == M_ADD2_BIAS_LEAKY) {
          const size_t ix = (size_t)m * Nn + n;
          const float ad = b2f(((const ushort*)addend)[ix]) + b2f(addend2[ix]);
          v = ad + v + bv;
          v = (v >= 0.f) ? v : 0.5f * v;
        } else {
          float ad;
          if constexpr (sizeof(ADT) == 4) ad = ((const float*)addend)[(size_t)m * Nn + n];
          else                            ad = b2f(((const ushort*)addend)[(size_t)m * Nn + n]);
          v = ad + v + bv;
          if constexpr (MODE == M_ADD_BIAS_ELU)
            v = (v > 0.f) ? v : (__builtin_amdgcn_exp2f(v * LOG2E) - 1.f);
          else if constexpr (MODE == M_ADD_BIAS_LEAKY) v = (v >= 0.f) ? v : 0.5f * v;
        }
        if constexpr (sizeof(OT) == 4) ((float*)Cout)[(size_t)m * Nn + n] = v;
        else                           ((ushort*)Cout)[(size_t)m * Nn + n] = f2b(v);
      }
    }
  }
}

template<typename ADT, typename OT, int MODE>
static void launch_mgemm(const void* A, const void* Wt, const void* bias, const void* add,
                         void* Cout, int M, int K, int Nn, const int* dtf, hipStream_t stream,
                         const void* add2 = nullptr)
{
  dim3 grid(Nn / 128, M / 128);
  mgemm_kernel<ADT, OT, MODE><<<grid, dim3(256), 0, stream>>>(
      (const ushort*)A, (const ushort*)Wt, bias, (const ADT*)add, (const ushort*)add2,
      (OT*)Cout, M, K, Nn, dtf);
}

// ---------------- MFMA bf16 GEMM (64x64 tile) for N<=512 layers -------------
template<typename ADT, typename OT, int MODE>
__global__ __launch_bounds__(256) void mgemm64_kernel(
    const ushort* __restrict__ A, const ushort* __restrict__ Wt,
    const void* __restrict__ bias, const ADT* __restrict__ addend,
    const ushort* __restrict__ addend2,
    OT* __restrict__ Cout, int M, int K, int Nn, const int* __restrict__ dtf)
{
  const int f32 = *dtf;
  __shared__ __align__(16) ushort As[64][40];
  __shared__ __align__(16) ushort Bs[64][40];
  const int tid = threadIdx.x;
  const int m0 = blockIdx.y * 64, n0 = blockIdx.x * 64;
  const int wave = tid >> 6, lane = tid & 63;
  const int wm = wave & 1, wn = wave >> 1;
  const int quad = lane >> 4, l15 = lane & 15;

  f32x4 acc[2][2];
  #pragma unroll
  for (int i = 0; i < 2; ++i)
    #pragma unroll
    for (int j = 0; j < 2; ++j) acc[i][j] = (f32x4){0.f, 0.f, 0.f, 0.f};

  const int srow = tid >> 2, sseg = (tid & 3) * 8;
  const size_t a_base = (size_t)(m0 + srow) * K + sseg;
  const size_t b_base = (size_t)(n0 + srow) * K + sseg;

  for (int k0 = 0; k0 < K; k0 += 32) {
    *reinterpret_cast<float4*>(&As[srow][sseg]) =
        *reinterpret_cast<const float4*>(A + a_base + k0);
    *reinterpret_cast<float4*>(&Bs[srow][sseg]) =
        *reinterpret_cast<const float4*>(Wt + b_base + k0);
    __syncthreads();
    short8 af[2], bf[2];
    #pragma unroll
    for (int i = 0; i < 2; ++i) {
      af[i] = *reinterpret_cast<const short8*>(&As[wm * 32 + i * 16 + l15][quad * 8]);
      bf[i] = *reinterpret_cast<const short8*>(&Bs[wn * 32 + i * 16 + l15][quad * 8]);
    }
    #pragma unroll
    for (int i = 0; i < 2; ++i)
      #pragma unroll
      for (int j = 0; j < 2; ++j)
        acc[i][j] = __builtin_amdgcn_mfma_f32_16x16x32_bf16(af[i], bf[j], acc[i][j], 0, 0, 0);
    __syncthreads();
  }

  #pragma unroll
  for (int j = 0; j < 2; ++j) {
    const int n = n0 + wn * 32 + j * 16 + l15;
    const float bv = lin(bias, n, f32);
    #pragma unroll
    for (int i = 0; i < 2; ++i) {
      #pragma unroll
      for (int r = 0; r < 4; ++r) {
        const int m = m0 + wm * 32 + i * 16 + quad * 4 + r;
        float v = acc[i][j][r];
        if constexpr (MODE == M_BIAS) {
          v += bv;
        } else if constexpr (MODE == M_BIAS_RELU) {
          v = fmaxf(v + bv, 0.f);
        } else if constexpr (MODE == M_ADD2_BIAS_LEAKY) {
          const size_t ix = (size_t)m * Nn + n;
          const float ad = b2f(((const ushort*)addend)[ix]) + b2f(addend2[ix]);
          v = ad + v + bv;
          v = (v >= 0.f) ? v : 0.5f * v;
        } else {
          float ad;
          if constexpr (sizeof(ADT) == 4) ad = ((const float*)addend)[(size_t)m * Nn + n];
          else                            ad = b2f(((const ushort*)addend)[(size_t)m * Nn + n]);
          v = ad + v + bv;
          if constexpr (MODE == M_ADD_BIAS_ELU)
            v = (v > 0.f) ? v : (__builtin_amdgcn_exp2f(v * LOG2E) - 1.f);
          else if constexpr (MODE == M_ADD_BIAS_LEAKY) v = (v >= 0.f) ? v : 0.5f * v;
        }
        if constexpr (sizeof(OT) == 4) ((float*)Cout)[(size_t)m * Nn + n] = v;
        else                           ((ushort*)Cout)[(size_t)m * Nn + n] = f2b(v);
      }
    }
  }
}

template<typename ADT, typename OT, int MODE>
static void launch_mgemm64(const void* A, const void* Wt, const void* bias, const void* add,
                           void* Cout, int M, int K, int Nn, const int* dtf, hipStream_t stream,
                           const void* add2 = nullptr)
{
  dim3 grid(Nn / 64, M / 64);
  mgemm64_kernel<ADT, OT, MODE><<<grid, dim3(256), 0, stream>>>(
      (const ushort*)A, (const ushort*)Wt, bias, (const ADT*)add, (const ushort*)add2,
      (OT*)Cout, M, K, Nn, dtf);
}

// ---------------- mgemm3: 64x64-tile hi/lo-split 3-MFMA GEMM ----------------
enum Epi3 { E3_RELU_PE = 0, E3_RELU_SPLIT = 1, E3_SPLIT = 2, E3_RELU_VT = 3 };

template<int EPI>
__global__ __launch_bounds__(256) void mgemm3_kernel(
    const ushort* __restrict__ Ah, const ushort* __restrict__ Al,
    const ushort* __restrict__ Bh, const ushort* __restrict__ Bl,
    const void* __restrict__ bias,
    ushort* __restrict__ Oh, ushort* __restrict__ Ol,
    int M, int K, int Nn, const int* __restrict__ dtf)
{
  const int f32 = *dtf;
  __shared__ __align__(16) ushort AsH[64][40];
  __shared__ __align__(16) ushort AsL[64][40];
  __shared__ __align__(16) ushort BsH[64][40];
  __shared__ __align__(16) ushort BsL[64][40];
  const int tid = threadIdx.x;
  const int m0 = blockIdx.y * 64, n0 = blockIdx.x * 64;
  const int wave = tid >> 6, lane = tid & 63;
  const int wm = wave & 1, wn = wave >> 1;
  const int quad = lane >> 4, l15 = lane & 15;

  f32x4 acc[2][2];
  #pragma unroll
  for (int i = 0; i < 2; ++i)
    #pragma unroll
    for (int j = 0; j < 2; ++j) acc[i][j] = (f32x4){0.f, 0.f, 0.f, 0.f};

  const int srow = tid >> 2, sseg = (tid & 3) * 8;
  const size_t a_base = (size_t)(m0 + srow) * K + sseg;
  const size_t b_base = (size_t)(n0 + srow) * K + sseg;

  for (int k0 = 0; k0 < K; k0 += 32) {
    *reinterpret_cast<float4*>(&AsH[srow][sseg]) =
        *reinterpret_cast<const float4*>(Ah + a_base + k0);
    *reinterpret_cast<float4*>(&AsL[srow][sseg]) =
        *reinterpret_cast<const float4*>(Al + a_base + k0);
    *reinterpret_cast<float4*>(&BsH[srow][sseg]) =
        *reinterpret_cast<const float4*>(Bh + b_base + k0);
    *reinterpret_cast<float4*>(&BsL[srow][sseg]) =
        *reinterpret_cast<const float4*>(Bl + b_base + k0);
    __syncthreads();
    short8 afh[2], afl[2], bfh[2], bfl[2];
    #pragma unroll
    for (int i = 0; i < 2; ++i) {
      afh[i] = *reinterpret_cast<const short8*>(&AsH[wm * 32 + i * 16 + l15][quad * 8]);
      afl[i] = *reinterpret_cast<const short8*>(&AsL[wm * 32 + i * 16 + l15][quad * 8]);
      bfh[i] = *reinterpret_cast<const short8*>(&BsH[wn * 32 + i * 16 + l15][quad * 8]);
      bfl[i] = *reinterpret_cast<const short8*>(&BsL[wn * 32 + i * 16 + l15][quad * 8]);
    }
    #pragma unroll
    for (int i = 0; i < 2; ++i)
      #pragma unroll
      for (int j = 0; j < 2; ++j) {
        acc[i][j] = __builtin_amdgcn_mfma_f32_16x16x32_bf16(afh[i], bfh[j], acc[i][j], 0, 0, 0);
        acc[i][j] = __builtin_amdgcn_mfma_f32_16x16x32_bf16(afh[i], bfl[j], acc[i][j], 0, 0, 0);
        acc[i][j] = __builtin_amdgcn_mfma_f32_16x16x32_bf16(afl[i], bfh[j], acc[i][j], 0, 0, 0);
      }
    __syncthreads();
  }

  #pragma unroll
  for (int j = 0; j < 2; ++j) {
    const int n = n0 + wn * 32 + j * 16 + l15;
    float bv = 0.f;
    if constexpr (EPI != E3_RELU_PE) bv = lin(bias, n, f32);
    #pragma unroll
    for (int i = 0; i < 2; ++i) {
      #pragma unroll
      for (int r = 0; r < 4; ++r) {
        const int m = m0 + wm * 32 + i * 16 + quad * 4 + r;
        float v = acc[i][j][r];
        if constexpr (EPI == E3_RELU_PE) {
          v = fmaxf(v, 0.f);
          const float freq = expf((float)(n & ~1) * (-0.017988946f)); // -ln(1e4)/512
          const float ang  = (float)(m & (CC - 1)) * freq;            // pos = c
          v += (n & 1) ? cosf(ang) : sinf(ang);
        } else if constexpr (EPI == E3_RELU_SPLIT || EPI == E3_RELU_VT) {
          v = fmaxf(v + bv, 0.f);
        } else {
          v = v + bv;
        }
        if constexpr (EPI == E3_RELU_VT) {
          // pre-transposed: vT[(lb*512 + n)][s] with lb = m>>9, s = m&511
          Oh[((size_t)((m >> 9) * 512 + n)) * 512 + (m & 511)] = f2b(v);
        } else {
          ushort hi, lo; split_bf(v, hi, lo);
          Oh[(size_t)m * Nn + n] = hi;
          Ol[(size_t)m * Nn + n] = lo;
        }
      }
    }
  }
}

template<int EPI>
static void launch_mgemm3(const void* Ahv, const void* Alv, const ushort* Bh,
                          const ushort* Bl, const void* bias, void* Oh, void* Ol,
                          int M, int K, int Nn, const int* dtf, hipStream_t stream)
{
  dim3 grid(Nn / 64, M / 64);
  mgemm3_kernel<EPI><<<grid, dim3(256), 0, stream>>>(
      (const ushort*)Ahv, (const ushort*)Alv, Bh, Bl, bias,
      (ushort*)Oh, (ushort*)Ol, M, K, Nn, dtf);
}

// ---------------- GAttn via MFMA: register scores + DPP top-k ---------------
// S-phase uses an explicit 2-stage prefetch pipeline (chunk c+1's K frags
// loaded into named regs before chunk c's MFMAs) so load latency overlaps
// MFMA regardless of regalloc heuristics.
__global__ __launch_bounds__(256, 2) void gattn_mfma(
    const ushort* __restrict__ qsh, const ushort* __restrict__ qsl,
    const ushort* __restrict__ ksh, const ushort* __restrict__ ksl,
    const ushort* __restrict__ vt, ushort* __restrict__ out)
{
  const int tid = threadIdx.x;
  const int wave = tid >> 6, lane = tid & 63;
  const int quad = lane >> 4, l15 = lane & 15;
  const int l0 = blockIdx.x * 16;
  const int h = blockIdx.y, bz = blockIdx.z;

  __shared__ __align__(16) ushort P[16][520];    // 16640 B (unnormalized bf16 weights)
  __shared__ float cand[16][40];                 // 2560 B (4 waves x sorted top-10)
  __shared__ float psum[16][4];                  // 256 B  (per-wave partial sums)

  // ---- Q fragments (hi/lo), kk-chunks 0,1 ----
  short8 ah[2], al[2];
  {
    const size_t qoff = ((size_t)bz * CC + l0 + l15) * DD + h * EE + quad * 8;
    ah[0] = *reinterpret_cast<const short8*>(qsh + qoff);
    ah[1] = *reinterpret_cast<const short8*>(qsh + qoff + 32);
    al[0] = *reinterpret_cast<const short8*>(qsl + qoff);
    al[1] = *reinterpret_cast<const short8*>(qsl + qoff + 32);
  }

  // ---- S phase into registers: sacc[c][r] = S[quad*4+r][c*64+wave*16+l15] --
  f32x4 sacc[8];
  {
    const size_t kbase = ((size_t)bz * CC + wave * 16 + l15) * DD + h * EE + quad * 8;
    short8 pbh0 = *reinterpret_cast<const short8*>(ksh + kbase);
    short8 pbl0 = *reinterpret_cast<const short8*>(ksl + kbase);
    short8 pbh1 = *reinterpret_cast<const short8*>(ksh + kbase + 32);
    short8 pbl1 = *reinterpret_cast<const short8*>(ksl + kbase + 32);
    #pragma unroll
    for (int c = 0; c < 8; ++c) {
      const short8 cbh0 = pbh0, cbl0 = pbl0, cbh1 = pbh1, cbl1 = pbl1;
      if (c < 7) {
        const size_t noff = kbase + (size_t)((c + 1) * 64) * DD;
        pbh0 = *reinterpret_cast<const short8*>(ksh + noff);
        pbl0 = *reinterpret_cast<const short8*>(ksl + noff);
        pbh1 = *reinterpret_cast<const short8*>(ksh + noff + 32);
        pbl1 = *reinterpret_cast<const short8*>(ksl + noff + 32);
      }
      f32x4 acc = (f32x4){0.f, 0.f, 0.f, 0.f};
      __builtin_amdgcn_s_setprio(1);
      acc = __builtin_amdgcn_mfma_f32_16x16x32_bf16(ah[0], cbh0, acc, 0, 0, 0);
      acc = __builtin_amdgcn_mfma_f32_16x16x32_bf16(ah[0], cbl0, acc, 0, 0, 0);
      acc = __builtin_amdgcn_mfma_f32_16x16x32_bf16(al[0], cbh0, acc, 0, 0, 0);
      acc = __builtin_amdgcn_mfma_f32_16x16x32_bf16(ah[1], cbh1, acc, 0, 0, 0);
      acc = __builtin_amdgcn_mfma_f32_16x16x32_bf16(ah[1], cbl1, acc, 0, 0, 0);
      acc = __builtin_amdgcn_mfma_f32_16x16x32_bf16(al[1], cbh1, acc, 0, 0, 0);
      __builtin_amdgcn_s_setprio(0);
      sacc[c] = acc;
    }
  }

  // ---- stage-1 top-k: each quad extracts its row's wave-local top-10 ----
  #pragma unroll
  for (int r = 0; r < 4; ++r) {
    float wk[8];
    #pragma unroll
    for (int c = 0; c < 8; ++c) wk[c] = sacc[c][r];
    float myg = 0.f;
    for (int it = 0; it < 10; ++it) {
      float lm = wk[0];
      #pragma unroll
      for (int c = 1; c < 8; ++c) lm = fmaxf(lm, wk[c]);
      const float gm = red16_max(lm);
      if (l15 == it) myg = gm;
      if (it < 9) {
        const unsigned long long msk = __ballot(lm == gm);
        const int sel = (__ffsll((unsigned long long)((msk >> (quad * 16)) & 0xFFFFull)) - 1)
                        + quad * 16;
        if (lane == sel) {
          #pragma unroll
          for (int c = 0; c < 8; ++c) { if (wk[c] == gm) { wk[c] = -FLT_MAX; break; } }
        }
      }
    }
    if (l15 < 10) cand[quad * 4 + r][wave * 10 + l15] = myg;
  }
  __syncthreads();

  // ---- merge 4 sorted lists of 10 -> global maxv + thr (10th) ----
  float mx, thr;
  {
    const int mr = lane & 15;
    float h0 = cand[mr][0], h1 = cand[mr][10], h2 = cand[mr][20], h3 = cand[mr][30];
    int i0 = 0, i1 = 0, i2 = 0, i3 = 0;
    float cur = 0.f;
    mx = 0.f;
    #pragma unroll
    for (int t = 0; t < 10; ++t) {
      cur = fmaxf(fmaxf(h0, h1), fmaxf(h2, h3));
      if (t == 0) mx = cur;
      if (t < 9) {
        const bool a0 = (cur == h0);
        const bool a1 = !a0 && (cur == h1);
        const bool a2 = !a0 && !a1 && (cur == h2);
        const int ni0 = i0 + (a0 ? 1 : 0);
        const int ni1 = i1 + (a1 ? 1 : 0);
        const int ni2 = i2 + (a2 ? 1 : 0);
        const int ni3 = i3 + ((a0 || a1 || a2) ? 0 : 1);
        const int off = a0 ? ni0 : (a1 ? 10 + ni1 : (a2 ? 20 + ni2 : 30 + ni3));
        const float nv = cand[mr][off];
        h0 = a0 ? nv : h0;
        h1 = a1 ? nv : h1;
        h2 = a2 ? nv : h2;
        h3 = (a0 || a1 || a2) ? h3 : nv;
        i0 = ni0; i1 = ni1; i2 = ni2; i3 = ni3;
      }
    }
    thr = cur;
  }
  // distribute row thr/max to the quad that owns the row
  float thrR[4], mxR[4];
  #pragma unroll
  for (int r = 0; r < 4; ++r) {
    thrR[r] = __shfl(thr, quad * 4 + r);
    mxR[r]  = __shfl(mx,  quad * 4 + r);
  }

  // ---- exp + partial sums + P write ----
  #pragma unroll
  for (int r = 0; r < 4; ++r) {
    const int Rr = quad * 4 + r;
    float s = 0.f;
    #pragma unroll
    for (int c = 0; c < 8; ++c) {
      const float sc = sacc[c][r];
      const float p = (sc >= thrR[r])
          ? __builtin_amdgcn_exp2f((sc - mxR[r]) * (0.125f * LOG2E)) : 0.f;
      P[Rr][c * 64 + wave * 16 + l15] = f2b(p);
      s += p;
    }
    s = red16_sum(s);
    if (l15 == 0) psum[Rr][wave] = s;
  }
  __syncthreads();

  // ---- PV phase: wave w owns e-cols w*16..w*16+15; vT loaded direct ----
  f32x4 pacc = (f32x4){0.f, 0.f, 0.f, 0.f};
  const size_t vbase = ((size_t)bz * 512 + h * EE + wave * 16 + l15) * 512 + quad * 8;
  #pragma unroll
  for (int c = 0; c < 4; ++c) {
    #pragma unroll
    for (int ks = 0; ks < 4; ++ks) {
      const int s0 = c * 128 + ks * 32;
      const short8 pa = *reinterpret_cast<const short8*>(&P[l15][s0 + quad * 8]);
      const short8 vb = *reinterpret_cast<const short8*>(vt + vbase + s0);
      __builtin_amdgcn_s_setprio(1);
      pacc = __builtin_amdgcn_mfma_f32_16x16x32_bf16(pa, vb, pacc, 0, 0, 0);
      __builtin_amdgcn_s_setprio(0);
    }
  }

  // ---- epilogue ----
  #pragma unroll
  for (int r = 0; r < 4; ++r) {
    const int Rr = quad * 4 + r;
    const float4 ps = *reinterpret_cast<const float4*>(&psum[Rr][0]);
    const float inv = 1.f / (ps.x + ps.y + ps.z + ps.w);
    out[((size_t)bz * CC + l0 + Rr) * DD + h * EE + wave * 16 + l15] = f2b(pacc[r] * inv);
  }
}

// ---------------- GAttn fallback (fp32 path only) -----------
template<typename OT>
__global__ __launch_bounds__(256) void gattn_fb(
    const float* __restrict__ q, const float* __restrict__ k,
    const float* __restrict__ v, OT* __restrict__ out)
{
  const int tid = threadIdx.x;
  const int wave = tid >> 6, lane = tid & 63;
  const int l0 = blockIdx.x * 4;
  const int h = blockIdx.y, bz = blockIdx.z;
  const int l = l0 + wave;
  const size_t base = ((size_t)bz * CC) * DD + h * EE;

  __shared__ __align__(16) float kt[64][68];
  __shared__ __align__(16) float qs[4][64];
  __shared__ __align__(16) float ww[4][512];

  qs[wave][lane] = q[((size_t)bz * CC + l) * DD + h * EE + lane];

  float sc[8];
  const int sl = tid >> 4;
  const int e4 = (tid & 15) * 4;
  for (int c8 = 0; c8 < 8; ++c8) {
    #pragma unroll
    for (int r = 0; r < 4; ++r) {
      const int s_local = sl + r * 16;
      const float4 kv = *reinterpret_cast<const float4*>(
          k + base + (size_t)(c8 * 64 + s_local) * DD + e4);
      *reinterpret_cast<float4*>(&kt[s_local][e4]) = kv;
    }
    __syncthreads();
    float a = 0.f;
    #pragma unroll
    for (int e = 0; e < 16; ++e) {
      const float4 qv = *reinterpret_cast<const float4*>(&qs[wave][e * 4]);
      const float4 kv = *reinterpret_cast<const float4*>(&kt[lane][e * 4]);
      a += qv.x * kv.x + qv.y * kv.y + qv.z * kv.z + qv.w * kv.w;
    }
    sc[c8] = a;
    __syncthreads();
  }

  float wk[8];
  #pragma unroll
  for (int j = 0; j < 8; ++j) wk[j] = sc[j];
  float maxv = 0.f, thr = 0.f;
  for (int it = 0; it < 10; ++it) {
    float lm = wk[0];
    #pragma unroll
    for (int j = 1; j < 8; ++j) lm = fmaxf(lm, wk[j]);
    float gm = lm;
    #pragma unroll
    for (int off = 32; off > 0; off >>= 1) gm = fmaxf(gm, __shfl_xor(gm, off));
    if (it == 0) maxv = gm;
    if (it == 9) { thr = gm; break; }
    const unsigned long long msk = __ballot(lm == gm);
    if (lane == __ffsll(msk) - 1) {
      #pragma unroll
      for (int j = 0; j < 8; ++j) { if (wk[j] == gm) { wk[j] = -FLT_MAX; break; } }
    }
  }

  float lsum = 0.f;
  #pragma unroll
  for (int j = 0; j < 8; ++j) {
    const float p = (sc[j] >= thr) ? expf((sc[j] - maxv) * 0.125f) : 0.f;
    ww[wave][j * 64 + lane] = p;
    lsum += p;
  }
  #pragma unroll
  for (int off = 32; off > 0; off >>= 1) lsum += __shfl_xor(lsum, off);
  const float inv = 1.f / lsum;
  __syncthreads();

  float acc = 0.f;
  const float* vp = v + base + lane;
  const float* wp = ww[wave];
  for (int s = 0; s < 512; s += 4) {
    const float4 w4 = *reinterpret_cast<const float4*>(&wp[s]);
    acc = fmaf(w4.x, vp[(size_t)(s + 0) * DD], acc);
    acc = fmaf(w4.y, vp[(size_t)(s + 1) * DD], acc);
    acc = fmaf(w4.z, vp[(size_t)(s + 2) * DD], acc);
    acc = fmaf(w4.w, vp[(size_t)(s + 3) * DD], acc);
  }
  const float res = acc * inv;
  const size_t oi = ((size_t)bz * CC + l) * DD + h * EE + lane;
  if constexpr (sizeof(OT) == 4) out[oi] = res;
  else                           out[oi] = f2b(res);
}

// ---------------- pwattn1 via MFMA: one row per wave ----------------
__global__ __launch_bounds__(256) void pwattn1_mfma(
    const ushort* __restrict__ query, const float* __restrict__ k1,
    const float* __restrict__ v1, ushort* __restrict__ V1)
{
  const int tid = threadIdx.x;
  const int wave = tid >> 6, lane = tid & 63;
  const int quad = lane >> 4, l15 = lane & 15;
  const int n = blockIdx.x * 4 + wave;

  __shared__ __align__(16) ushort Pl[4][16][40];   // stride 80B (16B-aligned)

  const ushort* qrow = query + (size_t)n * DFF;
  const float*  krow = k1 + (size_t)n * 512;
  const float*  vrow = v1 + (size_t)n * 512;
  ushort* orow = V1 + (size_t)n * DFF;

  const short8 zz = {0, 0, 0, 0, 0, 0, 0, 0};
  const f32x4 zacc = (f32x4){0.f, 0.f, 0.f, 0.f};

  // B-frags for scores: col s = nt*16+l15, k = e = quad*8+i (valid e<16)
  short8 bh[2], bl[2];
  #pragma unroll
  for (int nt = 0; nt < 2; ++nt) {
    short8 hh = zz, ll = zz;
    if (quad < 2) {
      const float* kp = krow + (nt * 16 + l15) * 16 + quad * 8;
      #pragma unroll
      for (int i = 0; i < 8; ++i) {
        ushort hi_, lo_; split_bf(kp[i], hi_, lo_);
        hh[i] = (short)hi_; ll[i] = (short)lo_;
      }
    }
    bh[nt] = hh; bl[nt] = ll;
  }
  // B-frag for PV: v[k=s=quad*8+i][n=e=l15]
  short8 vb;
  #pragma unroll
  for (int i = 0; i < 8; ++i) vb[i] = (short)f2b(vrow[(quad * 8 + i) * 16 + l15]);

  #pragma unroll
  for (int mt = 0; mt < 8; ++mt) {
    short8 qa = zz;
    if (quad < 2)
      qa = *reinterpret_cast<const short8*>(qrow + (mt * 16 + l15) * 16 + quad * 8);
    f32x4 acc[2];
    #pragma unroll
    for (int nt = 0; nt < 2; ++nt) {
      f32x4 t = __builtin_amdgcn_mfma_f32_16x16x32_bf16(qa, bl[nt], zacc, 0, 0, 0);
      acc[nt] = __builtin_amdgcn_mfma_f32_16x16x32_bf16(qa, bh[nt], t, 0, 0, 0);
    }
    // softmax over 32 cols (2 nt x 16 lanes); rows quad*4+r
    float inv[4];
    #pragma unroll
    for (int r = 0; r < 4; ++r) {
      float m = red16_max(fmaxf(acc[0][r], acc[1][r]));
      const float p0 = __builtin_amdgcn_exp2f((acc[0][r] - m) * (0.25f * LOG2E));
      const float p1 = __builtin_amdgcn_exp2f((acc[1][r] - m) * (0.25f * LOG2E));
      acc[0][r] = p0; acc[1][r] = p1;
      const float s = red16_sum(p0 + p1);
      inv[r] = 1.f / s;
    }
    #pragma unroll
    for (int nt = 0; nt < 2; ++nt)
      #pragma unroll
      for (int r = 0; r < 4; ++r)
        Pl[wave][quad * 4 + r][nt * 16 + l15] = f2b(acc[nt][r]);
    const short8 pa = *reinterpret_cast<const short8*>(&Pl[wave][l15][quad * 8]);
    const f32x4 pv = __builtin_amdgcn_mfma_f32_16x16x32_bf16(pa, vb, zacc, 0, 0, 0);
    #pragma unroll
    for (int r = 0; r < 4; ++r)
      orow[(mt * 16 + quad * 4 + r) * 16 + l15] = f2b(pv[r] * inv[r]);
  }
}

// ---------------- pwattn2 via MFMA: one row per wave ----------------
__global__ __launch_bounds__(256) void pwattn2_mfma(
    const float* __restrict__ query2, const ushort* __restrict__ k2,
    const ushort* __restrict__ v2, ushort* __restrict__ V2)
{
  const int tid = threadIdx.x;
  const int wave = tid >> 6, lane = tid & 63;
  const int quad = lane >> 4, l15 = lane & 15;
  const int n = blockIdx.x * 4 + wave;

  __shared__ __align__(16) ushort Pl[4][16][136];  // stride 272B (16B-aligned)

  const float*  qrow = query2 + (size_t)n * 512;
  const ushort* krow = k2 + (size_t)n * DFF;
  const ushort* vrow = v2 + (size_t)n * DFF;
  ushort* orow = V2 + (size_t)n * 512;

  const short8 zz = {0, 0, 0, 0, 0, 0, 0, 0};
  const f32x4 zacc = (f32x4){0.f, 0.f, 0.f, 0.f};

  // B-frags for scores: col s = nt*16+l15 (8 nt), k = e = quad*8+i (<16)
  short8 kb[8];
  #pragma unroll
  for (int nt = 0; nt < 8; ++nt)
    kb[nt] = (quad < 2)
        ? *reinterpret_cast<const short8*>(krow + (nt * 16 + l15) * 16 + quad * 8)
        : zz;

  // B-frags for PV: v[k=s=kt*32+quad*8+i][n=e=l15]
  short8 vb[4];
  #pragma unroll
  for (int kt = 0; kt < 4; ++kt)
    #pragma unroll
    for (int i = 0; i < 8; ++i)
      vb[kt][i] = (short)vrow[(kt * 32 + quad * 8 + i) * 16 + l15];

  #pragma unroll
  for (int mt = 0; mt < 2; ++mt) {
    // A hi/lo: q[m=mt*16+l15][k=quad*8+i (<16)]
    short8 ahh = zz, all_ = zz;
    if (quad < 2) {
      const float* qp = qrow + (mt * 16 + l15) * 16 + quad * 8;
      #pragma unroll
      for (int i = 0; i < 8; ++i) {
        ushort hi_, lo_; split_bf(qp[i], hi_, lo_);
        ahh[i] = (short)hi_; all_[i] = (short)lo_;
      }
    }
    f32x4 acc[8];
    #pragma unroll
    for (int nt = 0; nt < 8; ++nt) {
      f32x4 t = __builtin_amdgcn_mfma_f32_16x16x32_bf16(all_, kb[nt], zacc, 0, 0, 0);
      acc[nt] = __builtin_amdgcn_mfma_f32_16x16x32_bf16(ahh, kb[nt], t, 0, 0, 0);
    }
    // softmax over 128 cols (8 nt x 16 lanes); rows quad*4+r
    float inv[4];
    #pragma unroll
    for (int r = 0; r < 4; ++r) {
      float m = acc[0][r];
      #pragma unroll
      for (int nt = 1; nt < 8; ++nt) m = fmaxf(m, acc[nt][r]);
      m = red16_max(m);
      float s = 0.f;
      #pragma unroll
      for (int nt = 0; nt < 8; ++nt) {
        const float p = __builtin_amdgcn_exp2f((acc[nt][r] - m) * (0.25f * LOG2E));
        acc[nt][r] = p; s += p;
      }
      s = red16_sum(s);
      inv[r] = 1.f / s;
    }
    #pragma unroll
    for (int nt = 0; nt < 8; ++nt)
      #pragma unroll
      for (int r = 0; r < 4; ++r)
        Pl[wave][quad * 4 + r][nt * 16 + l15] = f2b(acc[nt][r]);
    f32x4 pv = zacc;
    #pragma unroll
    for (int kt = 0; kt < 4; ++kt) {
      const short8 pa = *reinterpret_cast<const short8*>(&Pl[wave][l15][kt * 32 + quad * 8]);
      pv = __builtin_amdgcn_mfma_f32_16x16x32_bf16(pa, vb[kt], pv, 0, 0, 0);
    }
    #pragma unroll
    for (int r = 0; r < 4; ++r)
      orow[(mt * 16 + quad * 4 + r) * 16 + l15] = f2b(pv[r] * inv[r]);
  }
}

// ---------------- pwattn1 (fallback) ----------------
__global__ __launch_bounds__(128) void pwattn1_kernel(
    const ushort* __restrict__ query, const float* __restrict__ k1,
    const float* __restrict__ v1, ushort* __restrict__ V1)
{
  const int n = blockIdx.x, tid = threadIdx.x;
  __shared__ float ks[512], vs[512];
  __shared__ float Am[128][33];
  for (int i = tid; i < 512; i += 128) { ks[i] = k1[(size_t)n * 512 + i]; vs[i] = v1[(size_t)n * 512 + i]; }
  __syncthreads();
  {
    const int l = tid;
    float qv[16];
    const ushort* qp = query + (size_t)n * DFF + l * 16;
    #pragma unroll
    for (int e = 0; e < 16; ++e) qv[e] = b2f(qp[e]);
    float scl[32], mx = -FLT_MAX;
    #pragma unroll
    for (int s = 0; s < 32; ++s) {
      float a = 0.f;
      #pragma unroll
      for (int e = 0; e < 16; ++e) a += qv[e] * ks[s * 16 + e];
      scl[s] = a; mx = fmaxf(mx, a);
    }
    float sum = 0.f;
    #pragma unroll
    for (int s = 0; s < 32; ++s) { const float p = expf((scl[s] - mx) * 0.25f); scl[s] = p; sum += p; }
    const float invs = 1.f / sum;
    #pragma unroll
    for (int s = 0; s < 32; ++s) Am[l][s] = scl[s] * invs;
  }
  __syncthreads();
  #pragma unroll
  for (int r = 0; r < 16; ++r) {
    const int idx = tid + 128 * r;
    const int l = idx >> 4, e = idx & 15;
    float a = 0.f;
    #pragma unroll
    for (int s = 0; s < 32; ++s) a += Am[l][s] * vs[s * 16 + e];
    V1[(size_t)n * DFF + idx] = f2b(a);
  }
}

// ---------------- LayerNorm over 2048, in-place bf16 ----------------
__global__ __launch_bounds__(256) void ln_kernel(
    ushort* __restrict__ h, const void* __restrict__ g, const void* __restrict__ bt,
    const int* __restrict__ dtf)
{
  const int f32 = *dtf;
  const int n = blockIdx.x, tid = threadIdx.x;
  ushort* hp = h + (size_t)n * DFF;
  float x[8]; float s = 0.f, s2 = 0.f;
  #pragma unroll
  for (int i = 0; i < 8; ++i) {
    const float xv = b2f(hp[tid + 256 * i]);
    x[i] = xv; s += xv; s2 += xv * xv;
  }
  __shared__ float rs[256], rq[256];
  rs[tid] = s; rq[tid] = s2;
  __syncthreads();
  for (int off = 128; off > 0; off >>= 1) {
    if (tid < off) { rs[tid] += rs[tid + off]; rq[tid] += rq[tid + off]; }
    __syncthreads();
  }
  const float mu  = rs[0] * (1.f / DFF);
  const float var = rq[0] * (1.f / DFF) - mu * mu;
  const float inv = rsqrtf(var + 1e-5f);
  #pragma unroll
  for (int i = 0; i < 8; ++i) {
    const int d = tid + 256 * i;
    hp[d] = f2b((x[i] - mu) * inv * lin(g, d, f32) + lin(bt, d, f32));
  }
}

// ---------------- pwattn2 (fallback), templated output -----------
template<typename OT>
__global__ __launch_bounds__(128) void pwattn2_kernel(
    const float* __restrict__ query2, const ushort* __restrict__ k2,
    const ushort* __restrict__ v2, OT* __restrict__ V2)
{
  const int n = blockIdx.x, tid = threadIdx.x;
  __shared__ float ks[2048], vs[2048];
  __shared__ float Am[32][129];
  for (int i = tid; i < 2048; i += 128) {
    ks[i] = b2f(k2[(size_t)n * DFF + i]);
    vs[i] = b2f(v2[(size_t)n * DFF + i]);
  }
  __syncthreads();
  if (tid < 32) {
    const int l = tid;
    float qv[16];
    #pragma unroll
    for (int e = 0; e < 16; ++e) qv[e] = query2[(size_t)n * 512 + l * 16 + e];
    float mx = -FLT_MAX;
    for (int s = 0; s < 128; ++s) {
      float a = 0.f;
      #pragma unroll
      for (int e = 0; e < 16; ++e) a += qv[e] * ks[s * 16 + e];
      Am[l][s] = a; mx = fmaxf(mx, a);
    }
    float sum = 0.f;
    for (int s = 0; s < 128; ++s) { const float p = expf((Am[l][s] - mx) * 0.25f); Am[l][s] = p; sum += p; }
    const float invs = 1.f / sum;
    for (int s = 0; s < 128; ++s) Am[l][s] *= invs;
  }
  __syncthreads();
  #pragma unroll
  for (int r = 0; r < 4; ++r) {
    const int idx = tid + 128 * r;
    const int l = idx >> 4, e = idx & 15;
    float a = 0.f;
    for (int s = 0; s < 128; ++s) a += Am[l][s] * vs[s * 16 + e];
    if constexpr (sizeof(OT) == 4) V2[(size_t)n * 512 + idx] = a;
    else                           V2[(size_t)n * 512 + idx] = f2b(a);
  }
}

// ---------------- final: dec = y@fc_w + fc_b; out = dec*std+mean -----------
// 8 rows/block (LDS-staged), thread owns 4 CONTIGUOUS output cols => one
// float4/ushort4 fc_w load per k-iteration (4x fewer load instructions).
__global__ __launch_bounds__(256) void final_kernel(
    const float* __restrict__ y, const void* __restrict__ fc_w,
    const void* __restrict__ fc_b, const float* __restrict__ meanb,
    const float* __restrict__ stdb, void* __restrict__ out, int row_base,
    const int* __restrict__ dtf)
{
  const int f32 = *dtf;
  const int tid = threadIdx.x;
  const int rloc = tid >> 5;           // 0..7 (row within block)
  const int t32 = tid & 31;            // 0..31
  __shared__ __align__(16) float yr[8][512];
  const int blk_row0 = blockIdx.x * 8;
  #pragma unroll
  for (int i = 0; i < 4; ++i) {
    const int idx = tid + i * 256;     // 1024 float4 slots total
    const int rr = idx >> 7, dd = (idx & 127) * 4;
    *reinterpret_cast<float4*>(&yr[rr][dd]) =
        *reinterpret_cast<const float4*>(y + (size_t)(blk_row0 + rr) * 512 + dd);
  }
  __syncthreads();
  if (t32 < 24) {
    const int n0 = t32 * 4;
    float a0 = 0.f, a1 = 0.f, a2 = 0.f, a3 = 0.f;
    if (f32) {
      const float* W = (const float*)fc_w + n0;
      for (int d = 0; d < 512; ++d) {
        const float4 w4 = *reinterpret_cast<const float4*>(W + (size_t)d * PRED);
        const float yv = yr[rloc][d];
        a0 = fmaf(yv, w4.x, a0); a1 = fmaf(yv, w4.y, a1);
        a2 = fmaf(yv, w4.z, a2); a3 = fmaf(yv, w4.w, a3);
      }
    } else {
      const ushort* W = (const ushort*)fc_w + n0;
      for (int d = 0; d < 512; ++d) {
        const ushort4 w4 = *reinterpret_cast<const ushort4*>(W + (size_t)d * PRED);
        const float yv = yr[rloc][d];
        a0 = fmaf(yv, b2f(w4.x), a0); a1 = fmaf(yv, b2f(w4.y), a1);
        a2 = fmaf(yv, b2f(w4.z), a2); a3 = fmaf(yv, b2f(w4.w), a3);
      }
    }
    const int row = row_base + blk_row0 + rloc;
    const int b = row >> 9, c = row & 511;
    const float sd = stdb[row], mu = meanb[row];
    const float av[4] = {a0, a1, a2, a3};
    #pragma unroll
    for (int j = 0; j < 4; ++j) {
      const float r = (av[j] + lin(fc_b, n0 + j, f32)) * sd + mu;
      const size_t oi = ((size_t)b * PRED + n0 + j) * CC + c;
      if (f32) ((float*)out)[oi] = r;
      else     ((ushort*)out)[oi] = f2b(r);
    }
  }
}

// ---------------------------------------------------------------------------
extern "C" void kernel_launch(void* const* d_in, const int* in_sizes, int n_in,
                              void* d_out, int out_size, void* d_ws, size_t ws_size,
                              hipStream_t stream)
{
  (void)in_sizes; (void)n_in; (void)out_size;
  const void* x_enc   = d_in[0];
  const void* embed_w = d_in[4];
  const void* q_w = d_in[5],  * q_b = d_in[6];
  const void* k_w = d_in[7],  * k_b = d_in[8];
  const void* v_w = d_in[9],  * v_b = d_in[10];
  const void* o_w = d_in[11], * o_b = d_in[12];
  const void* enc_w = d_in[13], * enc_b = d_in[14];
  const void* f1q_w = d_in[15], * f1q_b = d_in[16];
  const void* f1k_w = d_in[17], * f1k_b = d_in[18];
  const void* f1v_w = d_in[19], * f1v_b = d_in[20];
  const void* f1o_w = d_in[21], * f1o_b = d_in[22];
  const void* f2q_w = d_in[23], * f2q_b = d_in[24];
  const void* f2k_w = d_in[25], * f2k_b = d_in[26];
  const void* f2v_w = d_in[27], * f2v_b = d_in[28];
  const void* f2o_w = d_in[29], * f2o_b = d_in[30];
  const void* ln_g  = d_in[31], * ln_b  = d_in[32];
  const void* fc_w  = d_in[33], * fc_b  = d_in[34];

  const size_t HDR = 131072 + 1024;
  const size_t E_F1Q = 512ull * 2048, E_F1O = 2048ull * 2048, E_F2Q = 2048ull * 512;
  const size_t E_F2K = 2048ull * 2048, E_F2V = 2048ull * 2048, E_F2O = 512ull * 512;
  const size_t E_SQ  = 512ull * 512;   // o_w, enc_w, f1k_w, f1v_w each
  // + 8 split arrays (embed/q/k/v hi+lo)
  const size_t WT_EL = E_F1Q + E_F1O + E_F2Q + E_F2K + E_F2V + E_F2O + 4 * E_SQ + 8 * E_SQ;
  const size_t WT_BYTES = WT_EL * 2;   // ~34.5 MB
  const size_t PB_MFMA = 4ull * 512 * 512 * 4 + 3ull * 512 * DFF * 2; // 10.0MB
  const size_t PB_FB   = 5ull * 512 * 512 * 4 + 3ull * 512 * DFF * 2; // 11.0MB

  const int use_mfma = (HDR + WT_BYTES + PB_MFMA <= ws_size) ? 1 : 0;
  const size_t PER_BATCH = use_mfma ? PB_MFMA : PB_FB;
  const size_t FIXED = HDR + (use_mfma ? WT_BYTES : 0);
  int BPC = 1;
  for (int c = 8; c >= 1; c >>= 1) {
    if (FIXED + (size_t)c * PER_BATCH <= ws_size) { BPC = c; break; }
  }
  const int R = BPC * 512;

  char* ws = (char*)d_ws;
  float* meanb = (float*)ws;
  float* stdb  = (float*)(ws + 65536);
  int*   dtf   = (int*)(ws + 131072);
  ushort* wt_base = (ushort*)(ws + HDR);
  ushort* wt_f1q = wt_base;
  ushort* wt_f1o = wt_f1q + E_F1Q;
  ushort* wt_f2q = wt_f1o + E_F1O;
  ushort* wt_f2k = wt_f2q + E_F2Q;
  ushort* wt_f2v = wt_f2k + E_F2K;
  ushort* wt_f2o = wt_f2v + E_F2V;
  ushort* wt_o   = wt_f2o + E_F2O;
  ushort* wt_enc = wt_o   + E_SQ;
  ushort* wt_f1k = wt_enc + E_SQ;
  ushort* wt_f1v = wt_f1k + E_SQ;
  ushort* wt_embh = wt_f1v + E_SQ;
  ushort* wt_embl = wt_embh + E_SQ;
  ushort* wt_qh   = wt_embl + E_SQ;
  ushort* wt_ql   = wt_qh   + E_SQ;
  ushort* wt_kh   = wt_ql   + E_SQ;
  ushort* wt_kl   = wt_kh   + E_SQ;
  ushort* wt_vh   = wt_kl   + E_SQ;
  ushort* wt_vl   = wt_vh   + E_SQ;

  char* arena = ws + FIXED;
  const size_t FSL = (size_t)R * 512 * 4;
  const size_t GSL = (size_t)R * DFF * 2;
  void* A_ = arena;
  void* B_ = arena + FSL;
  void* C_ = arena + 2 * FSL;
  void* D_ = arena + 3 * FSL;
  void* E_ = arena + 4 * FSL;                     // fallback path only
  char* gb = arena + (size_t)(use_mfma ? 4 : 5) * FSL;
  void* G1 = gb;
  void* G2 = gb + GSL;
  void* G3 = gb + 2 * GSL;

  // mfma-path split buffers
  ushort* xTh  = (ushort*)G1; ushort* xTl  = xTh  + (size_t)R * 512; // in G1 (dead before f1q)
  ushort* embh = (ushort*)G2; ushort* embl = embh + (size_t)R * 512; // in G2 (dead before pwattn1)
  ushort* qsh  = (ushort*)C_; ushort* qsl  = qsh  + (size_t)R * 512;
  ushort* ksh  = (ushort*)D_; ushort* ksl  = ksh  + (size_t)R * 512;
  ushort* vt   = (ushort*)B_;                                        // vT, dead before f1v

  detect_dtype<<<1, 256, 0, stream>>>((const ushort*)x_enc, dtf);
  // two-phase instance-norm stats; partials live in the (still idle) arena
  instnorm_partial<<<dim3(2, NB, 8), 256, 0, stream>>>(
      x_enc, (float*)A_, (float*)B_, dtf);
  instnorm_reduce<<<dim3(2, NB), 256, 0, stream>>>(
      (const float*)A_, (const float*)B_, meanb, stdb);

  if (use_mfma) {   // one-time weight convert+transpose (KxN -> bf16 NxK)
    transpose_w<<<dim3(DFF / 32, 512 / 32), 256, 0, stream>>>(f1q_w, wt_f1q, 512, DFF, dtf);
    transpose_w<<<dim3(DFF / 32, DFF / 32), 256, 0, stream>>>(f1o_w, wt_f1o, DFF, DFF, dtf);
    transpose_w<<<dim3(512 / 32, DFF / 32), 256, 0, stream>>>(f2q_w, wt_f2q, DFF, 512, dtf);
    transpose_w<<<dim3(DFF / 32, DFF / 32), 256, 0, stream>>>(f2k_w, wt_f2k, DFF, DFF, dtf);
    transpose_w<<<dim3(DFF / 32, DFF / 32), 256, 0, stream>>>(f2v_w, wt_f2v, DFF, DFF, dtf);
    transpose_w<<<dim3(512 / 32, 512 / 32), 256, 0, stream>>>(f2o_w, wt_f2o, 512, 512, dtf);
    transpose_w<<<dim3(512 / 32, 512 / 32), 256, 0, stream>>>(o_w,   wt_o,   512, 512, dtf);
    transpose_w<<<dim3(512 / 32, 512 / 32), 256, 0, stream>>>(enc_w, wt_enc, 512, 512, dtf);
    transpose_w<<<dim3(512 / 32, 512 / 32), 256, 0, stream>>>(f1k_w, wt_f1k, 512, 512, dtf);
    transpose_w<<<dim3(512 / 32, 512 / 32), 256, 0, stream>>>(f1v_w, wt_f1v, 512, 512, dtf);
    transpose_w_split<<<dim3(512 / 32, 512 / 32), 256, 0, stream>>>(embed_w, wt_embh, wt_embl, 512, 512, dtf);
    transpose_w_split<<<dim3(512 / 32, 512 / 32), 256, 0, stream>>>(q_w, wt_qh, wt_ql, 512, 512, dtf);
    transpose_w_split<<<dim3(512 / 32, 512 / 32), 256, 0, stream>>>(k_w, wt_kh, wt_kl, 512, 512, dtf);
    transpose_w_split<<<dim3(512 / 32, 512 / 32), 256, 0, stream>>>(v_w, wt_vh, wt_vl, 512, 512, dtf);
  }

  for (int bc = 0; bc < NB / BPC; ++bc) {
    const int b0 = bc * BPC;
    if (use_mfma) {
      // --- stage 1: split-MFMA GEMMs ---
      norm_transpose_split<<<dim3(16, 16, BPC), 256, 0, stream>>>(
          x_enc, meanb, stdb, xTh, xTl, b0, dtf);
      launch_mgemm3<E3_RELU_PE>(xTh, xTl, wt_embh, wt_embl, nullptr,
                                embh, embl, R, 512, 512, dtf, stream);         // emb hi/lo
      launch_mgemm3<E3_RELU_SPLIT>(embh, embl, wt_qh, wt_ql, q_b,
                                   qsh, qsl, R, 512, 512, dtf, stream);        // q hi/lo
      launch_mgemm3<E3_SPLIT>(embh, embl, wt_kh, wt_kl, k_b,
                              ksh, ksl, R, 512, 512, dtf, stream);             // k hi/lo
      launch_mgemm3<E3_RELU_VT>(embh, embl, wt_vh, wt_vl, v_b,
                                vt, nullptr, R, 512, 512, dtf, stream);        // vT bf16
      gattn_mfma<<<dim3(CC / 16, HH, BPC), 256, 0, stream>>>(
          qsh, qsl, ksh, ksl, vt, (ushort*)A_);                                // attn bf16
      launch_mgemm64<ushort, ushort, M_ADD2_BIAS_LEAKY>(
          A_, wt_o, o_b, embh, C_, R, 512, 512, dtf, stream, embl);            // y bf16
      launch_mgemm64<float, ushort, M_BIAS>(C_, wt_enc, enc_b, nullptr, D_, R, 512, 512, dtf, stream);  // X1 bf16
      // --- stage 2: pwattn1 + LN ---
      launch_mgemm<float, ushort, M_BIAS_RELU>(D_, wt_f1q, f1q_b, nullptr, G1, R, 512, DFF, dtf, stream); // query1
      launch_mgemm64<float, float, M_BIAS     >(D_, wt_f1k, f1k_b, nullptr, A_, R, 512, 512, dtf, stream); // k1 f32
      launch_mgemm64<float, float, M_BIAS_RELU>(D_, wt_f1v, f1v_b, nullptr, B_, R, 512, 512, dtf, stream); // v1 f32
      pwattn1_mfma<<<R / 4, 256, 0, stream>>>(
          (const ushort*)G1, (const float*)A_, (const float*)B_, (ushort*)G2);
      launch_mgemm<ushort, ushort, M_ADD_BIAS_ELU>(G2, wt_f1o, f1o_b, G1, G1, R, DFF, DFF, dtf, stream);  // h
      ln_kernel<<<R, 256, 0, stream>>>((ushort*)G1, ln_g, ln_b, dtf);
      // --- stage 3: pwattn2 + out ---
      launch_mgemm64<float, float, M_BIAS_RELU>(G1, wt_f2q, f2q_b, nullptr, A_, R, DFF, 512, dtf, stream); // query2
      launch_mgemm<float, ushort, M_BIAS     >(G1, wt_f2k, f2k_b, nullptr, G2, R, DFF, DFF, dtf, stream); // k2
      launch_mgemm<float, ushort, M_BIAS_RELU>(G1, wt_f2v, f2v_b, nullptr, G3, R, DFF, DFF, dtf, stream); // v2
      pwattn2_mfma<<<R / 4, 256, 0, stream>>>(
          (const float*)A_, (const ushort*)G2, (const ushort*)G3, (ushort*)B_);
      launch_mgemm64<float, float, M_ADD_BIAS>(B_, wt_f2o, f2o_b, A_, C_, R, 512, 512, dtf, stream);      // y2
    } else {
      norm_transpose<<<dim3(16, 16, BPC), 256, 0, stream>>>(x_enc, meanb, stdb, (float*)A_, b0, dtf);
      launch_gemm<float, float, float, M_RELU_PE >(A_, embed_w, nullptr, nullptr, B_, R, 512, 512, dtf, stream);
      launch_gemm<float, float, float, M_BIAS_RELU>(B_, q_w, q_b, nullptr, C_, R, 512, 512, dtf, stream);
      launch_gemm<float, float, float, M_BIAS     >(B_, k_w, k_b, nullptr, D_, R, 512, 512, dtf, stream);
      launch_gemm<float, float, float, M_BIAS_RELU>(B_, v_w, v_b, nullptr, E_, R, 512, 512, dtf, stream);
      gattn_fb<float><<<dim3(CC / 4, HH, BPC), 256, 0, stream>>>(
          (float*)C_, (float*)D_, (float*)E_, (float*)A_);
      launch_gemm<float, float, float, M_ADD_BIAS_LEAKY>(A_, o_w, o_b, B_, C_, R, 512, 512, dtf, stream);
      launch_gemm<float, float, float, M_BIAS>(C_, enc_w, enc_b, nullptr, D_, R, 512, 512, dtf, stream);
      launch_gemm<float, float, ushort, M_BIAS_RELU>(D_, f1q_w, f1q_b, nullptr, G1, R, 512, DFF, dtf, stream);
      launch_gemm<float, float, float,  M_BIAS     >(D_, f1k_w, f1k_b, nullptr, A_, R, 512, 512, dtf, stream);
      launch_gemm<float, float, float,  M_BIAS_RELU>(D_, f1v_w, f1v_b, nullptr, B_, R, 512, 512, dtf, stream);
      pwattn1_kernel<<<R, 128, 0, stream>>>((const ushort*)G1, (const float*)A_, (const float*)B_, (ushort*)G2);
      launch_gemm<ushort, ushort, ushort, M_ADD_BIAS_ELU>(G2, f1o_w, f1o_b, G1, G1, R, DFF, DFF, dtf, stream);
      ln_kernel<<<R, 256, 0, stream>>>((ushort*)G1, ln_g, ln_b, dtf);
      launch_gemm<ushort, float, float,  M_BIAS_RELU>(G1, f2q_w, f2q_b, nullptr, A_, R, DFF, 512, dtf, stream);
      launch_gemm<ushort, float, ushort, M_BIAS     >(G1, f2k_w, f2k_b, nullptr, G2, R, DFF, DFF, dtf, stream);
      launch_gemm<ushort, float, ushort, M_BIAS_RELU>(G1, f2v_w, f2v_b, nullptr, G3, R, DFF, DFF, dtf, stream);
      pwattn2_kernel<float><<<R, 128, 0, stream>>>((const float*)A_, (const ushort*)G2, (const ushort*)G3, (float*)B_);
      launch_gemm<float, float, float, M_ADD_BIAS>(B_, f2o_w, f2o_b, A_, C_, R, 512, 512, dtf, stream);
    }
    final_kernel<<<R / 8, 256, 0, stream>>>((const float*)C_, fc_w, fc_b, meanb, stdb, d_out, b0 * 512, dtf);
  }
}

// Round 9
// 2247.364 us; speedup vs baseline: 1.2780x; 1.0361x over previous
//
#include <hip/hip_runtime.h>
#include <float.h>
#include <math.h>
#include <stdint.h>

// ---------------------------------------------------------------------------
// Model_33062658245168: Informer-style time-series model. fp32 in/out
// (runtime-detected; bf16 fallback kept). B=32 S=512 C=512 D=512 DF=2048 H=8
// E=64 P=16 PRED=96 K(topk)=10, N=16384.
//
// Round 20: global_load_lds staging for mgemm_kernel ONLY (r15 retry, bounded).
//  - r15 decomposition: gattn regression (+355us, codegen context) masked a
//    ~-67us mgemm gain. gattn has since been restructured (prefetch, 48 VGPR,
//    launch_bounds(256,2)) and survived 3 TU edits unchanged.
//  - mgemm 128^2: reg-staged float4->ds_write replaced by 16B global_load_lds
//    (m93->m97: +69%). Linear [128][32] LDS (64B rows) is analytically
//    bank-uniform for the b128 frag reads (8 accesses/bank) => NO swizzle.
//    LDS 20->16KB. mgemm64/mgemm3/gattn/everything else byte-frozen at r19.
//  - A/B condition: gattn must hold 73-76us; if >90 the context theory is
//    confirmed and this reverts permanently.
// ---------------------------------------------------------------------------

#define NB   32
#define SS   512
#define CC   512
#define DD   512
#define DFF  2048
#define HH   8
#define EE   64
#define PRED 96

typedef __attribute__((ext_vector_type(8))) short short8;
typedef __attribute__((ext_vector_type(4))) float f32x4;

#define LOG2E 1.4426950408889634f

__device__ __forceinline__ float b2f(ushort u) {
  union { float f; uint32_t i; } c; c.i = ((uint32_t)u) << 16; return c.f;
}
__device__ __forceinline__ ushort f2b(float f) {
  union { float f; uint32_t i; } c; c.f = f;
  uint32_t x = c.i;
  return (ushort)((x + 0x7fffu + ((x >> 16) & 1u)) >> 16);   // RNE
}
__device__ __forceinline__ float lin(const void* p, size_t i, int f32) {
  return f32 ? ((const float*)p)[i] : b2f(((const ushort*)p)[i]);
}
__device__ __forceinline__ void split_bf(float x, ushort& hi, ushort& lo) {
  hi = f2b(x);
  lo = f2b(x - b2f(hi));
}
// async global->LDS, 16B per lane; dst is wave-uniform base (+lane*16 by HW)
__device__ __forceinline__ void gl_lds16(const void* g, void* l) {
  __builtin_amdgcn_global_load_lds(
      (const __attribute__((address_space(1))) void*)g,
      (__attribute__((address_space(3))) void*)l, 16, 0, 0);
}

// ---- DPP 16-lane all-reduce (VALU only) ----
template<int CTRL>
__device__ __forceinline__ float dppmov(float x) {
  union { float f; int i; } a, b;
  a.f = x;
  b.i = __builtin_amdgcn_update_dpp(a.i, a.i, CTRL, 0xF, 0xF, false);
  return b.f;
}
__device__ __forceinline__ float red16_max(float x) {
  x = fmaxf(x, dppmov<0xB1>(x));    // quad_perm xor1
  x = fmaxf(x, dppmov<0x4E>(x));    // quad_perm xor2
  x = fmaxf(x, dppmov<0x141>(x));   // row_half_mirror
  x = fmaxf(x, dppmov<0x140>(x));   // row_mirror
  return x;
}
__device__ __forceinline__ float red16_sum(float x) {
  x += dppmov<0xB1>(x);
  x += dppmov<0x4E>(x);
  x += dppmov<0x141>(x);
  x += dppmov<0x140>(x);
  return x;
}

// ---------------- dtype detection (1 = fp32 inputs) ----------------
__global__ __launch_bounds__(256) void detect_dtype(
    const ushort* __restrict__ x, int* __restrict__ flag)
{
  __shared__ float red[256];
  const int t = threadIdx.x;
  float v = fabsf(b2f(x[2 * t]));
  if (!(v < 1e30f)) v = 1e30f;
  red[t] = v;
  __syncthreads();
  for (int off = 128; off > 0; off >>= 1) {
    if (t < off) red[t] = fmaxf(red[t], red[t + off]);
    __syncthreads();
  }
  if (t == 0) flag[0] = (red[0] > 1e6f) ? 1 : 0;
}

// ---------------- instance norm stats, two-phase ----------------
__global__ __launch_bounds__(256) void instnorm_partial(
    const void* __restrict__ x, float* __restrict__ ps, float* __restrict__ pq,
    const int* __restrict__ dtf)
{
  const int f32 = *dtf;
  const int c = blockIdx.x * 256 + threadIdx.x;
  const int b = blockIdx.y;
  const int t0 = blockIdx.z * 64;
  float s = 0.f, s2 = 0.f;
  for (int t = t0; t < t0 + 64; ++t) {
    const float xv = lin(x, ((size_t)(b * SS) + t) * CC + c, f32);
    s += xv; s2 += xv * xv;
  }
  const int pidx = (b * 8 + blockIdx.z) * CC + c;
  ps[pidx] = s; pq[pidx] = s2;
}

__global__ __launch_bounds__(256) void instnorm_reduce(
    const float* __restrict__ ps, const float* __restrict__ pq,
    float* __restrict__ meanb, float* __restrict__ stdb)
{
  const int c = blockIdx.x * 256 + threadIdx.x;
  const int b = blockIdx.y;
  float s = 0.f, s2 = 0.f;
  #pragma unroll
  for (int i = 0; i < 8; ++i) {
    s  += ps[(b * 8 + i) * CC + c];
    s2 += pq[(b * 8 + i) * CC + c];
  }
  const float mu  = s * (1.f / SS);
  const float var = s2 * (1.f / SS) - mu * mu;
  meanb[b * CC + c] = mu;
  stdb [b * CC + c] = sqrtf(var + 1e-5f);
}

// ---------------- normalize + transpose one chunk (fp32, fallback) ---------
__global__ __launch_bounds__(256) void norm_transpose(
    const void* __restrict__ x, const float* __restrict__ meanb,
    const float* __restrict__ stdb, float* __restrict__ xTc, int b_base,
    const int* __restrict__ dtf)
{
  const int f32 = *dtf;
  __shared__ float t[32][33];
  const int s0 = blockIdx.x * 32, c0 = blockIdx.y * 32, lb = blockIdx.z;
  const int b = b_base + lb;
  const int tx = threadIdx.x & 31, ty = threadIdx.x >> 5;
  #pragma unroll
  for (int i = 0; i < 4; ++i) {
    const int s = s0 + ty + i * 8;
    t[ty + i * 8][tx] = lin(x, ((size_t)(b * SS) + s) * CC + c0 + tx, f32);
  }
  __syncthreads();
  #pragma unroll
  for (int i = 0; i < 4; ++i) {
    const int c = c0 + ty + i * 8;
    const float mu = meanb[b * CC + c], sd = stdb[b * CC + c];
    xTc[((size_t)(lb * CC) + c) * SS + s0 + tx] = (t[tx][ty + i * 8] - mu) / sd;
  }
}

// ---------------- normalize + transpose, hi/lo split output ----------------
__global__ __launch_bounds__(256) void norm_transpose_split(
    const void* __restrict__ x, const float* __restrict__ meanb,
    const float* __restrict__ stdb, ushort* __restrict__ xh,
    ushort* __restrict__ xl, int b_base, const int* __restrict__ dtf)
{
  const int f32 = *dtf;
  __shared__ float t[32][33];
  const int s0 = blockIdx.x * 32, c0 = blockIdx.y * 32, lb = blockIdx.z;
  const int b = b_base + lb;
  const int tx = threadIdx.x & 31, ty = threadIdx.x >> 5;
  #pragma unroll
  for (int i = 0; i < 4; ++i) {
    const int s = s0 + ty + i * 8;
    t[ty + i * 8][tx] = lin(x, ((size_t)(b * SS) + s) * CC + c0 + tx, f32);
  }
  __syncthreads();
  #pragma unroll
  for (int i = 0; i < 4; ++i) {
    const int c = c0 + ty + i * 8;
    const float mu = meanb[b * CC + c], sd = stdb[b * CC + c];
    const float v = (t[tx][ty + i * 8] - mu) / sd;
    const size_t idx = ((size_t)(lb * CC) + c) * SS + s0 + tx;
    ushort hi, lo; split_bf(v, hi, lo);
    xh[idx] = hi; xl[idx] = lo;
  }
}

// ---------------- weight convert+transpose: W (KxN, input dtype) -> bf16 (NxK)
__global__ __launch_bounds__(256) void transpose_w(
    const void* __restrict__ W, ushort* __restrict__ Wt, int K, int N,
    const int* __restrict__ dtf)
{
  const int f32 = *dtf;
  __shared__ float t[32][33];
  const int n0 = blockIdx.x * 32, k0 = blockIdx.y * 32;
  const int tx = threadIdx.x & 31, ty = threadIdx.x >> 5;
  #pragma unroll
  for (int i = 0; i < 4; ++i)
    t[ty + i * 8][tx] = lin(W, (size_t)(k0 + ty + i * 8) * N + n0 + tx, f32);
  __syncthreads();
  #pragma unroll
  for (int i = 0; i < 4; ++i)
    Wt[(size_t)(n0 + ty + i * 8) * K + k0 + tx] = f2b(t[tx][ty + i * 8]);
}

// ---------------- weight transpose + hi/lo split ----------------
__global__ __launch_bounds__(256) void transpose_w_split(
    const void* __restrict__ W, ushort* __restrict__ Whi, ushort* __restrict__ Wlo,
    int K, int N, const int* __restrict__ dtf)
{
  const int f32 = *dtf;
  __shared__ float t[32][33];
  const int n0 = blockIdx.x * 32, k0 = blockIdx.y * 32;
  const int tx = threadIdx.x & 31, ty = threadIdx.x >> 5;
  #pragma unroll
  for (int i = 0; i < 4; ++i)
    t[ty + i * 8][tx] = lin(W, (size_t)(k0 + ty + i * 8) * N + n0 + tx, f32);
  __syncthreads();
  #pragma unroll
  for (int i = 0; i < 4; ++i) {
    const size_t idx = (size_t)(n0 + ty + i * 8) * K + k0 + tx;
    ushort hi, lo; split_bf(t[tx][ty + i * 8], hi, lo);
    Whi[idx] = hi; Wlo[idx] = lo;
  }
}

// ---------------- generic fp32 tiled GEMM (fallback path) ----------
enum GemmMode { M_BIAS = 0, M_BIAS_RELU = 1, M_RELU_PE = 2,
                M_ADD_BIAS_LEAKY = 3, M_ADD_BIAS_ELU = 4, M_ADD_BIAS = 5,
                M_ADD2_BIAS_LEAKY = 6 };

template<typename AT, typename ADT, typename OT, int MODE>
__global__ __launch_bounds__(256) void gemm_kernel(
    const AT* __restrict__ A, const void* __restrict__ Bw,
    const void* __restrict__ bias, const ADT* __restrict__ addend,
    OT* __restrict__ Cout, int M, int K, int Nn, const int* __restrict__ dtf)
{
  const int f32 = *dtf;
  __shared__ __align__(16) float As[16][68];
  __shared__ __align__(16) float Bs[16][68];
  const int tid = threadIdx.x;
  const int m0 = blockIdx.y * 64, n0 = blockIdx.x * 64;
  const int tx = tid & 15, ty = tid >> 4;
  const int la_m = tid >> 2, la_k = (tid & 3) * 4;
  const int lb_k = tid >> 4, lb_n = (tid & 15) * 4;
  float acc[4][4];
  #pragma unroll
  for (int i = 0; i < 4; ++i)
    #pragma unroll
    for (int j = 0; j < 4; ++j) acc[i][j] = 0.f;
  const size_t a_row = (size_t)(m0 + la_m) * K;

  for (int k0 = 0; k0 < K; k0 += 16) {
    if constexpr (sizeof(AT) == 4) {
      const float4 av = *reinterpret_cast<const float4*>(A + a_row + k0 + la_k);
      As[la_k + 0][la_m] = av.x; As[la_k + 1][la_m] = av.y;
      As[la_k + 2][la_m] = av.z; As[la_k + 3][la_m] = av.w;
    } else {
      const ushort4 av = *reinterpret_cast<const ushort4*>(A + a_row + k0 + la_k);
      As[la_k + 0][la_m] = b2f(av.x); As[la_k + 1][la_m] = b2f(av.y);
      As[la_k + 2][la_m] = b2f(av.z); As[la_k + 3][la_m] = b2f(av.w);
    }
    {
      const size_t boff = (size_t)(k0 + lb_k) * Nn + n0 + lb_n;
      if (f32) {
        const float4 bv = *reinterpret_cast<const float4*>((const float*)Bw + boff);
        Bs[lb_k][lb_n + 0] = bv.x; Bs[lb_k][lb_n + 1] = bv.y;
        Bs[lb_k][lb_n + 2] = bv.z; Bs[lb_k][lb_n + 3] = bv.w;
      } else {
        const ushort4 bv = *reinterpret_cast<const ushort4*>((const ushort*)Bw + boff);
        Bs[lb_k][lb_n + 0] = b2f(bv.x); Bs[lb_k][lb_n + 1] = b2f(bv.y);
        Bs[lb_k][lb_n + 2] = b2f(bv.z); Bs[lb_k][lb_n + 3] = b2f(bv.w);
      }
    }
    __syncthreads();
    #pragma unroll
    for (int k = 0; k < 16; ++k) {
      const float4 a4 = *reinterpret_cast<const float4*>(&As[k][ty * 4]);
      const float4 b4 = *reinterpret_cast<const float4*>(&Bs[k][tx * 4]);
      const float aa[4] = {a4.x, a4.y, a4.z, a4.w};
      const float bb[4] = {b4.x, b4.y, b4.z, b4.w};
      #pragma unroll
      for (int i = 0; i < 4; ++i)
        #pragma unroll
        for (int j = 0; j < 4; ++j)
          acc[i][j] = fmaf(aa[i], bb[j], acc[i][j]);
    }
    __syncthreads();
  }

  float biasv[4];
  if constexpr (MODE != M_RELU_PE) {
    #pragma unroll
    for (int j = 0; j < 4; ++j) biasv[j] = lin(bias, n0 + tx * 4 + j, f32);
  }
  #pragma unroll
  for (int i = 0; i < 4; ++i) {
    const int m = m0 + ty * 4 + i;
    #pragma unroll
    for (int j = 0; j < 4; ++j) {
      const int n = n0 + tx * 4 + j;
      float v = acc[i][j];
      if constexpr (MODE == M_BIAS) {
        v += biasv[j];
      } else if constexpr (MODE == M_BIAS_RELU) {
        v = fmaxf(v + biasv[j], 0.f);
      } else if constexpr (MODE == M_RELU_PE) {
        v = fmaxf(v, 0.f);
        const float freq = expf((float)(n & ~1) * (-0.017988946f)); // -ln(1e4)/512
        const float ang  = (float)(m & (CC - 1)) * freq;            // pos = c
        v += (n & 1) ? cosf(ang) : sinf(ang);
      } else {
        float ad;
        if constexpr (sizeof(ADT) == 4) ad = ((const float*)addend)[(size_t)m * Nn + n];
        else                            ad = b2f(((const ushort*)addend)[(size_t)m * Nn + n]);
        v = ad + v + biasv[j];
        if constexpr (MODE == M_ADD_BIAS_LEAKY) v = (v >= 0.f) ? v : 0.5f * v;
        else if constexpr (MODE == M_ADD_BIAS_ELU) v = (v > 0.f) ? v : expm1f(v);
      }
      if constexpr (sizeof(OT) == 4) ((float*)Cout)[(size_t)m * Nn + n] = v;
      else                           ((ushort*)Cout)[(size_t)m * Nn + n] = f2b(v);
    }
  }
}

template<typename AT, typename ADT, typename OT, int MODE>
static void launch_gemm(const void* A, const void* Bw, const void* bias, const void* add,
                        void* Cout, int M, int K, int Nn, const int* dtf, hipStream_t stream)
{
  dim3 grid(Nn / 64, M / 64);
  gemm_kernel<AT, ADT, OT, MODE><<<grid, dim3(256), 0, stream>>>(
      (const AT*)A, Bw, bias, (const ADT*)add, (OT*)Cout, M, K, Nn, dtf);
}

// ---------------- MFMA bf16 GEMM (128x128 tile), global_load_lds staging ----
// Linear LDS [128][32] (64B rows): HW writes base+lane*16; ds_read_b128 frag
// pattern is exactly bank-uniform (8 accesses/bank) => no swizzle needed.
template<typename ADT, typename OT, int MODE>
__global__ __launch_bounds__(256) void mgemm_kernel(
    const ushort* __restrict__ A, const ushort* __restrict__ Wt,
    const void* __restrict__ bias, const ADT* __restrict__ addend,
    const ushort* __restrict__ addend2,
    OT* __restrict__ Cout, int M, int K, int Nn, const int* __restrict__ dtf)
{
  const int f32 = *dtf;
  __shared__ __align__(16) ushort As[128][32];
  __shared__ __align__(16) ushort Bs[128][32];
  const int tid = threadIdx.x;
  const int m0 = blockIdx.y * 128, n0 = blockIdx.x * 128;
  const int wave = tid >> 6, lane = tid & 63;
  const int wm = wave & 1, wn = wave >> 1;
  const int quad = lane >> 4, l15 = lane & 15;

  f32x4 acc[4][4];
  #pragma unroll
  for (int i = 0; i < 4; ++i)
    #pragma unroll
    for (int j = 0; j < 4; ++j) acc[i][j] = (f32x4){0.f, 0.f, 0.f, 0.f};

  const int srow_l = lane >> 2;   // 0..15 row within a 16-row issue
  const int slot   = lane & 3;    // 0..3  (x8 ushort = 16B column slot)

  for (int k0 = 0; k0 < K; k0 += 32) {
    #pragma unroll
    for (int i = 0; i < 2; ++i) {
      const int row = wave * 32 + i * 16;   // wave-uniform LDS base row
      gl_lds16(A  + (size_t)(m0 + row + srow_l) * K + k0 + slot * 8, &As[row][0]);
      gl_lds16(Wt + (size_t)(n0 + row + srow_l) * K + k0 + slot * 8, &Bs[row][0]);
    }
    __syncthreads();
    short8 af[4], bf[4];
    #pragma unroll
    for (int i = 0; i < 4; ++i)
      af[i] = *reinterpret_cast<const short8*>(&As[wm * 64 + i * 16 + l15][quad * 8]);
    #pragma unroll
    for (int j = 0; j < 4; ++j)
      bf[j] = *reinterpret_cast<const short8*>(&Bs[wn * 64 + j * 16 + l15][quad * 8]);
    #pragma unroll
    for (int i = 0; i < 4; ++i)
      #pragma unroll
      for (int j = 0; j < 4; ++j)
        acc[i][j] = __builtin_amdgcn_mfma_f32_16x16x32_bf16(af[i], bf[j], acc[i][j], 0, 0, 0);
    __syncthreads();
  }

  #pragma unroll
  for (int j = 0; j < 4; ++j) {
    const int n = n0 + wn * 64 + j * 16 + l15;
    const float bv = lin(bias, n, f32);
    #pragma unroll
    for (int i = 0; i < 4; ++i) {
      #pragma unroll
      for (int r = 0; r < 4; ++r) {
        const int m = m0 + wm * 64 + i * 16 + quad * 4 + r;
        float v = acc[i][j][r];
        if constexpr (MODE == M_BIAS) {
          v += bv;
        } else if constexpr (MODE == M_BIAS_RELU) {
          v = fmaxf(v + bv, 0.f);
        } else if constexpr (MODE == M_ADD2_BIAS_LEAKY) {
          const size_t ix = (size_t)m * Nn + n;
          const float ad = b2f(((const ushort*)addend)[ix]) + b2f(addend2[ix]);
          v = ad + v + bv;
          v = (v >= 0.f) ? v : 0.5f * v;
        } else {
          float ad;
          if constexpr (sizeof(ADT) == 4) ad = ((const float*)addend)[(size_t)m * Nn + n];
          else                            ad = b2f(((const ushort*)addend)[(size_t)m * Nn + n]);
          v = ad + v + bv;
          if constexpr (MODE == M_ADD_BIAS_ELU)
            v = (v > 0.f) ? v : (__builtin_amdgcn_exp2f(v * LOG2E) - 1.f);
          else if constexpr (MODE == M_ADD_BIAS_LEAKY) v = (v >= 0.f) ? v : 0.5f * v;
        }
        if constexpr (sizeof(OT) == 4) ((float*)Cout)[(size_t)m * Nn + n] = v;
        else                           ((ushort*)Cout)[(size_t)m * Nn + n] = f2b(v);
      }
    }
  }
}

template<typename ADT, typename OT, int MODE>
static void launch_mgemm(const void* A, const void* Wt, const void* bias, const void* add,
                         void* Cout, int M, int K, int Nn, const int* dtf, hipStream_t stream,
                         const void* add2 = nullptr)
{
  dim3 grid(Nn / 128, M / 128);
  mgemm_kernel<ADT, OT, MODE><<<grid, dim3(256), 0, stream>>>(
      (const ushort*)A, (const ushort*)Wt, bias, (const ADT*)add, (const ushort*)add2,
      (OT*)Cout, M, K, Nn, dtf);
}

// ---------------- MFMA bf16 GEMM (64x64 tile) for N<=512 layers -------------
template<typename ADT, typename OT, int MODE>
__global__ __launch_bounds__(256) void mgemm64_kernel(
    const ushort* __restrict__ A, const ushort* __restrict__ Wt,
    const void* __restrict__ bias, const ADT* __restrict__ addend,
    const ushort* __restrict__ addend2,
    OT* __restrict__ Cout, int M, int K, int Nn, const int* __restrict__ dtf)
{
  const int f32 = *dtf;
  __shared__ __align__(16) ushort As[64][40];
  __shared__ __align__(16) ushort Bs[64][40];
  const int tid = threadIdx.x;
  const int m0 = blockIdx.y * 64, n0 = blockIdx.x * 64;
  const int wave = tid >> 6, lane = tid & 63;
  const int wm = wave & 1, wn = wave >> 1;
  const int quad = lane >> 4, l15 = lane & 15;

  f32x4 acc[2][2];
  #pragma unroll
  for (int i = 0; i < 2; ++i)
    #pragma unroll
    for (int j = 0; j < 2; ++j) acc[i][j] = (f32x4){0.f, 0.f, 0.f, 0.f};

  const int srow = tid >> 2, sseg = (tid & 3) * 8;
  const size_t a_base = (size_t)(m0 + srow) * K + sseg;
  const size_t b_base = (size_t)(n0 + srow) * K + sseg;

  for (int k0 = 0; k0 < K; k0 += 32) {
    *reinterpret_cast<float4*>(&As[srow][sseg]) =
        *reinterpret_cast<const float4*>(A + a_base + k0);
    *reinterpret_cast<float4*>(&Bs[srow][sseg]) =
        *reinterpret_cast<const float4*>(Wt + b_base + k0);
    __syncthreads();
    short8 af[2], bf[2];
    #pragma unroll
    for (int i = 0; i < 2; ++i) {
      af[i] = *reinterpret_cast<const short8*>(&As[wm * 32 + i * 16 + l15][quad * 8]);
      bf[i] = *reinterpret_cast<const short8*>(&Bs[wn * 32 + i * 16 + l15][quad * 8]);
    }
    #pragma unroll
    for (int i = 0; i < 2; ++i)
      #pragma unroll
      for (int j = 0; j < 2; ++j)
        acc[i][j] = __builtin_amdgcn_mfma_f32_16x16x32_bf16(af[i], bf[j], acc[i][j], 0, 0, 0);
    __syncthreads();
  }

  #pragma unroll
  for (int j = 0; j < 2; ++j) {
    const int n = n0 + wn * 32 + j * 16 + l15;
    const float bv = lin(bias, n, f32);
    #pragma unroll
    for (int i = 0; i < 2; ++i) {
      #pragma unroll
      for (int r = 0; r < 4; ++r) {
        const int m = m0 + wm * 32 + i * 16 + quad * 4 + r;
        float v = acc[i][j][r];
        if constexpr (MODE == M_BIAS) {
          v += bv;
        } else if constexpr (MODE == M_BIAS_RELU) {
          v = fmaxf(v + bv, 0.f);
        } else if constexpr (MODE == M_ADD2_BIAS_LEAKY) {
          const size_t ix = (size_t)m * Nn + n;
          const float ad = b2f(((const ushort*)addend)[ix]) + b2f(addend2[ix]);
          v = ad + v + bv;
          v = (v >= 0.f) ? v : 0.5f * v;
        } else {
          float ad;
          if constexpr (sizeof(ADT) == 4) ad = ((const float*)addend)[(size_t)m * Nn + n];
          else                            ad = b2f(((const ushort*)addend)[(size_t)m * Nn + n]);
          v = ad + v + bv;
          if constexpr (MODE == M_ADD_BIAS_ELU)
            v = (v > 0.f) ? v : (__builtin_amdgcn_exp2f(v * LOG2E) - 1.f);
          else if constexpr (MODE == M_ADD_BIAS_LEAKY) v = (v >= 0.f) ? v : 0.5f * v;
        }
        if constexpr (sizeof(OT) == 4) ((float*)Cout)[(size_t)m * Nn + n] = v;
        else                           ((ushort*)Cout)[(size_t)m * Nn + n] = f2b(v);
      }
    }
  }
}

template<typename ADT, typename OT, int MODE>
static void launch_mgemm64(const void* A, const void* Wt, const void* bias, const void* add,
                           void* Cout, int M, int K, int Nn, const int* dtf, hipStream_t stream,
                           const void* add2 = nullptr)
{
  dim3 grid(Nn / 64, M / 64);
  mgemm64_kernel<ADT, OT, MODE><<<grid, dim3(256), 0, stream>>>(
      (const ushort*)A, (const ushort*)Wt, bias, (const ADT*)add, (const ushort*)add2,
      (OT*)Cout, M, K, Nn, dtf);
}

// ---------------- mgemm3: 64x64-tile hi/lo-split 3-MFMA GEMM ----------------
enum Epi3 { E3_RELU_PE = 0, E3_RELU_SPLIT = 1, E3_SPLIT = 2, E3_RELU_VT = 3 };

template<int EPI>
__global__ __launch_bounds__(256) void mgemm3_kernel(
    const ushort* __restrict__ Ah, const ushort* __restrict__ Al,
    const ushort* __restrict__ Bh, const ushort* __restrict__ Bl,
    const void* __restrict__ bias,
    ushort* __restrict__ Oh, ushort* __restrict__ Ol,
    int M, int K, int Nn, const int* __restrict__ dtf)
{
  const int f32 = *dtf;
  __shared__ __align__(16) ushort AsH[64][40];
  __shared__ __align__(16) ushort AsL[64][40];
  __shared__ __align__(16) ushort BsH[64][40];
  __shared__ __align__(16) ushort BsL[64][40];
  const int tid = threadIdx.x;
  const int m0 = blockIdx.y * 64, n0 = blockIdx.x * 64;
  const int wave = tid >> 6, lane = tid & 63;
  const int wm = wave & 1, wn = wave >> 1;
  const int quad = lane >> 4, l15 = lane & 15;

  f32x4 acc[2][2];
  #pragma unroll
  for (int i = 0; i < 2; ++i)
    #pragma unroll
    for (int j = 0; j < 2; ++j) acc[i][j] = (f32x4){0.f, 0.f, 0.f, 0.f};

  const int srow = tid >> 2, sseg = (tid & 3) * 8;
  const size_t a_base = (size_t)(m0 + srow) * K + sseg;
  const size_t b_base = (size_t)(n0 + srow) * K + sseg;

  for (int k0 = 0; k0 < K; k0 += 32) {
    *reinterpret_cast<float4*>(&AsH[srow][sseg]) =
        *reinterpret_cast<const float4*>(Ah + a_base + k0);
    *reinterpret_cast<float4*>(&AsL[srow][sseg]) =
        *reinterpret_cast<const float4*>(Al + a_base + k0);
    *reinterpret_cast<float4*>(&BsH[srow][sseg]) =
        *reinterpret_cast<const float4*>(Bh + b_base + k0);
    *reinterpret_cast<float4*>(&BsL[srow][sseg]) =
        *reinterpret_cast<const float4*>(Bl + b_base + k0);
    __syncthreads();
    short8 afh[2], afl[2], bfh[2], bfl[2];
    #pragma unroll
    for (int i = 0; i < 2; ++i) {
      afh[i] = *reinterpret_cast<const short8*>(&AsH[wm * 32 + i * 16 + l15][quad * 8]);
      afl[i] = *reinterpret_cast<const short8*>(&AsL[wm * 32 + i * 16 + l15][quad * 8]);
      bfh[i] = *reinterpret_cast<const short8*>(&BsH[wn * 32 + i * 16 + l15][quad * 8]);
      bfl[i] = *reinterpret_cast<const short8*>(&BsL[wn * 32 + i * 16 + l15][quad * 8]);
    }
    #pragma unroll
    for (int i = 0; i < 2; ++i)
      #pragma unroll
      for (int j = 0; j < 2; ++j) {
        acc[i][j] = __builtin_amdgcn_mfma_f32_16x16x32_bf16(afh[i], bfh[j], acc[i][j], 0, 0, 0);
        acc[i][j] = __builtin_amdgcn_mfma_f32_16x16x32_bf16(afh[i], bfl[j], acc[i][j], 0, 0, 0);
        acc[i][j] = __builtin_amdgcn_mfma_f32_16x16x32_bf16(afl[i], bfh[j], acc[i][j], 0, 0, 0);
      }
    __syncthreads();
  }

  #pragma unroll
  for (int j = 0; j < 2; ++j) {
    const int n = n0 + wn * 32 + j * 16 + l15;
    float bv = 0.f;
    if constexpr (EPI != E3_RELU_PE) bv = lin(bias, n, f32);
    #pragma unroll
    for (int i = 0; i < 2; ++i) {
      #pragma unroll
      for (int r = 0; r < 4; ++r) {
        const int m = m0 + wm * 32 + i * 16 + quad * 4 + r;
        float v = acc[i][j][r];
        if constexpr (EPI == E3_RELU_PE) {
          v = fmaxf(v, 0.f);
          const float freq = expf((float)(n & ~1) * (-0.017988946f)); // -ln(1e4)/512
          const float ang  = (float)(m & (CC - 1)) * freq;            // pos = c
          v += (n & 1) ? cosf(ang) : sinf(ang);
        } else if constexpr (EPI == E3_RELU_SPLIT || EPI == E3_RELU_VT) {
          v = fmaxf(v + bv, 0.f);
        } else {
          v = v + bv;
        }
        if constexpr (EPI == E3_RELU_VT) {
          // pre-transposed: vT[(lb*512 + n)][s] with lb = m>>9, s = m&511
          Oh[((size_t)((m >> 9) * 512 + n)) * 512 + (m & 511)] = f2b(v);
        } else {
          ushort hi, lo; split_bf(v, hi, lo);
          Oh[(size_t)m * Nn + n] = hi;
          Ol[(size_t)m * Nn + n] = lo;
        }
      }
    }
  }
}

template<int EPI>
static void launch_mgemm3(const void* Ahv, const void* Alv, const ushort* Bh,
                          const ushort* Bl, const void* bias, void* Oh, void* Ol,
                          int M, int K, int Nn, const int* dtf, hipStream_t stream)
{
  dim3 grid(Nn / 64, M / 64);
  mgemm3_kernel<EPI><<<grid, dim3(256), 0, stream>>>(
      (const ushort*)Ahv, (const ushort*)Alv, Bh, Bl, bias,
      (ushort*)Oh, (ushort*)Ol, M, K, Nn, dtf);
}

// ---------------- GAttn via MFMA: register scores + DPP top-k ---------------
// S-phase uses an explicit 2-stage prefetch pipeline (chunk c+1's K frags
// loaded into named regs before chunk c's MFMAs) so load latency overlaps
// MFMA regardless of regalloc heuristics.
__global__ __launch_bounds__(256, 2) void gattn_mfma(
    const ushort* __restrict__ qsh, const ushort* __restrict__ qsl,
    const ushort* __restrict__ ksh, const ushort* __restrict__ ksl,
    const ushort* __restrict__ vt, ushort* __restrict__ out)
{
  const int tid = threadIdx.x;
  const int wave = tid >> 6, lane = tid & 63;
  const int quad = lane >> 4, l15 = lane & 15;
  const int l0 = blockIdx.x * 16;
  const int h = blockIdx.y, bz = blockIdx.z;

  __shared__ __align__(16) ushort P[16][520];    // 16640 B (unnormalized bf16 weights)
  __shared__ float cand[16][40];                 // 2560 B (4 waves x sorted top-10)
  __shared__ float psum[16][4];                  // 256 B  (per-wave partial sums)

  // ---- Q fragments (hi/lo), kk-chunks 0,1 ----
  short8 ah[2], al[2];
  {
    const size_t qoff = ((size_t)bz * CC + l0 + l15) * DD + h * EE + quad * 8;
    ah[0] = *reinterpret_cast<const short8*>(qsh + qoff);
    ah[1] = *reinterpret_cast<const short8*>(qsh + qoff + 32);
    al[0] = *reinterpret_cast<const short8*>(qsl + qoff);
    al[1] = *reinterpret_cast<const short8*>(qsl + qoff + 32);
  }

  // ---- S phase into registers: sacc[c][r] = S[quad*4+r][c*64+wave*16+l15] --
  f32x4 sacc[8];
  {
    const size_t kbase = ((size_t)bz * CC + wave * 16 + l15) * DD + h * EE + quad * 8;
    short8 pbh0 = *reinterpret_cast<const short8*>(ksh + kbase);
    short8 pbl0 = *reinterpret_cast<const short8*>(ksl + kbase);
    short8 pbh1 = *reinterpret_cast<const short8*>(ksh + kbase + 32);
    short8 pbl1 = *reinterpret_cast<const short8*>(ksl + kbase + 32);
    #pragma unroll
    for (int c = 0; c < 8; ++c) {
      const short8 cbh0 = pbh0, cbl0 = pbl0, cbh1 = pbh1, cbl1 = pbl1;
      if (c < 7) {
        const size_t noff = kbase + (size_t)((c + 1) * 64) * DD;
        pbh0 = *reinterpret_cast<const short8*>(ksh + noff);
        pbl0 = *reinterpret_cast<const short8*>(ksl + noff);
        pbh1 = *reinterpret_cast<const short8*>(ksh + noff + 32);
        pbl1 = *reinterpret_cast<const short8*>(ksl + noff + 32);
      }
      f32x4 acc = (f32x4){0.f, 0.f, 0.f, 0.f};
      __builtin_amdgcn_s_setprio(1);
      acc = __builtin_amdgcn_mfma_f32_16x16x32_bf16(ah[0], cbh0, acc, 0, 0, 0);
      acc = __builtin_amdgcn_mfma_f32_16x16x32_bf16(ah[0], cbl0, acc, 0, 0, 0);
      acc = __builtin_amdgcn_mfma_f32_16x16x32_bf16(al[0], cbh0, acc, 0, 0, 0);
      acc = __builtin_amdgcn_mfma_f32_16x16x32_bf16(ah[1], cbh1, acc, 0, 0, 0);
      acc = __builtin_amdgcn_mfma_f32_16x16x32_bf16(ah[1], cbl1, acc, 0, 0, 0);
      acc = __builtin_amdgcn_mfma_f32_16x16x32_bf16(al[1], cbh1, acc, 0, 0, 0);
      __builtin_amdgcn_s_setprio(0);
      sacc[c] = acc;
    }
  }

  // ---- stage-1 top-k: each quad extracts its row's wave-local top-10 ----
  #pragma unroll
  for (int r = 0; r < 4; ++r) {
    float wk[8];
    #pragma unroll
    for (int c = 0; c < 8; ++c) wk[c] = sacc[c][r];
    float myg = 0.f;
    for (int it = 0; it < 10; ++it) {
      float lm = wk[0];
      #pragma unroll
      for (int c = 1; c < 8; ++c) lm = fmaxf(lm, wk[c]);
      const float gm = red16_max(lm);
      if (l15 == it) myg = gm;
      if (it < 9) {
        const unsigned long long msk = __ballot(lm == gm);
        const int sel = (__ffsll((unsigned long long)((msk >> (quad * 16)) & 0xFFFFull)) - 1)
                        + quad * 16;
        if (lane == sel) {
          #pragma unroll
          for (int c = 0; c < 8; ++c) { if (wk[c] == gm) { wk[c] = -FLT_MAX; break; } }
        }
      }
    }
    if (l15 < 10) cand[quad * 4 + r][wave * 10 + l15] = myg;
  }
  __syncthreads();

  // ---- merge 4 sorted lists of 10 -> global maxv + thr (10th) ----
  float mx, thr;
  {
    const int mr = lane & 15;
    float h0 = cand[mr][0], h1 = cand[mr][10], h2 = cand[mr][20], h3 = cand[mr][30];
    int i0 = 0, i1 = 0, i2 = 0, i3 = 0;
    float cur = 0.f;
    mx = 0.f;
    #pragma unroll
    for (int t = 0; t < 10; ++t) {
      cur = fmaxf(fmaxf(h0, h1), fmaxf(h2, h3));
      if (t == 0) mx = cur;
      if (t < 9) {
        const bool a0 = (cur == h0);
        const bool a1 = !a0 && (cur == h1);
        const bool a2 = !a0 && !a1 && (cur == h2);
        const int ni0 = i0 + (a0 ? 1 : 0);
        const int ni1 = i1 + (a1 ? 1 : 0);
        const int ni2 = i2 + (a2 ? 1 : 0);
        const int ni3 = i3 + ((a0 || a1 || a2) ? 0 : 1);
        const int off = a0 ? ni0 : (a1 ? 10 + ni1 : (a2 ? 20 + ni2 : 30 + ni3));
        const float nv = cand[mr][off];
        h0 = a0 ? nv : h0;
        h1 = a1 ? nv : h1;
        h2 = a2 ? nv : h2;
        h3 = (a0 || a1 || a2) ? h3 : nv;
        i0 = ni0; i1 = ni1; i2 = ni2; i3 = ni3;
      }
    }
    thr = cur;
  }
  // distribute row thr/max to the quad that owns the row
  float thrR[4], mxR[4];
  #pragma unroll
  for (int r = 0; r < 4; ++r) {
    thrR[r] = __shfl(thr, quad * 4 + r);
    mxR[r]  = __shfl(mx,  quad * 4 + r);
  }

  // ---- exp + partial sums + P write ----
  #pragma unroll
  for (int r = 0; r < 4; ++r) {
    const int Rr = quad * 4 + r;
    float s = 0.f;
    #pragma unroll
    for (int c = 0; c < 8; ++c) {
      const float sc = sacc[c][r];
      const float p = (sc >= thrR[r])
          ? __builtin_amdgcn_exp2f((sc - mxR[r]) * (0.125f * LOG2E)) : 0.f;
      P[Rr][c * 64 + wave * 16 + l15] = f2b(p);
      s += p;
    }
    s = red16_sum(s);
    if (l15 == 0) psum[Rr][wave] = s;
  }
  __syncthreads();

  // ---- PV phase: wave w owns e-cols w*16..w*16+15; vT loaded direct ----
  f32x4 pacc = (f32x4){0.f, 0.f, 0.f, 0.f};
  const size_t vbase = ((size_t)bz * 512 + h * EE + wave * 16 + l15) * 512 + quad * 8;
  #pragma unroll
  for (int c = 0; c < 4; ++c) {
    #pragma unroll
    for (int ks = 0; ks < 4; ++ks) {
      const int s0 = c * 128 + ks * 32;
      const short8 pa = *reinterpret_cast<const short8*>(&P[l15][s0 + quad * 8]);
      const short8 vb = *reinterpret_cast<const short8*>(vt + vbase + s0);
      __builtin_amdgcn_s_setprio(1);
      pacc = __builtin_amdgcn_mfma_f32_16x16x32_bf16(pa, vb, pacc, 0, 0, 0);
      __builtin_amdgcn_s_setprio(0);
    }
  }

  // ---- epilogue ----
  #pragma unroll
  for (int r = 0; r < 4; ++r) {
    const int Rr = quad * 4 + r;
    const float4 ps = *reinterpret_cast<const float4*>(&psum[Rr][0]);
    const float inv = 1.f / (ps.x + ps.y + ps.z + ps.w);
    out[((size_t)bz * CC + l0 + Rr) * DD + h * EE + wave * 16 + l15] = f2b(pacc[r] * inv);
  }
}

// ---------------- GAttn fallback (fp32 path only) -----------
template<typename OT>
__global__ __launch_bounds__(256) void gattn_fb(
    const float* __restrict__ q, const float* __restrict__ k,
    const float* __restrict__ v, OT* __restrict__ out)
{
  const int tid = threadIdx.x;
  const int wave = tid >> 6, lane = tid & 63;
  const int l0 = blockIdx.x * 4;
  const int h = blockIdx.y, bz = blockIdx.z;
  const int l = l0 + wave;
  const size_t base = ((size_t)bz * CC) * DD + h * EE;

  __shared__ __align__(16) float kt[64][68];
  __shared__ __align__(16) float qs[4][64];
  __shared__ __align__(16) float ww[4][512];

  qs[wave][lane] = q[((size_t)bz * CC + l) * DD + h * EE + lane];

  float sc[8];
  const int sl = tid >> 4;
  const int e4 = (tid & 15) * 4;
  for (int c8 = 0; c8 < 8; ++c8) {
    #pragma unroll
    for (int r = 0; r < 4; ++r) {
      const int s_local = sl + r * 16;
      const float4 kv = *reinterpret_cast<const float4*>(
          k + base + (size_t)(c8 * 64 + s_local) * DD + e4);
      *reinterpret_cast<float4*>(&kt[s_local][e4]) = kv;
    }
    __syncthreads();
    float a = 0.f;
    #pragma unroll
    for (int e = 0; e < 16; ++e) {
      const float4 qv = *reinterpret_cast<const float4*>(&qs[wave][e * 4]);
      const float4 kv = *reinterpret_cast<const float4*>(&kt[lane][e * 4]);
      a += qv.x * kv.x + qv.y * kv.y + qv.z * kv.z + qv.w * kv.w;
    }
    sc[c8] = a;
    __syncthreads();
  }

  float wk[8];
  #pragma unroll
  for (int j = 0; j < 8; ++j) wk[j] = sc[j];
  float maxv = 0.f, thr = 0.f;
  for (int it = 0; it < 10; ++it) {
    float lm = wk[0];
    #pragma unroll
    for (int j = 1; j < 8; ++j) lm = fmaxf(lm, wk[j]);
    float gm = lm;
    #pragma unroll
    for (int off = 32; off > 0; off >>= 1) gm = fmaxf(gm, __shfl_xor(gm, off));
    if (it == 0) maxv = gm;
    if (it == 9) { thr = gm; break; }
    const unsigned long long msk = __ballot(lm == gm);
    if (lane == __ffsll(msk) - 1) {
      #pragma unroll
      for (int j = 0; j < 8; ++j) { if (wk[j] == gm) { wk[j] = -FLT_MAX; break; } }
    }
  }

  float lsum = 0.f;
  #pragma unroll
  for (int j = 0; j < 8; ++j) {
    const float p = (sc[j] >= thr) ? expf((sc[j] - maxv) * 0.125f) : 0.f;
    ww[wave][j * 64 + lane] = p;
    lsum += p;
  }
  #pragma unroll
  for (int off = 32; off > 0; off >>= 1) lsum += __shfl_xor(lsum, off);
  const float inv = 1.f / lsum;
  __syncthreads();

  float acc = 0.f;
  const float* vp = v + base + lane;
  const float* wp = ww[wave];
  for (int s = 0; s < 512; s += 4) {
    const float4 w4 = *reinterpret_cast<const float4*>(&wp[s]);
    acc = fmaf(w4.x, vp[(size_t)(s + 0) * DD], acc);
    acc = fmaf(w4.y, vp[(size_t)(s + 1) * DD], acc);
    acc = fmaf(w4.z, vp[(size_t)(s + 2) * DD], acc);
    acc = fmaf(w4.w, vp[(size_t)(s + 3) * DD], acc);
  }
  const float res = acc * inv;
  const size_t oi = ((size_t)bz * CC + l) * DD + h * EE + lane;
  if constexpr (sizeof(OT) == 4) out[oi] = res;
  else                           out[oi] = f2b(res);
}

// ---------------- pwattn1 via MFMA: one row per wave ----------------
__global__ __launch_bounds__(256) void pwattn1_mfma(
    const ushort* __restrict__ query, const float* __restrict__ k1,
    const float* __restrict__ v1, ushort* __restrict__ V1)
{
  const int tid = threadIdx.x;
  const int wave = tid >> 6, lane = tid & 63;
  const int quad = lane >> 4, l15 = lane & 15;
  const int n = blockIdx.x * 4 + wave;

  __shared__ __align__(16) ushort Pl[4][16][40];   // stride 80B (16B-aligned)

  const ushort* qrow = query + (size_t)n * DFF;
  const float*  krow = k1 + (size_t)n * 512;
  const float*  vrow = v1 + (size_t)n * 512;
  ushort* orow = V1 + (size_t)n * DFF;

  const short8 zz = {0, 0, 0, 0, 0, 0, 0, 0};
  const f32x4 zacc = (f32x4){0.f, 0.f, 0.f, 0.f};

  // B-frags for scores: col s = nt*16+l15, k = e = quad*8+i (valid e<16)
  short8 bh[2], bl[2];
  #pragma unroll
  for (int nt = 0; nt < 2; ++nt) {
    short8 hh = zz, ll = zz;
    if (quad < 2) {
      const float* kp = krow + (nt * 16 + l15) * 16 + quad * 8;
      #pragma unroll
      for (int i = 0; i < 8; ++i) {
        ushort hi_, lo_; split_bf(kp[i], hi_, lo_);
        hh[i] = (short)hi_; ll[i] = (short)lo_;
      }
    }
    bh[nt] = hh; bl[nt] = ll;
  }
  // B-frag for PV: v[k=s=quad*8+i][n=e=l15]
  short8 vb;
  #pragma unroll
  for (int i = 0; i < 8; ++i) vb[i] = (short)f2b(vrow[(quad * 8 + i) * 16 + l15]);

  #pragma unroll
  for (int mt = 0; mt < 8; ++mt) {
    short8 qa = zz;
    if (quad < 2)
      qa = *reinterpret_cast<const short8*>(qrow + (mt * 16 + l15) * 16 + quad * 8);
    f32x4 acc[2];
    #pragma unroll
    for (int nt = 0; nt < 2; ++nt) {
      f32x4 t = __builtin_amdgcn_mfma_f32_16x16x32_bf16(qa, bl[nt], zacc, 0, 0, 0);
      acc[nt] = __builtin_amdgcn_mfma_f32_16x16x32_bf16(qa, bh[nt], t, 0, 0, 0);
    }
    // softmax over 32 cols (2 nt x 16 lanes); rows quad*4+r
    float inv[4];
    #pragma unroll
    for (int r = 0; r < 4; ++r) {
      float m = red16_max(fmaxf(acc[0][r], acc[1][r]));
      const float p0 = __builtin_amdgcn_exp2f((acc[0][r] - m) * (0.25f * LOG2E));
      const float p1 = __builtin_amdgcn_exp2f((acc[1][r] - m) * (0.25f * LOG2E));
      acc[0][r] = p0; acc[1][r] = p1;
      const float s = red16_sum(p0 + p1);
      inv[r] = 1.f / s;
    }
    #pragma unroll
    for (int nt = 0; nt < 2; ++nt)
      #pragma unroll
      for (int r = 0; r < 4; ++r)
        Pl[wave][quad * 4 + r][nt * 16 + l15] = f2b(acc[nt][r]);
    const short8 pa = *reinterpret_cast<const short8*>(&Pl[wave][l15][quad * 8]);
    const f32x4 pv = __builtin_amdgcn_mfma_f32_16x16x32_bf16(pa, vb, zacc, 0, 0, 0);
    #pragma unroll
    for (int r = 0; r < 4; ++r)
      orow[(mt * 16 + quad * 4 + r) * 16 + l15] = f2b(pv[r] * inv[r]);
  }
}

// ---------------- pwattn2 via MFMA: one row per wave ----------------
__global__ __launch_bounds__(256) void pwattn2_mfma(
    const float* __restrict__ query2, const ushort* __restrict__ k2,
    const ushort* __restrict__ v2, ushort* __restrict__ V2)
{
  const int tid = threadIdx.x;
  const int wave = tid >> 6, lane = tid & 63;
  const int quad = lane >> 4, l15 = lane & 15;
  const int n = blockIdx.x * 4 + wave;

  __shared__ __align__(16) ushort Pl[4][16][136];  // stride 272B (16B-aligned)

  const float*  qrow = query2 + (size_t)n * 512;
  const ushort* krow = k2 + (size_t)n * DFF;
  const ushort* vrow = v2 + (size_t)n * DFF;
  ushort* orow = V2 + (size_t)n * 512;

  const short8 zz = {0, 0, 0, 0, 0, 0, 0, 0};
  const f32x4 zacc = (f32x4){0.f, 0.f, 0.f, 0.f};

  // B-frags for scores: col s = nt*16+l15 (8 nt), k = e = quad*8+i (<16)
  short8 kb[8];
  #pragma unroll
  for (int nt = 0; nt < 8; ++nt)
    kb[nt] = (quad < 2)
        ? *reinterpret_cast<const short8*>(krow + (nt * 16 + l15) * 16 + quad * 8)
        : zz;

  // B-frags for PV: v[k=s=kt*32+quad*8+i][n=e=l15]
  short8 vb[4];
  #pragma unroll
  for (int kt = 0; kt < 4; ++kt)
    #pragma unroll
    for (int i = 0; i < 8; ++i)
      vb[kt][i] = (short)vrow[(kt * 32 + quad * 8 + i) * 16 + l15];

  #pragma unroll
  for (int mt = 0; mt < 2; ++mt) {
    // A hi/lo: q[m=mt*16+l15][k=quad*8+i (<16)]
    short8 ahh = zz, all_ = zz;
    if (quad < 2) {
      const float* qp = qrow + (mt * 16 + l15) * 16 + quad * 8;
      #pragma unroll
      for (int i = 0; i < 8; ++i) {
        ushort hi_, lo_; split_bf(qp[i], hi_, lo_);
        ahh[i] = (short)hi_; all_[i] = (short)lo_;
      }
    }
    f32x4 acc[8];
    #pragma unroll
    for (int nt = 0; nt < 8; ++nt) {
      f32x4 t = __builtin_amdgcn_mfma_f32_16x16x32_bf16(all_, kb[nt], zacc, 0, 0, 0);
      acc[nt] = __builtin_amdgcn_mfma_f32_16x16x32_bf16(ahh, kb[nt], t, 0, 0, 0);
    }
    // softmax over 128 cols (8 nt x 16 lanes); rows quad*4+r
    float inv[4];
    #pragma unroll
    for (int r = 0; r < 4; ++r) {
      float m = acc[0][r];
      #pragma unroll
      for (int nt = 1; nt < 8; ++nt) m = fmaxf(m, acc[nt][r]);
      m = red16_max(m);
      float s = 0.f;
      #pragma unroll
      for (int nt = 0; nt < 8; ++nt) {
        const float p = __builtin_amdgcn_exp2f((acc[nt][r] - m) * (0.25f * LOG2E));
        acc[nt][r] = p; s += p;
      }
      s = red16_sum(s);
      inv[r] = 1.f / s;
    }
    #pragma unroll
    for (int nt = 0; nt < 8; ++nt)
      #pragma unroll
      for (int r = 0; r < 4; ++r)
        Pl[wave][quad * 4 + r][nt * 16 + l15] = f2b(acc[nt][r]);
    f32x4 pv = zacc;
    #pragma unroll
    for (int kt = 0; kt < 4; ++kt) {
      const short8 pa = *reinterpret_cast<const short8*>(&Pl[wave][l15][kt * 32 + quad * 8]);
      pv = __builtin_amdgcn_mfma_f32_16x16x32_bf16(pa, vb[kt], pv, 0, 0, 0);
    }
    #pragma unroll
    for (int r = 0; r < 4; ++r)
      orow[(mt * 16 + quad * 4 + r) * 16 + l15] = f2b(pv[r] * inv[r]);
  }
}

// ---------------- pwattn1 (fallback) ----------------
__global__ __launch_bounds__(128) void pwattn1_kernel(
    const ushort* __restrict__ query, const float* __restrict__ k1,
    const float* __restrict__ v1, ushort* __restrict__ V1)
{
  const int n = blockIdx.x, tid = threadIdx.x;
  __shared__ float ks[512], vs[512];
  __shared__ float Am[128][33];
  for (int i = tid; i < 512; i += 128) { ks[i] = k1[(size_t)n * 512 + i]; vs[i] = v1[(size_t)n * 512 + i]; }
  __syncthreads();
  {
    const int l = tid;
    float qv[16];
    const ushort* qp = query + (size_t)n * DFF + l * 16;
    #pragma unroll
    for (int e = 0; e < 16; ++e) qv[e] = b2f(qp[e]);
    float scl[32], mx = -FLT_MAX;
    #pragma unroll
    for (int s = 0; s < 32; ++s) {
      float a = 0.f;
      #pragma unroll
      for (int e = 0; e < 16; ++e) a += qv[e] * ks[s * 16 + e];
      scl[s] = a; mx = fmaxf(mx, a);
    }
    float sum = 0.f;
    #pragma unroll
    for (int s = 0; s < 32; ++s) { const float p = expf((scl[s] - mx) * 0.25f); scl[s] = p; sum += p; }
    const float invs = 1.f / sum;
    #pragma unroll
    for (int s = 0; s < 32; ++s) Am[l][s] = scl[s] * invs;
  }
  __syncthreads();
  #pragma unroll
  for (int r = 0; r < 16; ++r) {
    const int idx = tid + 128 * r;
    const int l = idx >> 4, e = idx & 15;
    float a = 0.f;
    #pragma unroll
    for (int s = 0; s < 32; ++s) a += Am[l][s] * vs[s * 16 + e];
    V1[(size_t)n * DFF + idx] = f2b(a);
  }
}

// ---------------- LayerNorm over 2048, in-place bf16 ----------------
__global__ __launch_bounds__(256) void ln_kernel(
    ushort* __restrict__ h, const void* __restrict__ g, const void* __restrict__ bt,
    const int* __restrict__ dtf)
{
  const int f32 = *dtf;
  const int n = blockIdx.x, tid = threadIdx.x;
  ushort* hp = h + (size_t)n * DFF;
  float x[8]; float s = 0.f, s2 = 0.f;
  #pragma unroll
  for (int i = 0; i < 8; ++i) {
    const float xv = b2f(hp[tid + 256 * i]);
    x[i] = xv; s += xv; s2 += xv * xv;
  }
  __shared__ float rs[256], rq[256];
  rs[tid] = s; rq[tid] = s2;
  __syncthreads();
  for (int off = 128; off > 0; off >>= 1) {
    if (tid < off) { rs[tid] += rs[tid + off]; rq[tid] += rq[tid + off]; }
    __syncthreads();
  }
  const float mu  = rs[0] * (1.f / DFF);
  const float var = rq[0] * (1.f / DFF) - mu * mu;
  const float inv = rsqrtf(var + 1e-5f);
  #pragma unroll
  for (int i = 0; i < 8; ++i) {
    const int d = tid + 256 * i;
    hp[d] = f2b((x[i] - mu) * inv * lin(g, d, f32) + lin(bt, d, f32));
  }
}

// ---------------- pwattn2 (fallback), templated output -----------
template<typename OT>
__global__ __launch_bounds__(128) void pwattn2_kernel(
    const float* __restrict__ query2, const ushort* __restrict__ k2,
    const ushort* __restrict__ v2, OT* __restrict__ V2)
{
  const int n = blockIdx.x, tid = threadIdx.x;
  __shared__ float ks[2048], vs[2048];
  __shared__ float Am[32][129];
  for (int i = tid; i < 2048; i += 128) {
    ks[i] = b2f(k2[(size_t)n * DFF + i]);
    vs[i] = b2f(v2[(size_t)n * DFF + i]);
  }
  __syncthreads();
  if (tid < 32) {
    const int l = tid;
    float qv[16];
    #pragma unroll
    for (int e = 0; e < 16; ++e) qv[e] = query2[(size_t)n * 512 + l * 16 + e];
    float mx = -FLT_MAX;
    for (int s = 0; s < 128; ++s) {
      float a = 0.f;
      #pragma unroll
      for (int e = 0; e < 16; ++e) a += qv[e] * ks[s * 16 + e];
      Am[l][s] = a; mx = fmaxf(mx, a);
    }
    float sum = 0.f;
    for (int s = 0; s < 128; ++s) { const float p = expf((Am[l][s] - mx) * 0.25f); Am[l][s] = p; sum += p; }
    const float invs = 1.f / sum;
    for (int s = 0; s < 128; ++s) Am[l][s] *= invs;
  }
  __syncthreads();
  #pragma unroll
  for (int r = 0; r < 4; ++r) {
    const int idx = tid + 128 * r;
    const int l = idx >> 4, e = idx & 15;
    float a = 0.f;
    for (int s = 0; s < 128; ++s) a += Am[l][s] * vs[s * 16 + e];
    if constexpr (sizeof(OT) == 4) V2[(size_t)n * 512 + idx] = a;
    else                           V2[(size_t)n * 512 + idx] = f2b(a);
  }
}

// ---------------- final: dec = y@fc_w + fc_b; out = dec*std+mean -----------
// 8 rows/block (LDS-staged), thread owns 4 CONTIGUOUS output cols => one
// float4/ushort4 fc_w load per k-iteration (4x fewer load instructions).
__global__ __launch_bounds__(256) void final_kernel(
    const float* __restrict__ y, const void* __restrict__ fc_w,
    const void* __restrict__ fc_b, const float* __restrict__ meanb,
    const float* __restrict__ stdb, void* __restrict__ out, int row_base,
    const int* __restrict__ dtf)
{
  const int f32 = *dtf;
  const int tid = threadIdx.x;
  const int rloc = tid >> 5;           // 0..7 (row within block)
  const int t32 = tid & 31;            // 0..31
  __shared__ __align__(16) float yr[8][512];
  const int blk_row0 = blockIdx.x * 8;
  #pragma unroll
  for (int i = 0; i < 4; ++i) {
    const int idx = tid + i * 256;     // 1024 float4 slots total
    const int rr = idx >> 7, dd = (idx & 127) * 4;
    *reinterpret_cast<float4*>(&yr[rr][dd]) =
        *reinterpret_cast<const float4*>(y + (size_t)(blk_row0 + rr) * 512 + dd);
  }
  __syncthreads();
  if (t32 < 24) {
    const int n0 = t32 * 4;
    float a0 = 0.f, a1 = 0.f, a2 = 0.f, a3 = 0.f;
    if (f32) {
      const float* W = (const float*)fc_w + n0;
      for (int d = 0; d < 512; ++d) {
        const float4 w4 = *reinterpret_cast<const float4*>(W + (size_t)d * PRED);
        const float yv = yr[rloc][d];
        a0 = fmaf(yv, w4.x, a0); a1 = fmaf(yv, w4.y, a1);
        a2 = fmaf(yv, w4.z, a2); a3 = fmaf(yv, w4.w, a3);
      }
    } else {
      const ushort* W = (const ushort*)fc_w + n0;
      for (int d = 0; d < 512; ++d) {
        const ushort4 w4 = *reinterpret_cast<const ushort4*>(W + (size_t)d * PRED);
        const float yv = yr[rloc][d];
        a0 = fmaf(yv, b2f(w4.x), a0); a1 = fmaf(yv, b2f(w4.y), a1);
        a2 = fmaf(yv, b2f(w4.z), a2); a3 = fmaf(yv, b2f(w4.w), a3);
      }
    }
    const int row = row_base + blk_row0 + rloc;
    const int b = row >> 9, c = row & 511;
    const float sd = stdb[row], mu = meanb[row];
    const float av[4] = {a0, a1, a2, a3};
    #pragma unroll
    for (int j = 0; j < 4; ++j) {
      const float r = (av[j] + lin(fc_b, n0 + j, f32)) * sd + mu;
      const size_t oi = ((size_t)b * PRED + n0 + j) * CC + c;
      if (f32) ((float*)out)[oi] = r;
      else     ((ushort*)out)[oi] = f2b(r);
    }
  }
}

// ---------------------------------------------------------------------------
extern "C" void kernel_launch(void* const* d_in, const int* in_sizes, int n_in,
                              void* d_out, int out_size, void* d_ws, size_t ws_size,
                              hipStream_t stream)
{
  (void)in_sizes; (void)n_in; (void)out_size;
  const void* x_enc   = d_in[0];
  const void* embed_w = d_in[4];
  const void* q_w = d_in[5],  * q_b = d_in[6];
  const void* k_w = d_in[7],  * k_b = d_in[8];
  const void* v_w = d_in[9],  * v_b = d_in[10];
  const void* o_w = d_in[11], * o_b = d_in[12];
  const void* enc_w = d_in[13], * enc_b = d_in[14];
  const void* f1q_w = d_in[15], * f1q_b = d_in[16];
  const void* f1k_w = d_in[17], * f1k_b = d_in[18];
  const void* f1v_w = d_in[19], * f1v_b = d_in[20];
  const void* f1o_w = d_in[21], * f1o_b = d_in[22];
  const void* f2q_w = d_in[23], * f2q_b = d_in[24];
  const void* f2k_w = d_in[25], * f2k_b = d_in[26];
  const void* f2v_w = d_in[27], * f2v_b = d_in[28];
  const void* f2o_w = d_in[29], * f2o_b = d_in[30];
  const void* ln_g  = d_in[31], * ln_b  = d_in[32];
  const void* fc_w  = d_in[33], * fc_b  = d_in[34];

  const size_t HDR = 131072 + 1024;
  const size_t E_F1Q = 512ull * 2048, E_F1O = 2048ull * 2048, E_F2Q = 2048ull * 512;
  const size_t E_F2K = 2048ull * 2048, E_F2V = 2048ull * 2048, E_F2O = 512ull * 512;
  const size_t E_SQ  = 512ull * 512;   // o_w, enc_w, f1k_w, f1v_w each
  // + 8 split arrays (embed/q/k/v hi+lo)
  const size_t WT_EL = E_F1Q + E_F1O + E_F2Q + E_F2K + E_F2V + E_F2O + 4 * E_SQ + 8 * E_SQ;
  const size_t WT_BYTES = WT_EL * 2;   // ~34.5 MB
  const size_t PB_MFMA = 4ull * 512 * 512 * 4 + 3ull * 512 * DFF * 2; // 10.0MB
  const size_t PB_FB   = 5ull * 512 * 512 * 4 + 3ull * 512 * DFF * 2; // 11.0MB

  const int use_mfma = (HDR + WT_BYTES + PB_MFMA <= ws_size) ? 1 : 0;
  const size_t PER_BATCH = use_mfma ? PB_MFMA : PB_FB;
  const size_t FIXED = HDR + (use_mfma ? WT_BYTES : 0);
  int BPC = 1;
  for (int c = 8; c >= 1; c >>= 1) {
    if (FIXED + (size_t)c * PER_BATCH <= ws_size) { BPC = c; break; }
  }
  const int R = BPC * 512;

  char* ws = (char*)d_ws;
  float* meanb = (float*)ws;
  float* stdb  = (float*)(ws + 65536);
  int*   dtf   = (int*)(ws + 131072);
  ushort* wt_base = (ushort*)(ws + HDR);
  ushort* wt_f1q = wt_base;
  ushort* wt_f1o = wt_f1q + E_F1Q;
  ushort* wt_f2q = wt_f1o + E_F1O;
  ushort* wt_f2k = wt_f2q + E_F2Q;
  ushort* wt_f2v = wt_f2k + E_F2K;
  ushort* wt_f2o = wt_f2v + E_F2V;
  ushort* wt_o   = wt_f2o + E_F2O;
  ushort* wt_enc = wt_o   + E_SQ;
  ushort* wt_f1k = wt_enc + E_SQ;
  ushort* wt_f1v = wt_f1k + E_SQ;
  ushort* wt_embh = wt_f1v + E_SQ;
  ushort* wt_embl = wt_embh + E_SQ;
  ushort* wt_qh   = wt_embl + E_SQ;
  ushort* wt_ql   = wt_qh   + E_SQ;
  ushort* wt_kh   = wt_ql   + E_SQ;
  ushort* wt_kl   = wt_kh   + E_SQ;
  ushort* wt_vh   = wt_kl   + E_SQ;
  ushort* wt_vl   = wt_vh   + E_SQ;

  char* arena = ws + FIXED;
  const size_t FSL = (size_t)R * 512 * 4;
  const size_t GSL = (size_t)R * DFF * 2;
  void* A_ = arena;
  void* B_ = arena + FSL;
  void* C_ = arena + 2 * FSL;
  void* D_ = arena + 3 * FSL;
  void* E_ = arena + 4 * FSL;                     // fallback path only
  char* gb = arena + (size_t)(use_mfma ? 4 : 5) * FSL;
  void* G1 = gb;
  void* G2 = gb + GSL;
  void* G3 = gb + 2 * GSL;

  // mfma-path split buffers
  ushort* xTh  = (ushort*)G1; ushort* xTl  = xTh  + (size_t)R * 512; // in G1 (dead before f1q)
  ushort* embh = (ushort*)G2; ushort* embl = embh + (size_t)R * 512; // in G2 (dead before pwattn1)
  ushort* qsh  = (ushort*)C_; ushort* qsl  = qsh  + (size_t)R * 512;
  ushort* ksh  = (ushort*)D_; ushort* ksl  = ksh  + (size_t)R * 512;
  ushort* vt   = (ushort*)B_;                                        // vT, dead before f1v

  detect_dtype<<<1, 256, 0, stream>>>((const ushort*)x_enc, dtf);
  // two-phase instance-norm stats; partials live in the (still idle) arena
  instnorm_partial<<<dim3(2, NB, 8), 256, 0, stream>>>(
      x_enc, (float*)A_, (float*)B_, dtf);
  instnorm_reduce<<<dim3(2, NB), 256, 0, stream>>>(
      (const float*)A_, (const float*)B_, meanb, stdb);

  if (use_mfma) {   // one-time weight convert+transpose (KxN -> bf16 NxK)
    transpose_w<<<dim3(DFF / 32, 512 / 32), 256, 0, stream>>>(f1q_w, wt_f1q, 512, DFF, dtf);
    transpose_w<<<dim3(DFF / 32, DFF / 32), 256, 0, stream>>>(f1o_w, wt_f1o, DFF, DFF, dtf);
    transpose_w<<<dim3(512 / 32, DFF / 32), 256, 0, stream>>>(f2q_w, wt_f2q, DFF, 512, dtf);
    transpose_w<<<dim3(DFF / 32, DFF / 32), 256, 0, stream>>>(f2k_w, wt_f2k, DFF, DFF, dtf);
    transpose_w<<<dim3(DFF / 32, DFF / 32), 256, 0, stream>>>(f2v_w, wt_f2v, DFF, DFF, dtf);
    transpose_w<<<dim3(512 / 32, 512 / 32), 256, 0, stream>>>(f2o_w, wt_f2o, 512, 512, dtf);
    transpose_w<<<dim3(512 / 32, 512 / 32), 256, 0, stream>>>(o_w,   wt_o,   512, 512, dtf);
    transpose_w<<<dim3(512 / 32, 512 / 32), 256, 0, stream>>>(enc_w, wt_enc, 512, 512, dtf);
    transpose_w<<<dim3(512 / 32, 512 / 32), 256, 0, stream>>>(f1k_w, wt_f1k, 512, 512, dtf);
    transpose_w<<<dim3(512 / 32, 512 / 32), 256, 0, stream>>>(f1v_w, wt_f1v, 512, 512, dtf);
    transpose_w_split<<<dim3(512 / 32, 512 / 32), 256, 0, stream>>>(embed_w, wt_embh, wt_embl, 512, 512, dtf);
    transpose_w_split<<<dim3(512 / 32, 512 / 32), 256, 0, stream>>>(q_w, wt_qh, wt_ql, 512, 512, dtf);
    transpose_w_split<<<dim3(512 / 32, 512 / 32), 256, 0, stream>>>(k_w, wt_kh, wt_kl, 512, 512, dtf);
    transpose_w_split<<<dim3(512 / 32, 512 / 32), 256, 0, stream>>>(v_w, wt_vh, wt_vl, 512, 512, dtf);
  }

  for (int bc = 0; bc < NB / BPC; ++bc) {
    const int b0 = bc * BPC;
    if (use_mfma) {
      // --- stage 1: split-MFMA GEMMs ---
      norm_transpose_split<<<dim3(16, 16, BPC), 256, 0, stream>>>(
          x_enc, meanb, stdb, xTh, xTl, b0, dtf);
      launch_mgemm3<E3_RELU_PE>(xTh, xTl, wt_embh, wt_embl, nullptr,
                                embh, embl, R, 512, 512, dtf, stream);         // emb hi/lo
      launch_mgemm3<E3_RELU_SPLIT>(embh, embl, wt_qh, wt_ql, q_b,
                                   qsh, qsl, R, 512, 512, dtf, stream);        // q hi/lo
      launch_mgemm3<E3_SPLIT>(embh, embl, wt_kh, wt_kl, k_b,
                              ksh, ksl, R, 512, 512, dtf, stream);             // k hi/lo
      launch_mgemm3<E3_RELU_VT>(embh, embl, wt_vh, wt_vl, v_b,
                                vt, nullptr, R, 512, 512, dtf, stream);        // vT bf16
      gattn_mfma<<<dim3(CC / 16, HH, BPC), 256, 0, stream>>>(
          qsh, qsl, ksh, ksl, vt, (ushort*)A_);                                // attn bf16
      launch_mgemm64<ushort, ushort, M_ADD2_BIAS_LEAKY>(
          A_, wt_o, o_b, embh, C_, R, 512, 512, dtf, stream, embl);            // y bf16
      launch_mgemm64<float, ushort, M_BIAS>(C_, wt_enc, enc_b, nullptr, D_, R, 512, 512, dtf, stream);  // X1 bf16
      // --- stage 2: pwattn1 + LN ---
      launch_mgemm<float, ushort, M_BIAS_RELU>(D_, wt_f1q, f1q_b, nullptr, G1, R, 512, DFF, dtf, stream); // query1
      launch_mgemm64<float, float, M_BIAS     >(D_, wt_f1k, f1k_b, nullptr, A_, R, 512, 512, dtf, stream); // k1 f32
      launch_mgemm64<float, float, M_BIAS_RELU>(D_, wt_f1v, f1v_b, nullptr, B_, R, 512, 512, dtf, stream); // v1 f32
      pwattn1_mfma<<<R / 4, 256, 0, stream>>>(
          (const ushort*)G1, (const float*)A_, (const float*)B_, (ushort*)G2);
      launch_mgemm<ushort, ushort, M_ADD_BIAS_ELU>(G2, wt_f1o, f1o_b, G1, G1, R, DFF, DFF, dtf, stream);  // h
      ln_kernel<<<R, 256, 0, stream>>>((ushort*)G1, ln_g, ln_b, dtf);
      // --- stage 3: pwattn2 + out ---
      launch_mgemm64<float, float, M_BIAS_RELU>(G1, wt_f2q, f2q_b, nullptr, A_, R, DFF, 512, dtf, stream); // query2
      launch_mgemm<float, ushort, M_BIAS     >(G1, wt_f2k, f2k_b, nullptr, G2, R, DFF, DFF, dtf, stream); // k2
      launch_mgemm<float, ushort, M_BIAS_RELU>(G1, wt_f2v, f2v_b, nullptr, G3, R, DFF, DFF, dtf, stream); // v2
      pwattn2_mfma<<<R / 4, 256, 0, stream>>>(
          (const float*)A_, (const ushort*)G2, (const ushort*)G3, (ushort*)B_);
      launch_mgemm64<float, float, M_ADD_BIAS>(B_, wt_f2o, f2o_b, A_, C_, R, 512, 512, dtf, stream);      // y2
    } else {
      norm_transpose<<<dim3(16, 16, BPC), 256, 0, stream>>>(x_enc, meanb, stdb, (float*)A_, b0, dtf);
      launch_gemm<float, float, float, M_RELU_PE >(A_, embed_w, nullptr, nullptr, B_, R, 512, 512, dtf, stream);
      launch_gemm<float, float, float, M_BIAS_RELU>(B_, q_w, q_b, nullptr, C_, R, 512, 512, dtf, stream);
      launch_gemm<float, float, float, M_BIAS     >(B_, k_w, k_b, nullptr, D_, R, 512, 512, dtf, stream);
      launch_gemm<float, float, float, M_BIAS_RELU>(B_, v_w, v_b, nullptr, E_, R, 512, 512, dtf, stream);
      gattn_fb<float><<<dim3(CC / 4, HH, BPC), 256, 0, stream>>>(
          (float*)C_, (float*)D_, (float*)E_, (float*)A_);
      launch_gemm<float, float, float, M_ADD_BIAS_LEAKY>(A_, o_w, o_b, B_, C_, R, 512, 512, dtf, stream);
      launch_gemm<float, float, float, M_BIAS>(C_, enc_w, enc_b, nullptr, D_, R, 512, 512, dtf, stream);
      launch_gemm<float, float, ushort, M_BIAS_RELU>(D_, f1q_w, f1q_b, nullptr, G1, R, 512, DFF, dtf, stream);
      launch_gemm<float, float, float,  M_BIAS     >(D_, f1k_w, f1k_b, nullptr, A_, R, 512, 512, dtf, stream);
      launch_gemm<float, float, float,  M_BIAS_RELU>(D_, f1v_w, f1v_b, nullptr, B_, R, 512, 512, dtf, stream);
      pwattn1_kernel<<<R, 128, 0, stream>>>((const ushort*)G1, (const float*)A_, (const float*)B_, (ushort*)G2);
      launch_gemm<ushort, ushort, ushort, M_ADD_BIAS_ELU>(G2, f1o_w, f1o_b, G1, G1, R, DFF, DFF, dtf, stream);
      ln_kernel<<<R, 256, 0, stream>>>((ushort*)G1, ln_g, ln_b, dtf);
      launch_gemm<ushort, float, float,  M_BIAS_RELU>(G1, f2q_w, f2q_b, nullptr, A_, R, DFF, 512, dtf, stream);
      launch_gemm<ushort, float, ushort, M_BIAS     >(G1, f2k_w, f2k_b, nullptr, G2, R, DFF, DFF, dtf, stream);
      launch_gemm<ushort, float, ushort, M_BIAS_RELU>(G1, f2v_w, f2v_b, nullptr, G3, R, DFF, DFF, dtf, stream);
      pwattn2_kernel<float><<<R, 128, 0, stream>>>((const float*)A_, (const ushort*)G2, (const ushort*)G3, (float*)B_);
      launch_gemm<float, float, float, M_ADD_BIAS>(B_, f2o_w, f2o_b, A_, C_, R, 512, 512, dtf, stream);
    }
    final_kernel<<<R / 8, 256, 0, stream>>>((const float*)C_, fc_w, fc_b, meanb, stdb, d_out, b0 * 512, dtf);
  }
}

// Round 10
// 2220.456 us; speedup vs baseline: 1.2935x; 1.0121x over previous
//
#include <hip/hip_runtime.h>
#include <float.h>
#include <math.h>
#include <stdint.h>

// ---------------------------------------------------------------------------
// Model_33062658245168: Informer-style time-series model. fp32 in/out
// (runtime-detected; bf16 fallback kept). B=32 S=512 C=512 D=512 DF=2048 H=8
// E=64 P=16 PRED=96 K(topk)=10, N=16384.
//
// Round 21: extend global_load_lds staging (verified +80us on mgemm in r20)
// to mgemm3 (stage-1 hi/lo GEMMs, 3x MFMA work => staging overhead counts
// triple) and mgemm64 (6 launches/chunk). Same linear [64][32] LDS (64B rows,
// analytically bank-uniform for the b128 frag reads), same 16-rows-per-wave
// one-issue-per-array geometry. mgemm3 LDS 20->16KB, mgemm64 10->8KB.
// gattn/pwattn/final byte-frozen at r20 (2247us). A/B: gattn holds 73-76us.
// ---------------------------------------------------------------------------

#define NB   32
#define SS   512
#define CC   512
#define DD   512
#define DFF  2048
#define HH   8
#define EE   64
#define PRED 96

typedef __attribute__((ext_vector_type(8))) short short8;
typedef __attribute__((ext_vector_type(4))) float f32x4;

#define LOG2E 1.4426950408889634f

__device__ __forceinline__ float b2f(ushort u) {
  union { float f; uint32_t i; } c; c.i = ((uint32_t)u) << 16; return c.f;
}
__device__ __forceinline__ ushort f2b(float f) {
  union { float f; uint32_t i; } c; c.f = f;
  uint32_t x = c.i;
  return (ushort)((x + 0x7fffu + ((x >> 16) & 1u)) >> 16);   // RNE
}
__device__ __forceinline__ float lin(const void* p, size_t i, int f32) {
  return f32 ? ((const float*)p)[i] : b2f(((const ushort*)p)[i]);
}
__device__ __forceinline__ void split_bf(float x, ushort& hi, ushort& lo) {
  hi = f2b(x);
  lo = f2b(x - b2f(hi));
}
// async global->LDS, 16B per lane; dst is wave-uniform base (+lane*16 by HW)
__device__ __forceinline__ void gl_lds16(const void* g, void* l) {
  __builtin_amdgcn_global_load_lds(
      (const __attribute__((address_space(1))) void*)g,
      (__attribute__((address_space(3))) void*)l, 16, 0, 0);
}

// ---- DPP 16-lane all-reduce (VALU only) ----
template<int CTRL>
__device__ __forceinline__ float dppmov(float x) {
  union { float f; int i; } a, b;
  a.f = x;
  b.i = __builtin_amdgcn_update_dpp(a.i, a.i, CTRL, 0xF, 0xF, false);
  return b.f;
}
__device__ __forceinline__ float red16_max(float x) {
  x = fmaxf(x, dppmov<0xB1>(x));    // quad_perm xor1
  x = fmaxf(x, dppmov<0x4E>(x));    // quad_perm xor2
  x = fmaxf(x, dppmov<0x141>(x));   // row_half_mirror
  x = fmaxf(x, dppmov<0x140>(x));   // row_mirror
  return x;
}
__device__ __forceinline__ float red16_sum(float x) {
  x += dppmov<0xB1>(x);
  x += dppmov<0x4E>(x);
  x += dppmov<0x141>(x);
  x += dppmov<0x140>(x);
  return x;
}

// ---------------- dtype detection (1 = fp32 inputs) ----------------
__global__ __launch_bounds__(256) void detect_dtype(
    const ushort* __restrict__ x, int* __restrict__ flag)
{
  __shared__ float red[256];
  const int t = threadIdx.x;
  float v = fabsf(b2f(x[2 * t]));
  if (!(v < 1e30f)) v = 1e30f;
  red[t] = v;
  __syncthreads();
  for (int off = 128; off > 0; off >>= 1) {
    if (t < off) red[t] = fmaxf(red[t], red[t + off]);
    __syncthreads();
  }
  if (t == 0) flag[0] = (red[0] > 1e6f) ? 1 : 0;
}

// ---------------- instance norm stats, two-phase ----------------
__global__ __launch_bounds__(256) void instnorm_partial(
    const void* __restrict__ x, float* __restrict__ ps, float* __restrict__ pq,
    const int* __restrict__ dtf)
{
  const int f32 = *dtf;
  const int c = blockIdx.x * 256 + threadIdx.x;
  const int b = blockIdx.y;
  const int t0 = blockIdx.z * 64;
  float s = 0.f, s2 = 0.f;
  for (int t = t0; t < t0 + 64; ++t) {
    const float xv = lin(x, ((size_t)(b * SS) + t) * CC + c, f32);
    s += xv; s2 += xv * xv;
  }
  const int pidx = (b * 8 + blockIdx.z) * CC + c;
  ps[pidx] = s; pq[pidx] = s2;
}

__global__ __launch_bounds__(256) void instnorm_reduce(
    const float* __restrict__ ps, const float* __restrict__ pq,
    float* __restrict__ meanb, float* __restrict__ stdb)
{
  const int c = blockIdx.x * 256 + threadIdx.x;
  const int b = blockIdx.y;
  float s = 0.f, s2 = 0.f;
  #pragma unroll
  for (int i = 0; i < 8; ++i) {
    s  += ps[(b * 8 + i) * CC + c];
    s2 += pq[(b * 8 + i) * CC + c];
  }
  const float mu  = s * (1.f / SS);
  const float var = s2 * (1.f / SS) - mu * mu;
  meanb[b * CC + c] = mu;
  stdb [b * CC + c] = sqrtf(var + 1e-5f);
}

// ---------------- normalize + transpose one chunk (fp32, fallback) ---------
__global__ __launch_bounds__(256) void norm_transpose(
    const void* __restrict__ x, const float* __restrict__ meanb,
    const float* __restrict__ stdb, float* __restrict__ xTc, int b_base,
    const int* __restrict__ dtf)
{
  const int f32 = *dtf;
  __shared__ float t[32][33];
  const int s0 = blockIdx.x * 32, c0 = blockIdx.y * 32, lb = blockIdx.z;
  const int b = b_base + lb;
  const int tx = threadIdx.x & 31, ty = threadIdx.x >> 5;
  #pragma unroll
  for (int i = 0; i < 4; ++i) {
    const int s = s0 + ty + i * 8;
    t[ty + i * 8][tx] = lin(x, ((size_t)(b * SS) + s) * CC + c0 + tx, f32);
  }
  __syncthreads();
  #pragma unroll
  for (int i = 0; i < 4; ++i) {
    const int c = c0 + ty + i * 8;
    const float mu = meanb[b * CC + c], sd = stdb[b * CC + c];
    xTc[((size_t)(lb * CC) + c) * SS + s0 + tx] = (t[tx][ty + i * 8] - mu) / sd;
  }
}

// ---------------- normalize + transpose, hi/lo split output ----------------
__global__ __launch_bounds__(256) void norm_transpose_split(
    const void* __restrict__ x, const float* __restrict__ meanb,
    const float* __restrict__ stdb, ushort* __restrict__ xh,
    ushort* __restrict__ xl, int b_base, const int* __restrict__ dtf)
{
  const int f32 = *dtf;
  __shared__ float t[32][33];
  const int s0 = blockIdx.x * 32, c0 = blockIdx.y * 32, lb = blockIdx.z;
  const int b = b_base + lb;
  const int tx = threadIdx.x & 31, ty = threadIdx.x >> 5;
  #pragma unroll
  for (int i = 0; i < 4; ++i) {
    const int s = s0 + ty + i * 8;
    t[ty + i * 8][tx] = lin(x, ((size_t)(b * SS) + s) * CC + c0 + tx, f32);
  }
  __syncthreads();
  #pragma unroll
  for (int i = 0; i < 4; ++i) {
    const int c = c0 + ty + i * 8;
    const float mu = meanb[b * CC + c], sd = stdb[b * CC + c];
    const float v = (t[tx][ty + i * 8] - mu) / sd;
    const size_t idx = ((size_t)(lb * CC) + c) * SS + s0 + tx;
    ushort hi, lo; split_bf(v, hi, lo);
    xh[idx] = hi; xl[idx] = lo;
  }
}

// ---------------- weight convert+transpose: W (KxN, input dtype) -> bf16 (NxK)
__global__ __launch_bounds__(256) void transpose_w(
    const void* __restrict__ W, ushort* __restrict__ Wt, int K, int N,
    const int* __restrict__ dtf)
{
  const int f32 = *dtf;
  __shared__ float t[32][33];
  const int n0 = blockIdx.x * 32, k0 = blockIdx.y * 32;
  const int tx = threadIdx.x & 31, ty = threadIdx.x >> 5;
  #pragma unroll
  for (int i = 0; i < 4; ++i)
    t[ty + i * 8][tx] = lin(W, (size_t)(k0 + ty + i * 8) * N + n0 + tx, f32);
  __syncthreads();
  #pragma unroll
  for (int i = 0; i < 4; ++i)
    Wt[(size_t)(n0 + ty + i * 8) * K + k0 + tx] = f2b(t[tx][ty + i * 8]);
}

// ---------------- weight transpose + hi/lo split ----------------
__global__ __launch_bounds__(256) void transpose_w_split(
    const void* __restrict__ W, ushort* __restrict__ Whi, ushort* __restrict__ Wlo,
    int K, int N, const int* __restrict__ dtf)
{
  const int f32 = *dtf;
  __shared__ float t[32][33];
  const int n0 = blockIdx.x * 32, k0 = blockIdx.y * 32;
  const int tx = threadIdx.x & 31, ty = threadIdx.x >> 5;
  #pragma unroll
  for (int i = 0; i < 4; ++i)
    t[ty + i * 8][tx] = lin(W, (size_t)(k0 + ty + i * 8) * N + n0 + tx, f32);
  __syncthreads();
  #pragma unroll
  for (int i = 0; i < 4; ++i) {
    const size_t idx = (size_t)(n0 + ty + i * 8) * K + k0 + tx;
    ushort hi, lo; split_bf(t[tx][ty + i * 8], hi, lo);
    Whi[idx] = hi; Wlo[idx] = lo;
  }
}

// ---------------- generic fp32 tiled GEMM (fallback path) ----------
enum GemmMode { M_BIAS = 0, M_BIAS_RELU = 1, M_RELU_PE = 2,
                M_ADD_BIAS_LEAKY = 3, M_ADD_BIAS_ELU = 4, M_ADD_BIAS = 5,
                M_ADD2_BIAS_LEAKY = 6 };

template<typename AT, typename ADT, typename OT, int MODE>
__global__ __launch_bounds__(256) void gemm_kernel(
    const AT* __restrict__ A, const void* __restrict__ Bw,
    const void* __restrict__ bias, const ADT* __restrict__ addend,
    OT* __restrict__ Cout, int M, int K, int Nn, const int* __restrict__ dtf)
{
  const int f32 = *dtf;
  __shared__ __align__(16) float As[16][68];
  __shared__ __align__(16) float Bs[16][68];
  const int tid = threadIdx.x;
  const int m0 = blockIdx.y * 64, n0 = blockIdx.x * 64;
  const int tx = tid & 15, ty = tid >> 4;
  const int la_m = tid >> 2, la_k = (tid & 3) * 4;
  const int lb_k = tid >> 4, lb_n = (tid & 15) * 4;
  float acc[4][4];
  #pragma unroll
  for (int i = 0; i < 4; ++i)
    #pragma unroll
    for (int j = 0; j < 4; ++j) acc[i][j] = 0.f;
  const size_t a_row = (size_t)(m0 + la_m) * K;

  for (int k0 = 0; k0 < K; k0 += 16) {
    if constexpr (sizeof(AT) == 4) {
      const float4 av = *reinterpret_cast<const float4*>(A + a_row + k0 + la_k);
      As[la_k + 0][la_m] = av.x; As[la_k + 1][la_m] = av.y;
      As[la_k + 2][la_m] = av.z; As[la_k + 3][la_m] = av.w;
    } else {
      const ushort4 av = *reinterpret_cast<const ushort4*>(A + a_row + k0 + la_k);
      As[la_k + 0][la_m] = b2f(av.x); As[la_k + 1][la_m] = b2f(av.y);
      As[la_k + 2][la_m] = b2f(av.z); As[la_k + 3][la_m] = b2f(av.w);
    }
    {
      const size_t boff = (size_t)(k0 + lb_k) * Nn + n0 + lb_n;
      if (f32) {
        const float4 bv = *reinterpret_cast<const float4*>((const float*)Bw + boff);
        Bs[lb_k][lb_n + 0] = bv.x; Bs[lb_k][lb_n + 1] = bv.y;
        Bs[lb_k][lb_n + 2] = bv.z; Bs[lb_k][lb_n + 3] = bv.w;
      } else {
        const ushort4 bv = *reinterpret_cast<const ushort4*>((const ushort*)Bw + boff);
        Bs[lb_k][lb_n + 0] = b2f(bv.x); Bs[lb_k][lb_n + 1] = b2f(bv.y);
        Bs[lb_k][lb_n + 2] = b2f(bv.z); Bs[lb_k][lb_n + 3] = b2f(bv.w);
      }
    }
    __syncthreads();
    #pragma unroll
    for (int k = 0; k < 16; ++k) {
      const float4 a4 = *reinterpret_cast<const float4*>(&As[k][ty * 4]);
      const float4 b4 = *reinterpret_cast<const float4*>(&Bs[k][tx * 4]);
      const float aa[4] = {a4.x, a4.y, a4.z, a4.w};
      const float bb[4] = {b4.x, b4.y, b4.z, b4.w};
      #pragma unroll
      for (int i = 0; i < 4; ++i)
        #pragma unroll
        for (int j = 0; j < 4; ++j)
          acc[i][j] = fmaf(aa[i], bb[j], acc[i][j]);
    }
    __syncthreads();
  }

  float biasv[4];
  if constexpr (MODE != M_RELU_PE) {
    #pragma unroll
    for (int j = 0; j < 4; ++j) biasv[j] = lin(bias, n0 + tx * 4 + j, f32);
  }
  #pragma unroll
  for (int i = 0; i < 4; ++i) {
    const int m = m0 + ty * 4 + i;
    #pragma unroll
    for (int j = 0; j < 4; ++j) {
      const int n = n0 + tx * 4 + j;
      float v = acc[i][j];
      if constexpr (MODE == M_BIAS) {
        v += biasv[j];
      } else if constexpr (MODE == M_BIAS_RELU) {
        v = fmaxf(v + biasv[j], 0.f);
      } else if constexpr (MODE == M_RELU_PE) {
        v = fmaxf(v, 0.f);
        const float freq = expf((float)(n & ~1) * (-0.017988946f)); // -ln(1e4)/512
        const float ang  = (float)(m & (CC - 1)) * freq;            // pos = c
        v += (n & 1) ? cosf(ang) : sinf(ang);
      } else {
        float ad;
        if constexpr (sizeof(ADT) == 4) ad = ((const float*)addend)[(size_t)m * Nn + n];
        else                            ad = b2f(((const ushort*)addend)[(size_t)m * Nn + n]);
        v = ad + v + biasv[j];
        if constexpr (MODE == M_ADD_BIAS_LEAKY) v = (v >= 0.f) ? v : 0.5f * v;
        else if constexpr (MODE == M_ADD_BIAS_ELU) v = (v > 0.f) ? v : expm1f(v);
      }
      if constexpr (sizeof(OT) == 4) ((float*)Cout)[(size_t)m * Nn + n] = v;
      else                           ((ushort*)Cout)[(size_t)m * Nn + n] = f2b(v);
    }
  }
}

template<typename AT, typename ADT, typename OT, int MODE>
static void launch_gemm(const void* A, const void* Bw, const void* bias, const void* add,
                        void* Cout, int M, int K, int Nn, const int* dtf, hipStream_t stream)
{
  dim3 grid(Nn / 64, M / 64);
  gemm_kernel<AT, ADT, OT, MODE><<<grid, dim3(256), 0, stream>>>(
      (const AT*)A, Bw, bias, (const ADT*)add, (OT*)Cout, M, K, Nn, dtf);
}

// ---------------- MFMA bf16 GEMM (128x128 tile), global_load_lds staging ----
// Linear LDS [128][32] (64B rows): HW writes base+lane*16; ds_read_b128 frag
// pattern is exactly bank-uniform (8 accesses/bank) => no swizzle needed.
template<typename ADT, typename OT, int MODE>
__global__ __launch_bounds__(256) void mgemm_kernel(
    const ushort* __restrict__ A, const ushort* __restrict__ Wt,
    const void* __restrict__ bias, const ADT* __restrict__ addend,
    const ushort* __restrict__ addend2,
    OT* __restrict__ Cout, int M, int K, int Nn, const int* __restrict__ dtf)
{
  const int f32 = *dtf;
  __shared__ __align__(16) ushort As[128][32];
  __shared__ __align__(16) ushort Bs[128][32];
  const int tid = threadIdx.x;
  const int m0 = blockIdx.y * 128, n0 = blockIdx.x * 128;
  const int wave = tid >> 6, lane = tid & 63;
  const int wm = wave & 1, wn = wave >> 1;
  const int quad = lane >> 4, l15 = lane & 15;

  f32x4 acc[4][4];
  #pragma unroll
  for (int i = 0; i < 4; ++i)
    #pragma unroll
    for (int j = 0; j < 4; ++j) acc[i][j] = (f32x4){0.f, 0.f, 0.f, 0.f};

  const int srow_l = lane >> 2;   // 0..15 row within a 16-row issue
  const int slot   = lane & 3;    // 0..3  (x8 ushort = 16B column slot)

  for (int k0 = 0; k0 < K; k0 += 32) {
    #pragma unroll
    for (int i = 0; i < 2; ++i) {
      const int row = wave * 32 + i * 16;   // wave-uniform LDS base row
      gl_lds16(A  + (size_t)(m0 + row + srow_l) * K + k0 + slot * 8, &As[row][0]);
      gl_lds16(Wt + (size_t)(n0 + row + srow_l) * K + k0 + slot * 8, &Bs[row][0]);
    }
    __syncthreads();
    short8 af[4], bf[4];
    #pragma unroll
    for (int i = 0; i < 4; ++i)
      af[i] = *reinterpret_cast<const short8*>(&As[wm * 64 + i * 16 + l15][quad * 8]);
    #pragma unroll
    for (int j = 0; j < 4; ++j)
      bf[j] = *reinterpret_cast<const short8*>(&Bs[wn * 64 + j * 16 + l15][quad * 8]);
    #pragma unroll
    for (int i = 0; i < 4; ++i)
      #pragma unroll
      for (int j = 0; j < 4; ++j)
        acc[i][j] = __builtin_amdgcn_mfma_f32_16x16x32_bf16(af[i], bf[j], acc[i][j], 0, 0, 0);
    __syncthreads();
  }

  #pragma unroll
  for (int j = 0; j < 4; ++j) {
    const int n = n0 + wn * 64 + j * 16 + l15;
    const float bv = lin(bias, n, f32);
    #pragma unroll
    for (int i = 0; i < 4; ++i) {
      #pragma unroll
      for (int r = 0; r < 4; ++r) {
        const int m = m0 + wm * 64 + i * 16 + quad * 4 + r;
        float v = acc[i][j][r];
        if constexpr (MODE == M_BIAS) {
          v += bv;
        } else if constexpr (MODE == M_BIAS_RELU) {
          v = fmaxf(v + bv, 0.f);
        } else if constexpr (MODE == M_ADD2_BIAS_LEAKY) {
          const size_t ix = (size_t)m * Nn + n;
          const float ad = b2f(((const ushort*)addend)[ix]) + b2f(addend2[ix]);
          v = ad + v + bv;
          v = (v >= 0.f) ? v : 0.5f * v;
        } else {
          float ad;
          if constexpr (sizeof(ADT) == 4) ad = ((const float*)addend)[(size_t)m * Nn + n];
          else                            ad = b2f(((const ushort*)addend)[(size_t)m * Nn + n]);
          v = ad + v + bv;
          if constexpr (MODE == M_ADD_BIAS_ELU)
            v = (v > 0.f) ? v : (__builtin_amdgcn_exp2f(v * LOG2E) - 1.f);
          else if constexpr (MODE == M_ADD_BIAS_LEAKY) v = (v >= 0.f) ? v : 0.5f * v;
        }
        if constexpr (sizeof(OT) == 4) ((float*)Cout)[(size_t)m * Nn + n] = v;
        else                           ((ushort*)Cout)[(size_t)m * Nn + n] = f2b(v);
      }
    }
  }
}

template<typename ADT, typename OT, int MODE>
static void launch_mgemm(const void* A, const void* Wt, const void* bias, const void* add,
                         void* Cout, int M, int K, int Nn, const int* dtf, hipStream_t stream,
                         const void* add2 = nullptr)
{
  dim3 grid(Nn / 128, M / 128);
  mgemm_kernel<ADT, OT, MODE><<<grid, dim3(256), 0, stream>>>(
      (const ushort*)A, (const ushort*)Wt, bias, (const ADT*)add, (const ushort*)add2,
      (OT*)Cout, M, K, Nn, dtf);
}

// ---------------- MFMA bf16 GEMM (64x64 tile), global_load_lds staging ------
// Same linear-[64][32] geometry: wave w stages rows w*16..w*16+15 with one
// gl_lds16 per array per K-step.
template<typename ADT, typename OT, int MODE>
__global__ __launch_bounds__(256) void mgemm64_kernel(
    const ushort* __restrict__ A, const ushort* __restrict__ Wt,
    const void* __restrict__ bias, const ADT* __restrict__ addend,
    const ushort* __restrict__ addend2,
    OT* __restrict__ Cout, int M, int K, int Nn, const int* __restrict__ dtf)
{
  const int f32 = *dtf;
  __shared__ __align__(16) ushort As[64][32];
  __shared__ __align__(16) ushort Bs[64][32];
  const int tid = threadIdx.x;
  const int m0 = blockIdx.y * 64, n0 = blockIdx.x * 64;
  const int wave = tid >> 6, lane = tid & 63;
  const int wm = wave & 1, wn = wave >> 1;
  const int quad = lane >> 4, l15 = lane & 15;

  f32x4 acc[2][2];
  #pragma unroll
  for (int i = 0; i < 2; ++i)
    #pragma unroll
    for (int j = 0; j < 2; ++j) acc[i][j] = (f32x4){0.f, 0.f, 0.f, 0.f};

  const int srow_l = lane >> 2;   // 0..15
  const int slot   = lane & 3;    // 0..3

  for (int k0 = 0; k0 < K; k0 += 32) {
    {
      const int row = wave * 16;            // wave-uniform LDS base row
      gl_lds16(A  + (size_t)(m0 + row + srow_l) * K + k0 + slot * 8, &As[row][0]);
      gl_lds16(Wt + (size_t)(n0 + row + srow_l) * K + k0 + slot * 8, &Bs[row][0]);
    }
    __syncthreads();
    short8 af[2], bf[2];
    #pragma unroll
    for (int i = 0; i < 2; ++i) {
      af[i] = *reinterpret_cast<const short8*>(&As[wm * 32 + i * 16 + l15][quad * 8]);
      bf[i] = *reinterpret_cast<const short8*>(&Bs[wn * 32 + i * 16 + l15][quad * 8]);
    }
    #pragma unroll
    for (int i = 0; i < 2; ++i)
      #pragma unroll
      for (int j = 0; j < 2; ++j)
        acc[i][j] = __builtin_amdgcn_mfma_f32_16x16x32_bf16(af[i], bf[j], acc[i][j], 0, 0, 0);
    __syncthreads();
  }

  #pragma unroll
  for (int j = 0; j < 2; ++j) {
    const int n = n0 + wn * 32 + j * 16 + l15;
    const float bv = lin(bias, n, f32);
    #pragma unroll
    for (int i = 0; i < 2; ++i) {
      #pragma unroll
      for (int r = 0; r < 4; ++r) {
        const int m = m0 + wm * 32 + i * 16 + quad * 4 + r;
        float v = acc[i][j][r];
        if constexpr (MODE == M_BIAS) {
          v += bv;
        } else if constexpr (MODE == M_BIAS_RELU) {
          v = fmaxf(v + bv, 0.f);
        } else if constexpr (MODE == M_ADD2_BIAS_LEAKY) {
          const size_t ix = (size_t)m * Nn + n;
          const float ad = b2f(((const ushort*)addend)[ix]) + b2f(addend2[ix]);
          v = ad + v + bv;
          v = (v >= 0.f) ? v : 0.5f * v;
        } else {
          float ad;
          if constexpr (sizeof(ADT) == 4) ad = ((const float*)addend)[(size_t)m * Nn + n];
          else                            ad = b2f(((const ushort*)addend)[(size_t)m * Nn + n]);
          v = ad + v + bv;
          if constexpr (MODE == M_ADD_BIAS_ELU)
            v = (v > 0.f) ? v : (__builtin_amdgcn_exp2f(v * LOG2E) - 1.f);
          else if constexpr (MODE == M_ADD_BIAS_LEAKY) v = (v >= 0.f) ? v : 0.5f * v;
        }
        if constexpr (sizeof(OT) == 4) ((float*)Cout)[(size_t)m * Nn + n] = v;
        else                           ((ushort*)Cout)[(size_t)m * Nn + n] = f2b(v);
      }
    }
  }
}

template<typename ADT, typename OT, int MODE>
static void launch_mgemm64(const void* A, const void* Wt, const void* bias, const void* add,
                           void* Cout, int M, int K, int Nn, const int* dtf, hipStream_t stream,
                           const void* add2 = nullptr)
{
  dim3 grid(Nn / 64, M / 64);
  mgemm64_kernel<ADT, OT, MODE><<<grid, dim3(256), 0, stream>>>(
      (const ushort*)A, (const ushort*)Wt, bias, (const ADT*)add, (const ushort*)add2,
      (OT*)Cout, M, K, Nn, dtf);
}

// ---------------- mgemm3: 64x64-tile hi/lo-split 3-MFMA GEMM ----------------
// global_load_lds staging for all 4 tiles (same geometry as mgemm64).
enum Epi3 { E3_RELU_PE = 0, E3_RELU_SPLIT = 1, E3_SPLIT = 2, E3_RELU_VT = 3 };

template<int EPI>
__global__ __launch_bounds__(256) void mgemm3_kernel(
    const ushort* __restrict__ Ah, const ushort* __restrict__ Al,
    const ushort* __restrict__ Bh, const ushort* __restrict__ Bl,
    const void* __restrict__ bias,
    ushort* __restrict__ Oh, ushort* __restrict__ Ol,
    int M, int K, int Nn, const int* __restrict__ dtf)
{
  const int f32 = *dtf;
  __shared__ __align__(16) ushort AsH[64][32];
  __shared__ __align__(16) ushort AsL[64][32];
  __shared__ __align__(16) ushort BsH[64][32];
  __shared__ __align__(16) ushort BsL[64][32];
  const int tid = threadIdx.x;
  const int m0 = blockIdx.y * 64, n0 = blockIdx.x * 64;
  const int wave = tid >> 6, lane = tid & 63;
  const int wm = wave & 1, wn = wave >> 1;
  const int quad = lane >> 4, l15 = lane & 15;

  f32x4 acc[2][2];
  #pragma unroll
  for (int i = 0; i < 2; ++i)
    #pragma unroll
    for (int j = 0; j < 2; ++j) acc[i][j] = (f32x4){0.f, 0.f, 0.f, 0.f};

  const int srow_l = lane >> 2;   // 0..15
  const int slot   = lane & 3;    // 0..3

  for (int k0 = 0; k0 < K; k0 += 32) {
    {
      const int row = wave * 16;            // wave-uniform LDS base row
      const size_t ga = (size_t)(m0 + row + srow_l) * K + k0 + slot * 8;
      const size_t gb = (size_t)(n0 + row + srow_l) * K + k0 + slot * 8;
      gl_lds16(Ah + ga, &AsH[row][0]);
      gl_lds16(Al + ga, &AsL[row][0]);
      gl_lds16(Bh + gb, &BsH[row][0]);
      gl_lds16(Bl + gb, &BsL[row][0]);
    }
    __syncthreads();
    short8 afh[2], afl[2], bfh[2], bfl[2];
    #pragma unroll
    for (int i = 0; i < 2; ++i) {
      afh[i] = *reinterpret_cast<const short8*>(&AsH[wm * 32 + i * 16 + l15][quad * 8]);
      afl[i] = *reinterpret_cast<const short8*>(&AsL[wm * 32 + i * 16 + l15][quad * 8]);
      bfh[i] = *reinterpret_cast<const short8*>(&BsH[wn * 32 + i * 16 + l15][quad * 8]);
      bfl[i] = *reinterpret_cast<const short8*>(&BsL[wn * 32 + i * 16 + l15][quad * 8]);
    }
    #pragma unroll
    for (int i = 0; i < 2; ++i)
      #pragma unroll
      for (int j = 0; j < 2; ++j) {
        acc[i][j] = __builtin_amdgcn_mfma_f32_16x16x32_bf16(afh[i], bfh[j], acc[i][j], 0, 0, 0);
        acc[i][j] = __builtin_amdgcn_mfma_f32_16x16x32_bf16(afh[i], bfl[j], acc[i][j], 0, 0, 0);
        acc[i][j] = __builtin_amdgcn_mfma_f32_16x16x32_bf16(afl[i], bfh[j], acc[i][j], 0, 0, 0);
      }
    __syncthreads();
  }

  #pragma unroll
  for (int j = 0; j < 2; ++j) {
    const int n = n0 + wn * 32 + j * 16 + l15;
    float bv = 0.f;
    if constexpr (EPI != E3_RELU_PE) bv = lin(bias, n, f32);
    #pragma unroll
    for (int i = 0; i < 2; ++i) {
      #pragma unroll
      for (int r = 0; r < 4; ++r) {
        const int m = m0 + wm * 32 + i * 16 + quad * 4 + r;
        float v = acc[i][j][r];
        if constexpr (EPI == E3_RELU_PE) {
          v = fmaxf(v, 0.f);
          const float freq = expf((float)(n & ~1) * (-0.017988946f)); // -ln(1e4)/512
          const float ang  = (float)(m & (CC - 1)) * freq;            // pos = c
          v += (n & 1) ? cosf(ang) : sinf(ang);
        } else if constexpr (EPI == E3_RELU_SPLIT || EPI == E3_RELU_VT) {
          v = fmaxf(v + bv, 0.f);
        } else {
          v = v + bv;
        }
        if constexpr (EPI == E3_RELU_VT) {
          // pre-transposed: vT[(lb*512 + n)][s] with lb = m>>9, s = m&511
          Oh[((size_t)((m >> 9) * 512 + n)) * 512 + (m & 511)] = f2b(v);
        } else {
          ushort hi, lo; split_bf(v, hi, lo);
          Oh[(size_t)m * Nn + n] = hi;
          Ol[(size_t)m * Nn + n] = lo;
        }
      }
    }
  }
}

template<int EPI>
static void launch_mgemm3(const void* Ahv, const void* Alv, const ushort* Bh,
                          const ushort* Bl, const void* bias, void* Oh, void* Ol,
                          int M, int K, int Nn, const int* dtf, hipStream_t stream)
{
  dim3 grid(Nn / 64, M / 64);
  mgemm3_kernel<EPI><<<grid, dim3(256), 0, stream>>>(
      (const ushort*)Ahv, (const ushort*)Alv, Bh, Bl, bias,
      (ushort*)Oh, (ushort*)Ol, M, K, Nn, dtf);
}

// ---------------- GAttn via MFMA: register scores + DPP top-k ---------------
// S-phase uses an explicit 2-stage prefetch pipeline (chunk c+1's K frags
// loaded into named regs before chunk c's MFMAs) so load latency overlaps
// MFMA regardless of regalloc heuristics.
__global__ __launch_bounds__(256, 2) void gattn_mfma(
    const ushort* __restrict__ qsh, const ushort* __restrict__ qsl,
    const ushort* __restrict__ ksh, const ushort* __restrict__ ksl,
    const ushort* __restrict__ vt, ushort* __restrict__ out)
{
  const int tid = threadIdx.x;
  const int wave = tid >> 6, lane = tid & 63;
  const int quad = lane >> 4, l15 = lane & 15;
  const int l0 = blockIdx.x * 16;
  const int h = blockIdx.y, bz = blockIdx.z;

  __shared__ __align__(16) ushort P[16][520];    // 16640 B (unnormalized bf16 weights)
  __shared__ float cand[16][40];                 // 2560 B (4 waves x sorted top-10)
  __shared__ float psum[16][4];                  // 256 B  (per-wave partial sums)

  // ---- Q fragments (hi/lo), kk-chunks 0,1 ----
  short8 ah[2], al[2];
  {
    const size_t qoff = ((size_t)bz * CC + l0 + l15) * DD + h * EE + quad * 8;
    ah[0] = *reinterpret_cast<const short8*>(qsh + qoff);
    ah[1] = *reinterpret_cast<const short8*>(qsh + qoff + 32);
    al[0] = *reinterpret_cast<const short8*>(qsl + qoff);
    al[1] = *reinterpret_cast<const short8*>(qsl + qoff + 32);
  }

  // ---- S phase into registers: sacc[c][r] = S[quad*4+r][c*64+wave*16+l15] --
  f32x4 sacc[8];
  {
    const size_t kbase = ((size_t)bz * CC + wave * 16 + l15) * DD + h * EE + quad * 8;
    short8 pbh0 = *reinterpret_cast<const short8*>(ksh + kbase);
    short8 pbl0 = *reinterpret_cast<const short8*>(ksl + kbase);
    short8 pbh1 = *reinterpret_cast<const short8*>(ksh + kbase + 32);
    short8 pbl1 = *reinterpret_cast<const short8*>(ksl + kbase + 32);
    #pragma unroll
    for (int c = 0; c < 8; ++c) {
      const short8 cbh0 = pbh0, cbl0 = pbl0, cbh1 = pbh1, cbl1 = pbl1;
      if (c < 7) {
        const size_t noff = kbase + (size_t)((c + 1) * 64) * DD;
        pbh0 = *reinterpret_cast<const short8*>(ksh + noff);
        pbl0 = *reinterpret_cast<const short8*>(ksl + noff);
        pbh1 = *reinterpret_cast<const short8*>(ksh + noff + 32);
        pbl1 = *reinterpret_cast<const short8*>(ksl + noff + 32);
      }
      f32x4 acc = (f32x4){0.f, 0.f, 0.f, 0.f};
      __builtin_amdgcn_s_setprio(1);
      acc = __builtin_amdgcn_mfma_f32_16x16x32_bf16(ah[0], cbh0, acc, 0, 0, 0);
      acc = __builtin_amdgcn_mfma_f32_16x16x32_bf16(ah[0], cbl0, acc, 0, 0, 0);
      acc = __builtin_amdgcn_mfma_f32_16x16x32_bf16(al[0], cbh0, acc, 0, 0, 0);
      acc = __builtin_amdgcn_mfma_f32_16x16x32_bf16(ah[1], cbh1, acc, 0, 0, 0);
      acc = __builtin_amdgcn_mfma_f32_16x16x32_bf16(ah[1], cbl1, acc, 0, 0, 0);
      acc = __builtin_amdgcn_mfma_f32_16x16x32_bf16(al[1], cbh1, acc, 0, 0, 0);
      __builtin_amdgcn_s_setprio(0);
      sacc[c] = acc;
    }
  }

  // ---- stage-1 top-k: each quad extracts its row's wave-local top-10 ----
  #pragma unroll
  for (int r = 0; r < 4; ++r) {
    float wk[8];
    #pragma unroll
    for (int c = 0; c < 8; ++c) wk[c] = sacc[c][r];
    float myg = 0.f;
    for (int it = 0; it < 10; ++it) {
      float lm = wk[0];
      #pragma unroll
      for (int c = 1; c < 8; ++c) lm = fmaxf(lm, wk[c]);
      const float gm = red16_max(lm);
      if (l15 == it) myg = gm;
      if (it < 9) {
        const unsigned long long msk = __ballot(lm == gm);
        const int sel = (__ffsll((unsigned long long)((msk >> (quad * 16)) & 0xFFFFull)) - 1)
                        + quad * 16;
        if (lane == sel) {
          #pragma unroll
          for (int c = 0; c < 8; ++c) { if (wk[c] == gm) { wk[c] = -FLT_MAX; break; } }
        }
      }
    }
    if (l15 < 10) cand[quad * 4 + r][wave * 10 + l15] = myg;
  }
  __syncthreads();

  // ---- merge 4 sorted lists of 10 -> global maxv + thr (10th) ----
  float mx, thr;
  {
    const int mr = lane & 15;
    float h0 = cand[mr][0], h1 = cand[mr][10], h2 = cand[mr][20], h3 = cand[mr][30];
    int i0 = 0, i1 = 0, i2 = 0, i3 = 0;
    float cur = 0.f;
    mx = 0.f;
    #pragma unroll
    for (int t = 0; t < 10; ++t) {
      cur = fmaxf(fmaxf(h0, h1), fmaxf(h2, h3));
      if (t == 0) mx = cur;
      if (t < 9) {
        const bool a0 = (cur == h0);
        const bool a1 = !a0 && (cur == h1);
        const bool a2 = !a0 && !a1 && (cur == h2);
        const int ni0 = i0 + (a0 ? 1 : 0);
        const int ni1 = i1 + (a1 ? 1 : 0);
        const int ni2 = i2 + (a2 ? 1 : 0);
        const int ni3 = i3 + ((a0 || a1 || a2) ? 0 : 1);
        const int off = a0 ? ni0 : (a1 ? 10 + ni1 : (a2 ? 20 + ni2 : 30 + ni3));
        const float nv = cand[mr][off];
        h0 = a0 ? nv : h0;
        h1 = a1 ? nv : h1;
        h2 = a2 ? nv : h2;
        h3 = (a0 || a1 || a2) ? h3 : nv;
        i0 = ni0; i1 = ni1; i2 = ni2; i3 = ni3;
      }
    }
    thr = cur;
  }
  // distribute row thr/max to the quad that owns the row
  float thrR[4], mxR[4];
  #pragma unroll
  for (int r = 0; r < 4; ++r) {
    thrR[r] = __shfl(thr, quad * 4 + r);
    mxR[r]  = __shfl(mx,  quad * 4 + r);
  }

  // ---- exp + partial sums + P write ----
  #pragma unroll
  for (int r = 0; r < 4; ++r) {
    const int Rr = quad * 4 + r;
    float s = 0.f;
    #pragma unroll
    for (int c = 0; c < 8; ++c) {
      const float sc = sacc[c][r];
      const float p = (sc >= thrR[r])
          ? __builtin_amdgcn_exp2f((sc - mxR[r]) * (0.125f * LOG2E)) : 0.f;
      P[Rr][c * 64 + wave * 16 + l15] = f2b(p);
      s += p;
    }
    s = red16_sum(s);
    if (l15 == 0) psum[Rr][wave] = s;
  }
  __syncthreads();

  // ---- PV phase: wave w owns e-cols w*16..w*16+15; vT loaded direct ----
  f32x4 pacc = (f32x4){0.f, 0.f, 0.f, 0.f};
  const size_t vbase = ((size_t)bz * 512 + h * EE + wave * 16 + l15) * 512 + quad * 8;
  #pragma unroll
  for (int c = 0; c < 4; ++c) {
    #pragma unroll
    for (int ks = 0; ks < 4; ++ks) {
      const int s0 = c * 128 + ks * 32;
      const short8 pa = *reinterpret_cast<const short8*>(&P[l15][s0 + quad * 8]);
      const short8 vb = *reinterpret_cast<const short8*>(vt + vbase + s0);
      __builtin_amdgcn_s_setprio(1);
      pacc = __builtin_amdgcn_mfma_f32_16x16x32_bf16(pa, vb, pacc, 0, 0, 0);
      __builtin_amdgcn_s_setprio(0);
    }
  }

  // ---- epilogue ----
  #pragma unroll
  for (int r = 0; r < 4; ++r) {
    const int Rr = quad * 4 + r;
    const float4 ps = *reinterpret_cast<const float4*>(&psum[Rr][0]);
    const float inv = 1.f / (ps.x + ps.y + ps.z + ps.w);
    out[((size_t)bz * CC + l0 + Rr) * DD + h * EE + wave * 16 + l15] = f2b(pacc[r] * inv);
  }
}

// ---------------- GAttn fallback (fp32 path only) -----------
template<typename OT>
__global__ __launch_bounds__(256) void gattn_fb(
    const float* __restrict__ q, const float* __restrict__ k,
    const float* __restrict__ v, OT* __restrict__ out)
{
  const int tid = threadIdx.x;
  const int wave = tid >> 6, lane = tid & 63;
  const int l0 = blockIdx.x * 4;
  const int h = blockIdx.y, bz = blockIdx.z;
  const int l = l0 + wave;
  const size_t base = ((size_t)bz * CC) * DD + h * EE;

  __shared__ __align__(16) float kt[64][68];
  __shared__ __align__(16) float qs[4][64];
  __shared__ __align__(16) float ww[4][512];

  qs[wave][lane] = q[((size_t)bz * CC + l) * DD + h * EE + lane];

  float sc[8];
  const int sl = tid >> 4;
  const int e4 = (tid & 15) * 4;
  for (int c8 = 0; c8 < 8; ++c8) {
    #pragma unroll
    for (int r = 0; r < 4; ++r) {
      const int s_local = sl + r * 16;
      const float4 kv = *reinterpret_cast<const float4*>(
          k + base + (size_t)(c8 * 64 + s_local) * DD + e4);
      *reinterpret_cast<float4*>(&kt[s_local][e4]) = kv;
    }
    __syncthreads();
    float a = 0.f;
    #pragma unroll
    for (int e = 0; e < 16; ++e) {
      const float4 qv = *reinterpret_cast<const float4*>(&qs[wave][e * 4]);
      const float4 kv = *reinterpret_cast<const float4*>(&kt[lane][e * 4]);
      a += qv.x * kv.x + qv.y * kv.y + qv.z * kv.z + qv.w * kv.w;
    }
    sc[c8] = a;
    __syncthreads();
  }

  float wk[8];
  #pragma unroll
  for (int j = 0; j < 8; ++j) wk[j] = sc[j];
  float maxv = 0.f, thr = 0.f;
  for (int it = 0; it < 10; ++it) {
    float lm = wk[0];
    #pragma unroll
    for (int j = 1; j < 8; ++j) lm = fmaxf(lm, wk[j]);
    float gm = lm;
    #pragma unroll
    for (int off = 32; off > 0; off >>= 1) gm = fmaxf(gm, __shfl_xor(gm, off));
    if (it == 0) maxv = gm;
    if (it == 9) { thr = gm; break; }
    const unsigned long long msk = __ballot(lm == gm);
    if (lane == __ffsll(msk) - 1) {
      #pragma unroll
      for (int j = 0; j < 8; ++j) { if (wk[j] == gm) { wk[j] = -FLT_MAX; break; } }
    }
  }

  float lsum = 0.f;
  #pragma unroll
  for (int j = 0; j < 8; ++j) {
    const float p = (sc[j] >= thr) ? expf((sc[j] - maxv) * 0.125f) : 0.f;
    ww[wave][j * 64 + lane] = p;
    lsum += p;
  }
  #pragma unroll
  for (int off = 32; off > 0; off >>= 1) lsum += __shfl_xor(lsum, off);
  const float inv = 1.f / lsum;
  __syncthreads();

  float acc = 0.f;
  const float* vp = v + base + lane;
  const float* wp = ww[wave];
  for (int s = 0; s < 512; s += 4) {
    const float4 w4 = *reinterpret_cast<const float4*>(&wp[s]);
    acc = fmaf(w4.x, vp[(size_t)(s + 0) * DD], acc);
    acc = fmaf(w4.y, vp[(size_t)(s + 1) * DD], acc);
    acc = fmaf(w4.z, vp[(size_t)(s + 2) * DD], acc);
    acc = fmaf(w4.w, vp[(size_t)(s + 3) * DD], acc);
  }
  const float res = acc * inv;
  const size_t oi = ((size_t)bz * CC + l) * DD + h * EE + lane;
  if constexpr (sizeof(OT) == 4) out[oi] = res;
  else                           out[oi] = f2b(res);
}

// ---------------- pwattn1 via MFMA: one row per wave ----------------
__global__ __launch_bounds__(256) void pwattn1_mfma(
    const ushort* __restrict__ query, const float* __restrict__ k1,
    const float* __restrict__ v1, ushort* __restrict__ V1)
{
  const int tid = threadIdx.x;
  const int wave = tid >> 6, lane = tid & 63;
  const int quad = lane >> 4, l15 = lane & 15;
  const int n = blockIdx.x * 4 + wave;

  __shared__ __align__(16) ushort Pl[4][16][40];   // stride 80B (16B-aligned)

  const ushort* qrow = query + (size_t)n * DFF;
  const float*  krow = k1 + (size_t)n * 512;
  const float*  vrow = v1 + (size_t)n * 512;
  ushort* orow = V1 + (size_t)n * DFF;

  const short8 zz = {0, 0, 0, 0, 0, 0, 0, 0};
  const f32x4 zacc = (f32x4){0.f, 0.f, 0.f, 0.f};

  // B-frags for scores: col s = nt*16+l15, k = e = quad*8+i (valid e<16)
  short8 bh[2], bl[2];
  #pragma unroll
  for (int nt = 0; nt < 2; ++nt) {
    short8 hh = zz, ll = zz;
    if (quad < 2) {
      const float* kp = krow + (nt * 16 + l15) * 16 + quad * 8;
      #pragma unroll
      for (int i = 0; i < 8; ++i) {
        ushort hi_, lo_; split_bf(kp[i], hi_, lo_);
        hh[i] = (short)hi_; ll[i] = (short)lo_;
      }
    }
    bh[nt] = hh; bl[nt] = ll;
  }
  // B-frag for PV: v[k=s=quad*8+i][n=e=l15]
  short8 vb;
  #pragma unroll
  for (int i = 0; i < 8; ++i) vb[i] = (short)f2b(vrow[(quad * 8 + i) * 16 + l15]);

  #pragma unroll
  for (int mt = 0; mt < 8; ++mt) {
    short8 qa = zz;
    if (quad < 2)
      qa = *reinterpret_cast<const short8*>(qrow + (mt * 16 + l15) * 16 + quad * 8);
    f32x4 acc[2];
    #pragma unroll
    for (int nt = 0; nt < 2; ++nt) {
      f32x4 t = __builtin_amdgcn_mfma_f32_16x16x32_bf16(qa, bl[nt], zacc, 0, 0, 0);
      acc[nt] = __builtin_amdgcn_mfma_f32_16x16x32_bf16(qa, bh[nt], t, 0, 0, 0);
    }
    // softmax over 32 cols (2 nt x 16 lanes); rows quad*4+r
    float inv[4];
    #pragma unroll
    for (int r = 0; r < 4; ++r) {
      float m = red16_max(fmaxf(acc[0][r], acc[1][r]));
      const float p0 = __builtin_amdgcn_exp2f((acc[0][r] - m) * (0.25f * LOG2E));
      const float p1 = __builtin_amdgcn_exp2f((acc[1][r] - m) * (0.25f * LOG2E));
      acc[0][r] = p0; acc[1][r] = p1;
      const float s = red16_sum(p0 + p1);
      inv[r] = 1.f / s;
    }
    #pragma unroll
    for (int nt = 0; nt < 2; ++nt)
      #pragma unroll
      for (int r = 0; r < 4; ++r)
        Pl[wave][quad * 4 + r][nt * 16 + l15] = f2b(acc[nt][r]);
    const short8 pa = *reinterpret_cast<const short8*>(&Pl[wave][l15][quad * 8]);
    const f32x4 pv = __builtin_amdgcn_mfma_f32_16x16x32_bf16(pa, vb, zacc, 0, 0, 0);
    #pragma unroll
    for (int r = 0; r < 4; ++r)
      orow[(mt * 16 + quad * 4 + r) * 16 + l15] = f2b(pv[r] * inv[r]);
  }
}

// ---------------- pwattn2 via MFMA: one row per wave ----------------
__global__ __launch_bounds__(256) void pwattn2_mfma(
    const float* __restrict__ query2, const ushort* __restrict__ k2,
    const ushort* __restrict__ v2, ushort* __restrict__ V2)
{
  const int tid = threadIdx.x;
  const int wave = tid >> 6, lane = tid & 63;
  const int quad = lane >> 4, l15 = lane & 15;
  const int n = blockIdx.x * 4 + wave;

  __shared__ __align__(16) ushort Pl[4][16][136];  // stride 272B (16B-aligned)

  const float*  qrow = query2 + (size_t)n * 512;
  const ushort* krow = k2 + (size_t)n * DFF;
  const ushort* vrow = v2 + (size_t)n * DFF;
  ushort* orow = V2 + (size_t)n * 512;

  const short8 zz = {0, 0, 0, 0, 0, 0, 0, 0};
  const f32x4 zacc = (f32x4){0.f, 0.f, 0.f, 0.f};

  // B-frags for scores: col s = nt*16+l15 (8 nt), k = e = quad*8+i (<16)
  short8 kb[8];
  #pragma unroll
  for (int nt = 0; nt < 8; ++nt)
    kb[nt] = (quad < 2)
        ? *reinterpret_cast<const short8*>(krow + (nt * 16 + l15) * 16 + quad * 8)
        : zz;

  // B-frags for PV: v[k=s=kt*32+quad*8+i][n=e=l15]
  short8 vb[4];
  #pragma unroll
  for (int kt = 0; kt < 4; ++kt)
    #pragma unroll
    for (int i = 0; i < 8; ++i)
      vb[kt][i] = (short)vrow[(kt * 32 + quad * 8 + i) * 16 + l15];

  #pragma unroll
  for (int mt = 0; mt < 2; ++mt) {
    // A hi/lo: q[m=mt*16+l15][k=quad*8+i (<16)]
    short8 ahh = zz, all_ = zz;
    if (quad < 2) {
      const float* qp = qrow + (mt * 16 + l15) * 16 + quad * 8;
      #pragma unroll
      for (int i = 0; i < 8; ++i) {
        ushort hi_, lo_; split_bf(qp[i], hi_, lo_);
        ahh[i] = (short)hi_; all_[i] = (short)lo_;
      }
    }
    f32x4 acc[8];
    #pragma unroll
    for (int nt = 0; nt < 8; ++nt) {
      f32x4 t = __builtin_amdgcn_mfma_f32_16x16x32_bf16(all_, kb[nt], zacc, 0, 0, 0);
      acc[nt] = __builtin_amdgcn_mfma_f32_16x16x32_bf16(ahh, kb[nt], t, 0, 0, 0);
    }
    // softmax over 128 cols (8 nt x 16 lanes); rows quad*4+r
    float inv[4];
    #pragma unroll
    for (int r = 0; r < 4; ++r) {
      float m = acc[0][r];
      #pragma unroll
      for (int nt = 1; nt < 8; ++nt) m = fmaxf(m, acc[nt][r]);
      m = red16_max(m);
      float s = 0.f;
      #pragma unroll
      for (int nt = 0; nt < 8; ++nt) {
        const float p = __builtin_amdgcn_exp2f((acc[nt][r] - m) * (0.25f * LOG2E));
        acc[nt][r] = p; s += p;
      }
      s = red16_sum(s);
      inv[r] = 1.f / s;
    }
    #pragma unroll
    for (int nt = 0; nt < 8; ++nt)
      #pragma unroll
      for (int r = 0; r < 4; ++r)
        Pl[wave][quad * 4 + r][nt * 16 + l15] = f2b(acc[nt][r]);
    f32x4 pv = zacc;
    #pragma unroll
    for (int kt = 0; kt < 4; ++kt) {
      const short8 pa = *reinterpret_cast<const short8*>(&Pl[wave][l15][kt * 32 + quad * 8]);
      pv = __builtin_amdgcn_mfma_f32_16x16x32_bf16(pa, vb[kt], pv, 0, 0, 0);
    }
    #pragma unroll
    for (int r = 0; r < 4; ++r)
      orow[(mt * 16 + quad * 4 + r) * 16 + l15] = f2b(pv[r] * inv[r]);
  }
}

// ---------------- pwattn1 (fallback) ----------------
__global__ __launch_bounds__(128) void pwattn1_kernel(
    const ushort* __restrict__ query, const float* __restrict__ k1,
    const float* __restrict__ v1, ushort* __restrict__ V1)
{
  const int n = blockIdx.x, tid = threadIdx.x;
  __shared__ float ks[512], vs[512];
  __shared__ float Am[128][33];
  for (int i = tid; i < 512; i += 128) { ks[i] = k1[(size_t)n * 512 + i]; vs[i] = v1[(size_t)n * 512 + i]; }
  __syncthreads();
  {
    const int l = tid;
    float qv[16];
    const ushort* qp = query + (size_t)n * DFF + l * 16;
    #pragma unroll
    for (int e = 0; e < 16; ++e) qv[e] = b2f(qp[e]);
    float scl[32], mx = -FLT_MAX;
    #pragma unroll
    for (int s = 0; s < 32; ++s) {
      float a = 0.f;
      #pragma unroll
      for (int e = 0; e < 16; ++e) a += qv[e] * ks[s * 16 + e];
      scl[s] = a; mx = fmaxf(mx, a);
    }
    float sum = 0.f;
    #pragma unroll
    for (int s = 0; s < 32; ++s) { const float p = expf((scl[s] - mx) * 0.25f); scl[s] = p; sum += p; }
    const float invs = 1.f / sum;
    #pragma unroll
    for (int s = 0; s < 32; ++s) Am[l][s] = scl[s] * invs;
  }
  __syncthreads();
  #pragma unroll
  for (int r = 0; r < 16; ++r) {
    const int idx = tid + 128 * r;
    const int l = idx >> 4, e = idx & 15;
    float a = 0.f;
    #pragma unroll
    for (int s = 0; s < 32; ++s) a += Am[l][s] * vs[s * 16 + e];
    V1[(size_t)n * DFF + idx] = f2b(a);
  }
}

// ---------------- LayerNorm over 2048, in-place bf16 ----------------
__global__ __launch_bounds__(256) void ln_kernel(
    ushort* __restrict__ h, const void* __restrict__ g, const void* __restrict__ bt,
    const int* __restrict__ dtf)
{
  const int f32 = *dtf;
  const int n = blockIdx.x, tid = threadIdx.x;
  ushort* hp = h + (size_t)n * DFF;
  float x[8]; float s = 0.f, s2 = 0.f;
  #pragma unroll
  for (int i = 0; i < 8; ++i) {
    const float xv = b2f(hp[tid + 256 * i]);
    x[i] = xv; s += xv; s2 += xv * xv;
  }
  __shared__ float rs[256], rq[256];
  rs[tid] = s; rq[tid] = s2;
  __syncthreads();
  for (int off = 128; off > 0; off >>= 1) {
    if (tid < off) { rs[tid] += rs[tid + off]; rq[tid] += rq[tid + off]; }
    __syncthreads();
  }
  const float mu  = rs[0] * (1.f / DFF);
  const float var = rq[0] * (1.f / DFF) - mu * mu;
  const float inv = rsqrtf(var + 1e-5f);
  #pragma unroll
  for (int i = 0; i < 8; ++i) {
    const int d = tid + 256 * i;
    hp[d] = f2b((x[i] - mu) * inv * lin(g, d, f32) + lin(bt, d, f32));
  }
}

// ---------------- pwattn2 (fallback), templated output -----------
template<typename OT>
__global__ __launch_bounds__(128) void pwattn2_kernel(
    const float* __restrict__ query2, const ushort* __restrict__ k2,
    const ushort* __restrict__ v2, OT* __restrict__ V2)
{
  const int n = blockIdx.x, tid = threadIdx.x;
  __shared__ float ks[2048], vs[2048];
  __shared__ float Am[32][129];
  for (int i = tid; i < 2048; i += 128) {
    ks[i] = b2f(k2[(size_t)n * DFF + i]);
    vs[i] = b2f(v2[(size_t)n * DFF + i]);
  }
  __syncthreads();
  if (tid < 32) {
    const int l = tid;
    float qv[16];
    #pragma unroll
    for (int e = 0; e < 16; ++e) qv[e] = query2[(size_t)n * 512 + l * 16 + e];
    float mx = -FLT_MAX;
    for (int s = 0; s < 128; ++s) {
      float a = 0.f;
      #pragma unroll
      for (int e = 0; e < 16; ++e) a += qv[e] * ks[s * 16 + e];
      Am[l][s] = a; mx = fmaxf(mx, a);
    }
    float sum = 0.f;
    for (int s = 0; s < 128; ++s) { const float p = expf((Am[l][s] - mx) * 0.25f); Am[l][s] = p; sum += p; }
    const float invs = 1.f / sum;
    for (int s = 0; s < 128; ++s) Am[l][s] *= invs;
  }
  __syncthreads();
  #pragma unroll
  for (int r = 0; r < 4; ++r) {
    const int idx = tid + 128 * r;
    const int l = idx >> 4, e = idx & 15;
    float a = 0.f;
    for (int s = 0; s < 128; ++s) a += Am[l][s] * vs[s * 16 + e];
    if constexpr (sizeof(OT) == 4) V2[(size_t)n * 512 + idx] = a;
    else                           V2[(size_t)n * 512 + idx] = f2b(a);
  }
}

// ---------------- final: dec = y@fc_w + fc_b; out = dec*std+mean -----------
// 8 rows/block (LDS-staged), thread owns 4 CONTIGUOUS output cols => one
// float4/ushort4 fc_w load per k-iteration (4x fewer load instructions).
__global__ __launch_bounds__(256) void final_kernel(
    const float* __restrict__ y, const void* __restrict__ fc_w,
    const void* __restrict__ fc_b, const float* __restrict__ meanb,
    const float* __restrict__ stdb, void* __restrict__ out, int row_base,
    const int* __restrict__ dtf)
{
  const int f32 = *dtf;
  const int tid = threadIdx.x;
  const int rloc = tid >> 5;           // 0..7 (row within block)
  const int t32 = tid & 31;            // 0..31
  __shared__ __align__(16) float yr[8][512];
  const int blk_row0 = blockIdx.x * 8;
  #pragma unroll
  for (int i = 0; i < 4; ++i) {
    const int idx = tid + i * 256;     // 1024 float4 slots total
    const int rr = idx >> 7, dd = (idx & 127) * 4;
    *reinterpret_cast<float4*>(&yr[rr][dd]) =
        *reinterpret_cast<const float4*>(y + (size_t)(blk_row0 + rr) * 512 + dd);
  }
  __syncthreads();
  if (t32 < 24) {
    const int n0 = t32 * 4;
    float a0 = 0.f, a1 = 0.f, a2 = 0.f, a3 = 0.f;
    if (f32) {
      const float* W = (const float*)fc_w + n0;
      for (int d = 0; d < 512; ++d) {
        const float4 w4 = *reinterpret_cast<const float4*>(W + (size_t)d * PRED);
        const float yv = yr[rloc][d];
        a0 = fmaf(yv, w4.x, a0); a1 = fmaf(yv, w4.y, a1);
        a2 = fmaf(yv, w4.z, a2); a3 = fmaf(yv, w4.w, a3);
      }
    } else {
      const ushort* W = (const ushort*)fc_w + n0;
      for (int d = 0; d < 512; ++d) {
        const ushort4 w4 = *reinterpret_cast<const ushort4*>(W + (size_t)d * PRED);
        const float yv = yr[rloc][d];
        a0 = fmaf(yv, b2f(w4.x), a0); a1 = fmaf(yv, b2f(w4.y), a1);
        a2 = fmaf(yv, b2f(w4.z), a2); a3 = fmaf(yv, b2f(w4.w), a3);
      }
    }
    const int row = row_base + blk_row0 + rloc;
    const int b = row >> 9, c = row & 511;
    const float sd = stdb[row], mu = meanb[row];
    const float av[4] = {a0, a1, a2, a3};
    #pragma unroll
    for (int j = 0; j < 4; ++j) {
      const float r = (av[j] + lin(fc_b, n0 + j, f32)) * sd + mu;
      const size_t oi = ((size_t)b * PRED + n0 + j) * CC + c;
      if (f32) ((float*)out)[oi] = r;
      else     ((ushort*)out)[oi] = f2b(r);
    }
  }
}

// ---------------------------------------------------------------------------
extern "C" void kernel_launch(void* const* d_in, const int* in_sizes, int n_in,
                              void* d_out, int out_size, void* d_ws, size_t ws_size,
                              hipStream_t stream)
{
  (void)in_sizes; (void)n_in; (void)out_size;
  const void* x_enc   = d_in[0];
  const void* embed_w = d_in[4];
  const void* q_w = d_in[5],  * q_b = d_in[6];
  const void* k_w = d_in[7],  * k_b = d_in[8];
  const void* v_w = d_in[9],  * v_b = d_in[10];
  const void* o_w = d_in[11], * o_b = d_in[12];
  const void* enc_w = d_in[13], * enc_b = d_in[14];
  const void* f1q_w = d_in[15], * f1q_b = d_in[16];
  const void* f1k_w = d_in[17], * f1k_b = d_in[18];
  const void* f1v_w = d_in[19], * f1v_b = d_in[20];
  const void* f1o_w = d_in[21], * f1o_b = d_in[22];
  const void* f2q_w = d_in[23], * f2q_b = d_in[24];
  const void* f2k_w = d_in[25], * f2k_b = d_in[26];
  const void* f2v_w = d_in[27], * f2v_b = d_in[28];
  const void* f2o_w = d_in[29], * f2o_b = d_in[30];
  const void* ln_g  = d_in[31], * ln_b  = d_in[32];
  const void* fc_w  = d_in[33], * fc_b  = d_in[34];

  const size_t HDR = 131072 + 1024;
  const size_t E_F1Q = 512ull * 2048, E_F1O = 2048ull * 2048, E_F2Q = 2048ull * 512;
  const size_t E_F2K = 2048ull * 2048, E_F2V = 2048ull * 2048, E_F2O = 512ull * 512;
  const size_t E_SQ  = 512ull * 512;   // o_w, enc_w, f1k_w, f1v_w each
  // + 8 split arrays (embed/q/k/v hi+lo)
  const size_t WT_EL = E_F1Q + E_F1O + E_F2Q + E_F2K + E_F2V + E_F2O + 4 * E_SQ + 8 * E_SQ;
  const size_t WT_BYTES = WT_EL * 2;   // ~34.5 MB
  const size_t PB_MFMA = 4ull * 512 * 512 * 4 + 3ull * 512 * DFF * 2; // 10.0MB
  const size_t PB_FB   = 5ull * 512 * 512 * 4 + 3ull * 512 * DFF * 2; // 11.0MB

  const int use_mfma = (HDR + WT_BYTES + PB_MFMA <= ws_size) ? 1 : 0;
  const size_t PER_BATCH = use_mfma ? PB_MFMA : PB_FB;
  const size_t FIXED = HDR + (use_mfma ? WT_BYTES : 0);
  int BPC = 1;
  for (int c = 8; c >= 1; c >>= 1) {
    if (FIXED + (size_t)c * PER_BATCH <= ws_size) { BPC = c; break; }
  }
  const int R = BPC * 512;

  char* ws = (char*)d_ws;
  float* meanb = (float*)ws;
  float* stdb  = (float*)(ws + 65536);
  int*   dtf   = (int*)(ws + 131072);
  ushort* wt_base = (ushort*)(ws + HDR);
  ushort* wt_f1q = wt_base;
  ushort* wt_f1o = wt_f1q + E_F1Q;
  ushort* wt_f2q = wt_f1o + E_F1O;
  ushort* wt_f2k = wt_f2q + E_F2Q;
  ushort* wt_f2v = wt_f2k + E_F2K;
  ushort* wt_f2o = wt_f2v + E_F2V;
  ushort* wt_o   = wt_f2o + E_F2O;
  ushort* wt_enc = wt_o   + E_SQ;
  ushort* wt_f1k = wt_enc + E_SQ;
  ushort* wt_f1v = wt_f1k + E_SQ;
  ushort* wt_embh = wt_f1v + E_SQ;
  ushort* wt_embl = wt_embh + E_SQ;
  ushort* wt_qh   = wt_embl + E_SQ;
  ushort* wt_ql   = wt_qh   + E_SQ;
  ushort* wt_kh   = wt_ql   + E_SQ;
  ushort* wt_kl   = wt_kh   + E_SQ;
  ushort* wt_vh   = wt_kl   + E_SQ;
  ushort* wt_vl   = wt_vh   + E_SQ;

  char* arena = ws + FIXED;
  const size_t FSL = (size_t)R * 512 * 4;
  const size_t GSL = (size_t)R * DFF * 2;
  void* A_ = arena;
  void* B_ = arena + FSL;
  void* C_ = arena + 2 * FSL;
  void* D_ = arena + 3 * FSL;
  void* E_ = arena + 4 * FSL;                     // fallback path only
  char* gb = arena + (size_t)(use_mfma ? 4 : 5) * FSL;
  void* G1 = gb;
  void* G2 = gb + GSL;
  void* G3 = gb + 2 * GSL;

  // mfma-path split buffers
  ushort* xTh  = (ushort*)G1; ushort* xTl  = xTh  + (size_t)R * 512; // in G1 (dead before f1q)
  ushort* embh = (ushort*)G2; ushort* embl = embh + (size_t)R * 512; // in G2 (dead before pwattn1)
  ushort* qsh  = (ushort*)C_; ushort* qsl  = qsh  + (size_t)R * 512;
  ushort* ksh  = (ushort*)D_; ushort* ksl  = ksh  + (size_t)R * 512;
  ushort* vt   = (ushort*)B_;                                        // vT, dead before f1v

  detect_dtype<<<1, 256, 0, stream>>>((const ushort*)x_enc, dtf);
  // two-phase instance-norm stats; partials live in the (still idle) arena
  instnorm_partial<<<dim3(2, NB, 8), 256, 0, stream>>>(
      x_enc, (float*)A_, (float*)B_, dtf);
  instnorm_reduce<<<dim3(2, NB), 256, 0, stream>>>(
      (const float*)A_, (const float*)B_, meanb, stdb);

  if (use_mfma) {   // one-time weight convert+transpose (KxN -> bf16 NxK)
    transpose_w<<<dim3(DFF / 32, 512 / 32), 256, 0, stream>>>(f1q_w, wt_f1q, 512, DFF, dtf);
    transpose_w<<<dim3(DFF / 32, DFF / 32), 256, 0, stream>>>(f1o_w, wt_f1o, DFF, DFF, dtf);
    transpose_w<<<dim3(512 / 32, DFF / 32), 256, 0, stream>>>(f2q_w, wt_f2q, DFF, 512, dtf);
    transpose_w<<<dim3(DFF / 32, DFF / 32), 256, 0, stream>>>(f2k_w, wt_f2k, DFF, DFF, dtf);
    transpose_w<<<dim3(DFF / 32, DFF / 32), 256, 0, stream>>>(f2v_w, wt_f2v, DFF, DFF, dtf);
    transpose_w<<<dim3(512 / 32, 512 / 32), 256, 0, stream>>>(f2o_w, wt_f2o, 512, 512, dtf);
    transpose_w<<<dim3(512 / 32, 512 / 32), 256, 0, stream>>>(o_w,   wt_o,   512, 512, dtf);
    transpose_w<<<dim3(512 / 32, 512 / 32), 256, 0, stream>>>(enc_w, wt_enc, 512, 512, dtf);
    transpose_w<<<dim3(512 / 32, 512 / 32), 256, 0, stream>>>(f1k_w, wt_f1k, 512, 512, dtf);
    transpose_w<<<dim3(512 / 32, 512 / 32), 256, 0, stream>>>(f1v_w, wt_f1v, 512, 512, dtf);
    transpose_w_split<<<dim3(512 / 32, 512 / 32), 256, 0, stream>>>(embed_w, wt_embh, wt_embl, 512, 512, dtf);
    transpose_w_split<<<dim3(512 / 32, 512 / 32), 256, 0, stream>>>(q_w, wt_qh, wt_ql, 512, 512, dtf);
    transpose_w_split<<<dim3(512 / 32, 512 / 32), 256, 0, stream>>>(k_w, wt_kh, wt_kl, 512, 512, dtf);
    transpose_w_split<<<dim3(512 / 32, 512 / 32), 256, 0, stream>>>(v_w, wt_vh, wt_vl, 512, 512, dtf);
  }

  for (int bc = 0; bc < NB / BPC; ++bc) {
    const int b0 = bc * BPC;
    if (use_mfma) {
      // --- stage 1: split-MFMA GEMMs ---
      norm_transpose_split<<<dim3(16, 16, BPC), 256, 0, stream>>>(
          x_enc, meanb, stdb, xTh, xTl, b0, dtf);
      launch_mgemm3<E3_RELU_PE>(xTh, xTl, wt_embh, wt_embl, nullptr,
                                embh, embl, R, 512, 512, dtf, stream);         // emb hi/lo
      launch_mgemm3<E3_RELU_SPLIT>(embh, embl, wt_qh, wt_ql, q_b,
                                   qsh, qsl, R, 512, 512, dtf, stream);        // q hi/lo
      launch_mgemm3<E3_SPLIT>(embh, embl, wt_kh, wt_kl, k_b,
                              ksh, ksl, R, 512, 512, dtf, stream);             // k hi/lo
      launch_mgemm3<E3_RELU_VT>(embh, embl, wt_vh, wt_vl, v_b,
                                vt, nullptr, R, 512, 512, dtf, stream);        // vT bf16
      gattn_mfma<<<dim3(CC / 16, HH, BPC), 256, 0, stream>>>(
          qsh, qsl, ksh, ksl, vt, (ushort*)A_);                                // attn bf16
      launch_mgemm64<ushort, ushort, M_ADD2_BIAS_LEAKY>(
          A_, wt_o, o_b, embh, C_, R, 512, 512, dtf, stream, embl);            // y bf16
      launch_mgemm64<float, ushort, M_BIAS>(C_, wt_enc, enc_b, nullptr, D_, R, 512, 512, dtf, stream);  // X1 bf16
      // --- stage 2: pwattn1 + LN ---
      launch_mgemm<float, ushort, M_BIAS_RELU>(D_, wt_f1q, f1q_b, nullptr, G1, R, 512, DFF, dtf, stream); // query1
      launch_mgemm64<float, float, M_BIAS     >(D_, wt_f1k, f1k_b, nullptr, A_, R, 512, 512, dtf, stream); // k1 f32
      launch_mgemm64<float, float, M_BIAS_RELU>(D_, wt_f1v, f1v_b, nullptr, B_, R, 512, 512, dtf, stream); // v1 f32
      pwattn1_mfma<<<R / 4, 256, 0, stream>>>(
          (const ushort*)G1, (const float*)A_, (const float*)B_, (ushort*)G2);
      launch_mgemm<ushort, ushort, M_ADD_BIAS_ELU>(G2, wt_f1o, f1o_b, G1, G1, R, DFF, DFF, dtf, stream);  // h
      ln_kernel<<<R, 256, 0, stream>>>((ushort*)G1, ln_g, ln_b, dtf);
      // --- stage 3: pwattn2 + out ---
      launch_mgemm64<float, float, M_BIAS_RELU>(G1, wt_f2q, f2q_b, nullptr, A_, R, DFF, 512, dtf, stream); // query2
      launch_mgemm<float, ushort, M_BIAS     >(G1, wt_f2k, f2k_b, nullptr, G2, R, DFF, DFF, dtf, stream); // k2
      launch_mgemm<float, ushort, M_BIAS_RELU>(G1, wt_f2v, f2v_b, nullptr, G3, R, DFF, DFF, dtf, stream); // v2
      pwattn2_mfma<<<R / 4, 256, 0, stream>>>(
          (const float*)A_, (const ushort*)G2, (const ushort*)G3, (ushort*)B_);
      launch_mgemm64<float, float, M_ADD_BIAS>(B_, wt_f2o, f2o_b, A_, C_, R, 512, 512, dtf, stream);      // y2
    } else {
      norm_transpose<<<dim3(16, 16, BPC), 256, 0, stream>>>(x_enc, meanb, stdb, (float*)A_, b0, dtf);
      launch_gemm<float, float, float, M_RELU_PE >(A_, embed_w, nullptr, nullptr, B_, R, 512, 512, dtf, stream);
      launch_gemm<float, float, float, M_BIAS_RELU>(B_, q_w, q_b, nullptr, C_, R, 512, 512, dtf, stream);
      launch_gemm<float, float, float, M_BIAS     >(B_, k_w, k_b, nullptr, D_, R, 512, 512, dtf, stream);
      launch_gemm<float, float, float, M_BIAS_RELU>(B_, v_w, v_b, nullptr, E_, R, 512, 512, dtf, stream);
      gattn_fb<float><<<dim3(CC / 4, HH, BPC), 256, 0, stream>>>(
          (float*)C_, (float*)D_, (float*)E_, (float*)A_);
      launch_gemm<float, float, float, M_ADD_BIAS_LEAKY>(A_, o_w, o_b, B_, C_, R, 512, 512, dtf, stream);
      launch_gemm<float, float, float, M_BIAS>(C_, enc_w, enc_b, nullptr, D_, R, 512, 512, dtf, stream);
      launch_gemm<float, float, ushort, M_BIAS_RELU>(D_, f1q_w, f1q_b, nullptr, G1, R, 512, DFF, dtf, stream);
      launch_gemm<float, float, float,  M_BIAS     >(D_, f1k_w, f1k_b, nullptr, A_, R, 512, 512, dtf, stream);
      launch_gemm<float, float, float,  M_BIAS_RELU>(D_, f1v_w, f1v_b, nullptr, B_, R, 512, 512, dtf, stream);
      pwattn1_kernel<<<R, 128, 0, stream>>>((const ushort*)G1, (const float*)A_, (const float*)B_, (ushort*)G2);
      launch_gemm<ushort, ushort, ushort, M_ADD_BIAS_ELU>(G2, f1o_w, f1o_b, G1, G1, R, DFF, DFF, dtf, stream);
      ln_kernel<<<R, 256, 0, stream>>>((ushort*)G1, ln_g, ln_b, dtf);
      launch_gemm<ushort, float, float,  M_BIAS_RELU>(G1, f2q_w, f2q_b, nullptr, A_, R, DFF, 512, dtf, stream);
      launch_gemm<ushort, float, ushort, M_BIAS     >(G1, f2k_w, f2k_b, nullptr, G2, R, DFF, DFF, dtf, stream);
      launch_gemm<ushort, float, ushort, M_BIAS_RELU>(G1, f2v_w, f2v_b, nullptr, G3, R, DFF, DFF, dtf, stream);
      pwattn2_kernel<float><<<R, 128, 0, stream>>>((const float*)A_, (const ushort*)G2, (const ushort*)G3, (float*)B_);
      launch_gemm<float, float, float, M_ADD_BIAS>(B_, f2o_w, f2o_b, A_, C_, R, 512, 512, dtf, stream);
    }
    final_kernel<<<R / 8, 256, 0, stream>>>((const float*)C_, fc_w, fc_b, meanb, stdb, d_out, b0 * 512, dtf);
  }
}

// Round 11
// 2130.065 us; speedup vs baseline: 1.3484x; 1.0424x over previous
//
#include <hip/hip_runtime.h>
#include <float.h>
#include <math.h>
#include <stdint.h>

// ---------------------------------------------------------------------------
// Model_33062658245168: Informer-style time-series model. fp32 in/out
// (runtime-detected; bf16 fallback kept). B=32 S=512 C=512 D=512 DF=2048 H=8
// E=64 P=16 PRED=96 K(topk)=10, N=16384.
//
// Round 22: concurrency via launch fusion. The DFF-wide 128^2 mgemms run at
// 256 blocks = 1 block/CU (1 wave/SIMD, no TLP to hide barrier drain; m114:
// the m97 structure needs ~3 blocks/CU overlap). Fuse same-input GEMM groups
// into one launch with blockIdx.z selecting {weights,bias,out,epilogue}:
//  - q/k/v mgemm3 triple (reads embh/embl)   -> 768-block launch
//  - f1k/f1v mgemm64 pair (reads D_)         -> 512-block launch
//  - f2k/f2v 128^2 mgemm pair (reads G1)     -> 512-block launch (2/CU)
// Inner loops byte-identical to r20/r21-verified bodies; epilogue switch is
// wave-uniform runtime. gattn/pwattn/final byte-frozen at r21 (2220us).
// A/B: gattn holds 73-76us.
// ---------------------------------------------------------------------------

#define NB   32
#define SS   512
#define CC   512
#define DD   512
#define DFF  2048
#define HH   8
#define EE   64
#define PRED 96

typedef __attribute__((ext_vector_type(8))) short short8;
typedef __attribute__((ext_vector_type(4))) float f32x4;

#define LOG2E 1.4426950408889634f

__device__ __forceinline__ float b2f(ushort u) {
  union { float f; uint32_t i; } c; c.i = ((uint32_t)u) << 16; return c.f;
}
__device__ __forceinline__ ushort f2b(float f) {
  union { float f; uint32_t i; } c; c.f = f;
  uint32_t x = c.i;
  return (ushort)((x + 0x7fffu + ((x >> 16) & 1u)) >> 16);   // RNE
}
__device__ __forceinline__ float lin(const void* p, size_t i, int f32) {
  return f32 ? ((const float*)p)[i] : b2f(((const ushort*)p)[i]);
}
__device__ __forceinline__ void split_bf(float x, ushort& hi, ushort& lo) {
  hi = f2b(x);
  lo = f2b(x - b2f(hi));
}
// async global->LDS, 16B per lane; dst is wave-uniform base (+lane*16 by HW)
__device__ __forceinline__ void gl_lds16(const void* g, void* l) {
  __builtin_amdgcn_global_load_lds(
      (const __attribute__((address_space(1))) void*)g,
      (__attribute__((address_space(3))) void*)l, 16, 0, 0);
}

// ---- DPP 16-lane all-reduce (VALU only) ----
template<int CTRL>
__device__ __forceinline__ float dppmov(float x) {
  union { float f; int i; } a, b;
  a.f = x;
  b.i = __builtin_amdgcn_update_dpp(a.i, a.i, CTRL, 0xF, 0xF, false);
  return b.f;
}
__device__ __forceinline__ float red16_max(float x) {
  x = fmaxf(x, dppmov<0xB1>(x));    // quad_perm xor1
  x = fmaxf(x, dppmov<0x4E>(x));    // quad_perm xor2
  x = fmaxf(x, dppmov<0x141>(x));   // row_half_mirror
  x = fmaxf(x, dppmov<0x140>(x));   // row_mirror
  return x;
}
__device__ __forceinline__ float red16_sum(float x) {
  x += dppmov<0xB1>(x);
  x += dppmov<0x4E>(x);
  x += dppmov<0x141>(x);
  x += dppmov<0x140>(x);
  return x;
}

// ---------------- dtype detection (1 = fp32 inputs) ----------------
__global__ __launch_bounds__(256) void detect_dtype(
    const ushort* __restrict__ x, int* __restrict__ flag)
{
  __shared__ float red[256];
  const int t = threadIdx.x;
  float v = fabsf(b2f(x[2 * t]));
  if (!(v < 1e30f)) v = 1e30f;
  red[t] = v;
  __syncthreads();
  for (int off = 128; off > 0; off >>= 1) {
    if (t < off) red[t] = fmaxf(red[t], red[t + off]);
    __syncthreads();
  }
  if (t == 0) flag[0] = (red[0] > 1e6f) ? 1 : 0;
}

// ---------------- instance norm stats, two-phase ----------------
__global__ __launch_bounds__(256) void instnorm_partial(
    const void* __restrict__ x, float* __restrict__ ps, float* __restrict__ pq,
    const int* __restrict__ dtf)
{
  const int f32 = *dtf;
  const int c = blockIdx.x * 256 + threadIdx.x;
  const int b = blockIdx.y;
  const int t0 = blockIdx.z * 64;
  float s = 0.f, s2 = 0.f;
  for (int t = t0; t < t0 + 64; ++t) {
    const float xv = lin(x, ((size_t)(b * SS) + t) * CC + c, f32);
    s += xv; s2 += xv * xv;
  }
  const int pidx = (b * 8 + blockIdx.z) * CC + c;
  ps[pidx] = s; pq[pidx] = s2;
}

__global__ __launch_bounds__(256) void instnorm_reduce(
    const float* __restrict__ ps, const float* __restrict__ pq,
    float* __restrict__ meanb, float* __restrict__ stdb)
{
  const int c = blockIdx.x * 256 + threadIdx.x;
  const int b = blockIdx.y;
  float s = 0.f, s2 = 0.f;
  #pragma unroll
  for (int i = 0; i < 8; ++i) {
    s  += ps[(b * 8 + i) * CC + c];
    s2 += pq[(b * 8 + i) * CC + c];
  }
  const float mu  = s * (1.f / SS);
  const float var = s2 * (1.f / SS) - mu * mu;
  meanb[b * CC + c] = mu;
  stdb [b * CC + c] = sqrtf(var + 1e-5f);
}

// ---------------- normalize + transpose one chunk (fp32, fallback) ---------
__global__ __launch_bounds__(256) void norm_transpose(
    const void* __restrict__ x, const float* __restrict__ meanb,
    const float* __restrict__ stdb, float* __restrict__ xTc, int b_base,
    const int* __restrict__ dtf)
{
  const int f32 = *dtf;
  __shared__ float t[32][33];
  const int s0 = blockIdx.x * 32, c0 = blockIdx.y * 32, lb = blockIdx.z;
  const int b = b_base + lb;
  const int tx = threadIdx.x & 31, ty = threadIdx.x >> 5;
  #pragma unroll
  for (int i = 0; i < 4; ++i) {
    const int s = s0 + ty + i * 8;
    t[ty + i * 8][tx] = lin(x, ((size_t)(b * SS) + s) * CC + c0 + tx, f32);
  }
  __syncthreads();
  #pragma unroll
  for (int i = 0; i < 4; ++i) {
    const int c = c0 + ty + i * 8;
    const float mu = meanb[b * CC + c], sd = stdb[b * CC + c];
    xTc[((size_t)(lb * CC) + c) * SS + s0 + tx] = (t[tx][ty + i * 8] - mu) / sd;
  }
}

// ---------------- normalize + transpose, hi/lo split output ----------------
__global__ __launch_bounds__(256) void norm_transpose_split(
    const void* __restrict__ x, const float* __restrict__ meanb,
    const float* __restrict__ stdb, ushort* __restrict__ xh,
    ushort* __restrict__ xl, int b_base, const int* __restrict__ dtf)
{
  const int f32 = *dtf;
  __shared__ float t[32][33];
  const int s0 = blockIdx.x * 32, c0 = blockIdx.y * 32, lb = blockIdx.z;
  const int b = b_base + lb;
  const int tx = threadIdx.x & 31, ty = threadIdx.x >> 5;
  #pragma unroll
  for (int i = 0; i < 4; ++i) {
    const int s = s0 + ty + i * 8;
    t[ty + i * 8][tx] = lin(x, ((size_t)(b * SS) + s) * CC + c0 + tx, f32);
  }
  __syncthreads();
  #pragma unroll
  for (int i = 0; i < 4; ++i) {
    const int c = c0 + ty + i * 8;
    const float mu = meanb[b * CC + c], sd = stdb[b * CC + c];
    const float v = (t[tx][ty + i * 8] - mu) / sd;
    const size_t idx = ((size_t)(lb * CC) + c) * SS + s0 + tx;
    ushort hi, lo; split_bf(v, hi, lo);
    xh[idx] = hi; xl[idx] = lo;
  }
}

// ---------------- weight convert+transpose: W (KxN, input dtype) -> bf16 (NxK)
__global__ __launch_bounds__(256) void transpose_w(
    const void* __restrict__ W, ushort* __restrict__ Wt, int K, int N,
    const int* __restrict__ dtf)
{
  const int f32 = *dtf;
  __shared__ float t[32][33];
  const int n0 = blockIdx.x * 32, k0 = blockIdx.y * 32;
  const int tx = threadIdx.x & 31, ty = threadIdx.x >> 5;
  #pragma unroll
  for (int i = 0; i < 4; ++i)
    t[ty + i * 8][tx] = lin(W, (size_t)(k0 + ty + i * 8) * N + n0 + tx, f32);
  __syncthreads();
  #pragma unroll
  for (int i = 0; i < 4; ++i)
    Wt[(size_t)(n0 + ty + i * 8) * K + k0 + tx] = f2b(t[tx][ty + i * 8]);
}

// ---------------- weight transpose + hi/lo split ----------------
__global__ __launch_bounds__(256) void transpose_w_split(
    const void* __restrict__ W, ushort* __restrict__ Whi, ushort* __restrict__ Wlo,
    int K, int N, const int* __restrict__ dtf)
{
  const int f32 = *dtf;
  __shared__ float t[32][33];
  const int n0 = blockIdx.x * 32, k0 = blockIdx.y * 32;
  const int tx = threadIdx.x & 31, ty = threadIdx.x >> 5;
  #pragma unroll
  for (int i = 0; i < 4; ++i)
    t[ty + i * 8][tx] = lin(W, (size_t)(k0 + ty + i * 8) * N + n0 + tx, f32);
  __syncthreads();
  #pragma unroll
  for (int i = 0; i < 4; ++i) {
    const size_t idx = (size_t)(n0 + ty + i * 8) * K + k0 + tx;
    ushort hi, lo; split_bf(t[tx][ty + i * 8], hi, lo);
    Whi[idx] = hi; Wlo[idx] = lo;
  }
}

// ---------------- generic fp32 tiled GEMM (fallback path) ----------
enum GemmMode { M_BIAS = 0, M_BIAS_RELU = 1, M_RELU_PE = 2,
                M_ADD_BIAS_LEAKY = 3, M_ADD_BIAS_ELU = 4, M_ADD_BIAS = 5,
                M_ADD2_BIAS_LEAKY = 6 };

template<typename AT, typename ADT, typename OT, int MODE>
__global__ __launch_bounds__(256) void gemm_kernel(
    const AT* __restrict__ A, const void* __restrict__ Bw,
    const void* __restrict__ bias, const ADT* __restrict__ addend,
    OT* __restrict__ Cout, int M, int K, int Nn, const int* __restrict__ dtf)
{
  const int f32 = *dtf;
  __shared__ __align__(16) float As[16][68];
  __shared__ __align__(16) float Bs[16][68];
  const int tid = threadIdx.x;
  const int m0 = blockIdx.y * 64, n0 = blockIdx.x * 64;
  const int tx = tid & 15, ty = tid >> 4;
  const int la_m = tid >> 2, la_k = (tid & 3) * 4;
  const int lb_k = tid >> 4, lb_n = (tid & 15) * 4;
  float acc[4][4];
  #pragma unroll
  for (int i = 0; i < 4; ++i)
    #pragma unroll
    for (int j = 0; j < 4; ++j) acc[i][j] = 0.f;
  const size_t a_row = (size_t)(m0 + la_m) * K;

  for (int k0 = 0; k0 < K; k0 += 16) {
    if constexpr (sizeof(AT) == 4) {
      const float4 av = *reinterpret_cast<const float4*>(A + a_row + k0 + la_k);
      As[la_k + 0][la_m] = av.x; As[la_k + 1][la_m] = av.y;
      As[la_k + 2][la_m] = av.z; As[la_k + 3][la_m] = av.w;
    } else {
      const ushort4 av = *reinterpret_cast<const ushort4*>(A + a_row + k0 + la_k);
      As[la_k + 0][la_m] = b2f(av.x); As[la_k + 1][la_m] = b2f(av.y);
      As[la_k + 2][la_m] = b2f(av.z); As[la_k + 3][la_m] = b2f(av.w);
    }
    {
      const size_t boff = (size_t)(k0 + lb_k) * Nn + n0 + lb_n;
      if (f32) {
        const float4 bv = *reinterpret_cast<const float4*>((const float*)Bw + boff);
        Bs[lb_k][lb_n + 0] = bv.x; Bs[lb_k][lb_n + 1] = bv.y;
        Bs[lb_k][lb_n + 2] = bv.z; Bs[lb_k][lb_n + 3] = bv.w;
      } else {
        const ushort4 bv = *reinterpret_cast<const ushort4*>((const ushort*)Bw + boff);
        Bs[lb_k][lb_n + 0] = b2f(bv.x); Bs[lb_k][lb_n + 1] = b2f(bv.y);
        Bs[lb_k][lb_n + 2] = b2f(bv.z); Bs[lb_k][lb_n + 3] = b2f(bv.w);
      }
    }
    __syncthreads();
    #pragma unroll
    for (int k = 0; k < 16; ++k) {
      const float4 a4 = *reinterpret_cast<const float4*>(&As[k][ty * 4]);
      const float4 b4 = *reinterpret_cast<const float4*>(&Bs[k][tx * 4]);
      const float aa[4] = {a4.x, a4.y, a4.z, a4.w};
      const float bb[4] = {b4.x, b4.y, b4.z, b4.w};
      #pragma unroll
      for (int i = 0; i < 4; ++i)
        #pragma unroll
        for (int j = 0; j < 4; ++j)
          acc[i][j] = fmaf(aa[i], bb[j], acc[i][j]);
    }
    __syncthreads();
  }

  float biasv[4];
  if constexpr (MODE != M_RELU_PE) {
    #pragma unroll
    for (int j = 0; j < 4; ++j) biasv[j] = lin(bias, n0 + tx * 4 + j, f32);
  }
  #pragma unroll
  for (int i = 0; i < 4; ++i) {
    const int m = m0 + ty * 4 + i;
    #pragma unroll
    for (int j = 0; j < 4; ++j) {
      const int n = n0 + tx * 4 + j;
      float v = acc[i][j];
      if constexpr (MODE == M_BIAS) {
        v += biasv[j];
      } else if constexpr (MODE == M_BIAS_RELU) {
        v = fmaxf(v + biasv[j], 0.f);
      } else if constexpr (MODE == M_RELU_PE) {
        v = fmaxf(v, 0.f);
        const float freq = expf((float)(n & ~1) * (-0.017988946f)); // -ln(1e4)/512
        const float ang  = (float)(m & (CC - 1)) * freq;            // pos = c
        v += (n & 1) ? cosf(ang) : sinf(ang);
      } else {
        float ad;
        if constexpr (sizeof(ADT) == 4) ad = ((const float*)addend)[(size_t)m * Nn + n];
        else                            ad = b2f(((const ushort*)addend)[(size_t)m * Nn + n]);
        v = ad + v + biasv[j];
        if constexpr (MODE == M_ADD_BIAS_LEAKY) v = (v >= 0.f) ? v : 0.5f * v;
        else if constexpr (MODE == M_ADD_BIAS_ELU) v = (v > 0.f) ? v : expm1f(v);
      }
      if constexpr (sizeof(OT) == 4) ((float*)Cout)[(size_t)m * Nn + n] = v;
      else                           ((ushort*)Cout)[(size_t)m * Nn + n] = f2b(v);
    }
  }
}

template<typename AT, typename ADT, typename OT, int MODE>
static void launch_gemm(const void* A, const void* Bw, const void* bias, const void* add,
                        void* Cout, int M, int K, int Nn, const int* dtf, hipStream_t stream)
{
  dim3 grid(Nn / 64, M / 64);
  gemm_kernel<AT, ADT, OT, MODE><<<grid, dim3(256), 0, stream>>>(
      (const AT*)A, Bw, bias, (const ADT*)add, (OT*)Cout, M, K, Nn, dtf);
}

// ---------------- MFMA bf16 GEMM (128x128 tile), global_load_lds staging ----
template<typename ADT, typename OT, int MODE>
__global__ __launch_bounds__(256) void mgemm_kernel(
    const ushort* __restrict__ A, const ushort* __restrict__ Wt,
    const void* __restrict__ bias, const ADT* __restrict__ addend,
    const ushort* __restrict__ addend2,
    OT* __restrict__ Cout, int M, int K, int Nn, const int* __restrict__ dtf)
{
  const int f32 = *dtf;
  __shared__ __align__(16) ushort As[128][32];
  __shared__ __align__(16) ushort Bs[128][32];
  const int tid = threadIdx.x;
  const int m0 = blockIdx.y * 128, n0 = blockIdx.x * 128;
  const int wave = tid >> 6, lane = tid & 63;
  const int wm = wave & 1, wn = wave >> 1;
  const int quad = lane >> 4, l15 = lane & 15;

  f32x4 acc[4][4];
  #pragma unroll
  for (int i = 0; i < 4; ++i)
    #pragma unroll
    for (int j = 0; j < 4; ++j) acc[i][j] = (f32x4){0.f, 0.f, 0.f, 0.f};

  const int srow_l = lane >> 2;   // 0..15 row within a 16-row issue
  const int slot   = lane & 3;    // 0..3  (x8 ushort = 16B column slot)

  for (int k0 = 0; k0 < K; k0 += 32) {
    #pragma unroll
    for (int i = 0; i < 2; ++i) {
      const int row = wave * 32 + i * 16;   // wave-uniform LDS base row
      gl_lds16(A  + (size_t)(m0 + row + srow_l) * K + k0 + slot * 8, &As[row][0]);
      gl_lds16(Wt + (size_t)(n0 + row + srow_l) * K + k0 + slot * 8, &Bs[row][0]);
    }
    __syncthreads();
    short8 af[4], bf[4];
    #pragma unroll
    for (int i = 0; i < 4; ++i)
      af[i] = *reinterpret_cast<const short8*>(&As[wm * 64 + i * 16 + l15][quad * 8]);
    #pragma unroll
    for (int j = 0; j < 4; ++j)
      bf[j] = *reinterpret_cast<const short8*>(&Bs[wn * 64 + j * 16 + l15][quad * 8]);
    #pragma unroll
    for (int i = 0; i < 4; ++i)
      #pragma unroll
      for (int j = 0; j < 4; ++j)
        acc[i][j] = __builtin_amdgcn_mfma_f32_16x16x32_bf16(af[i], bf[j], acc[i][j], 0, 0, 0);
    __syncthreads();
  }

  #pragma unroll
  for (int j = 0; j < 4; ++j) {
    const int n = n0 + wn * 64 + j * 16 + l15;
    const float bv = lin(bias, n, f32);
    #pragma unroll
    for (int i = 0; i < 4; ++i) {
      #pragma unroll
      for (int r = 0; r < 4; ++r) {
        const int m = m0 + wm * 64 + i * 16 + quad * 4 + r;
        float v = acc[i][j][r];
        if constexpr (MODE == M_BIAS) {
          v += bv;
        } else if constexpr (MODE == M_BIAS_RELU) {
          v = fmaxf(v + bv, 0.f);
        } else if constexpr (MODE == M_ADD2_BIAS_LEAKY) {
          const size_t ix = (size_t)m * Nn + n;
          const float ad = b2f(((const ushort*)addend)[ix]) + b2f(addend2[ix]);
          v = ad + v + bv;
          v = (v >= 0.f) ? v : 0.5f * v;
        } else {
          float ad;
          if constexpr (sizeof(ADT) == 4) ad = ((const float*)addend)[(size_t)m * Nn + n];
          else                            ad = b2f(((const ushort*)addend)[(size_t)m * Nn + n]);
          v = ad + v + bv;
          if constexpr (MODE == M_ADD_BIAS_ELU)
            v = (v > 0.f) ? v : (__builtin_amdgcn_exp2f(v * LOG2E) - 1.f);
          else if constexpr (MODE == M_ADD_BIAS_LEAKY) v = (v >= 0.f) ? v : 0.5f * v;
        }
        if constexpr (sizeof(OT) == 4) ((float*)Cout)[(size_t)m * Nn + n] = v;
        else                           ((ushort*)Cout)[(size_t)m * Nn + n] = f2b(v);
      }
    }
  }
}

template<typename ADT, typename OT, int MODE>
static void launch_mgemm(const void* A, const void* Wt, const void* bias, const void* add,
                         void* Cout, int M, int K, int Nn, const int* dtf, hipStream_t stream,
                         const void* add2 = nullptr)
{
  dim3 grid(Nn / 128, M / 128);
  mgemm_kernel<ADT, OT, MODE><<<grid, dim3(256), 0, stream>>>(
      (const ushort*)A, (const ushort*)Wt, bias, (const ADT*)add, (const ushort*)add2,
      (OT*)Cout, M, K, Nn, dtf);
}

// ---------------- FUSED dual 128x128 mgemm (bias + optional relu) ----------
// blockIdx.z selects {Wt, bias, out, relu}; body identical to mgemm_kernel.
template<typename OT>
__global__ __launch_bounds__(256) void mgemm_dual_kernel(
    const ushort* __restrict__ A,
    const ushort* __restrict__ Wt0, const ushort* __restrict__ Wt1,
    const void* __restrict__ bias0, const void* __restrict__ bias1,
    OT* __restrict__ out0, OT* __restrict__ out1, int relu0, int relu1,
    int M, int K, int Nn, const int* __restrict__ dtf)
{
  const int f32 = *dtf;
  const int z = blockIdx.z;
  const ushort* Wt = z ? Wt1 : Wt0;
  const void* bias = z ? bias1 : bias0;
  OT* Cout = z ? out1 : out0;
  const int relu = z ? relu1 : relu0;

  __shared__ __align__(16) ushort As[128][32];
  __shared__ __align__(16) ushort Bs[128][32];
  const int tid = threadIdx.x;
  const int m0 = blockIdx.y * 128, n0 = blockIdx.x * 128;
  const int wave = tid >> 6, lane = tid & 63;
  const int wm = wave & 1, wn = wave >> 1;
  const int quad = lane >> 4, l15 = lane & 15;

  f32x4 acc[4][4];
  #pragma unroll
  for (int i = 0; i < 4; ++i)
    #pragma unroll
    for (int j = 0; j < 4; ++j) acc[i][j] = (f32x4){0.f, 0.f, 0.f, 0.f};

  const int srow_l = lane >> 2;
  const int slot   = lane & 3;

  for (int k0 = 0; k0 < K; k0 += 32) {
    #pragma unroll
    for (int i = 0; i < 2; ++i) {
      const int row = wave * 32 + i * 16;
      gl_lds16(A  + (size_t)(m0 + row + srow_l) * K + k0 + slot * 8, &As[row][0]);
      gl_lds16(Wt + (size_t)(n0 + row + srow_l) * K + k0 + slot * 8, &Bs[row][0]);
    }
    __syncthreads();
    short8 af[4], bf[4];
    #pragma unroll
    for (int i = 0; i < 4; ++i)
      af[i] = *reinterpret_cast<const short8*>(&As[wm * 64 + i * 16 + l15][quad * 8]);
    #pragma unroll
    for (int j = 0; j < 4; ++j)
      bf[j] = *reinterpret_cast<const short8*>(&Bs[wn * 64 + j * 16 + l15][quad * 8]);
    #pragma unroll
    for (int i = 0; i < 4; ++i)
      #pragma unroll
      for (int j = 0; j < 4; ++j)
        acc[i][j] = __builtin_amdgcn_mfma_f32_16x16x32_bf16(af[i], bf[j], acc[i][j], 0, 0, 0);
    __syncthreads();
  }

  #pragma unroll
  for (int j = 0; j < 4; ++j) {
    const int n = n0 + wn * 64 + j * 16 + l15;
    const float bv = lin(bias, n, f32);
    #pragma unroll
    for (int i = 0; i < 4; ++i) {
      #pragma unroll
      for (int r = 0; r < 4; ++r) {
        const int m = m0 + wm * 64 + i * 16 + quad * 4 + r;
        float v = acc[i][j][r] + bv;
        if (relu) v = fmaxf(v, 0.f);
        if constexpr (sizeof(OT) == 4) ((float*)Cout)[(size_t)m * Nn + n] = v;
        else                           ((ushort*)Cout)[(size_t)m * Nn + n] = f2b(v);
      }
    }
  }
}

// ---------------- MFMA bf16 GEMM (64x64 tile), global_load_lds staging ------
template<typename ADT, typename OT, int MODE>
__global__ __launch_bounds__(256) void mgemm64_kernel(
    const ushort* __restrict__ A, const ushort* __restrict__ Wt,
    const void* __restrict__ bias, const ADT* __restrict__ addend,
    const ushort* __restrict__ addend2,
    OT* __restrict__ Cout, int M, int K, int Nn, const int* __restrict__ dtf)
{
  const int f32 = *dtf;
  __shared__ __align__(16) ushort As[64][32];
  __shared__ __align__(16) ushort Bs[64][32];
  const int tid = threadIdx.x;
  const int m0 = blockIdx.y * 64, n0 = blockIdx.x * 64;
  const int wave = tid >> 6, lane = tid & 63;
  const int wm = wave & 1, wn = wave >> 1;
  const int quad = lane >> 4, l15 = lane & 15;

  f32x4 acc[2][2];
  #pragma unroll
  for (int i = 0; i < 2; ++i)
    #pragma unroll
    for (int j = 0; j < 2; ++j) acc[i][j] = (f32x4){0.f, 0.f, 0.f, 0.f};

  const int srow_l = lane >> 2;
  const int slot   = lane & 3;

  for (int k0 = 0; k0 < K; k0 += 32) {
    {
      const int row = wave * 16;
      gl_lds16(A  + (size_t)(m0 + row + srow_l) * K + k0 + slot * 8, &As[row][0]);
      gl_lds16(Wt + (size_t)(n0 + row + srow_l) * K + k0 + slot * 8, &Bs[row][0]);
    }
    __syncthreads();
    short8 af[2], bf[2];
    #pragma unroll
    for (int i = 0; i < 2; ++i) {
      af[i] = *reinterpret_cast<const short8*>(&As[wm * 32 + i * 16 + l15][quad * 8]);
      bf[i] = *reinterpret_cast<const short8*>(&Bs[wn * 32 + i * 16 + l15][quad * 8]);
    }
    #pragma unroll
    for (int i = 0; i < 2; ++i)
      #pragma unroll
      for (int j = 0; j < 2; ++j)
        acc[i][j] = __builtin_amdgcn_mfma_f32_16x16x32_bf16(af[i], bf[j], acc[i][j], 0, 0, 0);
    __syncthreads();
  }

  #pragma unroll
  for (int j = 0; j < 2; ++j) {
    const int n = n0 + wn * 32 + j * 16 + l15;
    const float bv = lin(bias, n, f32);
    #pragma unroll
    for (int i = 0; i < 2; ++i) {
      #pragma unroll
      for (int r = 0; r < 4; ++r) {
        const int m = m0 + wm * 32 + i * 16 + quad * 4 + r;
        float v = acc[i][j][r];
        if constexpr (MODE == M_BIAS) {
          v += bv;
        } else if constexpr (MODE == M_BIAS_RELU) {
          v = fmaxf(v + bv, 0.f);
        } else if constexpr (MODE == M_ADD2_BIAS_LEAKY) {
          const size_t ix = (size_t)m * Nn + n;
          const float ad = b2f(((const ushort*)addend)[ix]) + b2f(addend2[ix]);
          v = ad + v + bv;
          v = (v >= 0.f) ? v : 0.5f * v;
        } else {
          float ad;
          if constexpr (sizeof(ADT) == 4) ad = ((const float*)addend)[(size_t)m * Nn + n];
          else                            ad = b2f(((const ushort*)addend)[(size_t)m * Nn + n]);
          v = ad + v + bv;
          if constexpr (MODE == M_ADD_BIAS_ELU)
            v = (v > 0.f) ? v : (__builtin_amdgcn_exp2f(v * LOG2E) - 1.f);
          else if constexpr (MODE == M_ADD_BIAS_LEAKY) v = (v >= 0.f) ? v : 0.5f * v;
        }
        if constexpr (sizeof(OT) == 4) ((float*)Cout)[(size_t)m * Nn + n] = v;
        else                           ((ushort*)Cout)[(size_t)m * Nn + n] = f2b(v);
      }
    }
  }
}

template<typename ADT, typename OT, int MODE>
static void launch_mgemm64(const void* A, const void* Wt, const void* bias, const void* add,
                           void* Cout, int M, int K, int Nn, const int* dtf, hipStream_t stream,
                           const void* add2 = nullptr)
{
  dim3 grid(Nn / 64, M / 64);
  mgemm64_kernel<ADT, OT, MODE><<<grid, dim3(256), 0, stream>>>(
      (const ushort*)A, (const ushort*)Wt, bias, (const ADT*)add, (const ushort*)add2,
      (OT*)Cout, M, K, Nn, dtf);
}

// ---------------- FUSED dual 64x64 mgemm (bias + optional relu) -------------
template<typename OT>
__global__ __launch_bounds__(256) void mgemm64_dual_kernel(
    const ushort* __restrict__ A,
    const ushort* __restrict__ Wt0, const ushort* __restrict__ Wt1,
    const void* __restrict__ bias0, const void* __restrict__ bias1,
    OT* __restrict__ out0, OT* __restrict__ out1, int relu0, int relu1,
    int M, int K, int Nn, const int* __restrict__ dtf)
{
  const int f32 = *dtf;
  const int z = blockIdx.z;
  const ushort* Wt = z ? Wt1 : Wt0;
  const void* bias = z ? bias1 : bias0;
  OT* Cout = z ? out1 : out0;
  const int relu = z ? relu1 : relu0;

  __shared__ __align__(16) ushort As[64][32];
  __shared__ __align__(16) ushort Bs[64][32];
  const int tid = threadIdx.x;
  const int m0 = blockIdx.y * 64, n0 = blockIdx.x * 64;
  const int wave = tid >> 6, lane = tid & 63;
  const int wm = wave & 1, wn = wave >> 1;
  const int quad = lane >> 4, l15 = lane & 15;

  f32x4 acc[2][2];
  #pragma unroll
  for (int i = 0; i < 2; ++i)
    #pragma unroll
    for (int j = 0; j < 2; ++j) acc[i][j] = (f32x4){0.f, 0.f, 0.f, 0.f};

  const int srow_l = lane >> 2;
  const int slot   = lane & 3;

  for (int k0 = 0; k0 < K; k0 += 32) {
    {
      const int row = wave * 16;
      gl_lds16(A  + (size_t)(m0 + row + srow_l) * K + k0 + slot * 8, &As[row][0]);
      gl_lds16(Wt + (size_t)(n0 + row + srow_l) * K + k0 + slot * 8, &Bs[row][0]);
    }
    __syncthreads();
    short8 af[2], bf[2];
    #pragma unroll
    for (int i = 0; i < 2; ++i) {
      af[i] = *reinterpret_cast<const short8*>(&As[wm * 32 + i * 16 + l15][quad * 8]);
      bf[i] = *reinterpret_cast<const short8*>(&Bs[wn * 32 + i * 16 + l15][quad * 8]);
    }
    #pragma unroll
    for (int i = 0; i < 2; ++i)
      #pragma unroll
      for (int j = 0; j < 2; ++j)
        acc[i][j] = __builtin_amdgcn_mfma_f32_16x16x32_bf16(af[i], bf[j], acc[i][j], 0, 0, 0);
    __syncthreads();
  }

  #pragma unroll
  for (int j = 0; j < 2; ++j) {
    const int n = n0 + wn * 32 + j * 16 + l15;
    const float bv = lin(bias, n, f32);
    #pragma unroll
    for (int i = 0; i < 2; ++i) {
      #pragma unroll
      for (int r = 0; r < 4; ++r) {
        const int m = m0 + wm * 32 + i * 16 + quad * 4 + r;
        float v = acc[i][j][r] + bv;
        if (relu) v = fmaxf(v, 0.f);
        if constexpr (sizeof(OT) == 4) ((float*)Cout)[(size_t)m * Nn + n] = v;
        else                           ((ushort*)Cout)[(size_t)m * Nn + n] = f2b(v);
      }
    }
  }
}

// ---------------- mgemm3: 64x64-tile hi/lo-split 3-MFMA GEMM ----------------
enum Epi3 { E3_RELU_PE = 0, E3_RELU_SPLIT = 1, E3_SPLIT = 2, E3_RELU_VT = 3 };

template<int EPI>
__global__ __launch_bounds__(256) void mgemm3_kernel(
    const ushort* __restrict__ Ah, const ushort* __restrict__ Al,
    const ushort* __restrict__ Bh, const ushort* __restrict__ Bl,
    const void* __restrict__ bias,
    ushort* __restrict__ Oh, ushort* __restrict__ Ol,
    int M, int K, int Nn, const int* __restrict__ dtf)
{
  const int f32 = *dtf;
  __shared__ __align__(16) ushort AsH[64][32];
  __shared__ __align__(16) ushort AsL[64][32];
  __shared__ __align__(16) ushort BsH[64][32];
  __shared__ __align__(16) ushort BsL[64][32];
  const int tid = threadIdx.x;
  const int m0 = blockIdx.y * 64, n0 = blockIdx.x * 64;
  const int wave = tid >> 6, lane = tid & 63;
  const int wm = wave & 1, wn = wave >> 1;
  const int quad = lane >> 4, l15 = lane & 15;

  f32x4 acc[2][2];
  #pragma unroll
  for (int i = 0; i < 2; ++i)
    #pragma unroll
    for (int j = 0; j < 2; ++j) acc[i][j] = (f32x4){0.f, 0.f, 0.f, 0.f};

  const int srow_l = lane >> 2;
  const int slot   = lane & 3;

  for (int k0 = 0; k0 < K; k0 += 32) {
    {
      const int row = wave * 16;
      const size_t ga = (size_t)(m0 + row + srow_l) * K + k0 + slot * 8;
      const size_t gb = (size_t)(n0 + row + srow_l) * K + k0 + slot * 8;
      gl_lds16(Ah + ga, &AsH[row][0]);
      gl_lds16(Al + ga, &AsL[row][0]);
      gl_lds16(Bh + gb, &BsH[row][0]);
      gl_lds16(Bl + gb, &BsL[row][0]);
    }
    __syncthreads();
    short8 afh[2], afl[2], bfh[2], bfl[2];
    #pragma unroll
    for (int i = 0; i < 2; ++i) {
      afh[i] = *reinterpret_cast<const short8*>(&AsH[wm * 32 + i * 16 + l15][quad * 8]);
      afl[i] = *reinterpret_cast<const short8*>(&AsL[wm * 32 + i * 16 + l15][quad * 8]);
      bfh[i] = *reinterpret_cast<const short8*>(&BsH[wn * 32 + i * 16 + l15][quad * 8]);
      bfl[i] = *reinterpret_cast<const short8*>(&BsL[wn * 32 + i * 16 + l15][quad * 8]);
    }
    #pragma unroll
    for (int i = 0; i < 2; ++i)
      #pragma unroll
      for (int j = 0; j < 2; ++j) {
        acc[i][j] = __builtin_amdgcn_mfma_f32_16x16x32_bf16(afh[i], bfh[j], acc[i][j], 0, 0, 0);
        acc[i][j] = __builtin_amdgcn_mfma_f32_16x16x32_bf16(afh[i], bfl[j], acc[i][j], 0, 0, 0);
        acc[i][j] = __builtin_amdgcn_mfma_f32_16x16x32_bf16(afl[i], bfh[j], acc[i][j], 0, 0, 0);
      }
    __syncthreads();
  }

  #pragma unroll
  for (int j = 0; j < 2; ++j) {
    const int n = n0 + wn * 32 + j * 16 + l15;
    float bv = 0.f;
    if constexpr (EPI != E3_RELU_PE) bv = lin(bias, n, f32);
    #pragma unroll
    for (int i = 0; i < 2; ++i) {
      #pragma unroll
      for (int r = 0; r < 4; ++r) {
        const int m = m0 + wm * 32 + i * 16 + quad * 4 + r;
        float v = acc[i][j][r];
        if constexpr (EPI == E3_RELU_PE) {
          v = fmaxf(v, 0.f);
          const float freq = expf((float)(n & ~1) * (-0.017988946f)); // -ln(1e4)/512
          const float ang  = (float)(m & (CC - 1)) * freq;            // pos = c
          v += (n & 1) ? cosf(ang) : sinf(ang);
        } else if constexpr (EPI == E3_RELU_SPLIT || EPI == E3_RELU_VT) {
          v = fmaxf(v + bv, 0.f);
        } else {
          v = v + bv;
        }
        if constexpr (EPI == E3_RELU_VT) {
          Oh[((size_t)((m >> 9) * 512 + n)) * 512 + (m & 511)] = f2b(v);
        } else {
          ushort hi, lo; split_bf(v, hi, lo);
          Oh[(size_t)m * Nn + n] = hi;
          Ol[(size_t)m * Nn + n] = lo;
        }
      }
    }
  }
}

template<int EPI>
static void launch_mgemm3(const void* Ahv, const void* Alv, const ushort* Bh,
                          const ushort* Bl, const void* bias, void* Oh, void* Ol,
                          int M, int K, int Nn, const int* dtf, hipStream_t stream)
{
  dim3 grid(Nn / 64, M / 64);
  mgemm3_kernel<EPI><<<grid, dim3(256), 0, stream>>>(
      (const ushort*)Ahv, (const ushort*)Alv, Bh, Bl, bias,
      (ushort*)Oh, (ushort*)Ol, M, K, Nn, dtf);
}

// ---------------- FUSED q/k/v mgemm3 (blockIdx.z selects set) ---------------
// z=0: q (relu, split->qh/ql); z=1: k (no relu, split->kh/kl);
// z=2: v (relu, transposed single -> vt). Body identical to mgemm3_kernel.
__global__ __launch_bounds__(256) void mgemm3_qkv_kernel(
    const ushort* __restrict__ Ah, const ushort* __restrict__ Al,
    const ushort* __restrict__ Bh0, const ushort* __restrict__ Bl0, const void* __restrict__ bias0,
    const ushort* __restrict__ Bh1, const ushort* __restrict__ Bl1, const void* __restrict__ bias1,
    const ushort* __restrict__ Bh2, const ushort* __restrict__ Bl2, const void* __restrict__ bias2,
    ushort* __restrict__ qh, ushort* __restrict__ ql,
    ushort* __restrict__ kh, ushort* __restrict__ kl,
    ushort* __restrict__ vt,
    int M, int K, int Nn, const int* __restrict__ dtf)
{
  const int f32 = *dtf;
  const int z = blockIdx.z;
  const ushort* Bh = (z == 0) ? Bh0 : (z == 1) ? Bh1 : Bh2;
  const ushort* Bl = (z == 0) ? Bl0 : (z == 1) ? Bl1 : Bl2;
  const void* bias = (z == 0) ? bias0 : (z == 1) ? bias1 : bias2;

  __shared__ __align__(16) ushort AsH[64][32];
  __shared__ __align__(16) ushort AsL[64][32];
  __shared__ __align__(16) ushort BsH[64][32];
  __shared__ __align__(16) ushort BsL[64][32];
  const int tid = threadIdx.x;
  const int m0 = blockIdx.y * 64, n0 = blockIdx.x * 64;
  const int wave = tid >> 6, lane = tid & 63;
  const int wm = wave & 1, wn = wave >> 1;
  const int quad = lane >> 4, l15 = lane & 15;

  f32x4 acc[2][2];
  #pragma unroll
  for (int i = 0; i < 2; ++i)
    #pragma unroll
    for (int j = 0; j < 2; ++j) acc[i][j] = (f32x4){0.f, 0.f, 0.f, 0.f};

  const int srow_l = lane >> 2;
  const int slot   = lane & 3;

  for (int k0 = 0; k0 < K; k0 += 32) {
    {
      const int row = wave * 16;
      const size_t ga = (size_t)(m0 + row + srow_l) * K + k0 + slot * 8;
      const size_t gb = (size_t)(n0 + row + srow_l) * K + k0 + slot * 8;
      gl_lds16(Ah + ga, &AsH[row][0]);
      gl_lds16(Al + ga, &AsL[row][0]);
      gl_lds16(Bh + gb, &BsH[row][0]);
      gl_lds16(Bl + gb, &BsL[row][0]);
    }
    __syncthreads();
    short8 afh[2], afl[2], bfh[2], bfl[2];
    #pragma unroll
    for (int i = 0; i < 2; ++i) {
      afh[i] = *reinterpret_cast<const short8*>(&AsH[wm * 32 + i * 16 + l15][quad * 8]);
      afl[i] = *reinterpret_cast<const short8*>(&AsL[wm * 32 + i * 16 + l15][quad * 8]);
      bfh[i] = *reinterpret_cast<const short8*>(&BsH[wn * 32 + i * 16 + l15][quad * 8]);
      bfl[i] = *reinterpret_cast<const short8*>(&BsL[wn * 32 + i * 16 + l15][quad * 8]);
    }
    #pragma unroll
    for (int i = 0; i < 2; ++i)
      #pragma unroll
      for (int j = 0; j < 2; ++j) {
        acc[i][j] = __builtin_amdgcn_mfma_f32_16x16x32_bf16(afh[i], bfh[j], acc[i][j], 0, 0, 0);
        acc[i][j] = __builtin_amdgcn_mfma_f32_16x16x32_bf16(afh[i], bfl[j], acc[i][j], 0, 0, 0);
        acc[i][j] = __builtin_amdgcn_mfma_f32_16x16x32_bf16(afl[i], bfh[j], acc[i][j], 0, 0, 0);
      }
    __syncthreads();
  }

  #pragma unroll
  for (int j = 0; j < 2; ++j) {
    const int n = n0 + wn * 32 + j * 16 + l15;
    const float bv = lin(bias, n, f32);
    #pragma unroll
    for (int i = 0; i < 2; ++i) {
      #pragma unroll
      for (int r = 0; r < 4; ++r) {
        const int m = m0 + wm * 32 + i * 16 + quad * 4 + r;
        float v = acc[i][j][r] + bv;
        if (z != 1) v = fmaxf(v, 0.f);          // q,v have relu
        if (z == 2) {
          // pre-transposed: vT[(lb*512 + n)][s] with lb = m>>9, s = m&511
          vt[((size_t)((m >> 9) * 512 + n)) * 512 + (m & 511)] = f2b(v);
        } else {
          ushort hi, lo; split_bf(v, hi, lo);
          ushort* Oh = z ? kh : qh;
          ushort* Ol = z ? kl : ql;
          Oh[(size_t)m * Nn + n] = hi;
          Ol[(size_t)m * Nn + n] = lo;
        }
      }
    }
  }
}

// ---------------- GAttn via MFMA: register scores + DPP top-k ---------------
__global__ __launch_bounds__(256, 2) void gattn_mfma(
    const ushort* __restrict__ qsh, const ushort* __restrict__ qsl,
    const ushort* __restrict__ ksh, const ushort* __restrict__ ksl,
    const ushort* __restrict__ vt, ushort* __restrict__ out)
{
  const int tid = threadIdx.x;
  const int wave = tid >> 6, lane = tid & 63;
  const int quad = lane >> 4, l15 = lane & 15;
  const int l0 = blockIdx.x * 16;
  const int h = blockIdx.y, bz = blockIdx.z;

  __shared__ __align__(16) ushort P[16][520];    // 16640 B (unnormalized bf16 weights)
  __shared__ float cand[16][40];                 // 2560 B (4 waves x sorted top-10)
  __shared__ float psum[16][4];                  // 256 B  (per-wave partial sums)

  // ---- Q fragments (hi/lo), kk-chunks 0,1 ----
  short8 ah[2], al[2];
  {
    const size_t qoff = ((size_t)bz * CC + l0 + l15) * DD + h * EE + quad * 8;
    ah[0] = *reinterpret_cast<const short8*>(qsh + qoff);
    ah[1] = *reinterpret_cast<const short8*>(qsh + qoff + 32);
    al[0] = *reinterpret_cast<const short8*>(qsl + qoff);
    al[1] = *reinterpret_cast<const short8*>(qsl + qoff + 32);
  }

  // ---- S phase into registers: sacc[c][r] = S[quad*4+r][c*64+wave*16+l15] --
  f32x4 sacc[8];
  {
    const size_t kbase = ((size_t)bz * CC + wave * 16 + l15) * DD + h * EE + quad * 8;
    short8 pbh0 = *reinterpret_cast<const short8*>(ksh + kbase);
    short8 pbl0 = *reinterpret_cast<const short8*>(ksl + kbase);
    short8 pbh1 = *reinterpret_cast<const short8*>(ksh + kbase + 32);
    short8 pbl1 = *reinterpret_cast<const short8*>(ksl + kbase + 32);
    #pragma unroll
    for (int c = 0; c < 8; ++c) {
      const short8 cbh0 = pbh0, cbl0 = pbl0, cbh1 = pbh1, cbl1 = pbl1;
      if (c < 7) {
        const size_t noff = kbase + (size_t)((c + 1) * 64) * DD;
        pbh0 = *reinterpret_cast<const short8*>(ksh + noff);
        pbl0 = *reinterpret_cast<const short8*>(ksl + noff);
        pbh1 = *reinterpret_cast<const short8*>(ksh + noff + 32);
        pbl1 = *reinterpret_cast<const short8*>(ksl + noff + 32);
      }
      f32x4 acc = (f32x4){0.f, 0.f, 0.f, 0.f};
      __builtin_amdgcn_s_setprio(1);
      acc = __builtin_amdgcn_mfma_f32_16x16x32_bf16(ah[0], cbh0, acc, 0, 0, 0);
      acc = __builtin_amdgcn_mfma_f32_16x16x32_bf16(ah[0], cbl0, acc, 0, 0, 0);
      acc = __builtin_amdgcn_mfma_f32_16x16x32_bf16(al[0], cbh0, acc, 0, 0, 0);
      acc = __builtin_amdgcn_mfma_f32_16x16x32_bf16(ah[1], cbh1, acc, 0, 0, 0);
      acc = __builtin_amdgcn_mfma_f32_16x16x32_bf16(ah[1], cbl1, acc, 0, 0, 0);
      acc = __builtin_amdgcn_mfma_f32_16x16x32_bf16(al[1], cbh1, acc, 0, 0, 0);
      __builtin_amdgcn_s_setprio(0);
      sacc[c] = acc;
    }
  }

  // ---- stage-1 top-k: each quad extracts its row's wave-local top-10 ----
  #pragma unroll
  for (int r = 0; r < 4; ++r) {
    float wk[8];
    #pragma unroll
    for (int c = 0; c < 8; ++c) wk[c] = sacc[c][r];
    float myg = 0.f;
    for (int it = 0; it < 10; ++it) {
      float lm = wk[0];
      #pragma unroll
      for (int c = 1; c < 8; ++c) lm = fmaxf(lm, wk[c]);
      const float gm = red16_max(lm);
      if (l15 == it) myg = gm;
      if (it < 9) {
        const unsigned long long msk = __ballot(lm == gm);
        const int sel = (__ffsll((unsigned long long)((msk >> (quad * 16)) & 0xFFFFull)) - 1)
                        + quad * 16;
        if (lane == sel) {
          #pragma unroll
          for (int c = 0; c < 8; ++c) { if (wk[c] == gm) { wk[c] = -FLT_MAX; break; } }
        }
      }
    }
    if (l15 < 10) cand[quad * 4 + r][wave * 10 + l15] = myg;
  }
  __syncthreads();

  // ---- merge 4 sorted lists of 10 -> global maxv + thr (10th) ----
  float mx, thr;
  {
    const int mr = lane & 15;
    float h0 = cand[mr][0], h1 = cand[mr][10], h2 = cand[mr][20], h3 = cand[mr][30];
    int i0 = 0, i1 = 0, i2 = 0, i3 = 0;
    float cur = 0.f;
    mx = 0.f;
    #pragma unroll
    for (int t = 0; t < 10; ++t) {
      cur = fmaxf(fmaxf(h0, h1), fmaxf(h2, h3));
      if (t == 0) mx = cur;
      if (t < 9) {
        const bool a0 = (cur == h0);
        const bool a1 = !a0 && (cur == h1);
        const bool a2 = !a0 && !a1 && (cur == h2);
        const int ni0 = i0 + (a0 ? 1 : 0);
        const int ni1 = i1 + (a1 ? 1 : 0);
        const int ni2 = i2 + (a2 ? 1 : 0);
        const int ni3 = i3 + ((a0 || a1 || a2) ? 0 : 1);
        const int off = a0 ? ni0 : (a1 ? 10 + ni1 : (a2 ? 20 + ni2 : 30 + ni3));
        const float nv = cand[mr][off];
        h0 = a0 ? nv : h0;
        h1 = a1 ? nv : h1;
        h2 = a2 ? nv : h2;
        h3 = (a0 || a1 || a2) ? h3 : nv;
        i0 = ni0; i1 = ni1; i2 = ni2; i3 = ni3;
      }
    }
    thr = cur;
  }
  // distribute row thr/max to the quad that owns the row
  float thrR[4], mxR[4];
  #pragma unroll
  for (int r = 0; r < 4; ++r) {
    thrR[r] = __shfl(thr, quad * 4 + r);
    mxR[r]  = __shfl(mx,  quad * 4 + r);
  }

  // ---- exp + partial sums + P write ----
  #pragma unroll
  for (int r = 0; r < 4; ++r) {
    const int Rr = quad * 4 + r;
    float s = 0.f;
    #pragma unroll
    for (int c = 0; c < 8; ++c) {
      const float sc = sacc[c][r];
      const float p = (sc >= thrR[r])
          ? __builtin_amdgcn_exp2f((sc - mxR[r]) * (0.125f * LOG2E)) : 0.f;
      P[Rr][c * 64 + wave * 16 + l15] = f2b(p);
      s += p;
    }
    s = red16_sum(s);
    if (l15 == 0) psum[Rr][wave] = s;
  }
  __syncthreads();

  // ---- PV phase: wave w owns e-cols w*16..w*16+15; vT loaded direct ----
  f32x4 pacc = (f32x4){0.f, 0.f, 0.f, 0.f};
  const size_t vbase = ((size_t)bz * 512 + h * EE + wave * 16 + l15) * 512 + quad * 8;
  #pragma unroll
  for (int c = 0; c < 4; ++c) {
    #pragma unroll
    for (int ks = 0; ks < 4; ++ks) {
      const int s0 = c * 128 + ks * 32;
      const short8 pa = *reinterpret_cast<const short8*>(&P[l15][s0 + quad * 8]);
      const short8 vb = *reinterpret_cast<const short8*>(vt + vbase + s0);
      __builtin_amdgcn_s_setprio(1);
      pacc = __builtin_amdgcn_mfma_f32_16x16x32_bf16(pa, vb, pacc, 0, 0, 0);
      __builtin_amdgcn_s_setprio(0);
    }
  }

  // ---- epilogue ----
  #pragma unroll
  for (int r = 0; r < 4; ++r) {
    const int Rr = quad * 4 + r;
    const float4 ps = *reinterpret_cast<const float4*>(&psum[Rr][0]);
    const float inv = 1.f / (ps.x + ps.y + ps.z + ps.w);
    out[((size_t)bz * CC + l0 + Rr) * DD + h * EE + wave * 16 + l15] = f2b(pacc[r] * inv);
  }
}

// ---------------- GAttn fallback (fp32 path only) -----------
template<typename OT>
__global__ __launch_bounds__(256) void gattn_fb(
    const float* __restrict__ q, const float* __restrict__ k,
    const float* __restrict__ v, OT* __restrict__ out)
{
  const int tid = threadIdx.x;
  const int wave = tid >> 6, lane = tid & 63;
  const int l0 = blockIdx.x * 4;
  const int h = blockIdx.y, bz = blockIdx.z;
  const int l = l0 + wave;
  const size_t base = ((size_t)bz * CC) * DD + h * EE;

  __shared__ __align__(16) float kt[64][68];
  __shared__ __align__(16) float qs[4][64];
  __shared__ __align__(16) float ww[4][512];

  qs[wave][lane] = q[((size_t)bz * CC + l) * DD + h * EE + lane];

  float sc[8];
  const int sl = tid >> 4;
  const int e4 = (tid & 15) * 4;
  for (int c8 = 0; c8 < 8; ++c8) {
    #pragma unroll
    for (int r = 0; r < 4; ++r) {
      const int s_local = sl + r * 16;
      const float4 kv = *reinterpret_cast<const float4*>(
          k + base + (size_t)(c8 * 64 + s_local) * DD + e4);
      *reinterpret_cast<float4*>(&kt[s_local][e4]) = kv;
    }
    __syncthreads();
    float a = 0.f;
    #pragma unroll
    for (int e = 0; e < 16; ++e) {
      const float4 qv = *reinterpret_cast<const float4*>(&qs[wave][e * 4]);
      const float4 kv = *reinterpret_cast<const float4*>(&kt[lane][e * 4]);
      a += qv.x * kv.x + qv.y * kv.y + qv.z * kv.z + qv.w * kv.w;
    }
    sc[c8] = a;
    __syncthreads();
  }

  float wk[8];
  #pragma unroll
  for (int j = 0; j < 8; ++j) wk[j] = sc[j];
  float maxv = 0.f, thr = 0.f;
  for (int it = 0; it < 10; ++it) {
    float lm = wk[0];
    #pragma unroll
    for (int j = 1; j < 8; ++j) lm = fmaxf(lm, wk[j]);
    float gm = lm;
    #pragma unroll
    for (int off = 32; off > 0; off >>= 1) gm = fmaxf(gm, __shfl_xor(gm, off));
    if (it == 0) maxv = gm;
    if (it == 9) { thr = gm; break; }
    const unsigned long long msk = __ballot(lm == gm);
    if (lane == __ffsll(msk) - 1) {
      #pragma unroll
      for (int j = 0; j < 8; ++j) { if (wk[j] == gm) { wk[j] = -FLT_MAX; break; } }
    }
  }

  float lsum = 0.f;
  #pragma unroll
  for (int j = 0; j < 8; ++j) {
    const float p = (sc[j] >= thr) ? expf((sc[j] - maxv) * 0.125f) : 0.f;
    ww[wave][j * 64 + lane] = p;
    lsum += p;
  }
  #pragma unroll
  for (int off = 32; off > 0; off >>= 1) lsum += __shfl_xor(lsum, off);
  const float inv = 1.f / lsum;
  __syncthreads();

  float acc = 0.f;
  const float* vp = v + base + lane;
  const float* wp = ww[wave];
  for (int s = 0; s < 512; s += 4) {
    const float4 w4 = *reinterpret_cast<const float4*>(&wp[s]);
    acc = fmaf(w4.x, vp[(size_t)(s + 0) * DD], acc);
    acc = fmaf(w4.y, vp[(size_t)(s + 1) * DD], acc);
    acc = fmaf(w4.z, vp[(size_t)(s + 2) * DD], acc);
    acc = fmaf(w4.w, vp[(size_t)(s + 3) * DD], acc);
  }
  const float res = acc * inv;
  const size_t oi = ((size_t)bz * CC + l) * DD + h * EE + lane;
  if constexpr (sizeof(OT) == 4) out[oi] = res;
  else                           out[oi] = f2b(res);
}

// ---------------- pwattn1 via MFMA: one row per wave ----------------
__global__ __launch_bounds__(256) void pwattn1_mfma(
    const ushort* __restrict__ query, const float* __restrict__ k1,
    const float* __restrict__ v1, ushort* __restrict__ V1)
{
  const int tid = threadIdx.x;
  const int wave = tid >> 6, lane = tid & 63;
  const int quad = lane >> 4, l15 = lane & 15;
  const int n = blockIdx.x * 4 + wave;

  __shared__ __align__(16) ushort Pl[4][16][40];   // stride 80B (16B-aligned)

  const ushort* qrow = query + (size_t)n * DFF;
  const float*  krow = k1 + (size_t)n * 512;
  const float*  vrow = v1 + (size_t)n * 512;
  ushort* orow = V1 + (size_t)n * DFF;

  const short8 zz = {0, 0, 0, 0, 0, 0, 0, 0};
  const f32x4 zacc = (f32x4){0.f, 0.f, 0.f, 0.f};

  // B-frags for scores: col s = nt*16+l15, k = e = quad*8+i (valid e<16)
  short8 bh[2], bl[2];
  #pragma unroll
  for (int nt = 0; nt < 2; ++nt) {
    short8 hh = zz, ll = zz;
    if (quad < 2) {
      const float* kp = krow + (nt * 16 + l15) * 16 + quad * 8;
      #pragma unroll
      for (int i = 0; i < 8; ++i) {
        ushort hi_, lo_; split_bf(kp[i], hi_, lo_);
        hh[i] = (short)hi_; ll[i] = (short)lo_;
      }
    }
    bh[nt] = hh; bl[nt] = ll;
  }
  // B-frag for PV: v[k=s=quad*8+i][n=e=l15]
  short8 vb;
  #pragma unroll
  for (int i = 0; i < 8; ++i) vb[i] = (short)f2b(vrow[(quad * 8 + i) * 16 + l15]);

  #pragma unroll
  for (int mt = 0; mt < 8; ++mt) {
    short8 qa = zz;
    if (quad < 2)
      qa = *reinterpret_cast<const short8*>(qrow + (mt * 16 + l15) * 16 + quad * 8);
    f32x4 acc[2];
    #pragma unroll
    for (int nt = 0; nt < 2; ++nt) {
      f32x4 t = __builtin_amdgcn_mfma_f32_16x16x32_bf16(qa, bl[nt], zacc, 0, 0, 0);
      acc[nt] = __builtin_amdgcn_mfma_f32_16x16x32_bf16(qa, bh[nt], t, 0, 0, 0);
    }
    // softmax over 32 cols (2 nt x 16 lanes); rows quad*4+r
    float inv[4];
    #pragma unroll
    for (int r = 0; r < 4; ++r) {
      float m = red16_max(fmaxf(acc[0][r], acc[1][r]));
      const float p0 = __builtin_amdgcn_exp2f((acc[0][r] - m) * (0.25f * LOG2E));
      const float p1 = __builtin_amdgcn_exp2f((acc[1][r] - m) * (0.25f * LOG2E));
      acc[0][r] = p0; acc[1][r] = p1;
      const float s = red16_sum(p0 + p1);
      inv[r] = 1.f / s;
    }
    #pragma unroll
    for (int nt = 0; nt < 2; ++nt)
      #pragma unroll
      for (int r = 0; r < 4; ++r)
        Pl[wave][quad * 4 + r][nt * 16 + l15] = f2b(acc[nt][r]);
    const short8 pa = *reinterpret_cast<const short8*>(&Pl[wave][l15][quad * 8]);
    const f32x4 pv = __builtin_amdgcn_mfma_f32_16x16x32_bf16(pa, vb, zacc, 0, 0, 0);
    #pragma unroll
    for (int r = 0; r < 4; ++r)
      orow[(mt * 16 + quad * 4 + r) * 16 + l15] = f2b(pv[r] * inv[r]);
  }
}

// ---------------- pwattn2 via MFMA: one row per wave ----------------
__global__ __launch_bounds__(256) void pwattn2_mfma(
    const float* __restrict__ query2, const ushort* __restrict__ k2,
    const ushort* __restrict__ v2, ushort* __restrict__ V2)
{
  const int tid = threadIdx.x;
  const int wave = tid >> 6, lane = tid & 63;
  const int quad = lane >> 4, l15 = lane & 15;
  const int n = blockIdx.x * 4 + wave;

  __shared__ __align__(16) ushort Pl[4][16][136];  // stride 272B (16B-aligned)

  const float*  qrow = query2 + (size_t)n * 512;
  const ushort* krow = k2 + (size_t)n * DFF;
  const ushort* vrow = v2 + (size_t)n * DFF;
  ushort* orow = V2 + (size_t)n * 512;

  const short8 zz = {0, 0, 0, 0, 0, 0, 0, 0};
  const f32x4 zacc = (f32x4){0.f, 0.f, 0.f, 0.f};

  // B-frags for scores: col s = nt*16+l15 (8 nt), k = e = quad*8+i (<16)
  short8 kb[8];
  #pragma unroll
  for (int nt = 0; nt < 8; ++nt)
    kb[nt] = (quad < 2)
        ? *reinterpret_cast<const short8*>(krow + (nt * 16 + l15) * 16 + quad * 8)
        : zz;

  // B-frags for PV: v[k=s=kt*32+quad*8+i][n=e=l15]
  short8 vb[4];
  #pragma unroll
  for (int kt = 0; kt < 4; ++kt)
    #pragma unroll
    for (int i = 0; i < 8; ++i)
      vb[kt][i] = (short)vrow[(kt * 32 + quad * 8 + i) * 16 + l15];

  #pragma unroll
  for (int mt = 0; mt < 2; ++mt) {
    // A hi/lo: q[m=mt*16+l15][k=quad*8+i (<16)]
    short8 ahh = zz, all_ = zz;
    if (quad < 2) {
      const float* qp = qrow + (mt * 16 + l15) * 16 + quad * 8;
      #pragma unroll
      for (int i = 0; i < 8; ++i) {
        ushort hi_, lo_; split_bf(qp[i], hi_, lo_);
        ahh[i] = (short)hi_; all_[i] = (short)lo_;
      }
    }
    f32x4 acc[8];
    #pragma unroll
    for (int nt = 0; nt < 8; ++nt) {
      f32x4 t = __builtin_amdgcn_mfma_f32_16x16x32_bf16(all_, kb[nt], zacc, 0, 0, 0);
      acc[nt] = __builtin_amdgcn_mfma_f32_16x16x32_bf16(ahh, kb[nt], t, 0, 0, 0);
    }
    // softmax over 128 cols (8 nt x 16 lanes); rows quad*4+r
    float inv[4];
    #pragma unroll
    for (int r = 0; r < 4; ++r) {
      float m = acc[0][r];
      #pragma unroll
      for (int nt = 1; nt < 8; ++nt) m = fmaxf(m, acc[nt][r]);
      m = red16_max(m);
      float s = 0.f;
      #pragma unroll
      for (int nt = 0; nt < 8; ++nt) {
        const float p = __builtin_amdgcn_exp2f((acc[nt][r] - m) * (0.25f * LOG2E));
        acc[nt][r] = p; s += p;
      }
      s = red16_sum(s);
      inv[r] = 1.f / s;
    }
    #pragma unroll
    for (int nt = 0; nt < 8; ++nt)
      #pragma unroll
      for (int r = 0; r < 4; ++r)
        Pl[wave][quad * 4 + r][nt * 16 + l15] = f2b(acc[nt][r]);
    f32x4 pv = zacc;
    #pragma unroll
    for (int kt = 0; kt < 4; ++kt) {
      const short8 pa = *reinterpret_cast<const short8*>(&Pl[wave][l15][kt * 32 + quad * 8]);
      pv = __builtin_amdgcn_mfma_f32_16x16x32_bf16(pa, vb[kt], pv, 0, 0, 0);
    }
    #pragma unroll
    for (int r = 0; r < 4; ++r)
      orow[(mt * 16 + quad * 4 + r) * 16 + l15] = f2b(pv[r] * inv[r]);
  }
}

// ---------------- pwattn1 (fallback) ----------------
__global__ __launch_bounds__(128) void pwattn1_kernel(
    const ushort* __restrict__ query, const float* __restrict__ k1,
    const float* __restrict__ v1, ushort* __restrict__ V1)
{
  const int n = blockIdx.x, tid = threadIdx.x;
  __shared__ float ks[512], vs[512];
  __shared__ float Am[128][33];
  for (int i = tid; i < 512; i += 128) { ks[i] = k1[(size_t)n * 512 + i]; vs[i] = v1[(size_t)n * 512 + i]; }
  __syncthreads();
  {
    const int l = tid;
    float qv[16];
    const ushort* qp = query + (size_t)n * DFF + l * 16;
    #pragma unroll
    for (int e = 0; e < 16; ++e) qv[e] = b2f(qp[e]);
    float scl[32], mx = -FLT_MAX;
    #pragma unroll
    for (int s = 0; s < 32; ++s) {
      float a = 0.f;
      #pragma unroll
      for (int e = 0; e < 16; ++e) a += qv[e] * ks[s * 16 + e];
      scl[s] = a; mx = fmaxf(mx, a);
    }
    float sum = 0.f;
    #pragma unroll
    for (int s = 0; s < 32; ++s) { const float p = expf((scl[s] - mx) * 0.25f); scl[s] = p; sum += p; }
    const float invs = 1.f / sum;
    #pragma unroll
    for (int s = 0; s < 32; ++s) Am[l][s] = scl[s] * invs;
  }
  __syncthreads();
  #pragma unroll
  for (int r = 0; r < 16; ++r) {
    const int idx = tid + 128 * r;
    const int l = idx >> 4, e = idx & 15;
    float a = 0.f;
    #pragma unroll
    for (int s = 0; s < 32; ++s) a += Am[l][s] * vs[s * 16 + e];
    V1[(size_t)n * DFF + idx] = f2b(a);
  }
}

// ---------------- LayerNorm over 2048, in-place bf16 ----------------
__global__ __launch_bounds__(256) void ln_kernel(
    ushort* __restrict__ h, const void* __restrict__ g, const void* __restrict__ bt,
    const int* __restrict__ dtf)
{
  const int f32 = *dtf;
  const int n = blockIdx.x, tid = threadIdx.x;
  ushort* hp = h + (size_t)n * DFF;
  float x[8]; float s = 0.f, s2 = 0.f;
  #pragma unroll
  for (int i = 0; i < 8; ++i) {
    const float xv = b2f(hp[tid + 256 * i]);
    x[i] = xv; s += xv; s2 += xv * xv;
  }
  __shared__ float rs[256], rq[256];
  rs[tid] = s; rq[tid] = s2;
  __syncthreads();
  for (int off = 128; off > 0; off >>= 1) {
    if (tid < off) { rs[tid] += rs[tid + off]; rq[tid] += rq[tid + off]; }
    __syncthreads();
  }
  const float mu  = rs[0] * (1.f / DFF);
  const float var = rq[0] * (1.f / DFF) - mu * mu;
  const float inv = rsqrtf(var + 1e-5f);
  #pragma unroll
  for (int i = 0; i < 8; ++i) {
    const int d = tid + 256 * i;
    hp[d] = f2b((x[i] - mu) * inv * lin(g, d, f32) + lin(bt, d, f32));
  }
}

// ---------------- pwattn2 (fallback), templated output -----------
template<typename OT>
__global__ __launch_bounds__(128) void pwattn2_kernel(
    const float* __restrict__ query2, const ushort* __restrict__ k2,
    const ushort* __restrict__ v2, OT* __restrict__ V2)
{
  const int n = blockIdx.x, tid = threadIdx.x;
  __shared__ float ks[2048], vs[2048];
  __shared__ float Am[32][129];
  for (int i = tid; i < 2048; i += 128) {
    ks[i] = b2f(k2[(size_t)n * DFF + i]);
    vs[i] = b2f(v2[(size_t)n * DFF + i]);
  }
  __syncthreads();
  if (tid < 32) {
    const int l = tid;
    float qv[16];
    #pragma unroll
    for (int e = 0; e < 16; ++e) qv[e] = query2[(size_t)n * 512 + l * 16 + e];
    float mx = -FLT_MAX;
    for (int s = 0; s < 128; ++s) {
      float a = 0.f;
      #pragma unroll
      for (int e = 0; e < 16; ++e) a += qv[e] * ks[s * 16 + e];
      Am[l][s] = a; mx = fmaxf(mx, a);
    }
    float sum = 0.f;
    for (int s = 0; s < 128; ++s) { const float p = expf((Am[l][s] - mx) * 0.25f); Am[l][s] = p; sum += p; }
    const float invs = 1.f / sum;
    for (int s = 0; s < 128; ++s) Am[l][s] *= invs;
  }
  __syncthreads();
  #pragma unroll
  for (int r = 0; r < 4; ++r) {
    const int idx = tid + 128 * r;
    const int l = idx >> 4, e = idx & 15;
    float a = 0.f;
    for (int s = 0; s < 128; ++s) a += Am[l][s] * vs[s * 16 + e];
    if constexpr (sizeof(OT) == 4) V2[(size_t)n * 512 + idx] = a;
    else                           V2[(size_t)n * 512 + idx] = f2b(a);
  }
}

// ---------------- final: dec = y@fc_w + fc_b; out = dec*std+mean -----------
__global__ __launch_bounds__(256) void final_kernel(
    const float* __restrict__ y, const void* __restrict__ fc_w,
    const void* __restrict__ fc_b, const float* __restrict__ meanb,
    const float* __restrict__ stdb, void* __restrict__ out, int row_base,
    const int* __restrict__ dtf)
{
  const int f32 = *dtf;
  const int tid = threadIdx.x;
  const int rloc = tid >> 5;           // 0..7 (row within block)
  const int t32 = tid & 31;            // 0..31
  __shared__ __align__(16) float yr[8][512];
  const int blk_row0 = blockIdx.x * 8;
  #pragma unroll
  for (int i = 0; i < 4; ++i) {
    const int idx = tid + i * 256;     // 1024 float4 slots total
    const int rr = idx >> 7, dd = (idx & 127) * 4;
    *reinterpret_cast<float4*>(&yr[rr][dd]) =
        *reinterpret_cast<const float4*>(y + (size_t)(blk_row0 + rr) * 512 + dd);
  }
  __syncthreads();
  if (t32 < 24) {
    const int n0 = t32 * 4;
    float a0 = 0.f, a1 = 0.f, a2 = 0.f, a3 = 0.f;
    if (f32) {
      const float* W = (const float*)fc_w + n0;
      for (int d = 0; d < 512; ++d) {
        const float4 w4 = *reinterpret_cast<const float4*>(W + (size_t)d * PRED);
        const float yv = yr[rloc][d];
        a0 = fmaf(yv, w4.x, a0); a1 = fmaf(yv, w4.y, a1);
        a2 = fmaf(yv, w4.z, a2); a3 = fmaf(yv, w4.w, a3);
      }
    } else {
      const ushort* W = (const ushort*)fc_w + n0;
      for (int d = 0; d < 512; ++d) {
        const ushort4 w4 = *reinterpret_cast<const ushort4*>(W + (size_t)d * PRED);
        const float yv = yr[rloc][d];
        a0 = fmaf(yv, b2f(w4.x), a0); a1 = fmaf(yv, b2f(w4.y), a1);
        a2 = fmaf(yv, b2f(w4.z), a2); a3 = fmaf(yv, b2f(w4.w), a3);
      }
    }
    const int row = row_base + blk_row0 + rloc;
    const int b = row >> 9, c = row & 511;
    const float sd = stdb[row], mu = meanb[row];
    const float av[4] = {a0, a1, a2, a3};
    #pragma unroll
    for (int j = 0; j < 4; ++j) {
      const float r = (av[j] + lin(fc_b, n0 + j, f32)) * sd + mu;
      const size_t oi = ((size_t)b * PRED + n0 + j) * CC + c;
      if (f32) ((float*)out)[oi] = r;
      else     ((ushort*)out)[oi] = f2b(r);
    }
  }
}

// ---------------------------------------------------------------------------
extern "C" void kernel_launch(void* const* d_in, const int* in_sizes, int n_in,
                              void* d_out, int out_size, void* d_ws, size_t ws_size,
                              hipStream_t stream)
{
  (void)in_sizes; (void)n_in; (void)out_size;
  const void* x_enc   = d_in[0];
  const void* embed_w = d_in[4];
  const void* q_w = d_in[5],  * q_b = d_in[6];
  const void* k_w = d_in[7],  * k_b = d_in[8];
  const void* v_w = d_in[9],  * v_b = d_in[10];
  const void* o_w = d_in[11], * o_b = d_in[12];
  const void* enc_w = d_in[13], * enc_b = d_in[14];
  const void* f1q_w = d_in[15], * f1q_b = d_in[16];
  const void* f1k_w = d_in[17], * f1k_b = d_in[18];
  const void* f1v_w = d_in[19], * f1v_b = d_in[20];
  const void* f1o_w = d_in[21], * f1o_b = d_in[22];
  const void* f2q_w = d_in[23], * f2q_b = d_in[24];
  const void* f2k_w = d_in[25], * f2k_b = d_in[26];
  const void* f2v_w = d_in[27], * f2v_b = d_in[28];
  const void* f2o_w = d_in[29], * f2o_b = d_in[30];
  const void* ln_g  = d_in[31], * ln_b  = d_in[32];
  const void* fc_w  = d_in[33], * fc_b  = d_in[34];

  const size_t HDR = 131072 + 1024;
  const size_t E_F1Q = 512ull * 2048, E_F1O = 2048ull * 2048, E_F2Q = 2048ull * 512;
  const size_t E_F2K = 2048ull * 2048, E_F2V = 2048ull * 2048, E_F2O = 512ull * 512;
  const size_t E_SQ  = 512ull * 512;   // o_w, enc_w, f1k_w, f1v_w each
  // + 8 split arrays (embed/q/k/v hi+lo)
  const size_t WT_EL = E_F1Q + E_F1O + E_F2Q + E_F2K + E_F2V + E_F2O + 4 * E_SQ + 8 * E_SQ;
  const size_t WT_BYTES = WT_EL * 2;   // ~34.5 MB
  const size_t PB_MFMA = 4ull * 512 * 512 * 4 + 3ull * 512 * DFF * 2; // 10.0MB
  const size_t PB_FB   = 5ull * 512 * 512 * 4 + 3ull * 512 * DFF * 2; // 11.0MB

  const int use_mfma = (HDR + WT_BYTES + PB_MFMA <= ws_size) ? 1 : 0;
  const size_t PER_BATCH = use_mfma ? PB_MFMA : PB_FB;
  const size_t FIXED = HDR + (use_mfma ? WT_BYTES : 0);
  int BPC = 1;
  for (int c = 8; c >= 1; c >>= 1) {
    if (FIXED + (size_t)c * PER_BATCH <= ws_size) { BPC = c; break; }
  }
  const int R = BPC * 512;

  char* ws = (char*)d_ws;
  float* meanb = (float*)ws;
  float* stdb  = (float*)(ws + 65536);
  int*   dtf   = (int*)(ws + 131072);
  ushort* wt_base = (ushort*)(ws + HDR);
  ushort* wt_f1q = wt_base;
  ushort* wt_f1o = wt_f1q + E_F1Q;
  ushort* wt_f2q = wt_f1o + E_F1O;
  ushort* wt_f2k = wt_f2q + E_F2Q;
  ushort* wt_f2v = wt_f2k + E_F2K;
  ushort* wt_f2o = wt_f2v + E_F2V;
  ushort* wt_o   = wt_f2o + E_F2O;
  ushort* wt_enc = wt_o   + E_SQ;
  ushort* wt_f1k = wt_enc + E_SQ;
  ushort* wt_f1v = wt_f1k + E_SQ;
  ushort* wt_embh = wt_f1v + E_SQ;
  ushort* wt_embl = wt_embh + E_SQ;
  ushort* wt_qh   = wt_embl + E_SQ;
  ushort* wt_ql   = wt_qh   + E_SQ;
  ushort* wt_kh   = wt_ql   + E_SQ;
  ushort* wt_kl   = wt_kh   + E_SQ;
  ushort* wt_vh   = wt_kl   + E_SQ;
  ushort* wt_vl   = wt_vh   + E_SQ;

  char* arena = ws + FIXED;
  const size_t FSL = (size_t)R * 512 * 4;
  const size_t GSL = (size_t)R * DFF * 2;
  void* A_ = arena;
  void* B_ = arena + FSL;
  void* C_ = arena + 2 * FSL;
  void* D_ = arena + 3 * FSL;
  void* E_ = arena + 4 * FSL;                     // fallback path only
  char* gb = arena + (size_t)(use_mfma ? 4 : 5) * FSL;
  void* G1 = gb;
  void* G2 = gb + GSL;
  void* G3 = gb + 2 * GSL;

  // mfma-path split buffers
  ushort* xTh  = (ushort*)G1; ushort* xTl  = xTh  + (size_t)R * 512; // in G1 (dead before f1q)
  ushort* embh = (ushort*)G2; ushort* embl = embh + (size_t)R * 512; // in G2 (dead before pwattn1)
  ushort* qsh  = (ushort*)C_; ushort* qsl  = qsh  + (size_t)R * 512;
  ushort* ksh  = (ushort*)D_; ushort* ksl  = ksh  + (size_t)R * 512;
  ushort* vt   = (ushort*)B_;                                        // vT, dead before f1v

  detect_dtype<<<1, 256, 0, stream>>>((const ushort*)x_enc, dtf);
  // two-phase instance-norm stats; partials live in the (still idle) arena
  instnorm_partial<<<dim3(2, NB, 8), 256, 0, stream>>>(
      x_enc, (float*)A_, (float*)B_, dtf);
  instnorm_reduce<<<dim3(2, NB), 256, 0, stream>>>(
      (const float*)A_, (const float*)B_, meanb, stdb);

  if (use_mfma) {   // one-time weight convert+transpose (KxN -> bf16 NxK)
    transpose_w<<<dim3(DFF / 32, 512 / 32), 256, 0, stream>>>(f1q_w, wt_f1q, 512, DFF, dtf);
    transpose_w<<<dim3(DFF / 32, DFF / 32), 256, 0, stream>>>(f1o_w, wt_f1o, DFF, DFF, dtf);
    transpose_w<<<dim3(512 / 32, DFF / 32), 256, 0, stream>>>(f2q_w, wt_f2q, DFF, 512, dtf);
    transpose_w<<<dim3(DFF / 32, DFF / 32), 256, 0, stream>>>(f2k_w, wt_f2k, DFF, DFF, dtf);
    transpose_w<<<dim3(DFF / 32, DFF / 32), 256, 0, stream>>>(f2v_w, wt_f2v, DFF, DFF, dtf);
    transpose_w<<<dim3(512 / 32, 512 / 32), 256, 0, stream>>>(f2o_w, wt_f2o, 512, 512, dtf);
    transpose_w<<<dim3(512 / 32, 512 / 32), 256, 0, stream>>>(o_w,   wt_o,   512, 512, dtf);
    transpose_w<<<dim3(512 / 32, 512 / 32), 256, 0, stream>>>(enc_w, wt_enc, 512, 512, dtf);
    transpose_w<<<dim3(512 / 32, 512 / 32), 256, 0, stream>>>(f1k_w, wt_f1k, 512, 512, dtf);
    transpose_w<<<dim3(512 / 32, 512 / 32), 256, 0, stream>>>(f1v_w, wt_f1v, 512, 512, dtf);
    transpose_w_split<<<dim3(512 / 32, 512 / 32), 256, 0, stream>>>(embed_w, wt_embh, wt_embl, 512, 512, dtf);
    transpose_w_split<<<dim3(512 / 32, 512 / 32), 256, 0, stream>>>(q_w, wt_qh, wt_ql, 512, 512, dtf);
    transpose_w_split<<<dim3(512 / 32, 512 / 32), 256, 0, stream>>>(k_w, wt_kh, wt_kl, 512, 512, dtf);
    transpose_w_split<<<dim3(512 / 32, 512 / 32), 256, 0, stream>>>(v_w, wt_vh, wt_vl, 512, 512, dtf);
  }

  for (int bc = 0; bc < NB / BPC; ++bc) {
    const int b0 = bc * BPC;
    if (use_mfma) {
      // --- stage 1: split-MFMA GEMMs ---
      norm_transpose_split<<<dim3(16, 16, BPC), 256, 0, stream>>>(
          x_enc, meanb, stdb, xTh, xTl, b0, dtf);
      launch_mgemm3<E3_RELU_PE>(xTh, xTl, wt_embh, wt_embl, nullptr,
                                embh, embl, R, 512, 512, dtf, stream);         // emb hi/lo
      mgemm3_qkv_kernel<<<dim3(512 / 64, R / 64, 3), 256, 0, stream>>>(
          embh, embl,
          wt_qh, wt_ql, q_b, wt_kh, wt_kl, k_b, wt_vh, wt_vl, v_b,
          qsh, qsl, ksh, ksl, vt, R, 512, 512, dtf);                           // q,k,v fused
      gattn_mfma<<<dim3(CC / 16, HH, BPC), 256, 0, stream>>>(
          qsh, qsl, ksh, ksl, vt, (ushort*)A_);                                // attn bf16
      launch_mgemm64<ushort, ushort, M_ADD2_BIAS_LEAKY>(
          A_, wt_o, o_b, embh, C_, R, 512, 512, dtf, stream, embl);            // y bf16
      launch_mgemm64<float, ushort, M_BIAS>(C_, wt_enc, enc_b, nullptr, D_, R, 512, 512, dtf, stream);  // X1 bf16
      // --- stage 2: pwattn1 + LN ---
      launch_mgemm<float, ushort, M_BIAS_RELU>(D_, wt_f1q, f1q_b, nullptr, G1, R, 512, DFF, dtf, stream); // query1
      mgemm64_dual_kernel<float><<<dim3(512 / 64, R / 64, 2), 256, 0, stream>>>(
          (const ushort*)D_, wt_f1k, wt_f1v, f1k_b, f1v_b,
          (float*)A_, (float*)B_, 0, 1, R, 512, 512, dtf);                     // k1,v1 fused
      pwattn1_mfma<<<R / 4, 256, 0, stream>>>(
          (const ushort*)G1, (const float*)A_, (const float*)B_, (ushort*)G2);
      launch_mgemm<ushort, ushort, M_ADD_BIAS_ELU>(G2, wt_f1o, f1o_b, G1, G1, R, DFF, DFF, dtf, stream);  // h
      ln_kernel<<<R, 256, 0, stream>>>((ushort*)G1, ln_g, ln_b, dtf);
      // --- stage 3: pwattn2 + out ---
      launch_mgemm64<float, float, M_BIAS_RELU>(G1, wt_f2q, f2q_b, nullptr, A_, R, DFF, 512, dtf, stream); // query2
      mgemm_dual_kernel<ushort><<<dim3(DFF / 128, R / 128, 2), 256, 0, stream>>>(
          (const ushort*)G1, wt_f2k, wt_f2v, f2k_b, f2v_b,
          (ushort*)G2, (ushort*)G3, 0, 1, R, DFF, DFF, dtf);                   // k2,v2 fused
      pwattn2_mfma<<<R / 4, 256, 0, stream>>>(
          (const float*)A_, (const ushort*)G2, (const ushort*)G3, (ushort*)B_);
      launch_mgemm64<float, float, M_ADD_BIAS>(B_, wt_f2o, f2o_b, A_, C_, R, 512, 512, dtf, stream);      // y2
    } else {
      norm_transpose<<<dim3(16, 16, BPC), 256, 0, stream>>>(x_enc, meanb, stdb, (float*)A_, b0, dtf);
      launch_gemm<float, float, float, M_RELU_PE >(A_, embed_w, nullptr, nullptr, B_, R, 512, 512, dtf, stream);
      launch_gemm<float, float, float, M_BIAS_RELU>(B_, q_w, q_b, nullptr, C_, R, 512, 512, dtf, stream);
      launch_gemm<float, float, float, M_BIAS     >(B_, k_w, k_b, nullptr, D_, R, 512, 512, dtf, stream);
      launch_gemm<float, float, float, M_BIAS_RELU>(B_, v_w, v_b, nullptr, E_, R, 512, 512, dtf, stream);
      gattn_fb<float><<<dim3(CC / 4, HH, BPC), 256, 0, stream>>>(
          (float*)C_, (float*)D_, (float*)E_, (float*)A_);
      launch_gemm<float, float, float, M_ADD_BIAS_LEAKY>(A_, o_w, o_b, B_, C_, R, 512, 512, dtf, stream);
      launch_gemm<float, float, float, M_BIAS>(C_, enc_w, enc_b, nullptr, D_, R, 512, 512, dtf, stream);
      launch_gemm<float, float, ushort, M_BIAS_RELU>(D_, f1q_w, f1q_b, nullptr, G1, R, 512, DFF, dtf, stream);
      launch_gemm<float, float, float,  M_BIAS     >(D_, f1k_w, f1k_b, nullptr, A_, R, 512, 512, dtf, stream);
      launch_gemm<float, float, float,  M_BIAS_RELU>(D_, f1v_w, f1v_b, nullptr, B_, R, 512, 512, dtf, stream);
      pwattn1_kernel<<<R, 128, 0, stream>>>((const ushort*)G1, (const float*)A_, (const float*)B_, (ushort*)G2);
      launch_gemm<ushort, ushort, ushort, M_ADD_BIAS_ELU>(G2, f1o_w, f1o_b, G1, G1, R, DFF, DFF, dtf, stream);
      ln_kernel<<<R, 256, 0, stream>>>((ushort*)G1, ln_g, ln_b, dtf);
      launch_gemm<ushort, float, float,  M_BIAS_RELU>(G1, f2q_w, f2q_b, nullptr, A_, R, DFF, 512, dtf, stream);
      launch_gemm<ushort, float, ushort, M_BIAS     >(G1, f2k_w, f2k_b, nullptr, G2, R, DFF, DFF, dtf, stream);
      launch_gemm<ushort, float, ushort, M_BIAS_RELU>(G1, f2v_w, f2v_b, nullptr, G3, R, DFF, DFF, dtf, stream);
      pwattn2_kernel<float><<<R, 128, 0, stream>>>((const float*)A_, (const ushort*)G2, (const ushort*)G3, (float*)B_);
      launch_gemm<float, float, float, M_ADD_BIAS>(B_, f2o_w, f2o_b, A_, C_, R, 512, 512, dtf, stream);
    }
    final_kernel<<<R / 8, 256, 0, stream>>>((const float*)C_, fc_w, fc_b, meanb, stdb, d_out, b0 * 512, dtf);
  }
}